// Round 2
// baseline (305.317 us; speedup 1.0000x reference)
//
#include <hip/hip_runtime.h>
#include <hip/hip_bf16.h>

typedef unsigned short u16;
typedef __attribute__((ext_vector_type(8))) __bf16 bf16x8;
typedef __attribute__((ext_vector_type(4))) float f32x4;

__device__ inline u16 f2bf(float f) {
  unsigned int x = __float_as_uint(f);
  unsigned int r = (x + 0x7FFFu + ((x >> 16) & 1u)) >> 16;
  return (u16)r;
}
__device__ inline float bf2f(u16 u) { return __uint_as_float(((unsigned int)u) << 16); }
__device__ inline void split2(float v, u16& h, u16& l) {
  h = f2bf(v);
  l = f2bf(v - bf2f(h));
}

// ---------------- x transpose: [B,C,N] f32 -> [B,N,C] f32 ----------------
__global__ __launch_bounds__(256) void transpose_x(const float* __restrict__ x,
                                                   float* __restrict__ Xt) {
  __shared__ float tile[32][33];
  int n0 = blockIdx.x * 32;
  int c0 = blockIdx.y * 32;
  int b  = blockIdx.z;
  int tx = threadIdx.x, ty = threadIdx.y;
#pragma unroll
  for (int j = 0; j < 4; ++j) {
    int c = c0 + ty + j * 8;
    tile[ty + j * 8][tx] = x[((size_t)b * 256 + c) * 1024 + n0 + tx];
  }
  __syncthreads();
#pragma unroll
  for (int j = 0; j < 4; ++j) {
    int n = n0 + ty + j * 8;
    Xt[((size_t)b * 1024 + n) * 256 + c0 + tx] = tile[tx][ty + j * 8];
  }
}

// ---------------- weight prep ----------------
__global__ __launch_bounds__(256) void prep_weights(
    const float* __restrict__ Wq, const float* __restrict__ Wk, const float* __restrict__ Wv,
    const float* __restrict__ bq, const float* __restrict__ bk, const float* __restrict__ bv,
    const float* __restrict__ W1, const float* __restrict__ W2,
    u16* __restrict__ WallH, u16* __restrict__ WallL,
    u16* __restrict__ W1b, u16* __restrict__ W2b,
    float* __restrict__ bqkv) {
  int i = blockIdx.x * 256 + threadIdx.x;
  float w = 0.f;
  bool hw = true;
  if (i < 65536) w = Wq[i];
  else if (i < 131072) w = Wk[i - 65536];
  else if (i < 196608) w = Wv[i - 131072];
  else hw = false;
  if (hw) {
    u16 h, l;
    split2(w, h, l);
    WallH[i] = h; WallL[i] = l;
  }
  if (i < 262144) { W1b[i] = f2bf(W1[i]); W2b[i] = f2bf(W2[i]); }
  if (i < 256) bqkv[i] = bq[i];
  else if (i < 512) bqkv[i] = bk[i - 256];
  else if (i < 768) bqkv[i] = bv[i - 512];
}

#define GBM 128
#define GBN 128
#define GBK 32
#define GKP 40

// ---------------- QKV GEMM: Xt[f32, M x K] * Wall[hi/lo bf16, N x K]^T -> f32 + bias
__global__ __launch_bounds__(256) void gemm_qkv(
    const float* __restrict__ A, int lda,
    const u16* __restrict__ Bh_, const u16* __restrict__ Bl_, int ldb,
    const float* __restrict__ bias,
    float* __restrict__ Cout, int ldc, int K) {
  __shared__ u16 Ah[GBM * GKP], Al[GBM * GKP];
  __shared__ u16 Bh[GBN * GKP], Bl[GBN * GKP];
  const int tid = threadIdx.x;
  const int lane = tid & 63, wid = tid >> 6;
  const int wr = wid >> 1, wc = wid & 1;
  const int m0 = blockIdx.y * GBM, n0 = blockIdx.x * GBN;

  f32x4 acc[4][4] = {};
  for (int kt = 0; kt < K; kt += GBK) {
    __syncthreads();
#pragma unroll
    for (int i = 0; i < 4; ++i) {
      int idx = tid + i * 256;
      int r = idx >> 3, c4 = (idx & 7) * 4;
      float4 v = *reinterpret_cast<const float4*>(A + (size_t)(m0 + r) * lda + kt + c4);
      u16 h, l;
      split2(v.x, h, l); Ah[r * GKP + c4 + 0] = h; Al[r * GKP + c4 + 0] = l;
      split2(v.y, h, l); Ah[r * GKP + c4 + 1] = h; Al[r * GKP + c4 + 1] = l;
      split2(v.z, h, l); Ah[r * GKP + c4 + 2] = h; Al[r * GKP + c4 + 2] = l;
      split2(v.w, h, l); Ah[r * GKP + c4 + 3] = h; Al[r * GKP + c4 + 3] = l;
    }
#pragma unroll
    for (int i = 0; i < 2; ++i) {
      int idx = tid + i * 256;
      int r = idx >> 2, cv = (idx & 3) * 8;
      uint4 vh = *reinterpret_cast<const uint4*>(Bh_ + (size_t)(n0 + r) * ldb + kt + cv);
      *reinterpret_cast<uint4*>(&Bh[r * GKP + cv]) = vh;
      uint4 vl = *reinterpret_cast<const uint4*>(Bl_ + (size_t)(n0 + r) * ldb + kt + cv);
      *reinterpret_cast<uint4*>(&Bl[r * GKP + cv]) = vl;
    }
    __syncthreads();
    bf16x8 afh[4], afl[4], bfh[4], bfl[4];
#pragma unroll
    for (int m = 0; m < 4; ++m) {
      int o = (wr * 64 + m * 16 + (lane & 15)) * GKP + (lane >> 4) * 8;
      afh[m] = *reinterpret_cast<const bf16x8*>(&Ah[o]);
      afl[m] = *reinterpret_cast<const bf16x8*>(&Al[o]);
    }
#pragma unroll
    for (int n = 0; n < 4; ++n) {
      int o = (wc * 64 + n * 16 + (lane & 15)) * GKP + (lane >> 4) * 8;
      bfh[n] = *reinterpret_cast<const bf16x8*>(&Bh[o]);
      bfl[n] = *reinterpret_cast<const bf16x8*>(&Bl[o]);
    }
#pragma unroll
    for (int m = 0; m < 4; ++m)
#pragma unroll
      for (int n = 0; n < 4; ++n) {
        acc[m][n] = __builtin_amdgcn_mfma_f32_16x16x32_bf16(afh[m], bfh[n], acc[m][n], 0, 0, 0);
        acc[m][n] = __builtin_amdgcn_mfma_f32_16x16x32_bf16(afh[m], bfl[n], acc[m][n], 0, 0, 0);
        acc[m][n] = __builtin_amdgcn_mfma_f32_16x16x32_bf16(afl[m], bfh[n], acc[m][n], 0, 0, 0);
      }
  }
#pragma unroll
  for (int m = 0; m < 4; ++m) {
    int row_b = m0 + wr * 64 + m * 16 + (lane >> 4) * 4;
#pragma unroll
    for (int n = 0; n < 4; ++n) {
      int col = n0 + wc * 64 + n * 16 + (lane & 15);
      float bb = bias[col];
#pragma unroll
      for (int r = 0; r < 4; ++r)
        Cout[(size_t)(row_b + r) * ldc + col] = acc[m][n][r] + bb;
    }
  }
}

// ---------------- FFN GEMM: A[f32, M x K] (split in-kernel) * Bw[bf16, N x K]^T
// EPI 1: out f32 = prelu(acc + bias[col], a)
// EPI 2: out f32 = acc + bias[col] + resid[row,col]
template <int EPI>
__global__ __launch_bounds__(256) void gemm_aft(
    const float* __restrict__ A, int lda,
    const u16* __restrict__ Bw, int ldb,
    const float* __restrict__ bias,
    const float* __restrict__ aslope,
    const float* __restrict__ resid,
    float* __restrict__ Cout, int ldc, int K) {
  __shared__ u16 Ah[GBM * GKP], Al[GBM * GKP];
  __shared__ u16 Bs[GBN * GKP];
  const int tid = threadIdx.x;
  const int lane = tid & 63, wid = tid >> 6;
  const int wr = wid >> 1, wc = wid & 1;
  const int m0 = blockIdx.y * GBM, n0 = blockIdx.x * GBN;

  f32x4 acc[4][4] = {};
  for (int kt = 0; kt < K; kt += GBK) {
    __syncthreads();
#pragma unroll
    for (int i = 0; i < 4; ++i) {
      int idx = tid + i * 256;
      int r = idx >> 3, c4 = (idx & 7) * 4;
      float4 v = *reinterpret_cast<const float4*>(A + (size_t)(m0 + r) * lda + kt + c4);
      u16 h, l;
      split2(v.x, h, l); Ah[r * GKP + c4 + 0] = h; Al[r * GKP + c4 + 0] = l;
      split2(v.y, h, l); Ah[r * GKP + c4 + 1] = h; Al[r * GKP + c4 + 1] = l;
      split2(v.z, h, l); Ah[r * GKP + c4 + 2] = h; Al[r * GKP + c4 + 2] = l;
      split2(v.w, h, l); Ah[r * GKP + c4 + 3] = h; Al[r * GKP + c4 + 3] = l;
    }
#pragma unroll
    for (int i = 0; i < 2; ++i) {
      int idx = tid + i * 256;
      int r = idx >> 2, cv = (idx & 3) * 8;
      uint4 vb = *reinterpret_cast<const uint4*>(Bw + (size_t)(n0 + r) * ldb + kt + cv);
      *reinterpret_cast<uint4*>(&Bs[r * GKP + cv]) = vb;
    }
    __syncthreads();
    bf16x8 afh[4], afl[4], bfr[4];
#pragma unroll
    for (int m = 0; m < 4; ++m) {
      int o = (wr * 64 + m * 16 + (lane & 15)) * GKP + (lane >> 4) * 8;
      afh[m] = *reinterpret_cast<const bf16x8*>(&Ah[o]);
      afl[m] = *reinterpret_cast<const bf16x8*>(&Al[o]);
    }
#pragma unroll
    for (int n = 0; n < 4; ++n)
      bfr[n] = *reinterpret_cast<const bf16x8*>(&Bs[(wc * 64 + n * 16 + (lane & 15)) * GKP + (lane >> 4) * 8]);
#pragma unroll
    for (int m = 0; m < 4; ++m)
#pragma unroll
      for (int n = 0; n < 4; ++n) {
        acc[m][n] = __builtin_amdgcn_mfma_f32_16x16x32_bf16(afh[m], bfr[n], acc[m][n], 0, 0, 0);
        acc[m][n] = __builtin_amdgcn_mfma_f32_16x16x32_bf16(afl[m], bfr[n], acc[m][n], 0, 0, 0);
      }
  }
  float a = (EPI == 1) ? aslope[0] : 0.f;
#pragma unroll
  for (int m = 0; m < 4; ++m) {
    int row_b = m0 + wr * 64 + m * 16 + (lane >> 4) * 4;
#pragma unroll
    for (int n = 0; n < 4; ++n) {
      int col = n0 + wc * 64 + n * 16 + (lane & 15);
      float bb = bias[col];
#pragma unroll
      for (int r = 0; r < 4; ++r) {
        int row = row_b + r;
        float v = acc[m][n][r] + bb;
        if (EPI == 1) v = (v >= 0.f) ? v : a * v;
        if (EPI == 2) v += resid[(size_t)row * ldc + col];
        Cout[(size_t)row * ldc + col] = v;
      }
    }
  }
}

// ---------------- fused flash attention per (qtile, head, batch) ----------------
// QKVf: [T=16384, 768] f32 (q | k | v). Writes Sout = O + Xt (f32 [T,256]).
#define AP 72
__global__ __launch_bounds__(256) void attn_kernel(const float* __restrict__ QKVf,
                                                   const float* __restrict__ Xt,
                                                   float* __restrict__ Sout) {
  __shared__ u16 Qh[64 * AP], Ql[64 * AP], Kh[64 * AP], Kl[64 * AP];
  __shared__ u16 Vs[64 * AP], Ph[64 * AP], Pl[64 * AP];
  const int tid = threadIdx.x, lane = tid & 63, w = tid >> 6;
  const int qt = blockIdx.x, h = blockIdx.y, b = blockIdx.z;
  const size_t base = (size_t)b * 1024 * 768;
  const int q0 = qt * 64;

#pragma unroll
  for (int i = 0; i < 4; ++i) {
    int s = tid + i * 256;
    int r = s >> 4, c4 = (s & 15) * 4;
    float4 v = *reinterpret_cast<const float4*>(QKVf + base + (size_t)(q0 + r) * 768 + h * 64 + c4);
    u16 hh, ll;
    split2(v.x, hh, ll); Qh[r * AP + c4 + 0] = hh; Ql[r * AP + c4 + 0] = ll;
    split2(v.y, hh, ll); Qh[r * AP + c4 + 1] = hh; Ql[r * AP + c4 + 1] = ll;
    split2(v.z, hh, ll); Qh[r * AP + c4 + 2] = hh; Ql[r * AP + c4 + 2] = ll;
    split2(v.w, hh, ll); Qh[r * AP + c4 + 3] = hh; Ql[r * AP + c4 + 3] = ll;
  }

  float m_prev[4], lsum[4];
  f32x4 oacc[4] = {};
#pragma unroll
  for (int r = 0; r < 4; ++r) { m_prev[r] = -1e30f; lsum[r] = 0.f; }

  for (int kt = 0; kt < 16; ++kt) {
    __syncthreads();
    int kb = kt * 64;
#pragma unroll
    for (int i = 0; i < 4; ++i) {
      int s = tid + i * 256;
      int r = s >> 4, c4 = (s & 15) * 4;
      float4 kv = *reinterpret_cast<const float4*>(QKVf + base + (size_t)(kb + r) * 768 + 256 + h * 64 + c4);
      u16 hh, ll;
      split2(kv.x, hh, ll); Kh[r * AP + c4 + 0] = hh; Kl[r * AP + c4 + 0] = ll;
      split2(kv.y, hh, ll); Kh[r * AP + c4 + 1] = hh; Kl[r * AP + c4 + 1] = ll;
      split2(kv.z, hh, ll); Kh[r * AP + c4 + 2] = hh; Kl[r * AP + c4 + 2] = ll;
      split2(kv.w, hh, ll); Kh[r * AP + c4 + 3] = hh; Kl[r * AP + c4 + 3] = ll;
      float4 vv = *reinterpret_cast<const float4*>(QKVf + base + (size_t)(kb + r) * 768 + 512 + h * 64 + c4);
      Vs[(c4 + 0) * AP + r] = f2bf(vv.x);
      Vs[(c4 + 1) * AP + r] = f2bf(vv.y);
      Vs[(c4 + 2) * AP + r] = f2bf(vv.z);
      Vs[(c4 + 3) * AP + r] = f2bf(vv.w);
    }
    __syncthreads();

    f32x4 sc[4] = {};
#pragma unroll
    for (int kk = 0; kk < 2; ++kk) {
      int qo = (w * 16 + (lane & 15)) * AP + kk * 32 + (lane >> 4) * 8;
      bf16x8 aqh = *reinterpret_cast<const bf16x8*>(&Qh[qo]);
      bf16x8 aql = *reinterpret_cast<const bf16x8*>(&Ql[qo]);
#pragma unroll
      for (int n = 0; n < 4; ++n) {
        int ko = (n * 16 + (lane & 15)) * AP + kk * 32 + (lane >> 4) * 8;
        bf16x8 bkh = *reinterpret_cast<const bf16x8*>(&Kh[ko]);
        bf16x8 bkl = *reinterpret_cast<const bf16x8*>(&Kl[ko]);
        sc[n] = __builtin_amdgcn_mfma_f32_16x16x32_bf16(aqh, bkh, sc[n], 0, 0, 0);
        sc[n] = __builtin_amdgcn_mfma_f32_16x16x32_bf16(aqh, bkl, sc[n], 0, 0, 0);
        sc[n] = __builtin_amdgcn_mfma_f32_16x16x32_bf16(aql, bkh, sc[n], 0, 0, 0);
      }
    }
    // online softmax (rows owned by this wave; reduce across 16 col-lanes)
    float scl[4];
#pragma unroll
    for (int r = 0; r < 4; ++r) {
      float v = fmaxf(fmaxf(sc[0][r], sc[1][r]), fmaxf(sc[2][r], sc[3][r]));
      v = fmaxf(v, __shfl_xor(v, 1, 64));
      v = fmaxf(v, __shfl_xor(v, 2, 64));
      v = fmaxf(v, __shfl_xor(v, 4, 64));
      v = fmaxf(v, __shfl_xor(v, 8, 64));
      float mn = fmaxf(m_prev[r], v);
      scl[r] = __expf(m_prev[r] - mn);
      m_prev[r] = mn;
    }
    float lt[4] = {0.f, 0.f, 0.f, 0.f};
#pragma unroll
    for (int n = 0; n < 4; ++n)
#pragma unroll
      for (int r = 0; r < 4; ++r) {
        float p = __expf(sc[n][r] - m_prev[r]);
        sc[n][r] = p;
        lt[r] += p;
      }
#pragma unroll
    for (int r = 0; r < 4; ++r) {
      float v = lt[r];
      v += __shfl_xor(v, 1, 64);
      v += __shfl_xor(v, 2, 64);
      v += __shfl_xor(v, 4, 64);
      v += __shfl_xor(v, 8, 64);
      lsum[r] = lsum[r] * scl[r] + v;
#pragma unroll
      for (int dn = 0; dn < 4; ++dn) oacc[dn][r] *= scl[r];
    }
    // P (hi/lo) -> LDS, wave-private rows
#pragma unroll
    for (int n = 0; n < 4; ++n)
#pragma unroll
      for (int r = 0; r < 4; ++r) {
        int po = (w * 16 + (lane >> 4) * 4 + r) * AP + n * 16 + (lane & 15);
        u16 hh, ll;
        split2(sc[n][r], hh, ll);
        Ph[po] = hh; Pl[po] = ll;
      }
    // PV
#pragma unroll
    for (int kk = 0; kk < 2; ++kk) {
      int po = (w * 16 + (lane & 15)) * AP + kk * 32 + (lane >> 4) * 8;
      bf16x8 aph = *reinterpret_cast<const bf16x8*>(&Ph[po]);
      bf16x8 apl = *reinterpret_cast<const bf16x8*>(&Pl[po]);
#pragma unroll
      for (int dn = 0; dn < 4; ++dn) {
        int vo = (dn * 16 + (lane & 15)) * AP + kk * 32 + (lane >> 4) * 8;
        bf16x8 bv = *reinterpret_cast<const bf16x8*>(&Vs[vo]);
        oacc[dn] = __builtin_amdgcn_mfma_f32_16x16x32_bf16(aph, bv, oacc[dn], 0, 0, 0);
        oacc[dn] = __builtin_amdgcn_mfma_f32_16x16x32_bf16(apl, bv, oacc[dn], 0, 0, 0);
      }
    }
  }
  // O / l + residual x
#pragma unroll
  for (int dn = 0; dn < 4; ++dn)
#pragma unroll
    for (int r = 0; r < 4; ++r) {
      int row = q0 + w * 16 + (lane >> 4) * 4 + r;
      int col = h * 64 + dn * 16 + (lane & 15);
      size_t gi = ((size_t)b * 1024 + row) * 256 + col;
      Sout[gi] = oacc[dn][r] / lsum[r] + Xt[gi];
    }
}

// ---------------- BatchNorm pieces ----------------
__global__ __launch_bounds__(256) void bn_stats(const float* __restrict__ S, float* __restrict__ stats) {
  int c = threadIdx.x;
  int t0 = blockIdx.x * 64;
  float sum = 0.f, sq = 0.f;
  for (int i = 0; i < 64; ++i) {
    float v = S[(size_t)(t0 + i) * 256 + c];
    sum += v; sq += v * v;
  }
  atomicAdd(&stats[c], sum);
  atomicAdd(&stats[256 + c], sq);
}

__global__ void bn_finalize(const float* __restrict__ stats, const float* __restrict__ gamma,
                            const float* __restrict__ beta, float* __restrict__ ss) {
  int c = threadIdx.x;
  float mean = stats[c] * (1.f / 16384.f);
  float var = stats[256 + c] * (1.f / 16384.f) - mean * mean;
  float rstd = rsqrtf(var + 1e-5f);
  float scg = gamma[c] * rstd;
  ss[c] = scg;
  ss[256 + c] = beta[c] - mean * scg;
}

__global__ __launch_bounds__(256) void bn_apply(float* __restrict__ S, const float* __restrict__ ss) {
  size_t i = (size_t)blockIdx.x * 256 + threadIdx.x;
  int c = (int)(i & 255);
  S[i] = S[i] * ss[c] + ss[256 + c];
}

// final BN + transpose [T,C] -> [B,C,N]
__global__ __launch_bounds__(256) void bn_final_out(const float* __restrict__ T2,
                                                    const float* __restrict__ ss,
                                                    float* __restrict__ out) {
  __shared__ float tile[32][33];
  int n0 = (blockIdx.x & 31) * 32;
  int b = blockIdx.x >> 5;
  int c0 = blockIdx.y * 32;
  int tx = threadIdx.x, ty = threadIdx.y;
#pragma unroll
  for (int j = 0; j < 4; ++j) {
    int r = ty + j * 8;
    int c = c0 + tx;
    float v = T2[((size_t)b * 1024 + n0 + r) * 256 + c];
    tile[r][tx] = v * ss[c] + ss[256 + c];
  }
  __syncthreads();
#pragma unroll
  for (int j = 0; j < 4; ++j) {
    int c = c0 + ty + j * 8;
    out[((size_t)b * 256 + c) * 1024 + n0 + tx] = tile[tx][ty + j * 8];
  }
}

// ---------------- launch ----------------
extern "C" void kernel_launch(void* const* d_in, const int* in_sizes, int n_in,
                              void* d_out, int out_size, void* d_ws, size_t ws_size,
                              hipStream_t stream) {
  const float* x = (const float*)d_in[0];
  const float* Wq = (const float*)d_in[1];
  const float* bq = (const float*)d_in[2];
  const float* Wk = (const float*)d_in[3];
  const float* bk = (const float*)d_in[4];
  const float* Wv = (const float*)d_in[5];
  const float* bv = (const float*)d_in[6];
  const float* gamma = (const float*)d_in[7];
  const float* beta = (const float*)d_in[8];
  const float* W1 = (const float*)d_in[9];
  const float* b1 = (const float*)d_in[10];
  const float* a = (const float*)d_in[11];
  const float* W2 = (const float*)d_in[12];
  const float* b2 = (const float*)d_in[13];
  float* out = (float*)d_out;

  char* wsb = (char*)d_ws;
  // Region 1 (64MB): QKVf f32 [T,768] (48MB) -> later H1f f32 [T,1024] (64MB)
  float* QKVf = (float*)(wsb);
  float* H1f  = (float*)(wsb);
  // Region 2 (16MB): XtF f32 [T,256] -> later T2 f32 [T,256]
  float* XtF = (float*)(wsb + (64ull << 20));
  float* T2  = XtF;
  // weights + stats
  char* wp = wsb + (80ull << 20);
  u16* WallH = (u16*)(wp);               // 384KB
  u16* WallL = (u16*)(wp + 393216);      // 384KB
  u16* W1b   = (u16*)(wp + 786432);      // 512KB
  u16* W2b   = (u16*)(wp + 1310720);     // 512KB
  float* bqkv = (float*)(wp + 1835008);  // 3KB
  float* stats = (float*)(wp + 1840128); // 8KB
  if (ws_size < (80ull << 20) + 1850000) return;

  float* S = out;  // d_out doubles as o+x / mh f32 buffer [T,256]

  hipMemsetAsync(stats, 0, 8192, stream);
  transpose_x<<<dim3(32, 8, 16), dim3(32, 8), 0, stream>>>(x, XtF);
  prep_weights<<<1024, 256, 0, stream>>>(Wq, Wk, Wv, bq, bk, bv, W1, W2, WallH, WallL, W1b, W2b, bqkv);
  // QKV projection (split x, split W): [16384,256] x [768,256]^T -> [16384,768] f32
  gemm_qkv<<<dim3(6, 128), 256, 0, stream>>>(XtF, 256, WallH, WallL, 256, bqkv, QKVf, 768, 256);
  // attention + residual
  attn_kernel<<<dim3(16, 4, 16), 256, 0, stream>>>(QKVf, XtF, S);
  // BN1 (in-place on S)
  bn_stats<<<256, 256, 0, stream>>>(S, stats);
  bn_finalize<<<1, 256, 0, stream>>>(stats, gamma, beta, stats + 512);
  bn_apply<<<16384, 256, 0, stream>>>(S, stats + 512);
  // FFN1: [16384,256](f32 split) x [1024,256]^T -> [16384,1024] f32, bias+PReLU
  gemm_aft<1><<<dim3(8, 128), 256, 0, stream>>>(S, 256, W1b, 256, b1, a, nullptr, H1f, 1024, 256);
  // FFN2: [16384,1024](f32 split) x [256,1024]^T -> [16384,256] f32, bias+resid(S)
  gemm_aft<2><<<dim3(2, 128), 256, 0, stream>>>(H1f, 1024, W2b, 1024, b2, nullptr, S, T2, 256, 1024);
  // BN2 + transpose out
  bn_stats<<<256, 256, 0, stream>>>(T2, stats + 1024);
  bn_finalize<<<1, 256, 0, stream>>>(stats + 1024, gamma, beta, stats + 1536);
  bn_final_out<<<dim3(512, 8), dim3(32, 8), 0, stream>>>(T2, stats + 1536, out);
}

// Round 3
// 302.511 us; speedup vs baseline: 1.0093x; 1.0093x over previous
//
#include <hip/hip_runtime.h>
#include <hip/hip_bf16.h>

typedef unsigned short u16;
typedef __attribute__((ext_vector_type(8))) __bf16 bf16x8;
typedef __attribute__((ext_vector_type(4))) float f32x4;

__device__ inline u16 f2bf(float f) {
  unsigned int x = __float_as_uint(f);
  unsigned int r = (x + 0x7FFFu + ((x >> 16) & 1u)) >> 16;
  return (u16)r;
}
__device__ inline float bf2f(u16 u) { return __uint_as_float(((unsigned int)u) << 16); }
__device__ inline void split2(float v, u16& h, u16& l) {
  h = f2bf(v);
  l = f2bf(v - bf2f(h));
}

// ---------------- x transpose: [B,C,N] f32 -> [B,N,C] f32 + bf16 hi/lo ----------------
__global__ __launch_bounds__(256) void transpose_x(const float* __restrict__ x,
                                                   float* __restrict__ XtF,
                                                   u16* __restrict__ XtbH,
                                                   u16* __restrict__ XtbL) {
  __shared__ float tile[32][33];
  int n0 = blockIdx.x * 32;
  int c0 = blockIdx.y * 32;
  int b  = blockIdx.z;
  int tx = threadIdx.x, ty = threadIdx.y;
#pragma unroll
  for (int j = 0; j < 4; ++j) {
    int c = c0 + ty + j * 8;
    tile[ty + j * 8][tx] = x[((size_t)b * 256 + c) * 1024 + n0 + tx];
  }
  __syncthreads();
#pragma unroll
  for (int j = 0; j < 4; ++j) {
    int n = n0 + ty + j * 8;
    float v = tile[tx][ty + j * 8];
    size_t o = ((size_t)b * 1024 + n) * 256 + c0 + tx;
    XtF[o] = v;
    u16 h, l;
    split2(v, h, l);
    XtbH[o] = h; XtbL[o] = l;
  }
}

// ---------------- weight prep ----------------
__global__ __launch_bounds__(256) void prep_weights(
    const float* __restrict__ Wq, const float* __restrict__ Wk, const float* __restrict__ Wv,
    const float* __restrict__ bq, const float* __restrict__ bk,
    const float* __restrict__ W1, const float* __restrict__ W2,
    u16* __restrict__ WallH, u16* __restrict__ WallL,
    u16* __restrict__ WvH, u16* __restrict__ WvL,
    u16* __restrict__ W1b, u16* __restrict__ W2b,
    float* __restrict__ bqk) {
  int i = blockIdx.x * 256 + threadIdx.x;
  if (i < 131072) {
    float w = (i < 65536) ? Wq[i] : Wk[i - 65536];
    u16 h, l;
    split2(w, h, l);
    WallH[i] = h; WallL[i] = l;
  }
  if (i < 65536) {
    u16 h, l;
    split2(Wv[i], h, l);
    WvH[i] = h; WvL[i] = l;
  }
  if (i < 262144) { W1b[i] = f2bf(W1[i]); W2b[i] = f2bf(W2[i]); }
  if (i < 256) bqk[i] = bq[i];
  else if (i < 512) bqk[i] = bk[i - 256];
}

#define GKP 40

// ---------------- QK projection GEMM (3-term hi/lo), out split bf16 ----------------
// A = Xtb hi/lo [16384,256], B = Wall hi/lo [512,256], C -> QKh/QKl [16384,512]
__global__ __launch_bounds__(256) void gemm_qk(
    const u16* __restrict__ Ah_, const u16* __restrict__ Al_,
    const u16* __restrict__ Bh_, const u16* __restrict__ Bl_,
    const float* __restrict__ bias,
    u16* __restrict__ Ch, u16* __restrict__ Cl) {
  __shared__ u16 Ah[128 * GKP], Al[128 * GKP], Bh[128 * GKP], Bl[128 * GKP];
  const int tid = threadIdx.x;
  const int lane = tid & 63, wid = tid >> 6;
  const int wr = wid >> 1, wc = wid & 1;
  const int m0 = blockIdx.y * 128, n0 = blockIdx.x * 128;

  f32x4 acc[4][4] = {};
  for (int kt = 0; kt < 256; kt += 32) {
    __syncthreads();
#pragma unroll
    for (int i = 0; i < 2; ++i) {
      int idx = tid + i * 256;
      int r = idx >> 2, cv = (idx & 3) * 8;
      *reinterpret_cast<uint4*>(&Ah[r * GKP + cv]) = *reinterpret_cast<const uint4*>(Ah_ + (size_t)(m0 + r) * 256 + kt + cv);
      *reinterpret_cast<uint4*>(&Al[r * GKP + cv]) = *reinterpret_cast<const uint4*>(Al_ + (size_t)(m0 + r) * 256 + kt + cv);
      *reinterpret_cast<uint4*>(&Bh[r * GKP + cv]) = *reinterpret_cast<const uint4*>(Bh_ + (size_t)(n0 + r) * 256 + kt + cv);
      *reinterpret_cast<uint4*>(&Bl[r * GKP + cv]) = *reinterpret_cast<const uint4*>(Bl_ + (size_t)(n0 + r) * 256 + kt + cv);
    }
    __syncthreads();
    bf16x8 afh[4], afl[4], bfh[4], bfl[4];
#pragma unroll
    for (int m = 0; m < 4; ++m) {
      int o = (wr * 64 + m * 16 + (lane & 15)) * GKP + (lane >> 4) * 8;
      afh[m] = *reinterpret_cast<const bf16x8*>(&Ah[o]);
      afl[m] = *reinterpret_cast<const bf16x8*>(&Al[o]);
    }
#pragma unroll
    for (int n = 0; n < 4; ++n) {
      int o = (wc * 64 + n * 16 + (lane & 15)) * GKP + (lane >> 4) * 8;
      bfh[n] = *reinterpret_cast<const bf16x8*>(&Bh[o]);
      bfl[n] = *reinterpret_cast<const bf16x8*>(&Bl[o]);
    }
#pragma unroll
    for (int m = 0; m < 4; ++m)
#pragma unroll
      for (int n = 0; n < 4; ++n) {
        acc[m][n] = __builtin_amdgcn_mfma_f32_16x16x32_bf16(afh[m], bfh[n], acc[m][n], 0, 0, 0);
        acc[m][n] = __builtin_amdgcn_mfma_f32_16x16x32_bf16(afh[m], bfl[n], acc[m][n], 0, 0, 0);
        acc[m][n] = __builtin_amdgcn_mfma_f32_16x16x32_bf16(afl[m], bfh[n], acc[m][n], 0, 0, 0);
      }
  }
#pragma unroll
  for (int m = 0; m < 4; ++m) {
    int row_b = m0 + wr * 64 + m * 16 + (lane >> 4) * 4;
#pragma unroll
    for (int n = 0; n < 4; ++n) {
      int col = n0 + wc * 64 + n * 16 + (lane & 15);
      float bb = bias[col];
#pragma unroll
      for (int r = 0; r < 4; ++r) {
        size_t o = (size_t)(row_b + r) * 512 + col;
        u16 h, l;
        split2(acc[m][n][r] + bb, h, l);
        Ch[o] = h; Cl[o] = l;
      }
    }
  }
}

// ---------------- V projection, transposed output: Vt[b,d,n] ----------------
// A = WvAll hi/lo [256,256], B = XtbH[b] [1024,256], 2-term.
__global__ __launch_bounds__(256) void gemm_vt(
    const u16* __restrict__ WvH_, const u16* __restrict__ WvL_,
    const u16* __restrict__ XtbH, const float* __restrict__ bv,
    u16* __restrict__ Vt) {
  __shared__ u16 Ah[128 * GKP], Al[128 * GKP], Bh[128 * GKP];
  const int tid = threadIdx.x;
  const int lane = tid & 63, wid = tid >> 6;
  const int wr = wid >> 1, wc = wid & 1;
  const int b = blockIdx.z;
  const int m0 = blockIdx.y * 128, n0 = blockIdx.x * 128;
  const u16* Bp = XtbH + (size_t)b * 1024 * 256;

  f32x4 acc[4][4] = {};
  for (int kt = 0; kt < 256; kt += 32) {
    __syncthreads();
#pragma unroll
    for (int i = 0; i < 2; ++i) {
      int idx = tid + i * 256;
      int r = idx >> 2, cv = (idx & 3) * 8;
      *reinterpret_cast<uint4*>(&Ah[r * GKP + cv]) = *reinterpret_cast<const uint4*>(WvH_ + (size_t)(m0 + r) * 256 + kt + cv);
      *reinterpret_cast<uint4*>(&Al[r * GKP + cv]) = *reinterpret_cast<const uint4*>(WvL_ + (size_t)(m0 + r) * 256 + kt + cv);
      *reinterpret_cast<uint4*>(&Bh[r * GKP + cv]) = *reinterpret_cast<const uint4*>(Bp + (size_t)(n0 + r) * 256 + kt + cv);
    }
    __syncthreads();
    bf16x8 afh[4], afl[4], bfr[4];
#pragma unroll
    for (int m = 0; m < 4; ++m) {
      int o = (wr * 64 + m * 16 + (lane & 15)) * GKP + (lane >> 4) * 8;
      afh[m] = *reinterpret_cast<const bf16x8*>(&Ah[o]);
      afl[m] = *reinterpret_cast<const bf16x8*>(&Al[o]);
    }
#pragma unroll
    for (int n = 0; n < 4; ++n)
      bfr[n] = *reinterpret_cast<const bf16x8*>(&Bh[(wc * 64 + n * 16 + (lane & 15)) * GKP + (lane >> 4) * 8]);
#pragma unroll
    for (int m = 0; m < 4; ++m)
#pragma unroll
      for (int n = 0; n < 4; ++n) {
        acc[m][n] = __builtin_amdgcn_mfma_f32_16x16x32_bf16(afh[m], bfr[n], acc[m][n], 0, 0, 0);
        acc[m][n] = __builtin_amdgcn_mfma_f32_16x16x32_bf16(afl[m], bfr[n], acc[m][n], 0, 0, 0);
      }
  }
#pragma unroll
  for (int m = 0; m < 4; ++m) {
    int row_b = m0 + wr * 64 + m * 16 + (lane >> 4) * 4;  // d index
#pragma unroll
    for (int n = 0; n < 4; ++n) {
      int col = n0 + wc * 64 + n * 16 + (lane & 15);      // token n
#pragma unroll
      for (int r = 0; r < 4; ++r) {
        int row = row_b + r;
        Vt[((size_t)b * 256 + row) * 1024 + col] = f2bf(acc[m][n][r] + bv[row]);
      }
    }
  }
}

// ---------------- FFN GEMM (single bf16, 1-term) ----------------
// EPI 1: out u16 = f2bf(prelu(acc + bias[col], a))
// EPI 2: out f32 = acc + bias[col] + resid[row,col]
template <int EPI>
__global__ __launch_bounds__(256) void gemm_ffn(
    const u16* __restrict__ A_, int lda,
    const u16* __restrict__ B_, int ldb,
    const float* __restrict__ bias,
    const float* __restrict__ aslope,
    const float* __restrict__ resid,
    void* __restrict__ Cout, int ldc, int K) {
  __shared__ u16 As[128 * GKP], Bs[128 * GKP];
  const int tid = threadIdx.x;
  const int lane = tid & 63, wid = tid >> 6;
  const int wr = wid >> 1, wc = wid & 1;
  const int m0 = blockIdx.y * 128, n0 = blockIdx.x * 128;

  f32x4 acc[4][4] = {};
  for (int kt = 0; kt < K; kt += 32) {
    __syncthreads();
#pragma unroll
    for (int i = 0; i < 2; ++i) {
      int idx = tid + i * 256;
      int r = idx >> 2, cv = (idx & 3) * 8;
      *reinterpret_cast<uint4*>(&As[r * GKP + cv]) = *reinterpret_cast<const uint4*>(A_ + (size_t)(m0 + r) * lda + kt + cv);
      *reinterpret_cast<uint4*>(&Bs[r * GKP + cv]) = *reinterpret_cast<const uint4*>(B_ + (size_t)(n0 + r) * ldb + kt + cv);
    }
    __syncthreads();
    bf16x8 af[4], bfr[4];
#pragma unroll
    for (int m = 0; m < 4; ++m)
      af[m] = *reinterpret_cast<const bf16x8*>(&As[(wr * 64 + m * 16 + (lane & 15)) * GKP + (lane >> 4) * 8]);
#pragma unroll
    for (int n = 0; n < 4; ++n)
      bfr[n] = *reinterpret_cast<const bf16x8*>(&Bs[(wc * 64 + n * 16 + (lane & 15)) * GKP + (lane >> 4) * 8]);
#pragma unroll
    for (int m = 0; m < 4; ++m)
#pragma unroll
      for (int n = 0; n < 4; ++n)
        acc[m][n] = __builtin_amdgcn_mfma_f32_16x16x32_bf16(af[m], bfr[n], acc[m][n], 0, 0, 0);
  }
  float a = (EPI == 1) ? aslope[0] : 0.f;
#pragma unroll
  for (int m = 0; m < 4; ++m) {
    int row_b = m0 + wr * 64 + m * 16 + (lane >> 4) * 4;
#pragma unroll
    for (int n = 0; n < 4; ++n) {
      int col = n0 + wc * 64 + n * 16 + (lane & 15);
      float bb = bias[col];
#pragma unroll
      for (int r = 0; r < 4; ++r) {
        int row = row_b + r;
        float v = acc[m][n][r] + bb;
        if (EPI == 1) {
          v = (v >= 0.f) ? v : a * v;
          ((u16*)Cout)[(size_t)row * ldc + col] = f2bf(v);
        } else {
          ((float*)Cout)[(size_t)row * ldc + col] = v + resid[(size_t)row * ldc + col];
        }
      }
    }
  }
}

// ---------------- fused flash attention, 256 q-rows per block ----------------
// QKh/QKl: [T,512] bf16 (q ch 0-255 | k ch 256-511). Vt: [B,256,1024] bf16.
#define AP 72
__global__ __launch_bounds__(256, 2) void attn_kernel(const u16* __restrict__ QKh,
                                                      const u16* __restrict__ QKl,
                                                      const u16* __restrict__ Vt,
                                                      const float* __restrict__ XtF,
                                                      float* __restrict__ Sout) {
  __shared__ u16 Kh[64 * AP], Kl[64 * AP], Vs[64 * AP];
  __shared__ u16 Psh[4 * 16 * AP], Psl[4 * 16 * AP];
  const int tid = threadIdx.x, lane = tid & 63, w = tid >> 6;
  const int qc = blockIdx.x, h = blockIdx.y, b = blockIdx.z;
  const size_t tb = (size_t)b * 1024;
  const int qrow0 = qc * 256 + w * 64;

  // Q fragments in registers (hi/lo)
  bf16x8 qh[4][2], ql[4][2];
#pragma unroll
  for (int m = 0; m < 4; ++m)
#pragma unroll
    for (int kk = 0; kk < 2; ++kk) {
      size_t ro = (tb + qrow0 + m * 16 + (lane & 15)) * 512 + h * 64 + kk * 32 + (lane >> 4) * 8;
      qh[m][kk] = *reinterpret_cast<const bf16x8*>(QKh + ro);
      ql[m][kk] = *reinterpret_cast<const bf16x8*>(QKl + ro);
    }

  f32x4 oacc[4][4] = {};
  float mprev[4][4], lsum[4][4];
#pragma unroll
  for (int m = 0; m < 4; ++m)
#pragma unroll
    for (int r = 0; r < 4; ++r) { mprev[m][r] = -3e38f; lsum[m][r] = 0.f; }

  for (int kt = 0; kt < 16; ++kt) {
    __syncthreads();
    const int kb = kt * 64;
    {
      int r = tid >> 2, c = tid & 3;
      size_t krow = (tb + kb + r) * 512 + 256 + h * 64;
      *reinterpret_cast<uint4*>(&Kh[r * AP + c * 8])       = *reinterpret_cast<const uint4*>(QKh + krow + c * 8);
      *reinterpret_cast<uint4*>(&Kh[r * AP + (c + 4) * 8]) = *reinterpret_cast<const uint4*>(QKh + krow + (c + 4) * 8);
      *reinterpret_cast<uint4*>(&Kl[r * AP + c * 8])       = *reinterpret_cast<const uint4*>(QKl + krow + c * 8);
      *reinterpret_cast<uint4*>(&Kl[r * AP + (c + 4) * 8]) = *reinterpret_cast<const uint4*>(QKl + krow + (c + 4) * 8);
      size_t vrow = ((size_t)b * 256 + h * 64 + r) * 1024 + kb;
      *reinterpret_cast<uint4*>(&Vs[r * AP + c * 8])       = *reinterpret_cast<const uint4*>(Vt + vrow + c * 8);
      *reinterpret_cast<uint4*>(&Vs[r * AP + (c + 4) * 8]) = *reinterpret_cast<const uint4*>(Vt + vrow + (c + 4) * 8);
    }
    __syncthreads();

#pragma unroll
    for (int m = 0; m < 4; ++m) {
      f32x4 sc[4] = {};
#pragma unroll
      for (int kk = 0; kk < 2; ++kk)
#pragma unroll
        for (int n = 0; n < 4; ++n) {
          int ko = (n * 16 + (lane & 15)) * AP + kk * 32 + (lane >> 4) * 8;
          bf16x8 bkh = *reinterpret_cast<const bf16x8*>(&Kh[ko]);
          bf16x8 bkl = *reinterpret_cast<const bf16x8*>(&Kl[ko]);
          sc[n] = __builtin_amdgcn_mfma_f32_16x16x32_bf16(qh[m][kk], bkh, sc[n], 0, 0, 0);
          sc[n] = __builtin_amdgcn_mfma_f32_16x16x32_bf16(qh[m][kk], bkl, sc[n], 0, 0, 0);
          sc[n] = __builtin_amdgcn_mfma_f32_16x16x32_bf16(ql[m][kk], bkh, sc[n], 0, 0, 0);
        }
      // online softmax for this m-tile's 16 rows
      float scl[4];
#pragma unroll
      for (int r = 0; r < 4; ++r) {
        float v = fmaxf(fmaxf(sc[0][r], sc[1][r]), fmaxf(sc[2][r], sc[3][r]));
        v = fmaxf(v, __shfl_xor(v, 1, 64));
        v = fmaxf(v, __shfl_xor(v, 2, 64));
        v = fmaxf(v, __shfl_xor(v, 4, 64));
        v = fmaxf(v, __shfl_xor(v, 8, 64));
        float mn = fmaxf(mprev[m][r], v);
        scl[r] = __expf(mprev[m][r] - mn);
        mprev[m][r] = mn;
      }
      float lt[4] = {0.f, 0.f, 0.f, 0.f};
#pragma unroll
      for (int n = 0; n < 4; ++n)
#pragma unroll
        for (int r = 0; r < 4; ++r) {
          float p = __expf(sc[n][r] - mprev[m][r]);
          sc[n][r] = p;
          lt[r] += p;
        }
#pragma unroll
      for (int r = 0; r < 4; ++r) {
        float v = lt[r];
        v += __shfl_xor(v, 1, 64);
        v += __shfl_xor(v, 2, 64);
        v += __shfl_xor(v, 4, 64);
        v += __shfl_xor(v, 8, 64);
        lsum[m][r] = lsum[m][r] * scl[r] + v;
#pragma unroll
        for (int dn = 0; dn < 4; ++dn) oacc[m][dn][r] *= scl[r];
      }
      // P hi/lo -> wave-private LDS
#pragma unroll
      for (int n = 0; n < 4; ++n)
#pragma unroll
        for (int r = 0; r < 4; ++r) {
          int po = w * 16 * AP + ((lane >> 4) * 4 + r) * AP + n * 16 + (lane & 15);
          u16 hh, ll;
          split2(sc[n][r], hh, ll);
          Psh[po] = hh; Psl[po] = ll;
        }
      // PV for this m-tile
#pragma unroll
      for (int kk = 0; kk < 2; ++kk) {
        int po = w * 16 * AP + (lane & 15) * AP + kk * 32 + (lane >> 4) * 8;
        bf16x8 ph = *reinterpret_cast<const bf16x8*>(&Psh[po]);
        bf16x8 pl = *reinterpret_cast<const bf16x8*>(&Psl[po]);
#pragma unroll
        for (int dn = 0; dn < 4; ++dn) {
          int vo = (dn * 16 + (lane & 15)) * AP + kk * 32 + (lane >> 4) * 8;
          bf16x8 vv = *reinterpret_cast<const bf16x8*>(&Vs[vo]);
          oacc[m][dn] = __builtin_amdgcn_mfma_f32_16x16x32_bf16(ph, vv, oacc[m][dn], 0, 0, 0);
          oacc[m][dn] = __builtin_amdgcn_mfma_f32_16x16x32_bf16(pl, vv, oacc[m][dn], 0, 0, 0);
        }
      }
    }
  }
  // epilogue: O/l + residual x
#pragma unroll
  for (int m = 0; m < 4; ++m)
#pragma unroll
    for (int dn = 0; dn < 4; ++dn)
#pragma unroll
      for (int r = 0; r < 4; ++r) {
        int row = qrow0 + m * 16 + (lane >> 4) * 4 + r;
        int col = h * 64 + dn * 16 + (lane & 15);
        size_t gi = (tb + row) * 256 + col;
        Sout[gi] = oacc[m][dn][r] / lsum[m][r] + XtF[gi];
      }
}

// ---------------- BatchNorm pieces ----------------
__global__ __launch_bounds__(256) void bn_stats(const float* __restrict__ S, float* __restrict__ stats) {
  int c = threadIdx.x;
  int t0 = blockIdx.x * 64;
  float sum = 0.f, sq = 0.f;
  for (int i = 0; i < 64; ++i) {
    float v = S[(size_t)(t0 + i) * 256 + c];
    sum += v; sq += v * v;
  }
  atomicAdd(&stats[c], sum);
  atomicAdd(&stats[256 + c], sq);
}

__global__ void bn_finalize(const float* __restrict__ stats, const float* __restrict__ gamma,
                            const float* __restrict__ beta, float* __restrict__ ss) {
  int c = threadIdx.x;
  float mean = stats[c] * (1.f / 16384.f);
  float var = stats[256 + c] * (1.f / 16384.f) - mean * mean;
  float rstd = rsqrtf(var + 1e-5f);
  float scg = gamma[c] * rstd;
  ss[c] = scg;
  ss[256 + c] = beta[c] - mean * scg;
}

__global__ __launch_bounds__(256) void bn_apply(float* __restrict__ S, u16* __restrict__ mhb,
                                                const float* __restrict__ ss) {
  size_t i = (size_t)blockIdx.x * 256 + threadIdx.x;
  int c = (int)(i & 255);
  float v = S[i] * ss[c] + ss[256 + c];
  S[i] = v;
  mhb[i] = f2bf(v);
}

// final BN + transpose [T,C] -> [B,C,N]
__global__ __launch_bounds__(256) void bn_final_out(const float* __restrict__ T2,
                                                    const float* __restrict__ ss,
                                                    float* __restrict__ out) {
  __shared__ float tile[32][33];
  int n0 = (blockIdx.x & 31) * 32;
  int b = blockIdx.x >> 5;
  int c0 = blockIdx.y * 32;
  int tx = threadIdx.x, ty = threadIdx.y;
#pragma unroll
  for (int j = 0; j < 4; ++j) {
    int r = ty + j * 8;
    int c = c0 + tx;
    float v = T2[((size_t)b * 1024 + n0 + r) * 256 + c];
    tile[r][tx] = v * ss[c] + ss[256 + c];
  }
  __syncthreads();
#pragma unroll
  for (int j = 0; j < 4; ++j) {
    int c = c0 + ty + j * 8;
    out[((size_t)b * 256 + c) * 1024 + n0 + tx] = tile[tx][ty + j * 8];
  }
}

// ---------------- launch ----------------
extern "C" void kernel_launch(void* const* d_in, const int* in_sizes, int n_in,
                              void* d_out, int out_size, void* d_ws, size_t ws_size,
                              hipStream_t stream) {
  const float* x = (const float*)d_in[0];
  const float* Wq = (const float*)d_in[1];
  const float* bq = (const float*)d_in[2];
  const float* Wk = (const float*)d_in[3];
  const float* bk = (const float*)d_in[4];
  const float* Wv = (const float*)d_in[5];
  const float* bv = (const float*)d_in[6];
  const float* gamma = (const float*)d_in[7];
  const float* beta = (const float*)d_in[8];
  const float* W1 = (const float*)d_in[9];
  const float* b1 = (const float*)d_in[10];
  const float* a = (const float*)d_in[11];
  const float* W2 = (const float*)d_in[12];
  const float* b2 = (const float*)d_in[13];
  float* out = (float*)d_out;

  char* wsb = (char*)d_ws;
  const size_t MB = 1ull << 20;
  u16* XtbH = (u16*)(wsb + 0 * MB);       // 8MB; aliased by mhB after attn
  u16* XtbL = (u16*)(wsb + 8 * MB);       // 8MB
  float* XtF = (float*)(wsb + 16 * MB);   // 16MB; aliased by T2 after attn
  u16* QKh = (u16*)(wsb + 32 * MB);       // 16MB; aliased by H1B (32MB) after attn
  u16* QKl = (u16*)(wsb + 48 * MB);       // 16MB
  u16* Vt = (u16*)(wsb + 64 * MB);        // 8MB
  char* wp = wsb + 72 * MB;
  u16* WallH = (u16*)(wp);                // 256KB
  u16* WallL = (u16*)(wp + 262144);       // 256KB
  u16* WvH = (u16*)(wp + 524288);         // 128KB
  u16* WvL = (u16*)(wp + 655360);         // 128KB
  u16* W1b = (u16*)(wp + 786432);         // 512KB
  u16* W2b = (u16*)(wp + 1310720);        // 512KB
  float* bqk = (float*)(wp + 1835008);    // 2KB
  float* stats = (float*)(wp + 1837056);  // 8KB
  if (ws_size < 75 * MB) return;

  u16* mhB = XtbH;   // [T,256] bf16, after attn
  float* T2 = XtF;   // [T,256] f32, after attn
  u16* H1B = QKh;    // [T,1024] bf16, after attn
  float* S = out;    // d_out doubles as o+x / mh f32 buffer [T,256]

  hipMemsetAsync(stats, 0, 8192, stream);
  transpose_x<<<dim3(32, 8, 16), dim3(32, 8), 0, stream>>>(x, XtF, XtbH, XtbL);
  prep_weights<<<1024, 256, 0, stream>>>(Wq, Wk, Wv, bq, bk, W1, W2,
                                         WallH, WallL, WvH, WvL, W1b, W2b, bqk);
  // QK projection: [16384,256] x [512,256]^T -> QKh/QKl [16384,512]
  gemm_qk<<<dim3(4, 128), 256, 0, stream>>>(XtbH, XtbL, WallH, WallL, bqk, QKh, QKl);
  // V projection transposed: per batch [256,256] x [1024,256]^T -> Vt[b,256,1024]
  gemm_vt<<<dim3(8, 2, 16), 256, 0, stream>>>(WvH, WvL, XtbH, bv, Vt);
  // attention + residual
  attn_kernel<<<dim3(4, 4, 16), 256, 0, stream>>>(QKh, QKl, Vt, XtF, S);
  // BN1 (in-place on S, emits bf16 mh)
  bn_stats<<<256, 256, 0, stream>>>(S, stats);
  bn_finalize<<<1, 256, 0, stream>>>(stats, gamma, beta, stats + 512);
  bn_apply<<<16384, 256, 0, stream>>>(S, mhB, stats + 512);
  // FFN1: [16384,256] x [1024,256]^T -> H1B bf16, bias+PReLU
  gemm_ffn<1><<<dim3(8, 128), 256, 0, stream>>>(mhB, 256, W1b, 256, b1, a, nullptr, H1B, 1024, 256);
  // FFN2: [16384,1024] x [256,1024]^T -> T2 f32, bias + resid(S)
  gemm_ffn<2><<<dim3(2, 128), 256, 0, stream>>>(H1B, 1024, W2b, 1024, b2, nullptr, S, T2, 256, 1024);
  // BN2 + transpose out
  bn_stats<<<256, 256, 0, stream>>>(T2, stats + 1024);
  bn_finalize<<<1, 256, 0, stream>>>(stats + 1024, gamma, beta, stats + 1536);
  bn_final_out<<<dim3(512, 8), dim3(32, 8), 0, stream>>>(T2, stats + 1536, out);
}

// Round 4
// 219.552 us; speedup vs baseline: 1.3906x; 1.3779x over previous
//
#include <hip/hip_runtime.h>
#include <hip/hip_bf16.h>

typedef unsigned short u16;
typedef __attribute__((ext_vector_type(8))) __bf16 bf16x8;
typedef __attribute__((ext_vector_type(4))) float f32x4;

__device__ inline u16 f2bf(float f) {
  unsigned int x = __float_as_uint(f);
  unsigned int r = (x + 0x7FFFu + ((x >> 16) & 1u)) >> 16;
  return (u16)r;
}
__device__ inline float bf2f(u16 u) { return __uint_as_float(((unsigned int)u) << 16); }
__device__ inline void split2(float v, u16& h, u16& l) {
  h = f2bf(v);
  l = f2bf(v - bf2f(h));
}

// ---------------- x transpose: [B,C,N] f32 -> [B,N,C] f32 + bf16 hi/lo ----------------
__global__ __launch_bounds__(256) void transpose_x(const float* __restrict__ x,
                                                   float* __restrict__ XtF,
                                                   u16* __restrict__ XtbH,
                                                   u16* __restrict__ XtbL) {
  __shared__ float tile[32][33];
  int n0 = blockIdx.x * 32;
  int c0 = blockIdx.y * 32;
  int b  = blockIdx.z;
  int tx = threadIdx.x, ty = threadIdx.y;
#pragma unroll
  for (int j = 0; j < 4; ++j) {
    int c = c0 + ty + j * 8;
    tile[ty + j * 8][tx] = x[((size_t)b * 256 + c) * 1024 + n0 + tx];
  }
  __syncthreads();
#pragma unroll
  for (int j = 0; j < 4; ++j) {
    int n = n0 + ty + j * 8;
    float v = tile[tx][ty + j * 8];
    size_t o = ((size_t)b * 1024 + n) * 256 + c0 + tx;
    XtF[o] = v;
    u16 h, l;
    split2(v, h, l);
    XtbH[o] = h; XtbL[o] = l;
  }
}

// ---------------- weight prep ----------------
__global__ __launch_bounds__(256) void prep_weights(
    const float* __restrict__ Wq, const float* __restrict__ Wk, const float* __restrict__ Wv,
    const float* __restrict__ bq, const float* __restrict__ bk,
    const float* __restrict__ W1, const float* __restrict__ W2,
    u16* __restrict__ WallH, u16* __restrict__ WallL,
    u16* __restrict__ WvH, u16* __restrict__ WvL,
    u16* __restrict__ W1b, u16* __restrict__ W2b,
    float* __restrict__ bqk) {
  int i = blockIdx.x * 256 + threadIdx.x;
  if (i < 131072) {
    float w = (i < 65536) ? Wq[i] : Wk[i - 65536];
    u16 h, l;
    split2(w, h, l);
    WallH[i] = h; WallL[i] = l;
  }
  if (i < 65536) {
    u16 h, l;
    split2(Wv[i], h, l);
    WvH[i] = h; WvL[i] = l;
  }
  if (i < 262144) { W1b[i] = f2bf(W1[i]); W2b[i] = f2bf(W2[i]); }
  if (i < 256) bqk[i] = bq[i];
  else if (i < 512) bqk[i] = bk[i - 256];
}

#define GKP 40

// ---------------- QK projection GEMM (3-term hi/lo), out split bf16 ----------------
__global__ __launch_bounds__(256) void gemm_qk(
    const u16* __restrict__ Ah_, const u16* __restrict__ Al_,
    const u16* __restrict__ Bh_, const u16* __restrict__ Bl_,
    const float* __restrict__ bias,
    u16* __restrict__ Ch, u16* __restrict__ Cl) {
  __shared__ u16 Ah[128 * GKP], Al[128 * GKP], Bh[128 * GKP], Bl[128 * GKP];
  const int tid = threadIdx.x;
  const int lane = tid & 63, wid = tid >> 6;
  const int wr = wid >> 1, wc = wid & 1;
  const int m0 = blockIdx.y * 128, n0 = blockIdx.x * 128;

  f32x4 acc[4][4] = {};
  for (int kt = 0; kt < 256; kt += 32) {
    __syncthreads();
#pragma unroll
    for (int i = 0; i < 2; ++i) {
      int idx = tid + i * 256;
      int r = idx >> 2, cv = (idx & 3) * 8;
      *reinterpret_cast<uint4*>(&Ah[r * GKP + cv]) = *reinterpret_cast<const uint4*>(Ah_ + (size_t)(m0 + r) * 256 + kt + cv);
      *reinterpret_cast<uint4*>(&Al[r * GKP + cv]) = *reinterpret_cast<const uint4*>(Al_ + (size_t)(m0 + r) * 256 + kt + cv);
      *reinterpret_cast<uint4*>(&Bh[r * GKP + cv]) = *reinterpret_cast<const uint4*>(Bh_ + (size_t)(n0 + r) * 256 + kt + cv);
      *reinterpret_cast<uint4*>(&Bl[r * GKP + cv]) = *reinterpret_cast<const uint4*>(Bl_ + (size_t)(n0 + r) * 256 + kt + cv);
    }
    __syncthreads();
    bf16x8 afh[4], afl[4], bfh[4], bfl[4];
#pragma unroll
    for (int m = 0; m < 4; ++m) {
      int o = (wr * 64 + m * 16 + (lane & 15)) * GKP + (lane >> 4) * 8;
      afh[m] = *reinterpret_cast<const bf16x8*>(&Ah[o]);
      afl[m] = *reinterpret_cast<const bf16x8*>(&Al[o]);
    }
#pragma unroll
    for (int n = 0; n < 4; ++n) {
      int o = (wc * 64 + n * 16 + (lane & 15)) * GKP + (lane >> 4) * 8;
      bfh[n] = *reinterpret_cast<const bf16x8*>(&Bh[o]);
      bfl[n] = *reinterpret_cast<const bf16x8*>(&Bl[o]);
    }
#pragma unroll
    for (int m = 0; m < 4; ++m)
#pragma unroll
      for (int n = 0; n < 4; ++n) {
        acc[m][n] = __builtin_amdgcn_mfma_f32_16x16x32_bf16(afh[m], bfh[n], acc[m][n], 0, 0, 0);
        acc[m][n] = __builtin_amdgcn_mfma_f32_16x16x32_bf16(afh[m], bfl[n], acc[m][n], 0, 0, 0);
        acc[m][n] = __builtin_amdgcn_mfma_f32_16x16x32_bf16(afl[m], bfh[n], acc[m][n], 0, 0, 0);
      }
  }
#pragma unroll
  for (int m = 0; m < 4; ++m) {
    int row_b = m0 + wr * 64 + m * 16 + (lane >> 4) * 4;
#pragma unroll
    for (int n = 0; n < 4; ++n) {
      int col = n0 + wc * 64 + n * 16 + (lane & 15);
      float bb = bias[col];
#pragma unroll
      for (int r = 0; r < 4; ++r) {
        size_t o = (size_t)(row_b + r) * 512 + col;
        u16 h, l;
        split2(acc[m][n][r] + bb, h, l);
        Ch[o] = h; Cl[o] = l;
      }
    }
  }
}

// ---------------- V projection, transposed output: Vt[b,d,n] ----------------
__global__ __launch_bounds__(256) void gemm_vt(
    const u16* __restrict__ WvH_, const u16* __restrict__ WvL_,
    const u16* __restrict__ XtbH, const float* __restrict__ bv,
    u16* __restrict__ Vt) {
  __shared__ u16 Ah[128 * GKP], Al[128 * GKP], Bh[128 * GKP];
  const int tid = threadIdx.x;
  const int lane = tid & 63, wid = tid >> 6;
  const int wr = wid >> 1, wc = wid & 1;
  const int b = blockIdx.z;
  const int m0 = blockIdx.y * 128, n0 = blockIdx.x * 128;
  const u16* Bp = XtbH + (size_t)b * 1024 * 256;

  f32x4 acc[4][4] = {};
  for (int kt = 0; kt < 256; kt += 32) {
    __syncthreads();
#pragma unroll
    for (int i = 0; i < 2; ++i) {
      int idx = tid + i * 256;
      int r = idx >> 2, cv = (idx & 3) * 8;
      *reinterpret_cast<uint4*>(&Ah[r * GKP + cv]) = *reinterpret_cast<const uint4*>(WvH_ + (size_t)(m0 + r) * 256 + kt + cv);
      *reinterpret_cast<uint4*>(&Al[r * GKP + cv]) = *reinterpret_cast<const uint4*>(WvL_ + (size_t)(m0 + r) * 256 + kt + cv);
      *reinterpret_cast<uint4*>(&Bh[r * GKP + cv]) = *reinterpret_cast<const uint4*>(Bp + (size_t)(n0 + r) * 256 + kt + cv);
    }
    __syncthreads();
    bf16x8 afh[4], afl[4], bfr[4];
#pragma unroll
    for (int m = 0; m < 4; ++m) {
      int o = (wr * 64 + m * 16 + (lane & 15)) * GKP + (lane >> 4) * 8;
      afh[m] = *reinterpret_cast<const bf16x8*>(&Ah[o]);
      afl[m] = *reinterpret_cast<const bf16x8*>(&Al[o]);
    }
#pragma unroll
    for (int n = 0; n < 4; ++n)
      bfr[n] = *reinterpret_cast<const bf16x8*>(&Bh[(wc * 64 + n * 16 + (lane & 15)) * GKP + (lane >> 4) * 8]);
#pragma unroll
    for (int m = 0; m < 4; ++m)
#pragma unroll
      for (int n = 0; n < 4; ++n) {
        acc[m][n] = __builtin_amdgcn_mfma_f32_16x16x32_bf16(afh[m], bfr[n], acc[m][n], 0, 0, 0);
        acc[m][n] = __builtin_amdgcn_mfma_f32_16x16x32_bf16(afl[m], bfr[n], acc[m][n], 0, 0, 0);
      }
  }
#pragma unroll
  for (int m = 0; m < 4; ++m) {
    int row_b = m0 + wr * 64 + m * 16 + (lane >> 4) * 4;  // d index
#pragma unroll
    for (int n = 0; n < 4; ++n) {
      int col = n0 + wc * 64 + n * 16 + (lane & 15);      // token n
#pragma unroll
      for (int r = 0; r < 4; ++r) {
        int row = row_b + r;
        Vt[((size_t)b * 256 + row) * 1024 + col] = f2bf(acc[m][n][r] + bv[row]);
      }
    }
  }
}

// ---------------- FFN GEMM (single bf16, 1-term) ----------------
template <int EPI>
__global__ __launch_bounds__(256) void gemm_ffn(
    const u16* __restrict__ A_, int lda,
    const u16* __restrict__ B_, int ldb,
    const float* __restrict__ bias,
    const float* __restrict__ aslope,
    const float* __restrict__ resid,
    void* __restrict__ Cout, int ldc, int K) {
  __shared__ u16 As[128 * GKP], Bs[128 * GKP];
  const int tid = threadIdx.x;
  const int lane = tid & 63, wid = tid >> 6;
  const int wr = wid >> 1, wc = wid & 1;
  const int m0 = blockIdx.y * 128, n0 = blockIdx.x * 128;

  f32x4 acc[4][4] = {};
  for (int kt = 0; kt < K; kt += 32) {
    __syncthreads();
#pragma unroll
    for (int i = 0; i < 2; ++i) {
      int idx = tid + i * 256;
      int r = idx >> 2, cv = (idx & 3) * 8;
      *reinterpret_cast<uint4*>(&As[r * GKP + cv]) = *reinterpret_cast<const uint4*>(A_ + (size_t)(m0 + r) * lda + kt + cv);
      *reinterpret_cast<uint4*>(&Bs[r * GKP + cv]) = *reinterpret_cast<const uint4*>(B_ + (size_t)(n0 + r) * ldb + kt + cv);
    }
    __syncthreads();
    bf16x8 af[4], bfr[4];
#pragma unroll
    for (int m = 0; m < 4; ++m)
      af[m] = *reinterpret_cast<const bf16x8*>(&As[(wr * 64 + m * 16 + (lane & 15)) * GKP + (lane >> 4) * 8]);
#pragma unroll
    for (int n = 0; n < 4; ++n)
      bfr[n] = *reinterpret_cast<const bf16x8*>(&Bs[(wc * 64 + n * 16 + (lane & 15)) * GKP + (lane >> 4) * 8]);
#pragma unroll
    for (int m = 0; m < 4; ++m)
#pragma unroll
      for (int n = 0; n < 4; ++n)
        acc[m][n] = __builtin_amdgcn_mfma_f32_16x16x32_bf16(af[m], bfr[n], acc[m][n], 0, 0, 0);
  }
  float a = (EPI == 1) ? aslope[0] : 0.f;
#pragma unroll
  for (int m = 0; m < 4; ++m) {
    int row_b = m0 + wr * 64 + m * 16 + (lane >> 4) * 4;
#pragma unroll
    for (int n = 0; n < 4; ++n) {
      int col = n0 + wc * 64 + n * 16 + (lane & 15);
      float bb = bias[col];
#pragma unroll
      for (int r = 0; r < 4; ++r) {
        int row = row_b + r;
        float v = acc[m][n][r] + bb;
        if (EPI == 1) {
          v = (v >= 0.f) ? v : a * v;
          ((u16*)Cout)[(size_t)row * ldc + col] = f2bf(v);
        } else {
          ((float*)Cout)[(size_t)row * ldc + col] = v + resid[(size_t)row * ldc + col];
        }
      }
    }
  }
}

// ---------------- fused flash attention: 8 waves, 128 q-rows/block ----------------
// QKh/QKl: [T,512] bf16 (q ch 0-255 | k ch 256-511). Vt: [B,256,1024] bf16.
#define AP 72
__global__ __launch_bounds__(512, 4) void attn_kernel(const u16* __restrict__ QKh,
                                                      const u16* __restrict__ QKl,
                                                      const u16* __restrict__ Vt,
                                                      const float* __restrict__ XtF,
                                                      float* __restrict__ Sout) {
  __shared__ u16 Kh[64 * AP], Kl[64 * AP], Vs[64 * AP];
  __shared__ u16 Ps[8 * 16 * AP];
  const int tid = threadIdx.x, lane = tid & 63, w = tid >> 6;
  const int h = blockIdx.y, b = blockIdx.z;
  const size_t tb = (size_t)b * 1024;
  const int qrow0 = blockIdx.x * 128 + w * 16;  // this wave's 16 q-rows

  // Q fragments in registers (hi/lo), one 16-row m-tile per wave
  bf16x8 qh[2], ql[2];
#pragma unroll
  for (int kk = 0; kk < 2; ++kk) {
    size_t ro = (tb + qrow0 + (lane & 15)) * 512 + h * 64 + kk * 32 + (lane >> 4) * 8;
    qh[kk] = *reinterpret_cast<const bf16x8*>(QKh + ro);
    ql[kk] = *reinterpret_cast<const bf16x8*>(QKl + ro);
  }

  f32x4 oacc[4] = {};
  float mprev[4], lsum[4];
#pragma unroll
  for (int r = 0; r < 4; ++r) { mprev[r] = -3e38f; lsum[r] = 0.f; }

  const int sr = tid >> 3, sc8 = (tid & 7) * 8;  // staging: row 0..63, col-oct
  for (int kt = 0; kt < 16; ++kt) {
    __syncthreads();
    const int kb = kt * 64;
    {
      size_t krow = (tb + kb + sr) * 512 + 256 + h * 64 + sc8;
      *reinterpret_cast<uint4*>(&Kh[sr * AP + sc8]) = *reinterpret_cast<const uint4*>(QKh + krow);
      *reinterpret_cast<uint4*>(&Kl[sr * AP + sc8]) = *reinterpret_cast<const uint4*>(QKl + krow);
      size_t vrow = ((size_t)b * 256 + h * 64 + sr) * 1024 + kb + sc8;
      *reinterpret_cast<uint4*>(&Vs[sr * AP + sc8]) = *reinterpret_cast<const uint4*>(Vt + vrow);
    }
    __syncthreads();

    f32x4 sc[4] = {};
#pragma unroll
    for (int kk = 0; kk < 2; ++kk)
#pragma unroll
      for (int n = 0; n < 4; ++n) {
        int ko = (n * 16 + (lane & 15)) * AP + kk * 32 + (lane >> 4) * 8;
        bf16x8 bkh = *reinterpret_cast<const bf16x8*>(&Kh[ko]);
        bf16x8 bkl = *reinterpret_cast<const bf16x8*>(&Kl[ko]);
        sc[n] = __builtin_amdgcn_mfma_f32_16x16x32_bf16(qh[kk], bkh, sc[n], 0, 0, 0);
        sc[n] = __builtin_amdgcn_mfma_f32_16x16x32_bf16(qh[kk], bkl, sc[n], 0, 0, 0);
        sc[n] = __builtin_amdgcn_mfma_f32_16x16x32_bf16(ql[kk], bkh, sc[n], 0, 0, 0);
      }
    // per-row max across the 16 col-lanes
    float vmax[4];
#pragma unroll
    for (int r = 0; r < 4; ++r) {
      float v = fmaxf(fmaxf(sc[0][r], sc[1][r]), fmaxf(sc[2][r], sc[3][r]));
      v = fmaxf(v, __shfl_xor(v, 1, 64));
      v = fmaxf(v, __shfl_xor(v, 2, 64));
      v = fmaxf(v, __shfl_xor(v, 4, 64));
      v = fmaxf(v, __shfl_xor(v, 8, 64));
      vmax[r] = v;
    }
    // defer-max: skip rescale when all rows' max grew by <= 8
    bool ok = (vmax[0] <= mprev[0] + 8.f) && (vmax[1] <= mprev[1] + 8.f) &&
              (vmax[2] <= mprev[2] + 8.f) && (vmax[3] <= mprev[3] + 8.f);
    if (!__all(ok)) {
#pragma unroll
      for (int r = 0; r < 4; ++r) {
        float mn = fmaxf(mprev[r], vmax[r]);
        float scl = __expf(mprev[r] - mn);
        mprev[r] = mn;
        lsum[r] *= scl;
#pragma unroll
        for (int dn = 0; dn < 4; ++dn) oacc[dn][r] *= scl;
      }
    }
    float lt[4] = {0.f, 0.f, 0.f, 0.f};
#pragma unroll
    for (int n = 0; n < 4; ++n)
#pragma unroll
      for (int r = 0; r < 4; ++r) {
        float p = __expf(sc[n][r] - mprev[r]);
        sc[n][r] = p;
        lt[r] += p;
      }
#pragma unroll
    for (int r = 0; r < 4; ++r) {
      float v = lt[r];
      v += __shfl_xor(v, 1, 64);
      v += __shfl_xor(v, 2, 64);
      v += __shfl_xor(v, 4, 64);
      v += __shfl_xor(v, 8, 64);
      lsum[r] += v;
    }
    // P -> wave-private LDS (single bf16)
#pragma unroll
    for (int n = 0; n < 4; ++n)
#pragma unroll
      for (int r = 0; r < 4; ++r) {
        int po = w * 16 * AP + ((lane >> 4) * 4 + r) * AP + n * 16 + (lane & 15);
        Ps[po] = f2bf(sc[n][r]);
      }
    // PV
#pragma unroll
    for (int kk = 0; kk < 2; ++kk) {
      int po = w * 16 * AP + (lane & 15) * AP + kk * 32 + (lane >> 4) * 8;
      bf16x8 ph = *reinterpret_cast<const bf16x8*>(&Ps[po]);
#pragma unroll
      for (int dn = 0; dn < 4; ++dn) {
        int vo = (dn * 16 + (lane & 15)) * AP + kk * 32 + (lane >> 4) * 8;
        bf16x8 vv = *reinterpret_cast<const bf16x8*>(&Vs[vo]);
        oacc[dn] = __builtin_amdgcn_mfma_f32_16x16x32_bf16(ph, vv, oacc[dn], 0, 0, 0);
      }
    }
  }
  // epilogue: O/l + residual x
#pragma unroll
  for (int dn = 0; dn < 4; ++dn)
#pragma unroll
    for (int r = 0; r < 4; ++r) {
      int row = qrow0 + (lane >> 4) * 4 + r;
      int col = h * 64 + dn * 16 + (lane & 15);
      size_t gi = (tb + row) * 256 + col;
      Sout[gi] = oacc[dn][r] / lsum[r] + XtF[gi];
    }
}

// ---------------- BatchNorm pieces ----------------
__global__ __launch_bounds__(256) void bn_stats(const float* __restrict__ S, float* __restrict__ stats) {
  int c = threadIdx.x;
  int t0 = blockIdx.x * 64;
  float sum = 0.f, sq = 0.f;
  for (int i = 0; i < 64; ++i) {
    float v = S[(size_t)(t0 + i) * 256 + c];
    sum += v; sq += v * v;
  }
  atomicAdd(&stats[c], sum);
  atomicAdd(&stats[256 + c], sq);
}

__global__ void bn_finalize(const float* __restrict__ stats, const float* __restrict__ gamma,
                            const float* __restrict__ beta, float* __restrict__ ss) {
  int c = threadIdx.x;
  float mean = stats[c] * (1.f / 16384.f);
  float var = stats[256 + c] * (1.f / 16384.f) - mean * mean;
  float rstd = rsqrtf(var + 1e-5f);
  float scg = gamma[c] * rstd;
  ss[c] = scg;
  ss[256 + c] = beta[c] - mean * scg;
}

__global__ __launch_bounds__(256) void bn_apply(float* __restrict__ S, u16* __restrict__ mhb,
                                                const float* __restrict__ ss) {
  size_t i = (size_t)blockIdx.x * 256 + threadIdx.x;
  int c = (int)(i & 255);
  float v = S[i] * ss[c] + ss[256 + c];
  S[i] = v;
  mhb[i] = f2bf(v);
}

// final BN + transpose [T,C] -> [B,C,N]
__global__ __launch_bounds__(256) void bn_final_out(const float* __restrict__ T2,
                                                    const float* __restrict__ ss,
                                                    float* __restrict__ out) {
  __shared__ float tile[32][33];
  int n0 = (blockIdx.x & 31) * 32;
  int b = blockIdx.x >> 5;
  int c0 = blockIdx.y * 32;
  int tx = threadIdx.x, ty = threadIdx.y;
#pragma unroll
  for (int j = 0; j < 4; ++j) {
    int r = ty + j * 8;
    int c = c0 + tx;
    float v = T2[((size_t)b * 1024 + n0 + r) * 256 + c];
    tile[r][tx] = v * ss[c] + ss[256 + c];
  }
  __syncthreads();
#pragma unroll
  for (int j = 0; j < 4; ++j) {
    int c = c0 + ty + j * 8;
    out[((size_t)b * 256 + c) * 1024 + n0 + tx] = tile[tx][ty + j * 8];
  }
}

// ---------------- launch ----------------
extern "C" void kernel_launch(void* const* d_in, const int* in_sizes, int n_in,
                              void* d_out, int out_size, void* d_ws, size_t ws_size,
                              hipStream_t stream) {
  const float* x = (const float*)d_in[0];
  const float* Wq = (const float*)d_in[1];
  const float* bq = (const float*)d_in[2];
  const float* Wk = (const float*)d_in[3];
  const float* bk = (const float*)d_in[4];
  const float* Wv = (const float*)d_in[5];
  const float* bv = (const float*)d_in[6];
  const float* gamma = (const float*)d_in[7];
  const float* beta = (const float*)d_in[8];
  const float* W1 = (const float*)d_in[9];
  const float* b1 = (const float*)d_in[10];
  const float* a = (const float*)d_in[11];
  const float* W2 = (const float*)d_in[12];
  const float* b2 = (const float*)d_in[13];
  float* out = (float*)d_out;

  char* wsb = (char*)d_ws;
  const size_t MB = 1ull << 20;
  u16* XtbH = (u16*)(wsb + 0 * MB);       // 8MB; aliased by mhB after attn
  u16* XtbL = (u16*)(wsb + 8 * MB);       // 8MB
  float* XtF = (float*)(wsb + 16 * MB);   // 16MB; aliased by T2 after attn
  u16* QKh = (u16*)(wsb + 32 * MB);       // 16MB; aliased by H1B (32MB) after attn
  u16* QKl = (u16*)(wsb + 48 * MB);       // 16MB
  u16* Vt = (u16*)(wsb + 64 * MB);        // 8MB
  char* wp = wsb + 72 * MB;
  u16* WallH = (u16*)(wp);                // 256KB
  u16* WallL = (u16*)(wp + 262144);       // 256KB
  u16* WvH = (u16*)(wp + 524288);         // 128KB
  u16* WvL = (u16*)(wp + 655360);         // 128KB
  u16* W1b = (u16*)(wp + 786432);         // 512KB
  u16* W2b = (u16*)(wp + 1310720);        // 512KB
  float* bqk = (float*)(wp + 1835008);    // 2KB
  float* stats = (float*)(wp + 1837056);  // 8KB
  if (ws_size < 75 * MB) return;

  u16* mhB = XtbH;   // [T,256] bf16, after attn
  float* T2 = XtF;   // [T,256] f32, after attn
  u16* H1B = QKh;    // [T,1024] bf16, after attn
  float* S = out;    // d_out doubles as o+x / mh f32 buffer [T,256]

  hipMemsetAsync(stats, 0, 8192, stream);
  transpose_x<<<dim3(32, 8, 16), dim3(32, 8), 0, stream>>>(x, XtF, XtbH, XtbL);
  prep_weights<<<1024, 256, 0, stream>>>(Wq, Wk, Wv, bq, bk, W1, W2,
                                         WallH, WallL, WvH, WvL, W1b, W2b, bqk);
  // QK projection: [16384,256] x [512,256]^T -> QKh/QKl [16384,512]
  gemm_qk<<<dim3(4, 128), 256, 0, stream>>>(XtbH, XtbL, WallH, WallL, bqk, QKh, QKl);
  // V projection transposed: per batch [256,256] x [1024,256]^T -> Vt[b,256,1024]
  gemm_vt<<<dim3(8, 2, 16), 256, 0, stream>>>(WvH, WvL, XtbH, bv, Vt);
  // attention + residual: 512 blocks x 8 waves, 128 q-rows each
  attn_kernel<<<dim3(8, 4, 16), 512, 0, stream>>>(QKh, QKl, Vt, XtF, S);
  // BN1 (in-place on S, emits bf16 mh)
  bn_stats<<<256, 256, 0, stream>>>(S, stats);
  bn_finalize<<<1, 256, 0, stream>>>(stats, gamma, beta, stats + 512);
  bn_apply<<<16384, 256, 0, stream>>>(S, mhB, stats + 512);
  // FFN1: [16384,256] x [1024,256]^T -> H1B bf16, bias+PReLU
  gemm_ffn<1><<<dim3(8, 128), 256, 0, stream>>>(mhB, 256, W1b, 256, b1, a, nullptr, H1B, 1024, 256);
  // FFN2: [16384,1024] x [256,1024]^T -> T2 f32, bias + resid(S)
  gemm_ffn<2><<<dim3(2, 128), 256, 0, stream>>>(H1B, 1024, W2b, 1024, b2, nullptr, S, T2, 256, 1024);
  // BN2 + transpose out
  bn_stats<<<256, 256, 0, stream>>>(T2, stats + 1024);
  bn_finalize<<<1, 256, 0, stream>>>(stats + 1024, gamma, beta, stats + 1536);
  bn_final_out<<<dim3(512, 8), dim3(32, 8), 0, stream>>>(T2, stats + 1536, out);
}

// Round 5
// 196.240 us; speedup vs baseline: 1.5558x; 1.1188x over previous
//
#include <hip/hip_runtime.h>
#include <hip/hip_bf16.h>

typedef unsigned short u16;
typedef __attribute__((ext_vector_type(8))) __bf16 bf16x8;
typedef __attribute__((ext_vector_type(4))) float f32x4;

__device__ inline u16 f2bf(float f) {
  unsigned int x = __float_as_uint(f);
  unsigned int r = (x + 0x7FFFu + ((x >> 16) & 1u)) >> 16;
  return (u16)r;
}
__device__ inline float bf2f(u16 u) { return __uint_as_float(((unsigned int)u) << 16); }
__device__ inline void split2(float v, u16& h, u16& l) {
  h = f2bf(v);
  l = f2bf(v - bf2f(h));
}

// ---------------- x transpose: [B,C,N] f32 -> [B,N,C] f32 + bf16 hi/lo ----------------
__global__ __launch_bounds__(256) void transpose_x(const float* __restrict__ x,
                                                   float* __restrict__ XtF,
                                                   u16* __restrict__ XtbH,
                                                   u16* __restrict__ XtbL) {
  __shared__ float tile[32][33];
  int n0 = blockIdx.x * 32;
  int c0 = blockIdx.y * 32;
  int b  = blockIdx.z;
  int tx = threadIdx.x, ty = threadIdx.y;
#pragma unroll
  for (int j = 0; j < 4; ++j) {
    int c = c0 + ty + j * 8;
    tile[ty + j * 8][tx] = x[((size_t)b * 256 + c) * 1024 + n0 + tx];
  }
  __syncthreads();
#pragma unroll
  for (int j = 0; j < 4; ++j) {
    int n = n0 + ty + j * 8;
    float v = tile[tx][ty + j * 8];
    size_t o = ((size_t)b * 1024 + n) * 256 + c0 + tx;
    XtF[o] = v;
    u16 h, l;
    split2(v, h, l);
    XtbH[o] = h; XtbL[o] = l;
  }
}

// ---------------- weight prep ----------------
__global__ __launch_bounds__(256) void prep_weights(
    const float* __restrict__ Wq, const float* __restrict__ Wk, const float* __restrict__ Wv,
    const float* __restrict__ bq, const float* __restrict__ bk,
    const float* __restrict__ W1, const float* __restrict__ W2,
    u16* __restrict__ WallH, u16* __restrict__ WallL,
    u16* __restrict__ WvH, u16* __restrict__ WvL,
    u16* __restrict__ W1b, u16* __restrict__ W2b,
    float* __restrict__ bqk) {
  int i = blockIdx.x * 256 + threadIdx.x;
  if (i < 131072) {
    float w = (i < 65536) ? Wq[i] : Wk[i - 65536];
    u16 h, l;
    split2(w, h, l);
    WallH[i] = h; WallL[i] = l;
  }
  if (i < 65536) {
    u16 h, l;
    split2(Wv[i], h, l);
    WvH[i] = h; WvL[i] = l;
  }
  if (i < 262144) { W1b[i] = f2bf(W1[i]); W2b[i] = f2bf(W2[i]); }
  if (i < 256) bqk[i] = bq[i];
  else if (i < 512) bqk[i] = bk[i - 256];
}

#define GKP 40

// ---------------- QK projection GEMM (3-term hi/lo), out split bf16 ----------------
__global__ __launch_bounds__(256) void gemm_qk(
    const u16* __restrict__ Ah_, const u16* __restrict__ Al_,
    const u16* __restrict__ Bh_, const u16* __restrict__ Bl_,
    const float* __restrict__ bias,
    u16* __restrict__ Ch, u16* __restrict__ Cl) {
  __shared__ u16 Ah[128 * GKP], Al[128 * GKP], Bh[128 * GKP], Bl[128 * GKP];
  const int tid = threadIdx.x;
  const int lane = tid & 63, wid = tid >> 6;
  const int wr = wid >> 1, wc = wid & 1;
  const int m0 = blockIdx.y * 128, n0 = blockIdx.x * 128;

  f32x4 acc[4][4] = {};
  for (int kt = 0; kt < 256; kt += 32) {
    __syncthreads();
#pragma unroll
    for (int i = 0; i < 2; ++i) {
      int idx = tid + i * 256;
      int r = idx >> 2, cv = (idx & 3) * 8;
      *reinterpret_cast<uint4*>(&Ah[r * GKP + cv]) = *reinterpret_cast<const uint4*>(Ah_ + (size_t)(m0 + r) * 256 + kt + cv);
      *reinterpret_cast<uint4*>(&Al[r * GKP + cv]) = *reinterpret_cast<const uint4*>(Al_ + (size_t)(m0 + r) * 256 + kt + cv);
      *reinterpret_cast<uint4*>(&Bh[r * GKP + cv]) = *reinterpret_cast<const uint4*>(Bh_ + (size_t)(n0 + r) * 256 + kt + cv);
      *reinterpret_cast<uint4*>(&Bl[r * GKP + cv]) = *reinterpret_cast<const uint4*>(Bl_ + (size_t)(n0 + r) * 256 + kt + cv);
    }
    __syncthreads();
    bf16x8 afh[4], afl[4], bfh[4], bfl[4];
#pragma unroll
    for (int m = 0; m < 4; ++m) {
      int o = (wr * 64 + m * 16 + (lane & 15)) * GKP + (lane >> 4) * 8;
      afh[m] = *reinterpret_cast<const bf16x8*>(&Ah[o]);
      afl[m] = *reinterpret_cast<const bf16x8*>(&Al[o]);
    }
#pragma unroll
    for (int n = 0; n < 4; ++n) {
      int o = (wc * 64 + n * 16 + (lane & 15)) * GKP + (lane >> 4) * 8;
      bfh[n] = *reinterpret_cast<const bf16x8*>(&Bh[o]);
      bfl[n] = *reinterpret_cast<const bf16x8*>(&Bl[o]);
    }
#pragma unroll
    for (int m = 0; m < 4; ++m)
#pragma unroll
      for (int n = 0; n < 4; ++n) {
        acc[m][n] = __builtin_amdgcn_mfma_f32_16x16x32_bf16(afh[m], bfh[n], acc[m][n], 0, 0, 0);
        acc[m][n] = __builtin_amdgcn_mfma_f32_16x16x32_bf16(afh[m], bfl[n], acc[m][n], 0, 0, 0);
        acc[m][n] = __builtin_amdgcn_mfma_f32_16x16x32_bf16(afl[m], bfh[n], acc[m][n], 0, 0, 0);
      }
  }
#pragma unroll
  for (int m = 0; m < 4; ++m) {
    int row_b = m0 + wr * 64 + m * 16 + (lane >> 4) * 4;
#pragma unroll
    for (int n = 0; n < 4; ++n) {
      int col = n0 + wc * 64 + n * 16 + (lane & 15);
      float bb = bias[col];
#pragma unroll
      for (int r = 0; r < 4; ++r) {
        size_t o = (size_t)(row_b + r) * 512 + col;
        u16 h, l;
        split2(acc[m][n][r] + bb, h, l);
        Ch[o] = h; Cl[o] = l;
      }
    }
  }
}

// ---------------- V projection, transposed output: Vt[b,d,n] ----------------
__global__ __launch_bounds__(256) void gemm_vt(
    const u16* __restrict__ WvH_, const u16* __restrict__ WvL_,
    const u16* __restrict__ XtbH, const float* __restrict__ bv,
    u16* __restrict__ Vt) {
  __shared__ u16 Ah[128 * GKP], Al[128 * GKP], Bh[128 * GKP];
  const int tid = threadIdx.x;
  const int lane = tid & 63, wid = tid >> 6;
  const int wr = wid >> 1, wc = wid & 1;
  const int b = blockIdx.z;
  const int m0 = blockIdx.y * 128, n0 = blockIdx.x * 128;
  const u16* Bp = XtbH + (size_t)b * 1024 * 256;

  f32x4 acc[4][4] = {};
  for (int kt = 0; kt < 256; kt += 32) {
    __syncthreads();
#pragma unroll
    for (int i = 0; i < 2; ++i) {
      int idx = tid + i * 256;
      int r = idx >> 2, cv = (idx & 3) * 8;
      *reinterpret_cast<uint4*>(&Ah[r * GKP + cv]) = *reinterpret_cast<const uint4*>(WvH_ + (size_t)(m0 + r) * 256 + kt + cv);
      *reinterpret_cast<uint4*>(&Al[r * GKP + cv]) = *reinterpret_cast<const uint4*>(WvL_ + (size_t)(m0 + r) * 256 + kt + cv);
      *reinterpret_cast<uint4*>(&Bh[r * GKP + cv]) = *reinterpret_cast<const uint4*>(Bp + (size_t)(n0 + r) * 256 + kt + cv);
    }
    __syncthreads();
    bf16x8 afh[4], afl[4], bfr[4];
#pragma unroll
    for (int m = 0; m < 4; ++m) {
      int o = (wr * 64 + m * 16 + (lane & 15)) * GKP + (lane >> 4) * 8;
      afh[m] = *reinterpret_cast<const bf16x8*>(&Ah[o]);
      afl[m] = *reinterpret_cast<const bf16x8*>(&Al[o]);
    }
#pragma unroll
    for (int n = 0; n < 4; ++n)
      bfr[n] = *reinterpret_cast<const bf16x8*>(&Bh[(wc * 64 + n * 16 + (lane & 15)) * GKP + (lane >> 4) * 8]);
#pragma unroll
    for (int m = 0; m < 4; ++m)
#pragma unroll
      for (int n = 0; n < 4; ++n) {
        acc[m][n] = __builtin_amdgcn_mfma_f32_16x16x32_bf16(afh[m], bfr[n], acc[m][n], 0, 0, 0);
        acc[m][n] = __builtin_amdgcn_mfma_f32_16x16x32_bf16(afl[m], bfr[n], acc[m][n], 0, 0, 0);
      }
  }
#pragma unroll
  for (int m = 0; m < 4; ++m) {
    int row_b = m0 + wr * 64 + m * 16 + (lane >> 4) * 4;  // d index
#pragma unroll
    for (int n = 0; n < 4; ++n) {
      int col = n0 + wc * 64 + n * 16 + (lane & 15);      // token n
#pragma unroll
      for (int r = 0; r < 4; ++r) {
        int row = row_b + r;
        Vt[((size_t)b * 256 + row) * 1024 + col] = f2bf(acc[m][n][r] + bv[row]);
      }
    }
  }
}

// ---------------- FFN1: A = BN(Sraw) applied in staging, PReLU epilogue -> bf16 ----------------
__global__ __launch_bounds__(256) void gemm_ffn1(
    const float* __restrict__ Sraw,
    const u16* __restrict__ B_,
    const float* __restrict__ bias,
    const float* __restrict__ aslope,
    const float* __restrict__ ss,
    u16* __restrict__ H1B) {
  __shared__ u16 As[128 * GKP], Bs[128 * GKP];
  __shared__ float ssl[512];
  const int tid = threadIdx.x;
  const int lane = tid & 63, wid = tid >> 6;
  const int wr = wid >> 1, wc = wid & 1;
  const int m0 = blockIdx.y * 128, n0 = blockIdx.x * 128;
  ssl[tid] = ss[tid];
  ssl[256 + tid] = ss[256 + tid];

  f32x4 acc[4][4] = {};
  for (int kt = 0; kt < 256; kt += 32) {
    __syncthreads();
    // A-stage: BN affine + bf16 convert from raw S
#pragma unroll
    for (int i = 0; i < 4; ++i) {
      int idx = tid + i * 256;
      int r = idx >> 3, c4 = (idx & 7) * 4;
      float4 v = *reinterpret_cast<const float4*>(Sraw + (size_t)(m0 + r) * 256 + kt + c4);
      ushort4 o;
      o.x = f2bf(v.x * ssl[kt + c4 + 0] + ssl[256 + kt + c4 + 0]);
      o.y = f2bf(v.y * ssl[kt + c4 + 1] + ssl[256 + kt + c4 + 1]);
      o.z = f2bf(v.z * ssl[kt + c4 + 2] + ssl[256 + kt + c4 + 2]);
      o.w = f2bf(v.w * ssl[kt + c4 + 3] + ssl[256 + kt + c4 + 3]);
      *reinterpret_cast<ushort4*>(&As[r * GKP + c4]) = o;
    }
#pragma unroll
    for (int i = 0; i < 2; ++i) {
      int idx = tid + i * 256;
      int r = idx >> 2, cv = (idx & 3) * 8;
      *reinterpret_cast<uint4*>(&Bs[r * GKP + cv]) = *reinterpret_cast<const uint4*>(B_ + (size_t)(n0 + r) * 256 + kt + cv);
    }
    __syncthreads();
    bf16x8 af[4], bfr[4];
#pragma unroll
    for (int m = 0; m < 4; ++m)
      af[m] = *reinterpret_cast<const bf16x8*>(&As[(wr * 64 + m * 16 + (lane & 15)) * GKP + (lane >> 4) * 8]);
#pragma unroll
    for (int n = 0; n < 4; ++n)
      bfr[n] = *reinterpret_cast<const bf16x8*>(&Bs[(wc * 64 + n * 16 + (lane & 15)) * GKP + (lane >> 4) * 8]);
#pragma unroll
    for (int m = 0; m < 4; ++m)
#pragma unroll
      for (int n = 0; n < 4; ++n)
        acc[m][n] = __builtin_amdgcn_mfma_f32_16x16x32_bf16(af[m], bfr[n], acc[m][n], 0, 0, 0);
  }
  float a = aslope[0];
#pragma unroll
  for (int m = 0; m < 4; ++m) {
    int row_b = m0 + wr * 64 + m * 16 + (lane >> 4) * 4;
#pragma unroll
    for (int n = 0; n < 4; ++n) {
      int col = n0 + wc * 64 + n * 16 + (lane & 15);
      float bb = bias[col];
#pragma unroll
      for (int r = 0; r < 4; ++r) {
        float v = acc[m][n][r] + bb;
        v = (v >= 0.f) ? v : a * v;
        H1B[(size_t)(row_b + r) * 1024 + col] = f2bf(v);
      }
    }
  }
}

// ---------------- FFN2: bias + BN1(resid) epilogue -> f32, fused BN2 stats ----------------
__global__ __launch_bounds__(256) void gemm_ffn2(
    const u16* __restrict__ A_,
    const u16* __restrict__ B_,
    const float* __restrict__ bias,
    const float* __restrict__ Sraw,
    const float* __restrict__ ss,
    float* __restrict__ T2,
    float* __restrict__ stats2) {
  __shared__ u16 As[128 * GKP], Bs[128 * GKP];
  __shared__ float sred[2][128];
  const int tid = threadIdx.x;
  const int lane = tid & 63, wid = tid >> 6;
  const int wr = wid >> 1, wc = wid & 1;
  const int m0 = blockIdx.y * 128, n0 = blockIdx.x * 128;
  if (tid < 128) { sred[0][tid] = 0.f; sred[1][tid] = 0.f; }

  f32x4 acc[4][4] = {};
  for (int kt = 0; kt < 1024; kt += 32) {
    __syncthreads();
#pragma unroll
    for (int i = 0; i < 2; ++i) {
      int idx = tid + i * 256;
      int r = idx >> 2, cv = (idx & 3) * 8;
      *reinterpret_cast<uint4*>(&As[r * GKP + cv]) = *reinterpret_cast<const uint4*>(A_ + (size_t)(m0 + r) * 1024 + kt + cv);
      *reinterpret_cast<uint4*>(&Bs[r * GKP + cv]) = *reinterpret_cast<const uint4*>(B_ + (size_t)(n0 + r) * 1024 + kt + cv);
    }
    __syncthreads();
    bf16x8 af[4], bfr[4];
#pragma unroll
    for (int m = 0; m < 4; ++m)
      af[m] = *reinterpret_cast<const bf16x8*>(&As[(wr * 64 + m * 16 + (lane & 15)) * GKP + (lane >> 4) * 8]);
#pragma unroll
    for (int n = 0; n < 4; ++n)
      bfr[n] = *reinterpret_cast<const bf16x8*>(&Bs[(wc * 64 + n * 16 + (lane & 15)) * GKP + (lane >> 4) * 8]);
#pragma unroll
    for (int m = 0; m < 4; ++m)
#pragma unroll
      for (int n = 0; n < 4; ++n)
        acc[m][n] = __builtin_amdgcn_mfma_f32_16x16x32_bf16(af[m], bfr[n], acc[m][n], 0, 0, 0);
  }
  float s1a[4] = {0.f, 0.f, 0.f, 0.f}, s2a[4] = {0.f, 0.f, 0.f, 0.f};
#pragma unroll
  for (int m = 0; m < 4; ++m) {
    int row_b = m0 + wr * 64 + m * 16 + (lane >> 4) * 4;
#pragma unroll
    for (int n = 0; n < 4; ++n) {
      int col = n0 + wc * 64 + n * 16 + (lane & 15);
      float bb = bias[col];
      float sc_ = ss[col], of_ = ss[256 + col];
#pragma unroll
      for (int r = 0; r < 4; ++r) {
        int row = row_b + r;
        float resid = Sraw[(size_t)row * 256 + col] * sc_ + of_;
        float v = acc[m][n][r] + bb + resid;
        T2[(size_t)row * 256 + col] = v;
        s1a[n] += v;
        s2a[n] += v * v;
      }
    }
  }
  // reduce over the 4 lane-groups, combine 2 row-waves via LDS atomics
#pragma unroll
  for (int n = 0; n < 4; ++n) {
    float a1 = s1a[n];
    a1 += __shfl_xor(a1, 16, 64);
    a1 += __shfl_xor(a1, 32, 64);
    float a2 = s2a[n];
    a2 += __shfl_xor(a2, 16, 64);
    a2 += __shfl_xor(a2, 32, 64);
    if (lane < 16) {
      atomicAdd(&sred[0][wc * 64 + n * 16 + lane], a1);
      atomicAdd(&sred[1][wc * 64 + n * 16 + lane], a2);
    }
  }
  __syncthreads();
  if (tid < 128) {
    atomicAdd(&stats2[n0 + tid], sred[0][tid]);
    atomicAdd(&stats2[256 + n0 + tid], sred[1][tid]);
  }
}

// ---------------- fused flash attention: 8 waves, 128 q-rows, double-buffered ----------------
// grid (64, 8): x = hb (h = hb&3, b = hb>>2) -> same-XCD grouping of a (b,h)'s q-chunks.
#define AP 72
__global__ __launch_bounds__(512, 4) void attn_kernel(const u16* __restrict__ QKh,
                                                      const u16* __restrict__ QKl,
                                                      const u16* __restrict__ Vt,
                                                      const float* __restrict__ XtF,
                                                      float* __restrict__ Sout,
                                                      float* __restrict__ stats) {
  __shared__ u16 Kh[2][64 * AP], Kl[2][64 * AP], Vs[2][64 * AP];
  __shared__ u16 Ps[8 * 16 * AP];
  __shared__ float sred[2][64];
  const int tid = threadIdx.x, lane = tid & 63, w = tid >> 6;
  const int hb = blockIdx.x, h = hb & 3, b = hb >> 2;
  const size_t tb = (size_t)b * 1024;
  const int qrow0 = blockIdx.y * 128 + w * 16;

  if (tid < 64) { sred[0][tid] = 0.f; sred[1][tid] = 0.f; }

  // Q fragments in registers (hi/lo)
  bf16x8 qh[2], ql[2];
#pragma unroll
  for (int kk = 0; kk < 2; ++kk) {
    size_t ro = (tb + qrow0 + (lane & 15)) * 512 + h * 64 + kk * 32 + (lane >> 4) * 8;
    qh[kk] = *reinterpret_cast<const bf16x8*>(QKh + ro);
    ql[kk] = *reinterpret_cast<const bf16x8*>(QKl + ro);
  }

  f32x4 oacc[4] = {};
  float mprev[4], lsum[4];
#pragma unroll
  for (int r = 0; r < 4; ++r) { mprev[r] = -3e38f; lsum[r] = 0.f; }

  const int sr = tid >> 3, sc8 = (tid & 7) * 8;
  const size_t kbase = (tb + sr) * 512 + 256 + h * 64 + sc8;
  const size_t vbase = ((size_t)b * 256 + h * 64 + sr) * 1024 + sc8;

  // prologue: stage tile 0 into buf 0
  uint4 rkh = *reinterpret_cast<const uint4*>(QKh + kbase);
  uint4 rkl = *reinterpret_cast<const uint4*>(QKl + kbase);
  uint4 rv  = *reinterpret_cast<const uint4*>(Vt + vbase);
  *reinterpret_cast<uint4*>(&Kh[0][sr * AP + sc8]) = rkh;
  *reinterpret_cast<uint4*>(&Kl[0][sr * AP + sc8]) = rkl;
  *reinterpret_cast<uint4*>(&Vs[0][sr * AP + sc8]) = rv;
  __syncthreads();

  int cur = 0;
  for (int kt = 0; kt < 16; ++kt) {
    // issue next tile's global loads early (hide under compute)
    if (kt < 15) {
      rkh = *reinterpret_cast<const uint4*>(QKh + kbase + (size_t)(kt + 1) * 32768);
      rkl = *reinterpret_cast<const uint4*>(QKl + kbase + (size_t)(kt + 1) * 32768);
      rv  = *reinterpret_cast<const uint4*>(Vt + vbase + (size_t)(kt + 1) * 64);
    }

    f32x4 sc[4] = {};
    __builtin_amdgcn_s_setprio(1);
#pragma unroll
    for (int kk = 0; kk < 2; ++kk)
#pragma unroll
      for (int n = 0; n < 4; ++n) {
        int ko = (n * 16 + (lane & 15)) * AP + kk * 32 + (lane >> 4) * 8;
        bf16x8 bkh = *reinterpret_cast<const bf16x8*>(&Kh[cur][ko]);
        bf16x8 bkl = *reinterpret_cast<const bf16x8*>(&Kl[cur][ko]);
        sc[n] = __builtin_amdgcn_mfma_f32_16x16x32_bf16(qh[kk], bkh, sc[n], 0, 0, 0);
        sc[n] = __builtin_amdgcn_mfma_f32_16x16x32_bf16(qh[kk], bkl, sc[n], 0, 0, 0);
        sc[n] = __builtin_amdgcn_mfma_f32_16x16x32_bf16(ql[kk], bkh, sc[n], 0, 0, 0);
      }
    __builtin_amdgcn_s_setprio(0);
    // per-row max across the 16 col-lanes
    float vmax[4];
#pragma unroll
    for (int r = 0; r < 4; ++r) {
      float v = fmaxf(fmaxf(sc[0][r], sc[1][r]), fmaxf(sc[2][r], sc[3][r]));
      v = fmaxf(v, __shfl_xor(v, 1, 64));
      v = fmaxf(v, __shfl_xor(v, 2, 64));
      v = fmaxf(v, __shfl_xor(v, 4, 64));
      v = fmaxf(v, __shfl_xor(v, 8, 64));
      vmax[r] = v;
    }
    // defer-max: skip rescale when all rows' max grew by <= 8
    bool ok = (vmax[0] <= mprev[0] + 8.f) && (vmax[1] <= mprev[1] + 8.f) &&
              (vmax[2] <= mprev[2] + 8.f) && (vmax[3] <= mprev[3] + 8.f);
    if (!__all(ok)) {
#pragma unroll
      for (int r = 0; r < 4; ++r) {
        float mn = fmaxf(mprev[r], vmax[r]);
        float scl = __expf(mprev[r] - mn);
        mprev[r] = mn;
        lsum[r] *= scl;
#pragma unroll
        for (int dn = 0; dn < 4; ++dn) oacc[dn][r] *= scl;
      }
    }
    float lt[4] = {0.f, 0.f, 0.f, 0.f};
#pragma unroll
    for (int n = 0; n < 4; ++n)
#pragma unroll
      for (int r = 0; r < 4; ++r) {
        float p = __expf(sc[n][r] - mprev[r]);
        sc[n][r] = p;
        lt[r] += p;
      }
#pragma unroll
    for (int r = 0; r < 4; ++r) {
      float v = lt[r];
      v += __shfl_xor(v, 1, 64);
      v += __shfl_xor(v, 2, 64);
      v += __shfl_xor(v, 4, 64);
      v += __shfl_xor(v, 8, 64);
      lsum[r] += v;
    }
    // P -> wave-private LDS (single bf16)
#pragma unroll
    for (int n = 0; n < 4; ++n)
#pragma unroll
      for (int r = 0; r < 4; ++r) {
        int po = w * 16 * AP + ((lane >> 4) * 4 + r) * AP + n * 16 + (lane & 15);
        Ps[po] = f2bf(sc[n][r]);
      }
    // PV
    __builtin_amdgcn_s_setprio(1);
#pragma unroll
    for (int kk = 0; kk < 2; ++kk) {
      int po = w * 16 * AP + (lane & 15) * AP + kk * 32 + (lane >> 4) * 8;
      bf16x8 ph = *reinterpret_cast<const bf16x8*>(&Ps[po]);
#pragma unroll
      for (int dn = 0; dn < 4; ++dn) {
        int vo = (dn * 16 + (lane & 15)) * AP + kk * 32 + (lane >> 4) * 8;
        bf16x8 vv = *reinterpret_cast<const bf16x8*>(&Vs[cur][vo]);
        oacc[dn] = __builtin_amdgcn_mfma_f32_16x16x32_bf16(ph, vv, oacc[dn], 0, 0, 0);
      }
    }
    __builtin_amdgcn_s_setprio(0);
    // write next tile to the other buffer, then one barrier
    if (kt < 15) {
      *reinterpret_cast<uint4*>(&Kh[cur ^ 1][sr * AP + sc8]) = rkh;
      *reinterpret_cast<uint4*>(&Kl[cur ^ 1][sr * AP + sc8]) = rkl;
      *reinterpret_cast<uint4*>(&Vs[cur ^ 1][sr * AP + sc8]) = rv;
    }
    __syncthreads();
    cur ^= 1;
  }
  // epilogue: O/l + residual x, fused BN1 stats
  float s1a[4] = {0.f, 0.f, 0.f, 0.f}, s2a[4] = {0.f, 0.f, 0.f, 0.f};
#pragma unroll
  for (int dn = 0; dn < 4; ++dn)
#pragma unroll
    for (int r = 0; r < 4; ++r) {
      int row = qrow0 + (lane >> 4) * 4 + r;
      int col = h * 64 + dn * 16 + (lane & 15);
      size_t gi = (tb + row) * 256 + col;
      float v = oacc[dn][r] / lsum[r] + XtF[gi];
      Sout[gi] = v;
      s1a[dn] += v;
      s2a[dn] += v * v;
    }
#pragma unroll
  for (int dn = 0; dn < 4; ++dn) {
    float a1 = s1a[dn];
    a1 += __shfl_xor(a1, 16, 64);
    a1 += __shfl_xor(a1, 32, 64);
    float a2 = s2a[dn];
    a2 += __shfl_xor(a2, 16, 64);
    a2 += __shfl_xor(a2, 32, 64);
    if (lane < 16) {
      atomicAdd(&sred[0][dn * 16 + lane], a1);
      atomicAdd(&sred[1][dn * 16 + lane], a2);
    }
  }
  __syncthreads();
  if (tid < 64) {
    atomicAdd(&stats[h * 64 + tid], sred[0][tid]);
    atomicAdd(&stats[256 + h * 64 + tid], sred[1][tid]);
  }
}

// ---------------- BN finalize ----------------
__global__ void bn_finalize(const float* __restrict__ stats, const float* __restrict__ gamma,
                            const float* __restrict__ beta, float* __restrict__ ss) {
  int c = threadIdx.x;
  float mean = stats[c] * (1.f / 16384.f);
  float var = stats[256 + c] * (1.f / 16384.f) - mean * mean;
  float rstd = rsqrtf(var + 1e-5f);
  float scg = gamma[c] * rstd;
  ss[c] = scg;
  ss[256 + c] = beta[c] - mean * scg;
}

// final BN + transpose [T,C] -> [B,C,N]
__global__ __launch_bounds__(256) void bn_final_out(const float* __restrict__ T2,
                                                    const float* __restrict__ ss,
                                                    float* __restrict__ out) {
  __shared__ float tile[32][33];
  int n0 = (blockIdx.x & 31) * 32;
  int b = blockIdx.x >> 5;
  int c0 = blockIdx.y * 32;
  int tx = threadIdx.x, ty = threadIdx.y;
#pragma unroll
  for (int j = 0; j < 4; ++j) {
    int r = ty + j * 8;
    int c = c0 + tx;
    float v = T2[((size_t)b * 1024 + n0 + r) * 256 + c];
    tile[r][tx] = v * ss[c] + ss[256 + c];
  }
  __syncthreads();
#pragma unroll
  for (int j = 0; j < 4; ++j) {
    int c = c0 + ty + j * 8;
    out[((size_t)b * 256 + c) * 1024 + n0 + tx] = tile[tx][ty + j * 8];
  }
}

// ---------------- launch ----------------
extern "C" void kernel_launch(void* const* d_in, const int* in_sizes, int n_in,
                              void* d_out, int out_size, void* d_ws, size_t ws_size,
                              hipStream_t stream) {
  const float* x = (const float*)d_in[0];
  const float* Wq = (const float*)d_in[1];
  const float* bq = (const float*)d_in[2];
  const float* Wk = (const float*)d_in[3];
  const float* bk = (const float*)d_in[4];
  const float* Wv = (const float*)d_in[5];
  const float* bv = (const float*)d_in[6];
  const float* gamma = (const float*)d_in[7];
  const float* beta = (const float*)d_in[8];
  const float* W1 = (const float*)d_in[9];
  const float* b1 = (const float*)d_in[10];
  const float* a = (const float*)d_in[11];
  const float* W2 = (const float*)d_in[12];
  const float* b2 = (const float*)d_in[13];
  float* out = (float*)d_out;

  char* wsb = (char*)d_ws;
  const size_t MB = 1ull << 20;
  u16* XtbH = (u16*)(wsb + 0 * MB);       // 8MB
  u16* XtbL = (u16*)(wsb + 8 * MB);       // 8MB
  float* XtF = (float*)(wsb + 16 * MB);   // 16MB; aliased by T2 after attn
  u16* QKh = (u16*)(wsb + 32 * MB);       // 16MB; aliased by H1B (32MB) after attn
  u16* QKl = (u16*)(wsb + 48 * MB);       // 16MB
  u16* Vt = (u16*)(wsb + 64 * MB);        // 8MB
  char* wp = wsb + 72 * MB;
  u16* WallH = (u16*)(wp);                // 256KB
  u16* WallL = (u16*)(wp + 262144);       // 256KB
  u16* WvH = (u16*)(wp + 524288);         // 128KB
  u16* WvL = (u16*)(wp + 655360);         // 128KB
  u16* W1b = (u16*)(wp + 786432);         // 512KB
  u16* W2b = (u16*)(wp + 1310720);        // 512KB
  float* bqk = (float*)(wp + 1835008);    // 2KB
  float* stats = (float*)(wp + 1837056);  // 8KB: stats1|ss1|stats2|ss2
  if (ws_size < 75 * MB) return;

  float* T2 = XtF;   // [T,256] f32, after attn
  u16* H1B = QKh;    // [T,1024] bf16, after attn
  float* S = out;    // d_out doubles as o+x raw residual buffer [T,256]

  hipMemsetAsync(stats, 0, 8192, stream);
  transpose_x<<<dim3(32, 8, 16), dim3(32, 8), 0, stream>>>(x, XtF, XtbH, XtbL);
  prep_weights<<<1024, 256, 0, stream>>>(Wq, Wk, Wv, bq, bk, W1, W2,
                                         WallH, WallL, WvH, WvL, W1b, W2b, bqk);
  // QK projection: [16384,256] x [512,256]^T -> QKh/QKl [16384,512]
  gemm_qk<<<dim3(4, 128), 256, 0, stream>>>(XtbH, XtbL, WallH, WallL, bqk, QKh, QKl);
  // V projection transposed: per batch [256,256] x [1024,256]^T -> Vt[b,256,1024]
  gemm_vt<<<dim3(8, 2, 16), 256, 0, stream>>>(WvH, WvL, XtbH, bv, Vt);
  // attention + residual + BN1 stats: grid (hb, qc) for XCD-local K/V reuse
  attn_kernel<<<dim3(64, 8), 512, 0, stream>>>(QKh, QKl, Vt, XtF, S, stats);
  bn_finalize<<<1, 256, 0, stream>>>(stats, gamma, beta, stats + 512);
  // FFN1: A = BN1(S) on the fly -> H1B bf16, bias+PReLU
  gemm_ffn1<<<dim3(8, 128), 256, 0, stream>>>(S, W1b, b1, a, stats + 512, H1B);
  // FFN2: [16384,1024] x [256,1024]^T -> T2 f32, bias + BN1(S) resid + BN2 stats
  gemm_ffn2<<<dim3(2, 128), 256, 0, stream>>>(H1B, W2b, b2, S, stats + 512, T2, stats + 1024);
  bn_finalize<<<1, 256, 0, stream>>>(stats + 1024, gamma, beta, stats + 1536);
  // BN2 apply + transpose out
  bn_final_out<<<dim3(512, 8), dim3(32, 8), 0, stream>>>(T2, stats + 1536, out);
}

// Round 6
// 185.779 us; speedup vs baseline: 1.6434x; 1.0563x over previous
//
#include <hip/hip_runtime.h>
#include <hip/hip_bf16.h>

typedef unsigned short u16;
typedef unsigned int u32;
typedef __attribute__((ext_vector_type(8))) __bf16 bf16x8;
typedef __attribute__((ext_vector_type(4))) float f32x4;

__device__ inline u16 f2bf(float f) {
  unsigned int x = __float_as_uint(f);
  unsigned int r = (x + 0x7FFFu + ((x >> 16) & 1u)) >> 16;
  return (u16)r;
}
__device__ inline float bf2f(u16 u) { return __uint_as_float(((unsigned int)u) << 16); }
__device__ inline void split2(float v, u16& h, u16& l) {
  h = f2bf(v);
  l = f2bf(v - bf2f(h));
}
__device__ inline u32 cvt_pk_bf16(float lo, float hi) {
  u32 r;
  asm("v_cvt_pk_bf16_f32 %0, %1, %2" : "=v"(r) : "v"(lo), "v"(hi));
  return r;
}

// ---------------- x transpose: [B,C,N] f32 -> [B,N,C] f32 + bf16 hi/lo ----------------
__global__ __launch_bounds__(256) void transpose_x(const float* __restrict__ x,
                                                   float* __restrict__ XtF,
                                                   u16* __restrict__ XtbH,
                                                   u16* __restrict__ XtbL) {
  __shared__ float tile[32][33];
  int n0 = blockIdx.x * 32;
  int c0 = blockIdx.y * 32;
  int b  = blockIdx.z;
  int tx = threadIdx.x, ty = threadIdx.y;
#pragma unroll
  for (int j = 0; j < 4; ++j) {
    int c = c0 + ty + j * 8;
    tile[ty + j * 8][tx] = x[((size_t)b * 256 + c) * 1024 + n0 + tx];
  }
  __syncthreads();
#pragma unroll
  for (int j = 0; j < 4; ++j) {
    int n = n0 + ty + j * 8;
    float v = tile[tx][ty + j * 8];
    size_t o = ((size_t)b * 1024 + n) * 256 + c0 + tx;
    XtF[o] = v;
    u16 h, l;
    split2(v, h, l);
    XtbH[o] = h; XtbL[o] = l;
  }
}

// ---------------- weight prep ----------------
__global__ __launch_bounds__(256) void prep_weights(
    const float* __restrict__ Wq, const float* __restrict__ Wk, const float* __restrict__ Wv,
    const float* __restrict__ bq, const float* __restrict__ bk,
    const float* __restrict__ W1, const float* __restrict__ W2,
    u16* __restrict__ WallH, u16* __restrict__ WallL,
    u16* __restrict__ WvH, u16* __restrict__ WvL,
    u16* __restrict__ W1b, u16* __restrict__ W2b,
    float* __restrict__ bqk) {
  int i = blockIdx.x * 256 + threadIdx.x;
  if (i < 131072) {
    float w = (i < 65536) ? Wq[i] : Wk[i - 65536];
    u16 h, l;
    split2(w, h, l);
    WallH[i] = h; WallL[i] = l;
  }
  if (i < 65536) {
    u16 h, l;
    split2(Wv[i], h, l);
    WvH[i] = h; WvL[i] = l;
  }
  if (i < 262144) { W1b[i] = f2bf(W1[i]); W2b[i] = f2bf(W2[i]); }
  if (i < 256) bqk[i] = bq[i];
  else if (i < 512) bqk[i] = bk[i - 256];
}

#define GKP 40

// ---------------- QK projection GEMM (3-term hi/lo), out split bf16 ----------------
__global__ __launch_bounds__(256) void gemm_qk(
    const u16* __restrict__ Ah_, const u16* __restrict__ Al_,
    const u16* __restrict__ Bh_, const u16* __restrict__ Bl_,
    const float* __restrict__ bias,
    u16* __restrict__ Ch, u16* __restrict__ Cl) {
  __shared__ u16 Ah[128 * GKP], Al[128 * GKP], Bh[128 * GKP], Bl[128 * GKP];
  const int tid = threadIdx.x;
  const int lane = tid & 63, wid = tid >> 6;
  const int wr = wid >> 1, wc = wid & 1;
  const int m0 = blockIdx.y * 128, n0 = blockIdx.x * 128;

  f32x4 acc[4][4] = {};
  for (int kt = 0; kt < 256; kt += 32) {
    __syncthreads();
#pragma unroll
    for (int i = 0; i < 2; ++i) {
      int idx = tid + i * 256;
      int r = idx >> 2, cv = (idx & 3) * 8;
      *reinterpret_cast<uint4*>(&Ah[r * GKP + cv]) = *reinterpret_cast<const uint4*>(Ah_ + (size_t)(m0 + r) * 256 + kt + cv);
      *reinterpret_cast<uint4*>(&Al[r * GKP + cv]) = *reinterpret_cast<const uint4*>(Al_ + (size_t)(m0 + r) * 256 + kt + cv);
      *reinterpret_cast<uint4*>(&Bh[r * GKP + cv]) = *reinterpret_cast<const uint4*>(Bh_ + (size_t)(n0 + r) * 256 + kt + cv);
      *reinterpret_cast<uint4*>(&Bl[r * GKP + cv]) = *reinterpret_cast<const uint4*>(Bl_ + (size_t)(n0 + r) * 256 + kt + cv);
    }
    __syncthreads();
    bf16x8 afh[4], afl[4], bfh[4], bfl[4];
#pragma unroll
    for (int m = 0; m < 4; ++m) {
      int o = (wr * 64 + m * 16 + (lane & 15)) * GKP + (lane >> 4) * 8;
      afh[m] = *reinterpret_cast<const bf16x8*>(&Ah[o]);
      afl[m] = *reinterpret_cast<const bf16x8*>(&Al[o]);
    }
#pragma unroll
    for (int n = 0; n < 4; ++n) {
      int o = (wc * 64 + n * 16 + (lane & 15)) * GKP + (lane >> 4) * 8;
      bfh[n] = *reinterpret_cast<const bf16x8*>(&Bh[o]);
      bfl[n] = *reinterpret_cast<const bf16x8*>(&Bl[o]);
    }
#pragma unroll
    for (int m = 0; m < 4; ++m)
#pragma unroll
      for (int n = 0; n < 4; ++n) {
        acc[m][n] = __builtin_amdgcn_mfma_f32_16x16x32_bf16(afh[m], bfh[n], acc[m][n], 0, 0, 0);
        acc[m][n] = __builtin_amdgcn_mfma_f32_16x16x32_bf16(afh[m], bfl[n], acc[m][n], 0, 0, 0);
        acc[m][n] = __builtin_amdgcn_mfma_f32_16x16x32_bf16(afl[m], bfh[n], acc[m][n], 0, 0, 0);
      }
  }
#pragma unroll
  for (int m = 0; m < 4; ++m) {
    int row_b = m0 + wr * 64 + m * 16 + (lane >> 4) * 4;
#pragma unroll
    for (int n = 0; n < 4; ++n) {
      int col = n0 + wc * 64 + n * 16 + (lane & 15);
      float bb = bias[col];
#pragma unroll
      for (int r = 0; r < 4; ++r) {
        size_t o = (size_t)(row_b + r) * 512 + col;
        u16 h, l;
        split2(acc[m][n][r] + bb, h, l);
        Ch[o] = h; Cl[o] = l;
      }
    }
  }
}

// ---------------- V projection, transposed output: Vt[b,d,n] ----------------
__global__ __launch_bounds__(256) void gemm_vt(
    const u16* __restrict__ WvH_, const u16* __restrict__ WvL_,
    const u16* __restrict__ XtbH, const float* __restrict__ bv,
    u16* __restrict__ Vt) {
  __shared__ u16 Ah[128 * GKP], Al[128 * GKP], Bh[128 * GKP];
  const int tid = threadIdx.x;
  const int lane = tid & 63, wid = tid >> 6;
  const int wr = wid >> 1, wc = wid & 1;
  const int b = blockIdx.z;
  const int m0 = blockIdx.y * 128, n0 = blockIdx.x * 128;
  const u16* Bp = XtbH + (size_t)b * 1024 * 256;

  f32x4 acc[4][4] = {};
  for (int kt = 0; kt < 256; kt += 32) {
    __syncthreads();
#pragma unroll
    for (int i = 0; i < 2; ++i) {
      int idx = tid + i * 256;
      int r = idx >> 2, cv = (idx & 3) * 8;
      *reinterpret_cast<uint4*>(&Ah[r * GKP + cv]) = *reinterpret_cast<const uint4*>(WvH_ + (size_t)(m0 + r) * 256 + kt + cv);
      *reinterpret_cast<uint4*>(&Al[r * GKP + cv]) = *reinterpret_cast<const uint4*>(WvL_ + (size_t)(m0 + r) * 256 + kt + cv);
      *reinterpret_cast<uint4*>(&Bh[r * GKP + cv]) = *reinterpret_cast<const uint4*>(Bp + (size_t)(n0 + r) * 256 + kt + cv);
    }
    __syncthreads();
    bf16x8 afh[4], afl[4], bfr[4];
#pragma unroll
    for (int m = 0; m < 4; ++m) {
      int o = (wr * 64 + m * 16 + (lane & 15)) * GKP + (lane >> 4) * 8;
      afh[m] = *reinterpret_cast<const bf16x8*>(&Ah[o]);
      afl[m] = *reinterpret_cast<const bf16x8*>(&Al[o]);
    }
#pragma unroll
    for (int n = 0; n < 4; ++n)
      bfr[n] = *reinterpret_cast<const bf16x8*>(&Bh[(wc * 64 + n * 16 + (lane & 15)) * GKP + (lane >> 4) * 8]);
#pragma unroll
    for (int m = 0; m < 4; ++m)
#pragma unroll
      for (int n = 0; n < 4; ++n) {
        acc[m][n] = __builtin_amdgcn_mfma_f32_16x16x32_bf16(afh[m], bfr[n], acc[m][n], 0, 0, 0);
        acc[m][n] = __builtin_amdgcn_mfma_f32_16x16x32_bf16(afl[m], bfr[n], acc[m][n], 0, 0, 0);
      }
  }
#pragma unroll
  for (int m = 0; m < 4; ++m) {
    int row_b = m0 + wr * 64 + m * 16 + (lane >> 4) * 4;  // d index
#pragma unroll
    for (int n = 0; n < 4; ++n) {
      int col = n0 + wc * 64 + n * 16 + (lane & 15);      // token n
#pragma unroll
      for (int r = 0; r < 4; ++r) {
        int row = row_b + r;
        Vt[((size_t)b * 256 + row) * 1024 + col] = f2bf(acc[m][n][r] + bv[row]);
      }
    }
  }
}

// ---------------- FFN1: A = BN(Sraw) applied in staging, PReLU epilogue -> bf16 ----------------
__global__ __launch_bounds__(256) void gemm_ffn1(
    const float* __restrict__ Sraw,
    const u16* __restrict__ B_,
    const float* __restrict__ bias,
    const float* __restrict__ aslope,
    const float* __restrict__ ss,
    u16* __restrict__ H1B) {
  __shared__ u16 As[128 * GKP], Bs[128 * GKP];
  __shared__ float ssl[512];
  const int tid = threadIdx.x;
  const int lane = tid & 63, wid = tid >> 6;
  const int wr = wid >> 1, wc = wid & 1;
  const int m0 = blockIdx.y * 128, n0 = blockIdx.x * 128;
  ssl[tid] = ss[tid];
  ssl[256 + tid] = ss[256 + tid];

  f32x4 acc[4][4] = {};
  for (int kt = 0; kt < 256; kt += 32) {
    __syncthreads();
#pragma unroll
    for (int i = 0; i < 4; ++i) {
      int idx = tid + i * 256;
      int r = idx >> 3, c4 = (idx & 7) * 4;
      float4 v = *reinterpret_cast<const float4*>(Sraw + (size_t)(m0 + r) * 256 + kt + c4);
      ushort4 o;
      o.x = f2bf(v.x * ssl[kt + c4 + 0] + ssl[256 + kt + c4 + 0]);
      o.y = f2bf(v.y * ssl[kt + c4 + 1] + ssl[256 + kt + c4 + 1]);
      o.z = f2bf(v.z * ssl[kt + c4 + 2] + ssl[256 + kt + c4 + 2]);
      o.w = f2bf(v.w * ssl[kt + c4 + 3] + ssl[256 + kt + c4 + 3]);
      *reinterpret_cast<ushort4*>(&As[r * GKP + c4]) = o;
    }
#pragma unroll
    for (int i = 0; i < 2; ++i) {
      int idx = tid + i * 256;
      int r = idx >> 2, cv = (idx & 3) * 8;
      *reinterpret_cast<uint4*>(&Bs[r * GKP + cv]) = *reinterpret_cast<const uint4*>(B_ + (size_t)(n0 + r) * 256 + kt + cv);
    }
    __syncthreads();
    bf16x8 af[4], bfr[4];
#pragma unroll
    for (int m = 0; m < 4; ++m)
      af[m] = *reinterpret_cast<const bf16x8*>(&As[(wr * 64 + m * 16 + (lane & 15)) * GKP + (lane >> 4) * 8]);
#pragma unroll
    for (int n = 0; n < 4; ++n)
      bfr[n] = *reinterpret_cast<const bf16x8*>(&Bs[(wc * 64 + n * 16 + (lane & 15)) * GKP + (lane >> 4) * 8]);
#pragma unroll
    for (int m = 0; m < 4; ++m)
#pragma unroll
      for (int n = 0; n < 4; ++n)
        acc[m][n] = __builtin_amdgcn_mfma_f32_16x16x32_bf16(af[m], bfr[n], acc[m][n], 0, 0, 0);
  }
  float a = aslope[0];
#pragma unroll
  for (int m = 0; m < 4; ++m) {
    int row_b = m0 + wr * 64 + m * 16 + (lane >> 4) * 4;
#pragma unroll
    for (int n = 0; n < 4; ++n) {
      int col = n0 + wc * 64 + n * 16 + (lane & 15);
      float bb = bias[col];
#pragma unroll
      for (int r = 0; r < 4; ++r) {
        float v = acc[m][n][r] + bb;
        v = (v >= 0.f) ? v : a * v;
        H1B[(size_t)(row_b + r) * 1024 + col] = f2bf(v);
      }
    }
  }
}

// ---------------- FFN2: bias + BN1(resid) epilogue -> f32, fused BN2 stats ----------------
__global__ __launch_bounds__(256) void gemm_ffn2(
    const u16* __restrict__ A_,
    const u16* __restrict__ B_,
    const float* __restrict__ bias,
    const float* __restrict__ Sraw,
    const float* __restrict__ ss,
    float* __restrict__ T2,
    float* __restrict__ stats2) {
  __shared__ u16 As[128 * GKP], Bs[128 * GKP];
  __shared__ float sred[2][128];
  const int tid = threadIdx.x;
  const int lane = tid & 63, wid = tid >> 6;
  const int wr = wid >> 1, wc = wid & 1;
  const int m0 = blockIdx.y * 128, n0 = blockIdx.x * 128;
  if (tid < 128) { sred[0][tid] = 0.f; sred[1][tid] = 0.f; }

  f32x4 acc[4][4] = {};
  for (int kt = 0; kt < 1024; kt += 32) {
    __syncthreads();
#pragma unroll
    for (int i = 0; i < 2; ++i) {
      int idx = tid + i * 256;
      int r = idx >> 2, cv = (idx & 3) * 8;
      *reinterpret_cast<uint4*>(&As[r * GKP + cv]) = *reinterpret_cast<const uint4*>(A_ + (size_t)(m0 + r) * 1024 + kt + cv);
      *reinterpret_cast<uint4*>(&Bs[r * GKP + cv]) = *reinterpret_cast<const uint4*>(B_ + (size_t)(n0 + r) * 1024 + kt + cv);
    }
    __syncthreads();
    bf16x8 af[4], bfr[4];
#pragma unroll
    for (int m = 0; m < 4; ++m)
      af[m] = *reinterpret_cast<const bf16x8*>(&As[(wr * 64 + m * 16 + (lane & 15)) * GKP + (lane >> 4) * 8]);
#pragma unroll
    for (int n = 0; n < 4; ++n)
      bfr[n] = *reinterpret_cast<const bf16x8*>(&Bs[(wc * 64 + n * 16 + (lane & 15)) * GKP + (lane >> 4) * 8]);
#pragma unroll
    for (int m = 0; m < 4; ++m)
#pragma unroll
      for (int n = 0; n < 4; ++n)
        acc[m][n] = __builtin_amdgcn_mfma_f32_16x16x32_bf16(af[m], bfr[n], acc[m][n], 0, 0, 0);
  }
  float s1a[4] = {0.f, 0.f, 0.f, 0.f}, s2a[4] = {0.f, 0.f, 0.f, 0.f};
#pragma unroll
  for (int m = 0; m < 4; ++m) {
    int row_b = m0 + wr * 64 + m * 16 + (lane >> 4) * 4;
#pragma unroll
    for (int n = 0; n < 4; ++n) {
      int col = n0 + wc * 64 + n * 16 + (lane & 15);
      float bb = bias[col];
      float sc_ = ss[col], of_ = ss[256 + col];
#pragma unroll
      for (int r = 0; r < 4; ++r) {
        int row = row_b + r;
        float resid = Sraw[(size_t)row * 256 + col] * sc_ + of_;
        float v = acc[m][n][r] + bb + resid;
        T2[(size_t)row * 256 + col] = v;
        s1a[n] += v;
        s2a[n] += v * v;
      }
    }
  }
#pragma unroll
  for (int n = 0; n < 4; ++n) {
    float a1 = s1a[n];
    a1 += __shfl_xor(a1, 16, 64);
    a1 += __shfl_xor(a1, 32, 64);
    float a2 = s2a[n];
    a2 += __shfl_xor(a2, 16, 64);
    a2 += __shfl_xor(a2, 32, 64);
    if (lane < 16) {
      atomicAdd(&sred[0][wc * 64 + n * 16 + lane], a1);
      atomicAdd(&sred[1][wc * 64 + n * 16 + lane], a2);
    }
  }
  __syncthreads();
  if (tid < 128) {
    atomicAdd(&stats2[n0 + tid], sred[0][tid]);
    atomicAdd(&stats2[256 + n0 + tid], sred[1][tid]);
  }
}

// ---------------- fused flash attention: swapped QK^T, in-register softmax/P ----------------
// grid (64, 8): x = hb (h = hb&3, b = hb>>2) -> same-XCD grouping of a (b,h)'s q-chunks.
// LDS: 3 x dbuf x [64][64] u16 unpadded, XOR-swizzled -> 48.5KB -> 3 blocks/CU.
#define SWZ(row, bcol) ((bcol) ^ (((row) & 7) << 4))
__global__ __launch_bounds__(512, 6) void attn_kernel(const u16* __restrict__ QKh,
                                                      const u16* __restrict__ QKl,
                                                      const u16* __restrict__ Vt,
                                                      const float* __restrict__ XtF,
                                                      float* __restrict__ Sout,
                                                      float* __restrict__ stats) {
  __shared__ u16 Kh[2][4096], Kl[2][4096], Vs[2][4096];
  __shared__ float sred[2][64];
  const int tid = threadIdx.x, lane = tid & 63, w = tid >> 6;
  const int hb = blockIdx.x, h = hb & 3, b = hb >> 2;
  const size_t tb = (size_t)b * 1024;
  const int qrow0 = blockIdx.y * 128 + w * 16;
  const int q = lane & 15, G = lane >> 4;

  if (tid < 64) { sred[0][tid] = 0.f; sred[1][tid] = 0.f; }

  // Q fragments in registers (hi/lo); B-operand layout: row = q = lane&15
  bf16x8 qh[2], ql[2];
#pragma unroll
  for (int kk = 0; kk < 2; ++kk) {
    size_t ro = (tb + qrow0 + q) * 512 + h * 64 + kk * 32 + G * 8;
    qh[kk] = *reinterpret_cast<const bf16x8*>(QKh + ro);
    ql[kk] = *reinterpret_cast<const bf16x8*>(QKl + ro);
  }

  f32x4 oacc[4] = {};
  float mprev = -3e38f, lsum = 0.f;   // per-lane: q-row = lane&15 (partial over this lane's k's)

  // staging: thread -> (row sr, 16B slot), swizzled destination
  const int sr = tid >> 3;
  const int scb = (tid & 7) << 4;                // byte col
  const int dstb = sr * 128 + SWZ(sr, scb);      // byte offset within [64][64] u16 tile
  const size_t kbase = (tb + sr) * 512 + 256 + h * 64 + (scb >> 1);
  const size_t vbase = ((size_t)b * 256 + h * 64 + sr) * 1024 + (scb >> 1);

  // prologue: stage tile 0 into buf 0
  uint4 rkh = *reinterpret_cast<const uint4*>(QKh + kbase);
  uint4 rkl = *reinterpret_cast<const uint4*>(QKl + kbase);
  uint4 rv  = *reinterpret_cast<const uint4*>(Vt + vbase);
  *reinterpret_cast<uint4*>((char*)Kh[0] + dstb) = rkh;
  *reinterpret_cast<uint4*>((char*)Kl[0] + dstb) = rkl;
  *reinterpret_cast<uint4*>((char*)Vs[0] + dstb) = rv;
  __syncthreads();

  const int src0 = q + 32 * (G & 1);
  const int src1 = src0 + 16;
  const int nhi = G >> 1;

  int cur = 0;
  for (int kt = 0; kt < 16; ++kt) {
    // issue next tile's global loads early (hide under compute)
    if (kt < 15) {
      rkh = *reinterpret_cast<const uint4*>(QKh + kbase + (size_t)(kt + 1) * 32768);
      rkl = *reinterpret_cast<const uint4*>(QKl + kbase + (size_t)(kt + 1) * 32768);
      rv  = *reinterpret_cast<const uint4*>(Vt + vbase + (size_t)(kt + 1) * 64);
    }

    // QK^T swapped: sc[n] = mfma(K_n, Q) -> lane holds q=lane&15, k-tokens {16n+4G+r}
    f32x4 sc[4] = {};
    __builtin_amdgcn_s_setprio(1);
#pragma unroll
    for (int kk = 0; kk < 2; ++kk)
#pragma unroll
      for (int n = 0; n < 4; ++n) {
        int krow = n * 16 + q;
        int kb_ = krow * 128 + SWZ(krow, kk * 64 + G * 16);
        bf16x8 akh = *reinterpret_cast<const bf16x8*>((const char*)Kh[cur] + kb_);
        bf16x8 akl = *reinterpret_cast<const bf16x8*>((const char*)Kl[cur] + kb_);
        sc[n] = __builtin_amdgcn_mfma_f32_16x16x32_bf16(akh, qh[kk], sc[n], 0, 0, 0);
        sc[n] = __builtin_amdgcn_mfma_f32_16x16x32_bf16(akl, qh[kk], sc[n], 0, 0, 0);
        sc[n] = __builtin_amdgcn_mfma_f32_16x16x32_bf16(akh, ql[kk], sc[n], 0, 0, 0);
      }
    __builtin_amdgcn_s_setprio(0);

    // row max: in-lane tree over 16, then xor 16/32 across the 4 lane-groups
    float vm;
    {
      float a0 = fmaxf(fmaxf(sc[0][0], sc[0][1]), fmaxf(sc[0][2], sc[0][3]));
      float a1 = fmaxf(fmaxf(sc[1][0], sc[1][1]), fmaxf(sc[1][2], sc[1][3]));
      float a2 = fmaxf(fmaxf(sc[2][0], sc[2][1]), fmaxf(sc[2][2], sc[2][3]));
      float a3 = fmaxf(fmaxf(sc[3][0], sc[3][1]), fmaxf(sc[3][2], sc[3][3]));
      vm = fmaxf(fmaxf(a0, a1), fmaxf(a2, a3));
      vm = fmaxf(vm, __shfl_xor(vm, 16, 64));
      vm = fmaxf(vm, __shfl_xor(vm, 32, 64));
    }
    // defer-max (THR=8)
    bool ok = (vm <= mprev + 8.f);
    if (!__all(ok)) {
      float mn = fmaxf(mprev, vm);
      float scl = __expf(mprev - mn);
      mprev = mn;
      lsum *= scl;
      float sclr[4];
#pragma unroll
      for (int r = 0; r < 4; ++r) sclr[r] = __shfl(scl, G * 4 + r, 64);
#pragma unroll
      for (int dn = 0; dn < 4; ++dn)
#pragma unroll
        for (int r = 0; r < 4; ++r) oacc[dn][r] *= sclr[r];
    }
    // exp + per-lane partial row sum (lsum reduced only at epilogue)
    float lt = 0.f;
#pragma unroll
    for (int n = 0; n < 4; ++n)
#pragma unroll
      for (int r = 0; r < 4; ++r) {
        float p = __expf(sc[n][r] - mprev);
        sc[n][r] = p;
        lt += p;
      }
    lsum += lt;
    // pack P to bf16 pairs: pk0[n] = (r0,r1), pk1[n] = (r2,r3)
    u32 pk0[4], pk1[4];
#pragma unroll
    for (int n = 0; n < 4; ++n) {
      pk0[n] = cvt_pk_bf16(sc[n][0], sc[n][1]);
      pk1[n] = cvt_pk_bf16(sc[n][2], sc[n][3]);
    }
    // in-register P -> A-fragment shuffle network
    // lane (q,G) needs tokens kk*32+8G+{0..7}: n = 2kk+(G>>1), from lanes g=2(G&1), 2(G&1)+1
    bf16x8 pa[2];
#pragma unroll
    for (int kk = 0; kk < 2; ++kk) {
      int n_lo = 2 * kk, n_hi = 2 * kk + 1;
      u32 c0a = (u32)__shfl((int)pk0[n_lo], src0, 64);
      u32 c0b = (u32)__shfl((int)pk0[n_hi], src0, 64);
      u32 c1a = (u32)__shfl((int)pk1[n_lo], src0, 64);
      u32 c1b = (u32)__shfl((int)pk1[n_hi], src0, 64);
      u32 c2a = (u32)__shfl((int)pk0[n_lo], src1, 64);
      u32 c2b = (u32)__shfl((int)pk0[n_hi], src1, 64);
      u32 c3a = (u32)__shfl((int)pk1[n_lo], src1, 64);
      u32 c3b = (u32)__shfl((int)pk1[n_hi], src1, 64);
      uint4 pw;
      pw.x = nhi ? c0b : c0a;
      pw.y = nhi ? c1b : c1a;
      pw.z = nhi ? c2b : c2a;
      pw.w = nhi ? c3b : c3a;
      pa[kk] = *reinterpret_cast<bf16x8*>(&pw);
    }
    // PV: oacc = mfma(P, V) -> rows q' = G*4+r, cols d = lane&15
    __builtin_amdgcn_s_setprio(1);
#pragma unroll
    for (int kk = 0; kk < 2; ++kk)
#pragma unroll
      for (int dn = 0; dn < 4; ++dn) {
        int vrow = dn * 16 + q;
        int vb_ = vrow * 128 + SWZ(vrow, kk * 64 + G * 16);
        bf16x8 vv = *reinterpret_cast<const bf16x8*>((const char*)Vs[cur] + vb_);
        oacc[dn] = __builtin_amdgcn_mfma_f32_16x16x32_bf16(pa[kk], vv, oacc[dn], 0, 0, 0);
      }
    __builtin_amdgcn_s_setprio(0);
    // write next tile to the other buffer, then one barrier
    if (kt < 15) {
      *reinterpret_cast<uint4*>((char*)Kh[cur ^ 1] + dstb) = rkh;
      *reinterpret_cast<uint4*>((char*)Kl[cur ^ 1] + dstb) = rkl;
      *reinterpret_cast<uint4*>((char*)Vs[cur ^ 1] + dstb) = rv;
    }
    __syncthreads();
    cur ^= 1;
  }
  // full row-sums: reduce per-lane partials across the 4 lane-groups, redistribute to oacc rows
  float lf = lsum;
  lf += __shfl_xor(lf, 16, 64);
  lf += __shfl_xor(lf, 32, 64);
  float rinv[4];
#pragma unroll
  for (int r = 0; r < 4; ++r) rinv[r] = 1.f / __shfl(lf, G * 4 + r, 64);

  // epilogue: O/l + residual x, fused BN1 stats
  float s1a[4] = {0.f, 0.f, 0.f, 0.f}, s2a[4] = {0.f, 0.f, 0.f, 0.f};
#pragma unroll
  for (int dn = 0; dn < 4; ++dn)
#pragma unroll
    for (int r = 0; r < 4; ++r) {
      int row = qrow0 + G * 4 + r;
      int col = h * 64 + dn * 16 + q;
      size_t gi = (tb + row) * 256 + col;
      float v = oacc[dn][r] * rinv[r] + XtF[gi];
      Sout[gi] = v;
      s1a[dn] += v;
      s2a[dn] += v * v;
    }
#pragma unroll
  for (int dn = 0; dn < 4; ++dn) {
    float a1 = s1a[dn];
    a1 += __shfl_xor(a1, 16, 64);
    a1 += __shfl_xor(a1, 32, 64);
    float a2 = s2a[dn];
    a2 += __shfl_xor(a2, 16, 64);
    a2 += __shfl_xor(a2, 32, 64);
    if (lane < 16) {
      atomicAdd(&sred[0][dn * 16 + lane], a1);
      atomicAdd(&sred[1][dn * 16 + lane], a2);
    }
  }
  __syncthreads();
  if (tid < 64) {
    atomicAdd(&stats[h * 64 + tid], sred[0][tid]);
    atomicAdd(&stats[256 + h * 64 + tid], sred[1][tid]);
  }
}

// ---------------- BN finalize ----------------
__global__ void bn_finalize(const float* __restrict__ stats, const float* __restrict__ gamma,
                            const float* __restrict__ beta, float* __restrict__ ss) {
  int c = threadIdx.x;
  float mean = stats[c] * (1.f / 16384.f);
  float var = stats[256 + c] * (1.f / 16384.f) - mean * mean;
  float rstd = rsqrtf(var + 1e-5f);
  float scg = gamma[c] * rstd;
  ss[c] = scg;
  ss[256 + c] = beta[c] - mean * scg;
}

// final BN + transpose [T,C] -> [B,C,N]
__global__ __launch_bounds__(256) void bn_final_out(const float* __restrict__ T2,
                                                    const float* __restrict__ ss,
                                                    float* __restrict__ out) {
  __shared__ float tile[32][33];
  int n0 = (blockIdx.x & 31) * 32;
  int b = blockIdx.x >> 5;
  int c0 = blockIdx.y * 32;
  int tx = threadIdx.x, ty = threadIdx.y;
#pragma unroll
  for (int j = 0; j < 4; ++j) {
    int r = ty + j * 8;
    int c = c0 + tx;
    float v = T2[((size_t)b * 1024 + n0 + r) * 256 + c];
    tile[r][tx] = v * ss[c] + ss[256 + c];
  }
  __syncthreads();
#pragma unroll
  for (int j = 0; j < 4; ++j) {
    int c = c0 + ty + j * 8;
    out[((size_t)b * 256 + c) * 1024 + n0 + tx] = tile[tx][ty + j * 8];
  }
}

// ---------------- launch ----------------
extern "C" void kernel_launch(void* const* d_in, const int* in_sizes, int n_in,
                              void* d_out, int out_size, void* d_ws, size_t ws_size,
                              hipStream_t stream) {
  const float* x = (const float*)d_in[0];
  const float* Wq = (const float*)d_in[1];
  const float* bq = (const float*)d_in[2];
  const float* Wk = (const float*)d_in[3];
  const float* bk = (const float*)d_in[4];
  const float* Wv = (const float*)d_in[5];
  const float* bv = (const float*)d_in[6];
  const float* gamma = (const float*)d_in[7];
  const float* beta = (const float*)d_in[8];
  const float* W1 = (const float*)d_in[9];
  const float* b1 = (const float*)d_in[10];
  const float* a = (const float*)d_in[11];
  const float* W2 = (const float*)d_in[12];
  const float* b2 = (const float*)d_in[13];
  float* out = (float*)d_out;

  char* wsb = (char*)d_ws;
  const size_t MB = 1ull << 20;
  u16* XtbH = (u16*)(wsb + 0 * MB);       // 8MB
  u16* XtbL = (u16*)(wsb + 8 * MB);       // 8MB
  float* XtF = (float*)(wsb + 16 * MB);   // 16MB; aliased by T2 after attn
  u16* QKh = (u16*)(wsb + 32 * MB);       // 16MB; aliased by H1B (32MB) after attn
  u16* QKl = (u16*)(wsb + 48 * MB);       // 16MB
  u16* Vt = (u16*)(wsb + 64 * MB);        // 8MB
  char* wp = wsb + 72 * MB;
  u16* WallH = (u16*)(wp);                // 256KB
  u16* WallL = (u16*)(wp + 262144);       // 256KB
  u16* WvH = (u16*)(wp + 524288);         // 128KB
  u16* WvL = (u16*)(wp + 655360);         // 128KB
  u16* W1b = (u16*)(wp + 786432);         // 512KB
  u16* W2b = (u16*)(wp + 1310720);        // 512KB
  float* bqk = (float*)(wp + 1835008);    // 2KB
  float* stats = (float*)(wp + 1837056);  // 8KB: stats1|ss1|stats2|ss2
  if (ws_size < 75 * MB) return;

  float* T2 = XtF;   // [T,256] f32, after attn
  u16* H1B = QKh;    // [T,1024] bf16, after attn
  float* S = out;    // d_out doubles as o+x raw residual buffer [T,256]

  hipMemsetAsync(stats, 0, 8192, stream);
  transpose_x<<<dim3(32, 8, 16), dim3(32, 8), 0, stream>>>(x, XtF, XtbH, XtbL);
  prep_weights<<<1024, 256, 0, stream>>>(Wq, Wk, Wv, bq, bk, W1, W2,
                                         WallH, WallL, WvH, WvL, W1b, W2b, bqk);
  // QK projection: [16384,256] x [512,256]^T -> QKh/QKl [16384,512]
  gemm_qk<<<dim3(4, 128), 256, 0, stream>>>(XtbH, XtbL, WallH, WallL, bqk, QKh, QKl);
  // V projection transposed: per batch [256,256] x [1024,256]^T -> Vt[b,256,1024]
  gemm_vt<<<dim3(8, 2, 16), 256, 0, stream>>>(WvH, WvL, XtbH, bv, Vt);
  // attention + residual + BN1 stats: grid (hb, qc) for XCD-local K/V reuse
  attn_kernel<<<dim3(64, 8), 512, 0, stream>>>(QKh, QKl, Vt, XtF, S, stats);
  bn_finalize<<<1, 256, 0, stream>>>(stats, gamma, beta, stats + 512);
  // FFN1: A = BN1(S) on the fly -> H1B bf16, bias+PReLU
  gemm_ffn1<<<dim3(8, 128), 256, 0, stream>>>(S, W1b, b1, a, stats + 512, H1B);
  // FFN2: [16384,1024] x [256,1024]^T -> T2 f32, bias + BN1(S) resid + BN2 stats
  gemm_ffn2<<<dim3(2, 128), 256, 0, stream>>>(H1B, W2b, b2, S, stats + 512, T2, stats + 1024);
  bn_finalize<<<1, 256, 0, stream>>>(stats + 1024, gamma, beta, stats + 1536);
  // BN2 apply + transpose out
  bn_final_out<<<dim3(512, 8), dim3(32, 8), 0, stream>>>(T2, stats + 1536, out);
}

// Round 7
// 170.063 us; speedup vs baseline: 1.7953x; 1.0924x over previous
//
#include <hip/hip_runtime.h>
#include <hip/hip_bf16.h>

typedef unsigned short u16;
typedef unsigned int u32;
typedef __attribute__((ext_vector_type(8))) __bf16 bf16x8;
typedef __attribute__((ext_vector_type(4))) float f32x4;

__device__ inline u16 f2bf(float f) {
  unsigned int x = __float_as_uint(f);
  unsigned int r = (x + 0x7FFFu + ((x >> 16) & 1u)) >> 16;
  return (u16)r;
}
__device__ inline float bf2f(u16 u) { return __uint_as_float(((unsigned int)u) << 16); }
__device__ inline void split2(float v, u16& h, u16& l) {
  h = f2bf(v);
  l = f2bf(v - bf2f(h));
}
__device__ inline u32 cvt_pk_bf16(float lo, float hi) {
  u32 r;
  asm("v_cvt_pk_bf16_f32 %0, %1, %2" : "=v"(r) : "v"(lo), "v"(hi));
  return r;
}

// ---------------- x transpose: [B,C,N] f32 -> [B,N,C] f32 + bf16 hi/lo ----------------
__global__ __launch_bounds__(256) void transpose_x(const float* __restrict__ x,
                                                   float* __restrict__ XtF,
                                                   u16* __restrict__ XtbH,
                                                   u16* __restrict__ XtbL) {
  __shared__ float tile[32][33];
  int n0 = blockIdx.x * 32;
  int c0 = blockIdx.y * 32;
  int b  = blockIdx.z;
  int tx = threadIdx.x, ty = threadIdx.y;
#pragma unroll
  for (int j = 0; j < 4; ++j) {
    int c = c0 + ty + j * 8;
    tile[ty + j * 8][tx] = x[((size_t)b * 256 + c) * 1024 + n0 + tx];
  }
  __syncthreads();
#pragma unroll
  for (int j = 0; j < 4; ++j) {
    int n = n0 + ty + j * 8;
    float v = tile[tx][ty + j * 8];
    size_t o = ((size_t)b * 1024 + n) * 256 + c0 + tx;
    XtF[o] = v;
    u16 h, l;
    split2(v, h, l);
    XtbH[o] = h; XtbL[o] = l;
  }
}

// ---------------- weight prep ----------------
__global__ __launch_bounds__(256) void prep_weights(
    const float* __restrict__ Wq, const float* __restrict__ Wk, const float* __restrict__ Wv,
    const float* __restrict__ bq, const float* __restrict__ bk,
    const float* __restrict__ W1, const float* __restrict__ W2,
    u16* __restrict__ WallH, u16* __restrict__ WallL,
    u16* __restrict__ WvH, u16* __restrict__ WvL,
    u16* __restrict__ W1b, u16* __restrict__ W2b,
    float* __restrict__ bqk) {
  int i = blockIdx.x * 256 + threadIdx.x;
  if (i < 131072) {
    float w = (i < 65536) ? Wq[i] : Wk[i - 65536];
    u16 h, l;
    split2(w, h, l);
    WallH[i] = h; WallL[i] = l;
  }
  if (i < 65536) {
    u16 h, l;
    split2(Wv[i], h, l);
    WvH[i] = h; WvL[i] = l;
  }
  if (i < 262144) { W1b[i] = f2bf(W1[i]); W2b[i] = f2bf(W2[i]); }
  if (i < 256) bqk[i] = bq[i];
  else if (i < 512) bqk[i] = bk[i - 256];
}

#define GKP 40

// ---------------- QK projection GEMM (3-term hi/lo), out split bf16 ----------------
__global__ __launch_bounds__(256) void gemm_qk(
    const u16* __restrict__ Ah_, const u16* __restrict__ Al_,
    const u16* __restrict__ Bh_, const u16* __restrict__ Bl_,
    const float* __restrict__ bias,
    u16* __restrict__ Ch, u16* __restrict__ Cl) {
  __shared__ u16 Ah[128 * GKP], Al[128 * GKP], Bh[128 * GKP], Bl[128 * GKP];
  const int tid = threadIdx.x;
  const int lane = tid & 63, wid = tid >> 6;
  const int wr = wid >> 1, wc = wid & 1;
  const int m0 = blockIdx.y * 128, n0 = blockIdx.x * 128;

  f32x4 acc[4][4] = {};
  for (int kt = 0; kt < 256; kt += 32) {
    __syncthreads();
#pragma unroll
    for (int i = 0; i < 2; ++i) {
      int idx = tid + i * 256;
      int r = idx >> 2, cv = (idx & 3) * 8;
      *reinterpret_cast<uint4*>(&Ah[r * GKP + cv]) = *reinterpret_cast<const uint4*>(Ah_ + (size_t)(m0 + r) * 256 + kt + cv);
      *reinterpret_cast<uint4*>(&Al[r * GKP + cv]) = *reinterpret_cast<const uint4*>(Al_ + (size_t)(m0 + r) * 256 + kt + cv);
      *reinterpret_cast<uint4*>(&Bh[r * GKP + cv]) = *reinterpret_cast<const uint4*>(Bh_ + (size_t)(n0 + r) * 256 + kt + cv);
      *reinterpret_cast<uint4*>(&Bl[r * GKP + cv]) = *reinterpret_cast<const uint4*>(Bl_ + (size_t)(n0 + r) * 256 + kt + cv);
    }
    __syncthreads();
    bf16x8 afh[4], afl[4], bfh[4], bfl[4];
#pragma unroll
    for (int m = 0; m < 4; ++m) {
      int o = (wr * 64 + m * 16 + (lane & 15)) * GKP + (lane >> 4) * 8;
      afh[m] = *reinterpret_cast<const bf16x8*>(&Ah[o]);
      afl[m] = *reinterpret_cast<const bf16x8*>(&Al[o]);
    }
#pragma unroll
    for (int n = 0; n < 4; ++n) {
      int o = (wc * 64 + n * 16 + (lane & 15)) * GKP + (lane >> 4) * 8;
      bfh[n] = *reinterpret_cast<const bf16x8*>(&Bh[o]);
      bfl[n] = *reinterpret_cast<const bf16x8*>(&Bl[o]);
    }
#pragma unroll
    for (int m = 0; m < 4; ++m)
#pragma unroll
      for (int n = 0; n < 4; ++n) {
        acc[m][n] = __builtin_amdgcn_mfma_f32_16x16x32_bf16(afh[m], bfh[n], acc[m][n], 0, 0, 0);
        acc[m][n] = __builtin_amdgcn_mfma_f32_16x16x32_bf16(afh[m], bfl[n], acc[m][n], 0, 0, 0);
        acc[m][n] = __builtin_amdgcn_mfma_f32_16x16x32_bf16(afl[m], bfh[n], acc[m][n], 0, 0, 0);
      }
  }
#pragma unroll
  for (int m = 0; m < 4; ++m) {
    int row_b = m0 + wr * 64 + m * 16 + (lane >> 4) * 4;
#pragma unroll
    for (int n = 0; n < 4; ++n) {
      int col = n0 + wc * 64 + n * 16 + (lane & 15);
      float bb = bias[col];
#pragma unroll
      for (int r = 0; r < 4; ++r) {
        size_t o = (size_t)(row_b + r) * 512 + col;
        u16 h, l;
        split2(acc[m][n][r] + bb, h, l);
        Ch[o] = h; Cl[o] = l;
      }
    }
  }
}

// ---------------- V projection, transposed output: Vt[b,d,n] ----------------
__global__ __launch_bounds__(256) void gemm_vt(
    const u16* __restrict__ WvH_, const u16* __restrict__ WvL_,
    const u16* __restrict__ XtbH, const float* __restrict__ bv,
    u16* __restrict__ Vt) {
  __shared__ u16 Ah[128 * GKP], Al[128 * GKP], Bh[128 * GKP];
  const int tid = threadIdx.x;
  const int lane = tid & 63, wid = tid >> 6;
  const int wr = wid >> 1, wc = wid & 1;
  const int b = blockIdx.z;
  const int m0 = blockIdx.y * 128, n0 = blockIdx.x * 128;
  const u16* Bp = XtbH + (size_t)b * 1024 * 256;

  f32x4 acc[4][4] = {};
  for (int kt = 0; kt < 256; kt += 32) {
    __syncthreads();
#pragma unroll
    for (int i = 0; i < 2; ++i) {
      int idx = tid + i * 256;
      int r = idx >> 2, cv = (idx & 3) * 8;
      *reinterpret_cast<uint4*>(&Ah[r * GKP + cv]) = *reinterpret_cast<const uint4*>(WvH_ + (size_t)(m0 + r) * 256 + kt + cv);
      *reinterpret_cast<uint4*>(&Al[r * GKP + cv]) = *reinterpret_cast<const uint4*>(WvL_ + (size_t)(m0 + r) * 256 + kt + cv);
      *reinterpret_cast<uint4*>(&Bh[r * GKP + cv]) = *reinterpret_cast<const uint4*>(Bp + (size_t)(n0 + r) * 256 + kt + cv);
    }
    __syncthreads();
    bf16x8 afh[4], afl[4], bfr[4];
#pragma unroll
    for (int m = 0; m < 4; ++m) {
      int o = (wr * 64 + m * 16 + (lane & 15)) * GKP + (lane >> 4) * 8;
      afh[m] = *reinterpret_cast<const bf16x8*>(&Ah[o]);
      afl[m] = *reinterpret_cast<const bf16x8*>(&Al[o]);
    }
#pragma unroll
    for (int n = 0; n < 4; ++n)
      bfr[n] = *reinterpret_cast<const bf16x8*>(&Bh[(wc * 64 + n * 16 + (lane & 15)) * GKP + (lane >> 4) * 8]);
#pragma unroll
    for (int m = 0; m < 4; ++m)
#pragma unroll
      for (int n = 0; n < 4; ++n) {
        acc[m][n] = __builtin_amdgcn_mfma_f32_16x16x32_bf16(afh[m], bfr[n], acc[m][n], 0, 0, 0);
        acc[m][n] = __builtin_amdgcn_mfma_f32_16x16x32_bf16(afl[m], bfr[n], acc[m][n], 0, 0, 0);
      }
  }
#pragma unroll
  for (int m = 0; m < 4; ++m) {
    int row_b = m0 + wr * 64 + m * 16 + (lane >> 4) * 4;  // d index
#pragma unroll
    for (int n = 0; n < 4; ++n) {
      int col = n0 + wc * 64 + n * 16 + (lane & 15);      // token n
#pragma unroll
      for (int r = 0; r < 4; ++r) {
        int row = row_b + r;
        Vt[((size_t)b * 256 + row) * 1024 + col] = f2bf(acc[m][n][r] + bv[row]);
      }
    }
  }
}

// ---------------- FFN1: A = BN(Sraw) applied in staging, PReLU epilogue -> bf16 ----------------
__global__ __launch_bounds__(256) void gemm_ffn1(
    const float* __restrict__ Sraw,
    const u16* __restrict__ B_,
    const float* __restrict__ bias,
    const float* __restrict__ aslope,
    const float* __restrict__ ss,
    u16* __restrict__ H1B) {
  __shared__ u16 As[128 * GKP], Bs[128 * GKP];
  __shared__ float ssl[512];
  const int tid = threadIdx.x;
  const int lane = tid & 63, wid = tid >> 6;
  const int wr = wid >> 1, wc = wid & 1;
  const int m0 = blockIdx.y * 128, n0 = blockIdx.x * 128;
  ssl[tid] = ss[tid];
  ssl[256 + tid] = ss[256 + tid];

  f32x4 acc[4][4] = {};
  for (int kt = 0; kt < 256; kt += 32) {
    __syncthreads();
#pragma unroll
    for (int i = 0; i < 4; ++i) {
      int idx = tid + i * 256;
      int r = idx >> 3, c4 = (idx & 7) * 4;
      float4 v = *reinterpret_cast<const float4*>(Sraw + (size_t)(m0 + r) * 256 + kt + c4);
      ushort4 o;
      o.x = f2bf(v.x * ssl[kt + c4 + 0] + ssl[256 + kt + c4 + 0]);
      o.y = f2bf(v.y * ssl[kt + c4 + 1] + ssl[256 + kt + c4 + 1]);
      o.z = f2bf(v.z * ssl[kt + c4 + 2] + ssl[256 + kt + c4 + 2]);
      o.w = f2bf(v.w * ssl[kt + c4 + 3] + ssl[256 + kt + c4 + 3]);
      *reinterpret_cast<ushort4*>(&As[r * GKP + c4]) = o;
    }
#pragma unroll
    for (int i = 0; i < 2; ++i) {
      int idx = tid + i * 256;
      int r = idx >> 2, cv = (idx & 3) * 8;
      *reinterpret_cast<uint4*>(&Bs[r * GKP + cv]) = *reinterpret_cast<const uint4*>(B_ + (size_t)(n0 + r) * 256 + kt + cv);
    }
    __syncthreads();
    bf16x8 af[4], bfr[4];
#pragma unroll
    for (int m = 0; m < 4; ++m)
      af[m] = *reinterpret_cast<const bf16x8*>(&As[(wr * 64 + m * 16 + (lane & 15)) * GKP + (lane >> 4) * 8]);
#pragma unroll
    for (int n = 0; n < 4; ++n)
      bfr[n] = *reinterpret_cast<const bf16x8*>(&Bs[(wc * 64 + n * 16 + (lane & 15)) * GKP + (lane >> 4) * 8]);
#pragma unroll
    for (int m = 0; m < 4; ++m)
#pragma unroll
      for (int n = 0; n < 4; ++n)
        acc[m][n] = __builtin_amdgcn_mfma_f32_16x16x32_bf16(af[m], bfr[n], acc[m][n], 0, 0, 0);
  }
  float a = aslope[0];
#pragma unroll
  for (int m = 0; m < 4; ++m) {
    int row_b = m0 + wr * 64 + m * 16 + (lane >> 4) * 4;
#pragma unroll
    for (int n = 0; n < 4; ++n) {
      int col = n0 + wc * 64 + n * 16 + (lane & 15);
      float bb = bias[col];
#pragma unroll
      for (int r = 0; r < 4; ++r) {
        float v = acc[m][n][r] + bb;
        v = (v >= 0.f) ? v : a * v;
        H1B[(size_t)(row_b + r) * 1024 + col] = f2bf(v);
      }
    }
  }
}

// ---------------- FFN2: bias + BN1(resid) epilogue -> f32, fused BN2 stats ----------------
__global__ __launch_bounds__(256) void gemm_ffn2(
    const u16* __restrict__ A_,
    const u16* __restrict__ B_,
    const float* __restrict__ bias,
    const float* __restrict__ Sraw,
    const float* __restrict__ ss,
    float* __restrict__ T2,
    float* __restrict__ stats2) {
  __shared__ u16 As[128 * GKP], Bs[128 * GKP];
  __shared__ float sred[2][128];
  const int tid = threadIdx.x;
  const int lane = tid & 63, wid = tid >> 6;
  const int wr = wid >> 1, wc = wid & 1;
  const int m0 = blockIdx.y * 128, n0 = blockIdx.x * 128;
  if (tid < 128) { sred[0][tid] = 0.f; sred[1][tid] = 0.f; }

  f32x4 acc[4][4] = {};
  for (int kt = 0; kt < 1024; kt += 32) {
    __syncthreads();
#pragma unroll
    for (int i = 0; i < 2; ++i) {
      int idx = tid + i * 256;
      int r = idx >> 2, cv = (idx & 3) * 8;
      *reinterpret_cast<uint4*>(&As[r * GKP + cv]) = *reinterpret_cast<const uint4*>(A_ + (size_t)(m0 + r) * 1024 + kt + cv);
      *reinterpret_cast<uint4*>(&Bs[r * GKP + cv]) = *reinterpret_cast<const uint4*>(B_ + (size_t)(n0 + r) * 1024 + kt + cv);
    }
    __syncthreads();
    bf16x8 af[4], bfr[4];
#pragma unroll
    for (int m = 0; m < 4; ++m)
      af[m] = *reinterpret_cast<const bf16x8*>(&As[(wr * 64 + m * 16 + (lane & 15)) * GKP + (lane >> 4) * 8]);
#pragma unroll
    for (int n = 0; n < 4; ++n)
      bfr[n] = *reinterpret_cast<const bf16x8*>(&Bs[(wc * 64 + n * 16 + (lane & 15)) * GKP + (lane >> 4) * 8]);
#pragma unroll
    for (int m = 0; m < 4; ++m)
#pragma unroll
      for (int n = 0; n < 4; ++n)
        acc[m][n] = __builtin_amdgcn_mfma_f32_16x16x32_bf16(af[m], bfr[n], acc[m][n], 0, 0, 0);
  }
  float s1a[4] = {0.f, 0.f, 0.f, 0.f}, s2a[4] = {0.f, 0.f, 0.f, 0.f};
#pragma unroll
  for (int m = 0; m < 4; ++m) {
    int row_b = m0 + wr * 64 + m * 16 + (lane >> 4) * 4;
#pragma unroll
    for (int n = 0; n < 4; ++n) {
      int col = n0 + wc * 64 + n * 16 + (lane & 15);
      float bb = bias[col];
      float sc_ = ss[col], of_ = ss[256 + col];
#pragma unroll
      for (int r = 0; r < 4; ++r) {
        int row = row_b + r;
        float resid = Sraw[(size_t)row * 256 + col] * sc_ + of_;
        float v = acc[m][n][r] + bb + resid;
        T2[(size_t)row * 256 + col] = v;
        s1a[n] += v;
        s2a[n] += v * v;
      }
    }
  }
#pragma unroll
  for (int n = 0; n < 4; ++n) {
    float a1 = s1a[n];
    a1 += __shfl_xor(a1, 16, 64);
    a1 += __shfl_xor(a1, 32, 64);
    float a2 = s2a[n];
    a2 += __shfl_xor(a2, 16, 64);
    a2 += __shfl_xor(a2, 32, 64);
    if (lane < 16) {
      atomicAdd(&sred[0][wc * 64 + n * 16 + lane], a1);
      atomicAdd(&sred[1][wc * 64 + n * 16 + lane], a2);
    }
  }
  __syncthreads();
  if (tid < 128) {
    atomicAdd(&stats2[n0 + tid], sred[0][tid]);
    atomicAdd(&stats2[256 + n0 + tid], sred[1][tid]);
  }
}

// ---------------- fused flash attention: swapped QK^T, 2-term, in-register softmax/P --------
// grid (64, 16): x = hb (h = hb&3, b = hb>>2); id%8 = hb%8 -> XCD-local K/V.
// 4 waves x 16 q-rows = 64 rows/block; LDS 32.7KB -> 4 blocks/CU (grid: 1024 = 4/CU).
#define SWZ(row, bcol) ((bcol) ^ (((row) & 7) << 4))
__global__ __launch_bounds__(256, 4) void attn_kernel(const u16* __restrict__ QKh,
                                                      const u16* __restrict__ QKl,
                                                      const u16* __restrict__ Vt,
                                                      const float* __restrict__ XtF,
                                                      float* __restrict__ Sout,
                                                      float* __restrict__ stats) {
  __shared__ u16 Kh[2][4096], Vs[2][4096];
  __shared__ float sred[2][64];
  const int tid = threadIdx.x, lane = tid & 63, w = tid >> 6;
  const int hb = blockIdx.x, h = hb & 3, b = hb >> 2;
  const size_t tb = (size_t)b * 1024;
  const int qrow0 = blockIdx.y * 64 + w * 16;
  const int q = lane & 15, G = lane >> 4;

  if (tid < 64) { sred[0][tid] = 0.f; sred[1][tid] = 0.f; }

  // Q fragments in registers (hi/lo); B-operand layout: row = q = lane&15
  bf16x8 qh[2], ql[2];
#pragma unroll
  for (int kk = 0; kk < 2; ++kk) {
    size_t ro = (tb + qrow0 + q) * 512 + h * 64 + kk * 32 + G * 8;
    qh[kk] = *reinterpret_cast<const bf16x8*>(QKh + ro);
    ql[kk] = *reinterpret_cast<const bf16x8*>(QKl + ro);
  }

  f32x4 oacc[4] = {};
  float mprev = -3e38f, lsum = 0.f;

  // staging: 256 threads, 2 slots each per array (64 rows x 8 x 16B slots)
  int sr0 = tid >> 3, scb0 = (tid & 7) << 4;
  int sr1 = (tid + 256) >> 3, scb1 = ((tid + 256) & 7) << 4;
  const int dstb0 = sr0 * 128 + SWZ(sr0, scb0);
  const int dstb1 = sr1 * 128 + SWZ(sr1, scb1);
  const size_t kbase0 = (tb + sr0) * 512 + 256 + h * 64 + (scb0 >> 1);
  const size_t kbase1 = (tb + sr1) * 512 + 256 + h * 64 + (scb1 >> 1);
  const size_t vbase0 = ((size_t)b * 256 + h * 64 + sr0) * 1024 + (scb0 >> 1);
  const size_t vbase1 = ((size_t)b * 256 + h * 64 + sr1) * 1024 + (scb1 >> 1);

  // prologue: stage tile 0 into buf 0
  uint4 rk0 = *reinterpret_cast<const uint4*>(QKh + kbase0);
  uint4 rk1 = *reinterpret_cast<const uint4*>(QKh + kbase1);
  uint4 rv0 = *reinterpret_cast<const uint4*>(Vt + vbase0);
  uint4 rv1 = *reinterpret_cast<const uint4*>(Vt + vbase1);
  *reinterpret_cast<uint4*>((char*)Kh[0] + dstb0) = rk0;
  *reinterpret_cast<uint4*>((char*)Kh[0] + dstb1) = rk1;
  *reinterpret_cast<uint4*>((char*)Vs[0] + dstb0) = rv0;
  *reinterpret_cast<uint4*>((char*)Vs[0] + dstb1) = rv1;
  __syncthreads();

  const int src0 = q + 32 * (G & 1);
  const int src1 = src0 + 16;
  const int nhi = G >> 1;

  int cur = 0;
  for (int kt = 0; kt < 16; ++kt) {
    // issue next tile's global loads early (hide under compute)
    if (kt < 15) {
      rk0 = *reinterpret_cast<const uint4*>(QKh + kbase0 + (size_t)(kt + 1) * 32768);
      rk1 = *reinterpret_cast<const uint4*>(QKh + kbase1 + (size_t)(kt + 1) * 32768);
      rv0 = *reinterpret_cast<const uint4*>(Vt + vbase0 + (size_t)(kt + 1) * 64);
      rv1 = *reinterpret_cast<const uint4*>(Vt + vbase1 + (size_t)(kt + 1) * 64);
    }

    // QK^T swapped, 2-term (Qh*Kh + Ql*Kh): lane holds q=lane&15, k-tokens {16n+4G+r}
    f32x4 sc[4] = {};
    __builtin_amdgcn_s_setprio(1);
#pragma unroll
    for (int kk = 0; kk < 2; ++kk)
#pragma unroll
      for (int n = 0; n < 4; ++n) {
        int krow = n * 16 + q;
        int kb_ = krow * 128 + SWZ(krow, kk * 64 + G * 16);
        bf16x8 akh = *reinterpret_cast<const bf16x8*>((const char*)Kh[cur] + kb_);
        sc[n] = __builtin_amdgcn_mfma_f32_16x16x32_bf16(akh, qh[kk], sc[n], 0, 0, 0);
        sc[n] = __builtin_amdgcn_mfma_f32_16x16x32_bf16(akh, ql[kk], sc[n], 0, 0, 0);
      }
    __builtin_amdgcn_s_setprio(0);

    // row max: in-lane tree over 16, then xor 16/32 across the 4 lane-groups
    float vm;
    {
      float a0 = fmaxf(fmaxf(sc[0][0], sc[0][1]), fmaxf(sc[0][2], sc[0][3]));
      float a1 = fmaxf(fmaxf(sc[1][0], sc[1][1]), fmaxf(sc[1][2], sc[1][3]));
      float a2 = fmaxf(fmaxf(sc[2][0], sc[2][1]), fmaxf(sc[2][2], sc[2][3]));
      float a3 = fmaxf(fmaxf(sc[3][0], sc[3][1]), fmaxf(sc[3][2], sc[3][3]));
      vm = fmaxf(fmaxf(a0, a1), fmaxf(a2, a3));
      vm = fmaxf(vm, __shfl_xor(vm, 16, 64));
      vm = fmaxf(vm, __shfl_xor(vm, 32, 64));
    }
    // defer-max (THR=8)
    bool ok = (vm <= mprev + 8.f);
    if (!__all(ok)) {
      float mn = fmaxf(mprev, vm);
      float scl = __expf(mprev - mn);
      mprev = mn;
      lsum *= scl;
      float sclr[4];
#pragma unroll
      for (int r = 0; r < 4; ++r) sclr[r] = __shfl(scl, G * 4 + r, 64);
#pragma unroll
      for (int dn = 0; dn < 4; ++dn)
#pragma unroll
        for (int r = 0; r < 4; ++r) oacc[dn][r] *= sclr[r];
    }
    // exp + per-lane partial row sum
    float lt = 0.f;
#pragma unroll
    for (int n = 0; n < 4; ++n)
#pragma unroll
      for (int r = 0; r < 4; ++r) {
        float p = __expf(sc[n][r] - mprev);
        sc[n][r] = p;
        lt += p;
      }
    lsum += lt;
    // pack P to bf16 pairs
    u32 pk0[4], pk1[4];
#pragma unroll
    for (int n = 0; n < 4; ++n) {
      pk0[n] = cvt_pk_bf16(sc[n][0], sc[n][1]);
      pk1[n] = cvt_pk_bf16(sc[n][2], sc[n][3]);
    }
    // in-register P -> A-fragment shuffle network
    bf16x8 pa[2];
#pragma unroll
    for (int kk = 0; kk < 2; ++kk) {
      int n_lo = 2 * kk, n_hi = 2 * kk + 1;
      u32 c0a = (u32)__shfl((int)pk0[n_lo], src0, 64);
      u32 c0b = (u32)__shfl((int)pk0[n_hi], src0, 64);
      u32 c1a = (u32)__shfl((int)pk1[n_lo], src0, 64);
      u32 c1b = (u32)__shfl((int)pk1[n_hi], src0, 64);
      u32 c2a = (u32)__shfl((int)pk0[n_lo], src1, 64);
      u32 c2b = (u32)__shfl((int)pk0[n_hi], src1, 64);
      u32 c3a = (u32)__shfl((int)pk1[n_lo], src1, 64);
      u32 c3b = (u32)__shfl((int)pk1[n_hi], src1, 64);
      uint4 pw;
      pw.x = nhi ? c0b : c0a;
      pw.y = nhi ? c1b : c1a;
      pw.z = nhi ? c2b : c2a;
      pw.w = nhi ? c3b : c3a;
      pa[kk] = *reinterpret_cast<bf16x8*>(&pw);
    }
    // PV: oacc = mfma(P, V) -> rows q' = G*4+r, cols d = lane&15
    __builtin_amdgcn_s_setprio(1);
#pragma unroll
    for (int kk = 0; kk < 2; ++kk)
#pragma unroll
      for (int dn = 0; dn < 4; ++dn) {
        int vrow = dn * 16 + q;
        int vb_ = vrow * 128 + SWZ(vrow, kk * 64 + G * 16);
        bf16x8 vv = *reinterpret_cast<const bf16x8*>((const char*)Vs[cur] + vb_);
        oacc[dn] = __builtin_amdgcn_mfma_f32_16x16x32_bf16(pa[kk], vv, oacc[dn], 0, 0, 0);
      }
    __builtin_amdgcn_s_setprio(0);
    // write next tile to the other buffer, then one barrier
    if (kt < 15) {
      *reinterpret_cast<uint4*>((char*)Kh[cur ^ 1] + dstb0) = rk0;
      *reinterpret_cast<uint4*>((char*)Kh[cur ^ 1] + dstb1) = rk1;
      *reinterpret_cast<uint4*>((char*)Vs[cur ^ 1] + dstb0) = rv0;
      *reinterpret_cast<uint4*>((char*)Vs[cur ^ 1] + dstb1) = rv1;
    }
    __syncthreads();
    cur ^= 1;
  }
  // full row-sums: reduce per-lane partials, redistribute to oacc rows
  float lf = lsum;
  lf += __shfl_xor(lf, 16, 64);
  lf += __shfl_xor(lf, 32, 64);
  float rinv[4];
#pragma unroll
  for (int r = 0; r < 4; ++r) rinv[r] = 1.f / __shfl(lf, G * 4 + r, 64);

  // epilogue: O/l + residual x, fused BN1 stats
  float s1a[4] = {0.f, 0.f, 0.f, 0.f}, s2a[4] = {0.f, 0.f, 0.f, 0.f};
#pragma unroll
  for (int dn = 0; dn < 4; ++dn)
#pragma unroll
    for (int r = 0; r < 4; ++r) {
      int row = qrow0 + G * 4 + r;
      int col = h * 64 + dn * 16 + q;
      size_t gi = (tb + row) * 256 + col;
      float v = oacc[dn][r] * rinv[r] + XtF[gi];
      Sout[gi] = v;
      s1a[dn] += v;
      s2a[dn] += v * v;
    }
#pragma unroll
  for (int dn = 0; dn < 4; ++dn) {
    float a1 = s1a[dn];
    a1 += __shfl_xor(a1, 16, 64);
    a1 += __shfl_xor(a1, 32, 64);
    float a2 = s2a[dn];
    a2 += __shfl_xor(a2, 16, 64);
    a2 += __shfl_xor(a2, 32, 64);
    if (lane < 16) {
      atomicAdd(&sred[0][dn * 16 + lane], a1);
      atomicAdd(&sred[1][dn * 16 + lane], a2);
    }
  }
  __syncthreads();
  if (tid < 64) {
    atomicAdd(&stats[h * 64 + tid], sred[0][tid]);
    atomicAdd(&stats[256 + h * 64 + tid], sred[1][tid]);
  }
}

// ---------------- BN finalize ----------------
__global__ void bn_finalize(const float* __restrict__ stats, const float* __restrict__ gamma,
                            const float* __restrict__ beta, float* __restrict__ ss) {
  int c = threadIdx.x;
  float mean = stats[c] * (1.f / 16384.f);
  float var = stats[256 + c] * (1.f / 16384.f) - mean * mean;
  float rstd = rsqrtf(var + 1e-5f);
  float scg = gamma[c] * rstd;
  ss[c] = scg;
  ss[256 + c] = beta[c] - mean * scg;
}

// final BN + transpose [T,C] -> [B,C,N]
__global__ __launch_bounds__(256) void bn_final_out(const float* __restrict__ T2,
                                                    const float* __restrict__ ss,
                                                    float* __restrict__ out) {
  __shared__ float tile[32][33];
  int n0 = (blockIdx.x & 31) * 32;
  int b = blockIdx.x >> 5;
  int c0 = blockIdx.y * 32;
  int tx = threadIdx.x, ty = threadIdx.y;
#pragma unroll
  for (int j = 0; j < 4; ++j) {
    int r = ty + j * 8;
    int c = c0 + tx;
    float v = T2[((size_t)b * 1024 + n0 + r) * 256 + c];
    tile[r][tx] = v * ss[c] + ss[256 + c];
  }
  __syncthreads();
#pragma unroll
  for (int j = 0; j < 4; ++j) {
    int c = c0 + ty + j * 8;
    out[((size_t)b * 256 + c) * 1024 + n0 + tx] = tile[tx][ty + j * 8];
  }
}

// ---------------- launch ----------------
extern "C" void kernel_launch(void* const* d_in, const int* in_sizes, int n_in,
                              void* d_out, int out_size, void* d_ws, size_t ws_size,
                              hipStream_t stream) {
  const float* x = (const float*)d_in[0];
  const float* Wq = (const float*)d_in[1];
  const float* bq = (const float*)d_in[2];
  const float* Wk = (const float*)d_in[3];
  const float* bk = (const float*)d_in[4];
  const float* Wv = (const float*)d_in[5];
  const float* bv = (const float*)d_in[6];
  const float* gamma = (const float*)d_in[7];
  const float* beta = (const float*)d_in[8];
  const float* W1 = (const float*)d_in[9];
  const float* b1 = (const float*)d_in[10];
  const float* a = (const float*)d_in[11];
  const float* W2 = (const float*)d_in[12];
  const float* b2 = (const float*)d_in[13];
  float* out = (float*)d_out;

  char* wsb = (char*)d_ws;
  const size_t MB = 1ull << 20;
  u16* XtbH = (u16*)(wsb + 0 * MB);       // 8MB
  u16* XtbL = (u16*)(wsb + 8 * MB);       // 8MB
  float* XtF = (float*)(wsb + 16 * MB);   // 16MB; aliased by T2 after attn
  u16* QKh = (u16*)(wsb + 32 * MB);       // 16MB; aliased by H1B (32MB) after attn
  u16* QKl = (u16*)(wsb + 48 * MB);       // 16MB
  u16* Vt = (u16*)(wsb + 64 * MB);        // 8MB
  char* wp = wsb + 72 * MB;
  u16* WallH = (u16*)(wp);                // 256KB
  u16* WallL = (u16*)(wp + 262144);       // 256KB
  u16* WvH = (u16*)(wp + 524288);         // 128KB
  u16* WvL = (u16*)(wp + 655360);         // 128KB
  u16* W1b = (u16*)(wp + 786432);         // 512KB
  u16* W2b = (u16*)(wp + 1310720);        // 512KB
  float* bqk = (float*)(wp + 1835008);    // 2KB
  float* stats = (float*)(wp + 1837056);  // 8KB: stats1|ss1|stats2|ss2
  if (ws_size < 75 * MB) return;

  float* T2 = XtF;   // [T,256] f32, after attn
  u16* H1B = QKh;    // [T,1024] bf16, after attn
  float* S = out;    // d_out doubles as o+x raw residual buffer [T,256]

  hipMemsetAsync(stats, 0, 8192, stream);
  transpose_x<<<dim3(32, 8, 16), dim3(32, 8), 0, stream>>>(x, XtF, XtbH, XtbL);
  prep_weights<<<1024, 256, 0, stream>>>(Wq, Wk, Wv, bq, bk, W1, W2,
                                         WallH, WallL, WvH, WvL, W1b, W2b, bqk);
  // QK projection: [16384,256] x [512,256]^T -> QKh/QKl [16384,512]
  gemm_qk<<<dim3(4, 128), 256, 0, stream>>>(XtbH, XtbL, WallH, WallL, bqk, QKh, QKl);
  // V projection transposed: per batch [256,256] x [1024,256]^T -> Vt[b,256,1024]
  gemm_vt<<<dim3(8, 2, 16), 256, 0, stream>>>(WvH, WvL, XtbH, bv, Vt);
  // attention + residual + BN1 stats: grid (hb, qc16) for XCD-local K/V reuse
  attn_kernel<<<dim3(64, 16), 256, 0, stream>>>(QKh, QKl, Vt, XtF, S, stats);
  bn_finalize<<<1, 256, 0, stream>>>(stats, gamma, beta, stats + 512);
  // FFN1: A = BN1(S) on the fly -> H1B bf16, bias+PReLU
  gemm_ffn1<<<dim3(8, 128), 256, 0, stream>>>(S, W1b, b1, a, stats + 512, H1B);
  // FFN2: [16384,1024] x [256,1024]^T -> T2 f32, bias + BN1(S) resid + BN2 stats
  gemm_ffn2<<<dim3(2, 128), 256, 0, stream>>>(H1B, W2b, b2, S, stats + 512, T2, stats + 1024);
  bn_finalize<<<1, 256, 0, stream>>>(stats + 1024, gamma, beta, stats + 1536);
  // BN2 apply + transpose out
  bn_final_out<<<dim3(512, 8), dim3(32, 8), 0, stream>>>(T2, stats + 1536, out);
}

// Round 8
// 166.933 us; speedup vs baseline: 1.8290x; 1.0188x over previous
//
#include <hip/hip_runtime.h>
#include <hip/hip_bf16.h>

typedef unsigned short u16;
typedef unsigned int u32;
typedef __attribute__((ext_vector_type(8))) __bf16 bf16x8;
typedef __attribute__((ext_vector_type(4))) float f32x4;

__device__ inline u16 f2bf(float f) {
  unsigned int x = __float_as_uint(f);
  unsigned int r = (x + 0x7FFFu + ((x >> 16) & 1u)) >> 16;
  return (u16)r;
}
__device__ inline float bf2f(u16 u) { return __uint_as_float(((unsigned int)u) << 16); }
__device__ inline void split2(float v, u16& h, u16& l) {
  h = f2bf(v);
  l = f2bf(v - bf2f(h));
}
__device__ inline u32 cvt_pk_bf16(float lo, float hi) {
  u32 r;
  asm("v_cvt_pk_bf16_f32 %0, %1, %2" : "=v"(r) : "v"(lo), "v"(hi));
  return r;
}
// async global->LDS, 16B/lane; dest = wave-uniform base + lane*16
__device__ inline void gll16(const u16* g, u16* l) {
  __builtin_amdgcn_global_load_lds((const __attribute__((address_space(1))) void*)g,
                                   (__attribute__((address_space(3))) void*)l, 16, 0, 0);
}
// [R][32]-bf16 linear tile: logical (row, 16B-slot s) -> physical byte offset (XOR swizzle)
#define TOFF(r, s) (((r) << 6) + ((((s) ^ (((r) >> 1) & 3))) << 4))

// ---------------- x transpose: [B,C,N] f32 -> [B,N,C] f32 + bf16 hi/lo ----------------
__global__ __launch_bounds__(256) void transpose_x(const float* __restrict__ x,
                                                   float* __restrict__ XtF,
                                                   u16* __restrict__ XtbH,
                                                   u16* __restrict__ XtbL) {
  __shared__ float tile[32][33];
  int n0 = blockIdx.x * 32;
  int c0 = blockIdx.y * 32;
  int b  = blockIdx.z;
  int tx = threadIdx.x, ty = threadIdx.y;
#pragma unroll
  for (int j = 0; j < 4; ++j) {
    int c = c0 + ty + j * 8;
    tile[ty + j * 8][tx] = x[((size_t)b * 256 + c) * 1024 + n0 + tx];
  }
  __syncthreads();
#pragma unroll
  for (int j = 0; j < 4; ++j) {
    int n = n0 + ty + j * 8;
    float v = tile[tx][ty + j * 8];
    size_t o = ((size_t)b * 1024 + n) * 256 + c0 + tx;
    XtF[o] = v;
    u16 h, l;
    split2(v, h, l);
    XtbH[o] = h; XtbL[o] = l;
  }
}

// ---------------- weight prep ----------------
__global__ __launch_bounds__(256) void prep_weights(
    const float* __restrict__ Wq, const float* __restrict__ Wk, const float* __restrict__ Wv,
    const float* __restrict__ bq, const float* __restrict__ bk,
    const float* __restrict__ W1, const float* __restrict__ W2,
    u16* __restrict__ WallH, u16* __restrict__ WallL,
    u16* __restrict__ WvH, u16* __restrict__ WvL,
    u16* __restrict__ W1b, u16* __restrict__ W2b,
    float* __restrict__ bqk) {
  int i = blockIdx.x * 256 + threadIdx.x;
  if (i < 131072) {
    float w = (i < 65536) ? Wq[i] : Wk[i - 65536];
    u16 h, l;
    split2(w, h, l);
    WallH[i] = h; WallL[i] = l;
  }
  if (i < 65536) {
    u16 h, l;
    split2(Wv[i], h, l);
    WvH[i] = h; WvL[i] = l;
  }
  if (i < 262144) { W1b[i] = f2bf(W1[i]); W2b[i] = f2bf(W2[i]); }
  if (i < 256) bqk[i] = bq[i];
  else if (i < 512) bqk[i] = bk[i - 256];
}

// ---------------- QK projection GEMM (3-term hi/lo), global_load_lds staging ----------------
// 1D grid 512: m0 = (id&127)*128, n0 = (id>>7)*128 (XCD sees 16 A-panels -> L2-fit)
__global__ __launch_bounds__(256) void gemm_qk(
    const u16* __restrict__ Ah_, const u16* __restrict__ Al_,
    const u16* __restrict__ Bh_, const u16* __restrict__ Bl_,
    const float* __restrict__ bias,
    u16* __restrict__ Ch, u16* __restrict__ Cl) {
  __shared__ u16 Ah[4096], Al[4096], Bh[4096], Bl[4096];
  const int tid = threadIdx.x;
  const int lane = tid & 63, w = tid >> 6;
  const int wr = w >> 1, wc = w & 1;
  const int q = lane & 15, G = lane >> 4;
  const int id = blockIdx.x;
  const int m0 = (id & 127) * 128, n0 = (id >> 7) * 128;

  const int rr0 = w * 32 + (lane >> 2), rr1 = rr0 + 16;
  const int sl0 = (lane & 3) ^ ((rr0 >> 1) & 3);
  const int sl1 = (lane & 3) ^ ((rr1 >> 1) & 3);
  const size_t a0 = (size_t)(m0 + rr0) * 256 + sl0 * 8;
  const size_t a1 = (size_t)(m0 + rr1) * 256 + sl1 * 8;
  const size_t b0 = (size_t)(n0 + rr0) * 256 + sl0 * 8;
  const size_t b1 = (size_t)(n0 + rr1) * 256 + sl1 * 8;

  f32x4 acc[4][4] = {};
  for (int kt = 0; kt < 256; kt += 32) {
    __syncthreads();
    gll16(Ah_ + a0 + kt, &Ah[w * 1024]);
    gll16(Ah_ + a1 + kt, &Ah[w * 1024 + 512]);
    gll16(Al_ + a0 + kt, &Al[w * 1024]);
    gll16(Al_ + a1 + kt, &Al[w * 1024 + 512]);
    gll16(Bh_ + b0 + kt, &Bh[w * 1024]);
    gll16(Bh_ + b1 + kt, &Bh[w * 1024 + 512]);
    gll16(Bl_ + b0 + kt, &Bl[w * 1024]);
    gll16(Bl_ + b1 + kt, &Bl[w * 1024 + 512]);
    __syncthreads();
    bf16x8 afh[4], afl[4], bfh[4], bfl[4];
#pragma unroll
    for (int m = 0; m < 4; ++m) {
      int off = TOFF(wr * 64 + m * 16 + q, G);
      afh[m] = *reinterpret_cast<const bf16x8*>((const char*)Ah + off);
      afl[m] = *reinterpret_cast<const bf16x8*>((const char*)Al + off);
    }
#pragma unroll
    for (int n = 0; n < 4; ++n) {
      int off = TOFF(wc * 64 + n * 16 + q, G);
      bfh[n] = *reinterpret_cast<const bf16x8*>((const char*)Bh + off);
      bfl[n] = *reinterpret_cast<const bf16x8*>((const char*)Bl + off);
    }
#pragma unroll
    for (int m = 0; m < 4; ++m)
#pragma unroll
      for (int n = 0; n < 4; ++n) {
        acc[m][n] = __builtin_amdgcn_mfma_f32_16x16x32_bf16(afh[m], bfh[n], acc[m][n], 0, 0, 0);
        acc[m][n] = __builtin_amdgcn_mfma_f32_16x16x32_bf16(afh[m], bfl[n], acc[m][n], 0, 0, 0);
        acc[m][n] = __builtin_amdgcn_mfma_f32_16x16x32_bf16(afl[m], bfh[n], acc[m][n], 0, 0, 0);
      }
  }
#pragma unroll
  for (int m = 0; m < 4; ++m) {
    int row_b = m0 + wr * 64 + m * 16 + G * 4;
#pragma unroll
    for (int n = 0; n < 4; ++n) {
      int col = n0 + wc * 64 + n * 16 + q;
      float bb = bias[col];
#pragma unroll
      for (int r = 0; r < 4; ++r) {
        size_t o = (size_t)(row_b + r) * 512 + col;
        u16 h, l;
        split2(acc[m][n][r] + bb, h, l);
        Ch[o] = h; Cl[o] = l;
      }
    }
  }
}

// ---------------- V projection, transposed output: Vt[b,d,n], global_load_lds ----------------
__global__ __launch_bounds__(256) void gemm_vt(
    const u16* __restrict__ WvH_, const u16* __restrict__ WvL_,
    const u16* __restrict__ XtbH, const float* __restrict__ bv,
    u16* __restrict__ Vt) {
  __shared__ u16 Ah[4096], Al[4096], Bh[4096];
  const int tid = threadIdx.x;
  const int lane = tid & 63, w = tid >> 6;
  const int wr = w >> 1, wc = w & 1;
  const int q = lane & 15, G = lane >> 4;
  const int b = blockIdx.z;
  const int m0 = blockIdx.y * 128, n0 = blockIdx.x * 128;
  const u16* Bp = XtbH + (size_t)b * 1024 * 256;

  const int rr0 = w * 32 + (lane >> 2), rr1 = rr0 + 16;
  const int sl0 = (lane & 3) ^ ((rr0 >> 1) & 3);
  const int sl1 = (lane & 3) ^ ((rr1 >> 1) & 3);
  const size_t a0 = (size_t)(m0 + rr0) * 256 + sl0 * 8;
  const size_t a1 = (size_t)(m0 + rr1) * 256 + sl1 * 8;
  const size_t b0 = (size_t)(n0 + rr0) * 256 + sl0 * 8;
  const size_t b1 = (size_t)(n0 + rr1) * 256 + sl1 * 8;

  f32x4 acc[4][4] = {};
  for (int kt = 0; kt < 256; kt += 32) {
    __syncthreads();
    gll16(WvH_ + a0 + kt, &Ah[w * 1024]);
    gll16(WvH_ + a1 + kt, &Ah[w * 1024 + 512]);
    gll16(WvL_ + a0 + kt, &Al[w * 1024]);
    gll16(WvL_ + a1 + kt, &Al[w * 1024 + 512]);
    gll16(Bp + b0 + kt, &Bh[w * 1024]);
    gll16(Bp + b1 + kt, &Bh[w * 1024 + 512]);
    __syncthreads();
    bf16x8 afh[4], afl[4], bfr[4];
#pragma unroll
    for (int m = 0; m < 4; ++m) {
      int off = TOFF(wr * 64 + m * 16 + q, G);
      afh[m] = *reinterpret_cast<const bf16x8*>((const char*)Ah + off);
      afl[m] = *reinterpret_cast<const bf16x8*>((const char*)Al + off);
    }
#pragma unroll
    for (int n = 0; n < 4; ++n)
      bfr[n] = *reinterpret_cast<const bf16x8*>((const char*)Bh + TOFF(wc * 64 + n * 16 + q, G));
#pragma unroll
    for (int m = 0; m < 4; ++m)
#pragma unroll
      for (int n = 0; n < 4; ++n) {
        acc[m][n] = __builtin_amdgcn_mfma_f32_16x16x32_bf16(afh[m], bfr[n], acc[m][n], 0, 0, 0);
        acc[m][n] = __builtin_amdgcn_mfma_f32_16x16x32_bf16(afl[m], bfr[n], acc[m][n], 0, 0, 0);
      }
  }
#pragma unroll
  for (int m = 0; m < 4; ++m) {
    int row_b = m0 + wr * 64 + m * 16 + G * 4;  // d index
#pragma unroll
    for (int n = 0; n < 4; ++n) {
      int col = n0 + wc * 64 + n * 16 + q;      // token n
#pragma unroll
      for (int r = 0; r < 4; ++r) {
        int row = row_b + r;
        Vt[((size_t)b * 256 + row) * 1024 + col] = f2bf(acc[m][n][r] + bv[row]);
      }
    }
  }
}

// ---------------- FFN1: A = BN(Sraw) reg-staged (swizzled), B via global_load_lds ----------------
// 1D grid 1024: m0 = (id&127)*128, n0 = (id>>7)*128
__global__ __launch_bounds__(256) void gemm_ffn1(
    const float* __restrict__ Sraw,
    const u16* __restrict__ B_,
    const float* __restrict__ bias,
    const float* __restrict__ aslope,
    const float* __restrict__ ss,
    u16* __restrict__ H1B) {
  __shared__ u16 As[4096], Bs[4096];
  __shared__ float ssl[512];
  const int tid = threadIdx.x;
  const int lane = tid & 63, w = tid >> 6;
  const int wr = w >> 1, wc = w & 1;
  const int q = lane & 15, G = lane >> 4;
  const int id = blockIdx.x;
  const int m0 = (id & 127) * 128, n0 = (id >> 7) * 128;
  ssl[tid] = ss[tid];
  ssl[256 + tid] = ss[256 + tid];

  const int rr0 = w * 32 + (lane >> 2), rr1 = rr0 + 16;
  const int sl0 = (lane & 3) ^ ((rr0 >> 1) & 3);
  const int sl1 = (lane & 3) ^ ((rr1 >> 1) & 3);
  const size_t b0 = (size_t)(n0 + rr0) * 256 + sl0 * 8;
  const size_t b1 = (size_t)(n0 + rr1) * 256 + sl1 * 8;

  f32x4 acc[4][4] = {};
  for (int kt = 0; kt < 256; kt += 32) {
    __syncthreads();
    gll16(B_ + b0 + kt, &Bs[w * 1024]);
    gll16(B_ + b1 + kt, &Bs[w * 1024 + 512]);
    // A-stage: BN affine + bf16, swizzled ds_write
#pragma unroll
    for (int i = 0; i < 4; ++i) {
      int idx = tid + i * 256;
      int r = idx >> 3, cc = idx & 7;  // 8B chunk
      int c4 = cc * 4;
      float4 v = *reinterpret_cast<const float4*>(Sraw + (size_t)(m0 + r) * 256 + kt + c4);
      ushort4 o;
      o.x = f2bf(v.x * ssl[kt + c4 + 0] + ssl[256 + kt + c4 + 0]);
      o.y = f2bf(v.y * ssl[kt + c4 + 1] + ssl[256 + kt + c4 + 1]);
      o.z = f2bf(v.z * ssl[kt + c4 + 2] + ssl[256 + kt + c4 + 2]);
      o.w = f2bf(v.w * ssl[kt + c4 + 3] + ssl[256 + kt + c4 + 3]);
      int off = (r << 6) + ((((cc >> 1) ^ ((r >> 1) & 3))) << 4) + (cc & 1) * 8;
      *reinterpret_cast<ushort4*>((char*)As + off) = o;
    }
    __syncthreads();
    bf16x8 af[4], bfr[4];
#pragma unroll
    for (int m = 0; m < 4; ++m)
      af[m] = *reinterpret_cast<const bf16x8*>((const char*)As + TOFF(wr * 64 + m * 16 + q, G));
#pragma unroll
    for (int n = 0; n < 4; ++n)
      bfr[n] = *reinterpret_cast<const bf16x8*>((const char*)Bs + TOFF(wc * 64 + n * 16 + q, G));
#pragma unroll
    for (int m = 0; m < 4; ++m)
#pragma unroll
      for (int n = 0; n < 4; ++n)
        acc[m][n] = __builtin_amdgcn_mfma_f32_16x16x32_bf16(af[m], bfr[n], acc[m][n], 0, 0, 0);
  }
  float a = aslope[0];
#pragma unroll
  for (int m = 0; m < 4; ++m) {
    int row_b = m0 + wr * 64 + m * 16 + G * 4;
#pragma unroll
    for (int n = 0; n < 4; ++n) {
      int col = n0 + wc * 64 + n * 16 + q;
      float bb = bias[col];
#pragma unroll
      for (int r = 0; r < 4; ++r) {
        float v = acc[m][n][r] + bb;
        v = (v >= 0.f) ? v : a * v;
        H1B[(size_t)(row_b + r) * 1024 + col] = f2bf(v);
      }
    }
  }
}

// ---------------- FFN2: BM=128 x BN=64, global_load_lds, fused resid + BN2 stats ----------------
// 1D grid 512: m0 = (id&127)*128, n0 = (id>>7)*64
__global__ __launch_bounds__(256) void gemm_ffn2(
    const u16* __restrict__ A_,
    const u16* __restrict__ B_,
    const float* __restrict__ bias,
    const float* __restrict__ Sraw,
    const float* __restrict__ ss,
    float* __restrict__ T2,
    float* __restrict__ stats2) {
  __shared__ u16 As[4096], Bs[2048];
  __shared__ float sred[2][64];
  const int tid = threadIdx.x;
  const int lane = tid & 63, w = tid >> 6;
  const int wr = w >> 1, wc = w & 1;
  const int q = lane & 15, G = lane >> 4;
  const int id = blockIdx.x;
  const int m0 = (id & 127) * 128, n0 = (id >> 7) * 64;
  if (tid < 64) { sred[0][tid] = 0.f; sred[1][tid] = 0.f; }

  const int rrA0 = w * 32 + (lane >> 2), rrA1 = rrA0 + 16;
  const int slA0 = (lane & 3) ^ ((rrA0 >> 1) & 3);
  const int slA1 = (lane & 3) ^ ((rrA1 >> 1) & 3);
  const size_t a0 = (size_t)(m0 + rrA0) * 1024 + slA0 * 8;
  const size_t a1 = (size_t)(m0 + rrA1) * 1024 + slA1 * 8;
  const int rrB = w * 16 + (lane >> 2);
  const int slB = (lane & 3) ^ ((rrB >> 1) & 3);
  const size_t b0 = (size_t)(n0 + rrB) * 1024 + slB * 8;

  f32x4 acc[4][2] = {};
  for (int kt = 0; kt < 1024; kt += 32) {
    __syncthreads();
    gll16(A_ + a0 + kt, &As[w * 1024]);
    gll16(A_ + a1 + kt, &As[w * 1024 + 512]);
    gll16(B_ + b0 + kt, &Bs[w * 512]);
    __syncthreads();
    bf16x8 af[4], bf2[2];
#pragma unroll
    for (int m = 0; m < 4; ++m)
      af[m] = *reinterpret_cast<const bf16x8*>((const char*)As + TOFF(wr * 64 + m * 16 + q, G));
#pragma unroll
    for (int n = 0; n < 2; ++n)
      bf2[n] = *reinterpret_cast<const bf16x8*>((const char*)Bs + TOFF(wc * 32 + n * 16 + q, G));
#pragma unroll
    for (int m = 0; m < 4; ++m)
#pragma unroll
      for (int n = 0; n < 2; ++n)
        acc[m][n] = __builtin_amdgcn_mfma_f32_16x16x32_bf16(af[m], bf2[n], acc[m][n], 0, 0, 0);
  }
  float s1a[2] = {0.f, 0.f}, s2a[2] = {0.f, 0.f};
#pragma unroll
  for (int m = 0; m < 4; ++m) {
    int row_b = m0 + wr * 64 + m * 16 + G * 4;
#pragma unroll
    for (int n = 0; n < 2; ++n) {
      int col = n0 + wc * 32 + n * 16 + q;
      float bb = bias[col];
      float sc_ = ss[col], of_ = ss[256 + col];
#pragma unroll
      for (int r = 0; r < 4; ++r) {
        int row = row_b + r;
        float resid = Sraw[(size_t)row * 256 + col] * sc_ + of_;
        float v = acc[m][n][r] + bb + resid;
        T2[(size_t)row * 256 + col] = v;
        s1a[n] += v;
        s2a[n] += v * v;
      }
    }
  }
#pragma unroll
  for (int n = 0; n < 2; ++n) {
    float a1 = s1a[n];
    a1 += __shfl_xor(a1, 16, 64);
    a1 += __shfl_xor(a1, 32, 64);
    float a2 = s2a[n];
    a2 += __shfl_xor(a2, 16, 64);
    a2 += __shfl_xor(a2, 32, 64);
    if (lane < 16) {
      atomicAdd(&sred[0][wc * 32 + n * 16 + lane], a1);
      atomicAdd(&sred[1][wc * 32 + n * 16 + lane], a2);
    }
  }
  __syncthreads();
  if (tid < 64) {
    atomicAdd(&stats2[n0 + tid], sred[0][tid]);
    atomicAdd(&stats2[256 + n0 + tid], sred[1][tid]);
  }
}

// ---------------- fused flash attention: swapped QK^T, 2-term, in-register softmax/P --------
#define SWZ(row, bcol) ((bcol) ^ (((row) & 7) << 4))
__global__ __launch_bounds__(256, 4) void attn_kernel(const u16* __restrict__ QKh,
                                                      const u16* __restrict__ QKl,
                                                      const u16* __restrict__ Vt,
                                                      const float* __restrict__ XtF,
                                                      float* __restrict__ Sout,
                                                      float* __restrict__ stats) {
  __shared__ u16 Kh[2][4096], Vs[2][4096];
  __shared__ float sred[2][64];
  const int tid = threadIdx.x, lane = tid & 63, w = tid >> 6;
  const int hb = blockIdx.x, h = hb & 3, b = hb >> 2;
  const size_t tb = (size_t)b * 1024;
  const int qrow0 = blockIdx.y * 64 + w * 16;
  const int q = lane & 15, G = lane >> 4;

  if (tid < 64) { sred[0][tid] = 0.f; sred[1][tid] = 0.f; }

  bf16x8 qh[2], ql[2];
#pragma unroll
  for (int kk = 0; kk < 2; ++kk) {
    size_t ro = (tb + qrow0 + q) * 512 + h * 64 + kk * 32 + G * 8;
    qh[kk] = *reinterpret_cast<const bf16x8*>(QKh + ro);
    ql[kk] = *reinterpret_cast<const bf16x8*>(QKl + ro);
  }

  f32x4 oacc[4] = {};
  float mprev = -3e38f, lsum = 0.f;

  int sr0 = tid >> 3, scb0 = (tid & 7) << 4;
  int sr1 = (tid + 256) >> 3, scb1 = ((tid + 256) & 7) << 4;
  const int dstb0 = sr0 * 128 + SWZ(sr0, scb0);
  const int dstb1 = sr1 * 128 + SWZ(sr1, scb1);
  const size_t kbase0 = (tb + sr0) * 512 + 256 + h * 64 + (scb0 >> 1);
  const size_t kbase1 = (tb + sr1) * 512 + 256 + h * 64 + (scb1 >> 1);
  const size_t vbase0 = ((size_t)b * 256 + h * 64 + sr0) * 1024 + (scb0 >> 1);
  const size_t vbase1 = ((size_t)b * 256 + h * 64 + sr1) * 1024 + (scb1 >> 1);

  uint4 rk0 = *reinterpret_cast<const uint4*>(QKh + kbase0);
  uint4 rk1 = *reinterpret_cast<const uint4*>(QKh + kbase1);
  uint4 rv0 = *reinterpret_cast<const uint4*>(Vt + vbase0);
  uint4 rv1 = *reinterpret_cast<const uint4*>(Vt + vbase1);
  *reinterpret_cast<uint4*>((char*)Kh[0] + dstb0) = rk0;
  *reinterpret_cast<uint4*>((char*)Kh[0] + dstb1) = rk1;
  *reinterpret_cast<uint4*>((char*)Vs[0] + dstb0) = rv0;
  *reinterpret_cast<uint4*>((char*)Vs[0] + dstb1) = rv1;
  __syncthreads();

  const int src0 = q + 32 * (G & 1);
  const int src1 = src0 + 16;
  const int nhi = G >> 1;

  int cur = 0;
  for (int kt = 0; kt < 16; ++kt) {
    if (kt < 15) {
      rk0 = *reinterpret_cast<const uint4*>(QKh + kbase0 + (size_t)(kt + 1) * 32768);
      rk1 = *reinterpret_cast<const uint4*>(QKh + kbase1 + (size_t)(kt + 1) * 32768);
      rv0 = *reinterpret_cast<const uint4*>(Vt + vbase0 + (size_t)(kt + 1) * 64);
      rv1 = *reinterpret_cast<const uint4*>(Vt + vbase1 + (size_t)(kt + 1) * 64);
    }

    f32x4 sc[4] = {};
    __builtin_amdgcn_s_setprio(1);
#pragma unroll
    for (int kk = 0; kk < 2; ++kk)
#pragma unroll
      for (int n = 0; n < 4; ++n) {
        int krow = n * 16 + q;
        int kb_ = krow * 128 + SWZ(krow, kk * 64 + G * 16);
        bf16x8 akh = *reinterpret_cast<const bf16x8*>((const char*)Kh[cur] + kb_);
        sc[n] = __builtin_amdgcn_mfma_f32_16x16x32_bf16(akh, qh[kk], sc[n], 0, 0, 0);
        sc[n] = __builtin_amdgcn_mfma_f32_16x16x32_bf16(akh, ql[kk], sc[n], 0, 0, 0);
      }
    __builtin_amdgcn_s_setprio(0);

    float vm;
    {
      float a0 = fmaxf(fmaxf(sc[0][0], sc[0][1]), fmaxf(sc[0][2], sc[0][3]));
      float a1 = fmaxf(fmaxf(sc[1][0], sc[1][1]), fmaxf(sc[1][2], sc[1][3]));
      float a2 = fmaxf(fmaxf(sc[2][0], sc[2][1]), fmaxf(sc[2][2], sc[2][3]));
      float a3 = fmaxf(fmaxf(sc[3][0], sc[3][1]), fmaxf(sc[3][2], sc[3][3]));
      vm = fmaxf(fmaxf(a0, a1), fmaxf(a2, a3));
      vm = fmaxf(vm, __shfl_xor(vm, 16, 64));
      vm = fmaxf(vm, __shfl_xor(vm, 32, 64));
    }
    bool ok = (vm <= mprev + 8.f);
    if (!__all(ok)) {
      float mn = fmaxf(mprev, vm);
      float scl = __expf(mprev - mn);
      mprev = mn;
      lsum *= scl;
      float sclr[4];
#pragma unroll
      for (int r = 0; r < 4; ++r) sclr[r] = __shfl(scl, G * 4 + r, 64);
#pragma unroll
      for (int dn = 0; dn < 4; ++dn)
#pragma unroll
        for (int r = 0; r < 4; ++r) oacc[dn][r] *= sclr[r];
    }
    float lt = 0.f;
#pragma unroll
    for (int n = 0; n < 4; ++n)
#pragma unroll
      for (int r = 0; r < 4; ++r) {
        float p = __expf(sc[n][r] - mprev);
        sc[n][r] = p;
        lt += p;
      }
    lsum += lt;
    u32 pk0[4], pk1[4];
#pragma unroll
    for (int n = 0; n < 4; ++n) {
      pk0[n] = cvt_pk_bf16(sc[n][0], sc[n][1]);
      pk1[n] = cvt_pk_bf16(sc[n][2], sc[n][3]);
    }
    bf16x8 pa[2];
#pragma unroll
    for (int kk = 0; kk < 2; ++kk) {
      int n_lo = 2 * kk, n_hi = 2 * kk + 1;
      u32 c0a = (u32)__shfl((int)pk0[n_lo], src0, 64);
      u32 c0b = (u32)__shfl((int)pk0[n_hi], src0, 64);
      u32 c1a = (u32)__shfl((int)pk1[n_lo], src0, 64);
      u32 c1b = (u32)__shfl((int)pk1[n_hi], src0, 64);
      u32 c2a = (u32)__shfl((int)pk0[n_lo], src1, 64);
      u32 c2b = (u32)__shfl((int)pk0[n_hi], src1, 64);
      u32 c3a = (u32)__shfl((int)pk1[n_lo], src1, 64);
      u32 c3b = (u32)__shfl((int)pk1[n_hi], src1, 64);
      uint4 pw;
      pw.x = nhi ? c0b : c0a;
      pw.y = nhi ? c1b : c1a;
      pw.z = nhi ? c2b : c2a;
      pw.w = nhi ? c3b : c3a;
      pa[kk] = *reinterpret_cast<bf16x8*>(&pw);
    }
    __builtin_amdgcn_s_setprio(1);
#pragma unroll
    for (int kk = 0; kk < 2; ++kk)
#pragma unroll
      for (int dn = 0; dn < 4; ++dn) {
        int vrow = dn * 16 + q;
        int vb_ = vrow * 128 + SWZ(vrow, kk * 64 + G * 16);
        bf16x8 vv = *reinterpret_cast<const bf16x8*>((const char*)Vs[cur] + vb_);
        oacc[dn] = __builtin_amdgcn_mfma_f32_16x16x32_bf16(pa[kk], vv, oacc[dn], 0, 0, 0);
      }
    __builtin_amdgcn_s_setprio(0);
    if (kt < 15) {
      *reinterpret_cast<uint4*>((char*)Kh[cur ^ 1] + dstb0) = rk0;
      *reinterpret_cast<uint4*>((char*)Kh[cur ^ 1] + dstb1) = rk1;
      *reinterpret_cast<uint4*>((char*)Vs[cur ^ 1] + dstb0) = rv0;
      *reinterpret_cast<uint4*>((char*)Vs[cur ^ 1] + dstb1) = rv1;
    }
    __syncthreads();
    cur ^= 1;
  }
  float lf = lsum;
  lf += __shfl_xor(lf, 16, 64);
  lf += __shfl_xor(lf, 32, 64);
  float rinv[4];
#pragma unroll
  for (int r = 0; r < 4; ++r) rinv[r] = 1.f / __shfl(lf, G * 4 + r, 64);

  float s1a[4] = {0.f, 0.f, 0.f, 0.f}, s2a[4] = {0.f, 0.f, 0.f, 0.f};
#pragma unroll
  for (int dn = 0; dn < 4; ++dn)
#pragma unroll
    for (int r = 0; r < 4; ++r) {
      int row = qrow0 + G * 4 + r;
      int col = h * 64 + dn * 16 + q;
      size_t gi = (tb + row) * 256 + col;
      float v = oacc[dn][r] * rinv[r] + XtF[gi];
      Sout[gi] = v;
      s1a[dn] += v;
      s2a[dn] += v * v;
    }
#pragma unroll
  for (int dn = 0; dn < 4; ++dn) {
    float a1 = s1a[dn];
    a1 += __shfl_xor(a1, 16, 64);
    a1 += __shfl_xor(a1, 32, 64);
    float a2 = s2a[dn];
    a2 += __shfl_xor(a2, 16, 64);
    a2 += __shfl_xor(a2, 32, 64);
    if (lane < 16) {
      atomicAdd(&sred[0][dn * 16 + lane], a1);
      atomicAdd(&sred[1][dn * 16 + lane], a2);
    }
  }
  __syncthreads();
  if (tid < 64) {
    atomicAdd(&stats[h * 64 + tid], sred[0][tid]);
    atomicAdd(&stats[256 + h * 64 + tid], sred[1][tid]);
  }
}

// ---------------- BN finalize ----------------
__global__ void bn_finalize(const float* __restrict__ stats, const float* __restrict__ gamma,
                            const float* __restrict__ beta, float* __restrict__ ss) {
  int c = threadIdx.x;
  float mean = stats[c] * (1.f / 16384.f);
  float var = stats[256 + c] * (1.f / 16384.f) - mean * mean;
  float rstd = rsqrtf(var + 1e-5f);
  float scg = gamma[c] * rstd;
  ss[c] = scg;
  ss[256 + c] = beta[c] - mean * scg;
}

// final BN + transpose [T,C] -> [B,C,N]
__global__ __launch_bounds__(256) void bn_final_out(const float* __restrict__ T2,
                                                    const float* __restrict__ ss,
                                                    float* __restrict__ out) {
  __shared__ float tile[32][33];
  int n0 = (blockIdx.x & 31) * 32;
  int b = blockIdx.x >> 5;
  int c0 = blockIdx.y * 32;
  int tx = threadIdx.x, ty = threadIdx.y;
#pragma unroll
  for (int j = 0; j < 4; ++j) {
    int r = ty + j * 8;
    int c = c0 + tx;
    float v = T2[((size_t)b * 1024 + n0 + r) * 256 + c];
    tile[r][tx] = v * ss[c] + ss[256 + c];
  }
  __syncthreads();
#pragma unroll
  for (int j = 0; j < 4; ++j) {
    int c = c0 + ty + j * 8;
    out[((size_t)b * 256 + c) * 1024 + n0 + tx] = tile[tx][ty + j * 8];
  }
}

// ---------------- launch ----------------
extern "C" void kernel_launch(void* const* d_in, const int* in_sizes, int n_in,
                              void* d_out, int out_size, void* d_ws, size_t ws_size,
                              hipStream_t stream) {
  const float* x = (const float*)d_in[0];
  const float* Wq = (const float*)d_in[1];
  const float* bq = (const float*)d_in[2];
  const float* Wk = (const float*)d_in[3];
  const float* bk = (const float*)d_in[4];
  const float* Wv = (const float*)d_in[5];
  const float* bv = (const float*)d_in[6];
  const float* gamma = (const float*)d_in[7];
  const float* beta = (const float*)d_in[8];
  const float* W1 = (const float*)d_in[9];
  const float* b1 = (const float*)d_in[10];
  const float* a = (const float*)d_in[11];
  const float* W2 = (const float*)d_in[12];
  const float* b2 = (const float*)d_in[13];
  float* out = (float*)d_out;

  char* wsb = (char*)d_ws;
  const size_t MB = 1ull << 20;
  u16* XtbH = (u16*)(wsb + 0 * MB);       // 8MB
  u16* XtbL = (u16*)(wsb + 8 * MB);       // 8MB
  float* XtF = (float*)(wsb + 16 * MB);   // 16MB; aliased by T2 after attn
  u16* QKh = (u16*)(wsb + 32 * MB);       // 16MB; aliased by H1B (32MB) after attn
  u16* QKl = (u16*)(wsb + 48 * MB);       // 16MB
  u16* Vt = (u16*)(wsb + 64 * MB);        // 8MB
  char* wp = wsb + 72 * MB;
  u16* WallH = (u16*)(wp);                // 256KB
  u16* WallL = (u16*)(wp + 262144);       // 256KB
  u16* WvH = (u16*)(wp + 524288);         // 128KB
  u16* WvL = (u16*)(wp + 655360);         // 128KB
  u16* W1b = (u16*)(wp + 786432);         // 512KB
  u16* W2b = (u16*)(wp + 1310720);        // 512KB
  float* bqk = (float*)(wp + 1835008);    // 2KB
  float* stats = (float*)(wp + 1837056);  // 8KB: stats1|ss1|stats2|ss2
  if (ws_size < 75 * MB) return;

  float* T2 = XtF;   // [T,256] f32, after attn
  u16* H1B = QKh;    // [T,1024] bf16, after attn
  float* S = out;    // d_out doubles as o+x raw residual buffer [T,256]

  hipMemsetAsync(stats, 0, 8192, stream);
  transpose_x<<<dim3(32, 8, 16), dim3(32, 8), 0, stream>>>(x, XtF, XtbH, XtbL);
  prep_weights<<<1024, 256, 0, stream>>>(Wq, Wk, Wv, bq, bk, W1, W2,
                                         WallH, WallL, WvH, WvL, W1b, W2b, bqk);
  // QK projection: [16384,256] x [512,256]^T -> QKh/QKl [16384,512]
  gemm_qk<<<512, 256, 0, stream>>>(XtbH, XtbL, WallH, WallL, bqk, QKh, QKl);
  // V projection transposed: per batch [256,256] x [1024,256]^T -> Vt[b,256,1024]
  gemm_vt<<<dim3(8, 2, 16), 256, 0, stream>>>(WvH, WvL, XtbH, bv, Vt);
  // attention + residual + BN1 stats
  attn_kernel<<<dim3(64, 16), 256, 0, stream>>>(QKh, QKl, Vt, XtF, S, stats);
  bn_finalize<<<1, 256, 0, stream>>>(stats, gamma, beta, stats + 512);
  // FFN1: A = BN1(S) on the fly -> H1B bf16, bias+PReLU
  gemm_ffn1<<<1024, 256, 0, stream>>>(S, W1b, b1, a, stats + 512, H1B);
  // FFN2: [16384,1024] x [256,1024]^T -> T2 f32, bias + BN1(S) resid + BN2 stats
  gemm_ffn2<<<512, 256, 0, stream>>>(H1B, W2b, b2, S, stats + 512, T2, stats + 1024);
  bn_finalize<<<1, 256, 0, stream>>>(stats + 1024, gamma, beta, stats + 1536);
  // BN2 apply + transpose out
  bn_final_out<<<dim3(512, 8), dim3(32, 8), 0, stream>>>(T2, stats + 1536, out);
}

// Round 9
// 158.264 us; speedup vs baseline: 1.9292x; 1.0548x over previous
//
#include <hip/hip_runtime.h>
#include <hip/hip_bf16.h>

typedef unsigned short u16;
typedef unsigned int u32;
typedef __attribute__((ext_vector_type(8))) __bf16 bf16x8;
typedef __attribute__((ext_vector_type(4))) float f32x4;

__device__ inline u16 f2bf(float f) {
  unsigned int x = __float_as_uint(f);
  unsigned int r = (x + 0x7FFFu + ((x >> 16) & 1u)) >> 16;
  return (u16)r;
}
__device__ inline float bf2f(u16 u) { return __uint_as_float(((unsigned int)u) << 16); }
__device__ inline void split2(float v, u16& h, u16& l) {
  h = f2bf(v);
  l = f2bf(v - bf2f(h));
}
__device__ inline u32 cvt_pk_bf16(float lo, float hi) {
  u32 r;
  asm("v_cvt_pk_bf16_f32 %0, %1, %2" : "=v"(r) : "v"(lo), "v"(hi));
  return r;
}
// async global->LDS, 16B/lane; dest = wave-uniform base + lane*16
__device__ inline void gll16(const u16* g, u16* l) {
  __builtin_amdgcn_global_load_lds((const __attribute__((address_space(1))) void*)g,
                                   (__attribute__((address_space(3))) void*)l, 16, 0, 0);
}
// [R][32]-bf16 linear tile: logical (row, 16B-slot s) -> physical byte offset (XOR swizzle)
#define TOFF(r, s) (((r) << 6) + ((((s) ^ (((r) >> 1) & 3))) << 4))

// ---------------- x transpose: [B,C,N] f32 -> [B,N,C] bf16 hi/lo ----------------
__global__ __launch_bounds__(256) void transpose_x(const float* __restrict__ x,
                                                   u16* __restrict__ XtbH,
                                                   u16* __restrict__ XtbL) {
  __shared__ float tile[32][33];
  int n0 = blockIdx.x * 32;
  int c0 = blockIdx.y * 32;
  int b  = blockIdx.z;
  int tx = threadIdx.x, ty = threadIdx.y;
#pragma unroll
  for (int j = 0; j < 4; ++j) {
    int c = c0 + ty + j * 8;
    tile[ty + j * 8][tx] = x[((size_t)b * 256 + c) * 1024 + n0 + tx];
  }
  __syncthreads();
#pragma unroll
  for (int j = 0; j < 4; ++j) {
    int n = n0 + ty + j * 8;
    float v = tile[tx][ty + j * 8];
    size_t o = ((size_t)b * 1024 + n) * 256 + c0 + tx;
    u16 h, l;
    split2(v, h, l);
    XtbH[o] = h; XtbL[o] = l;
  }
}

// ---------------- weight prep ----------------
__global__ __launch_bounds__(256) void prep_weights(
    const float* __restrict__ Wq, const float* __restrict__ Wk, const float* __restrict__ Wv,
    const float* __restrict__ bq, const float* __restrict__ bk,
    const float* __restrict__ W1, const float* __restrict__ W2,
    u16* __restrict__ WallH, u16* __restrict__ WallL,
    u16* __restrict__ WvH, u16* __restrict__ WvL,
    u16* __restrict__ W1b, u16* __restrict__ W2b,
    float* __restrict__ bqk) {
  int i = blockIdx.x * 256 + threadIdx.x;
  if (i < 131072) {
    float w = (i < 65536) ? Wq[i] : Wk[i - 65536];
    u16 h, l;
    split2(w, h, l);
    WallH[i] = h; WallL[i] = l;
  }
  if (i < 65536) {
    u16 h, l;
    split2(Wv[i], h, l);
    WvH[i] = h; WvL[i] = l;
  }
  if (i < 262144) { W1b[i] = f2bf(W1[i]); W2b[i] = f2bf(W2[i]); }
  if (i < 256) bqk[i] = bq[i];
  else if (i < 512) bqk[i] = bk[i - 256];
}

// ---------------- QK projection GEMM (3-term hi/lo), global_load_lds staging ----------------
// 1D grid 512: m0 = (id&127)*128, n0 = (id>>7)*128
__global__ __launch_bounds__(256) void gemm_qk(
    const u16* __restrict__ Ah_, const u16* __restrict__ Al_,
    const u16* __restrict__ Bh_, const u16* __restrict__ Bl_,
    const float* __restrict__ bias,
    u16* __restrict__ Ch, u16* __restrict__ Cl) {
  __shared__ u16 Ah[4096], Al[4096], Bh[4096], Bl[4096];
  const int tid = threadIdx.x;
  const int lane = tid & 63, w = tid >> 6;
  const int wr = w >> 1, wc = w & 1;
  const int q = lane & 15, G = lane >> 4;
  const int id = blockIdx.x;
  const int m0 = (id & 127) * 128, n0 = (id >> 7) * 128;

  const int rr0 = w * 32 + (lane >> 2), rr1 = rr0 + 16;
  const int sl0 = (lane & 3) ^ ((rr0 >> 1) & 3);
  const int sl1 = (lane & 3) ^ ((rr1 >> 1) & 3);
  const size_t a0 = (size_t)(m0 + rr0) * 256 + sl0 * 8;
  const size_t a1 = (size_t)(m0 + rr1) * 256 + sl1 * 8;
  const size_t b0 = (size_t)(n0 + rr0) * 256 + sl0 * 8;
  const size_t b1 = (size_t)(n0 + rr1) * 256 + sl1 * 8;

  f32x4 acc[4][4] = {};
  for (int kt = 0; kt < 256; kt += 32) {
    __syncthreads();
    gll16(Ah_ + a0 + kt, &Ah[w * 1024]);
    gll16(Ah_ + a1 + kt, &Ah[w * 1024 + 512]);
    gll16(Al_ + a0 + kt, &Al[w * 1024]);
    gll16(Al_ + a1 + kt, &Al[w * 1024 + 512]);
    gll16(Bh_ + b0 + kt, &Bh[w * 1024]);
    gll16(Bh_ + b1 + kt, &Bh[w * 1024 + 512]);
    gll16(Bl_ + b0 + kt, &Bl[w * 1024]);
    gll16(Bl_ + b1 + kt, &Bl[w * 1024 + 512]);
    __syncthreads();
    bf16x8 afh[4], afl[4], bfh[4], bfl[4];
#pragma unroll
    for (int m = 0; m < 4; ++m) {
      int off = TOFF(wr * 64 + m * 16 + q, G);
      afh[m] = *reinterpret_cast<const bf16x8*>((const char*)Ah + off);
      afl[m] = *reinterpret_cast<const bf16x8*>((const char*)Al + off);
    }
#pragma unroll
    for (int n = 0; n < 4; ++n) {
      int off = TOFF(wc * 64 + n * 16 + q, G);
      bfh[n] = *reinterpret_cast<const bf16x8*>((const char*)Bh + off);
      bfl[n] = *reinterpret_cast<const bf16x8*>((const char*)Bl + off);
    }
#pragma unroll
    for (int m = 0; m < 4; ++m)
#pragma unroll
      for (int n = 0; n < 4; ++n) {
        acc[m][n] = __builtin_amdgcn_mfma_f32_16x16x32_bf16(afh[m], bfh[n], acc[m][n], 0, 0, 0);
        acc[m][n] = __builtin_amdgcn_mfma_f32_16x16x32_bf16(afh[m], bfl[n], acc[m][n], 0, 0, 0);
        acc[m][n] = __builtin_amdgcn_mfma_f32_16x16x32_bf16(afl[m], bfh[n], acc[m][n], 0, 0, 0);
      }
  }
  // cols >= 256 are K: only hi is ever read downstream (block-uniform skip of Cl)
  const bool needL = (n0 < 256);
#pragma unroll
  for (int m = 0; m < 4; ++m) {
    int row_b = m0 + wr * 64 + m * 16 + G * 4;
#pragma unroll
    for (int n = 0; n < 4; ++n) {
      int col = n0 + wc * 64 + n * 16 + q;
      float bb = bias[col];
#pragma unroll
      for (int r = 0; r < 4; ++r) {
        size_t o = (size_t)(row_b + r) * 512 + col;
        u16 h, l;
        split2(acc[m][n][r] + bb, h, l);
        Ch[o] = h;
        if (needL) Cl[o] = l;
      }
    }
  }
}

// ---------------- V projection, transposed output: Vt[b,d,n], global_load_lds ----------------
__global__ __launch_bounds__(256) void gemm_vt(
    const u16* __restrict__ WvH_, const u16* __restrict__ WvL_,
    const u16* __restrict__ XtbH, const float* __restrict__ bv,
    u16* __restrict__ Vt) {
  __shared__ u16 Ah[4096], Al[4096], Bh[4096];
  const int tid = threadIdx.x;
  const int lane = tid & 63, w = tid >> 6;
  const int wr = w >> 1, wc = w & 1;
  const int q = lane & 15, G = lane >> 4;
  const int b = blockIdx.z;
  const int m0 = blockIdx.y * 128, n0 = blockIdx.x * 128;
  const u16* Bp = XtbH + (size_t)b * 1024 * 256;

  const int rr0 = w * 32 + (lane >> 2), rr1 = rr0 + 16;
  const int sl0 = (lane & 3) ^ ((rr0 >> 1) & 3);
  const int sl1 = (lane & 3) ^ ((rr1 >> 1) & 3);
  const size_t a0 = (size_t)(m0 + rr0) * 256 + sl0 * 8;
  const size_t a1 = (size_t)(m0 + rr1) * 256 + sl1 * 8;
  const size_t b0 = (size_t)(n0 + rr0) * 256 + sl0 * 8;
  const size_t b1 = (size_t)(n0 + rr1) * 256 + sl1 * 8;

  f32x4 acc[4][4] = {};
  for (int kt = 0; kt < 256; kt += 32) {
    __syncthreads();
    gll16(WvH_ + a0 + kt, &Ah[w * 1024]);
    gll16(WvH_ + a1 + kt, &Ah[w * 1024 + 512]);
    gll16(WvL_ + a0 + kt, &Al[w * 1024]);
    gll16(WvL_ + a1 + kt, &Al[w * 1024 + 512]);
    gll16(Bp + b0 + kt, &Bh[w * 1024]);
    gll16(Bp + b1 + kt, &Bh[w * 1024 + 512]);
    __syncthreads();
    bf16x8 afh[4], afl[4], bfr[4];
#pragma unroll
    for (int m = 0; m < 4; ++m) {
      int off = TOFF(wr * 64 + m * 16 + q, G);
      afh[m] = *reinterpret_cast<const bf16x8*>((const char*)Ah + off);
      afl[m] = *reinterpret_cast<const bf16x8*>((const char*)Al + off);
    }
#pragma unroll
    for (int n = 0; n < 4; ++n)
      bfr[n] = *reinterpret_cast<const bf16x8*>((const char*)Bh + TOFF(wc * 64 + n * 16 + q, G));
#pragma unroll
    for (int m = 0; m < 4; ++m)
#pragma unroll
      for (int n = 0; n < 4; ++n) {
        acc[m][n] = __builtin_amdgcn_mfma_f32_16x16x32_bf16(afh[m], bfr[n], acc[m][n], 0, 0, 0);
        acc[m][n] = __builtin_amdgcn_mfma_f32_16x16x32_bf16(afl[m], bfr[n], acc[m][n], 0, 0, 0);
      }
  }
#pragma unroll
  for (int m = 0; m < 4; ++m) {
    int row_b = m0 + wr * 64 + m * 16 + G * 4;  // d index
#pragma unroll
    for (int n = 0; n < 4; ++n) {
      int col = n0 + wc * 64 + n * 16 + q;      // token n
#pragma unroll
      for (int r = 0; r < 4; ++r) {
        int row = row_b + r;
        Vt[((size_t)b * 256 + row) * 1024 + col] = f2bf(acc[m][n][r] + bv[row]);
      }
    }
  }
}

// ---------------- FFN1: A = BN(Sraw) reg-staged (swizzled), B via global_load_lds ----------------
// 1D grid 1024: m0 = (id&127)*128, n0 = (id>>7)*128
__global__ __launch_bounds__(256) void gemm_ffn1(
    const float* __restrict__ Sraw,
    const u16* __restrict__ B_,
    const float* __restrict__ bias,
    const float* __restrict__ aslope,
    const float* __restrict__ ss,
    u16* __restrict__ H1B) {
  __shared__ u16 As[4096], Bs[4096];
  __shared__ float ssl[512];
  const int tid = threadIdx.x;
  const int lane = tid & 63, w = tid >> 6;
  const int wr = w >> 1, wc = w & 1;
  const int q = lane & 15, G = lane >> 4;
  const int id = blockIdx.x;
  const int m0 = (id & 127) * 128, n0 = (id >> 7) * 128;
  ssl[tid] = ss[tid];
  ssl[256 + tid] = ss[256 + tid];

  const int rr0 = w * 32 + (lane >> 2), rr1 = rr0 + 16;
  const int sl0 = (lane & 3) ^ ((rr0 >> 1) & 3);
  const int sl1 = (lane & 3) ^ ((rr1 >> 1) & 3);
  const size_t b0 = (size_t)(n0 + rr0) * 256 + sl0 * 8;
  const size_t b1 = (size_t)(n0 + rr1) * 256 + sl1 * 8;

  f32x4 acc[4][4] = {};
  for (int kt = 0; kt < 256; kt += 32) {
    __syncthreads();
    gll16(B_ + b0 + kt, &Bs[w * 1024]);
    gll16(B_ + b1 + kt, &Bs[w * 1024 + 512]);
#pragma unroll
    for (int i = 0; i < 4; ++i) {
      int idx = tid + i * 256;
      int r = idx >> 3, cc = idx & 7;
      int c4 = cc * 4;
      float4 v = *reinterpret_cast<const float4*>(Sraw + (size_t)(m0 + r) * 256 + kt + c4);
      ushort4 o;
      o.x = f2bf(v.x * ssl[kt + c4 + 0] + ssl[256 + kt + c4 + 0]);
      o.y = f2bf(v.y * ssl[kt + c4 + 1] + ssl[256 + kt + c4 + 1]);
      o.z = f2bf(v.z * ssl[kt + c4 + 2] + ssl[256 + kt + c4 + 2]);
      o.w = f2bf(v.w * ssl[kt + c4 + 3] + ssl[256 + kt + c4 + 3]);
      int off = (r << 6) + ((((cc >> 1) ^ ((r >> 1) & 3))) << 4) + (cc & 1) * 8;
      *reinterpret_cast<ushort4*>((char*)As + off) = o;
    }
    __syncthreads();
    bf16x8 af[4], bfr[4];
#pragma unroll
    for (int m = 0; m < 4; ++m)
      af[m] = *reinterpret_cast<const bf16x8*>((const char*)As + TOFF(wr * 64 + m * 16 + q, G));
#pragma unroll
    for (int n = 0; n < 4; ++n)
      bfr[n] = *reinterpret_cast<const bf16x8*>((const char*)Bs + TOFF(wc * 64 + n * 16 + q, G));
#pragma unroll
    for (int m = 0; m < 4; ++m)
#pragma unroll
      for (int n = 0; n < 4; ++n)
        acc[m][n] = __builtin_amdgcn_mfma_f32_16x16x32_bf16(af[m], bfr[n], acc[m][n], 0, 0, 0);
  }
  float a = aslope[0];
#pragma unroll
  for (int m = 0; m < 4; ++m) {
    int row_b = m0 + wr * 64 + m * 16 + G * 4;
#pragma unroll
    for (int n = 0; n < 4; ++n) {
      int col = n0 + wc * 64 + n * 16 + q;
      float bb = bias[col];
#pragma unroll
      for (int r = 0; r < 4; ++r) {
        float v = acc[m][n][r] + bb;
        v = (v >= 0.f) ? v : a * v;
        H1B[(size_t)(row_b + r) * 1024 + col] = f2bf(v);
      }
    }
  }
}

// ---------------- FFN2: BM=128 x BN=64, global_load_lds, fused resid + BN2 stats ----------------
// 1D grid 512: m0 = (id&127)*128, n0 = (id>>7)*64
__global__ __launch_bounds__(256) void gemm_ffn2(
    const u16* __restrict__ A_,
    const u16* __restrict__ B_,
    const float* __restrict__ bias,
    const float* __restrict__ Sraw,
    const float* __restrict__ ss,
    float* __restrict__ T2,
    float* __restrict__ stats2) {
  __shared__ u16 As[4096], Bs[2048];
  __shared__ float sred[2][64];
  const int tid = threadIdx.x;
  const int lane = tid & 63, w = tid >> 6;
  const int wr = w >> 1, wc = w & 1;
  const int q = lane & 15, G = lane >> 4;
  const int id = blockIdx.x;
  const int m0 = (id & 127) * 128, n0 = (id >> 7) * 64;
  if (tid < 64) { sred[0][tid] = 0.f; sred[1][tid] = 0.f; }

  const int rrA0 = w * 32 + (lane >> 2), rrA1 = rrA0 + 16;
  const int slA0 = (lane & 3) ^ ((rrA0 >> 1) & 3);
  const int slA1 = (lane & 3) ^ ((rrA1 >> 1) & 3);
  const size_t a0 = (size_t)(m0 + rrA0) * 1024 + slA0 * 8;
  const size_t a1 = (size_t)(m0 + rrA1) * 1024 + slA1 * 8;
  const int rrB = w * 16 + (lane >> 2);
  const int slB = (lane & 3) ^ ((rrB >> 1) & 3);
  const size_t b0 = (size_t)(n0 + rrB) * 1024 + slB * 8;

  f32x4 acc[4][2] = {};
  for (int kt = 0; kt < 1024; kt += 32) {
    __syncthreads();
    gll16(A_ + a0 + kt, &As[w * 1024]);
    gll16(A_ + a1 + kt, &As[w * 1024 + 512]);
    gll16(B_ + b0 + kt, &Bs[w * 512]);
    __syncthreads();
    bf16x8 af[4], bf2[2];
#pragma unroll
    for (int m = 0; m < 4; ++m)
      af[m] = *reinterpret_cast<const bf16x8*>((const char*)As + TOFF(wr * 64 + m * 16 + q, G));
#pragma unroll
    for (int n = 0; n < 2; ++n)
      bf2[n] = *reinterpret_cast<const bf16x8*>((const char*)Bs + TOFF(wc * 32 + n * 16 + q, G));
#pragma unroll
    for (int m = 0; m < 4; ++m)
#pragma unroll
      for (int n = 0; n < 2; ++n)
        acc[m][n] = __builtin_amdgcn_mfma_f32_16x16x32_bf16(af[m], bf2[n], acc[m][n], 0, 0, 0);
  }
  float s1a[2] = {0.f, 0.f}, s2a[2] = {0.f, 0.f};
#pragma unroll
  for (int m = 0; m < 4; ++m) {
    int row_b = m0 + wr * 64 + m * 16 + G * 4;
#pragma unroll
    for (int n = 0; n < 2; ++n) {
      int col = n0 + wc * 32 + n * 16 + q;
      float bb = bias[col];
      float sc_ = ss[col], of_ = ss[256 + col];
#pragma unroll
      for (int r = 0; r < 4; ++r) {
        int row = row_b + r;
        float resid = Sraw[(size_t)row * 256 + col] * sc_ + of_;
        float v = acc[m][n][r] + bb + resid;
        T2[(size_t)row * 256 + col] = v;
        s1a[n] += v;
        s2a[n] += v * v;
      }
    }
  }
#pragma unroll
  for (int n = 0; n < 2; ++n) {
    float a1 = s1a[n];
    a1 += __shfl_xor(a1, 16, 64);
    a1 += __shfl_xor(a1, 32, 64);
    float a2 = s2a[n];
    a2 += __shfl_xor(a2, 16, 64);
    a2 += __shfl_xor(a2, 32, 64);
    if (lane < 16) {
      atomicAdd(&sred[0][wc * 32 + n * 16 + lane], a1);
      atomicAdd(&sred[1][wc * 32 + n * 16 + lane], a2);
    }
  }
  __syncthreads();
  if (tid < 64) {
    atomicAdd(&stats2[n0 + tid], sred[0][tid]);
    atomicAdd(&stats2[256 + n0 + tid], sred[1][tid]);
  }
}

// ---------------- fused flash attention: swapped QK^T, permuted-k PV (zero shuffles) --------
// k-permutation: token t=32a+16b'+4g+r stored at position p=32a+8g+4b'+r, applied to BOTH
// P (lane-local pa build) and V (staging column permute) -> PV identical, no cross-lane ops.
#define SWZ(row, bcol) ((bcol) ^ (((row) & 7) << 4))
__global__ __launch_bounds__(256, 4) void attn_kernel(const u16* __restrict__ QKh,
                                                      const u16* __restrict__ QKl,
                                                      const u16* __restrict__ Vt,
                                                      const float* __restrict__ x,
                                                      float* __restrict__ Sout,
                                                      float* __restrict__ stats) {
  __shared__ u16 Kh[2][4096], Vs[2][4096];
  __shared__ float sred[2][64];
  const int tid = threadIdx.x, lane = tid & 63, w = tid >> 6;
  const int hb = blockIdx.x, h = hb & 3, b = hb >> 2;
  const size_t tb = (size_t)b * 1024;
  const int qrow0 = blockIdx.y * 64 + w * 16;
  const int q = lane & 15, G = lane >> 4;

  if (tid < 64) { sred[0][tid] = 0.f; sred[1][tid] = 0.f; }

  bf16x8 qh[2], ql[2];
#pragma unroll
  for (int kk = 0; kk < 2; ++kk) {
    size_t ro = (tb + qrow0 + q) * 512 + h * 64 + kk * 32 + G * 8;
    qh[kk] = *reinterpret_cast<const bf16x8*>(QKh + ro);
    ql[kk] = *reinterpret_cast<const bf16x8*>(QKl + ro);
  }

  f32x4 oacc[4] = {};
  float mprev = -3e38f, lsum = 0.f;

  const int sr0 = tid >> 3, sr1 = sr0 + 32;
  const int c7 = tid & 7;
  const int scb0 = c7 << 4;
  // K staging (token rows, linear cols + swizzle)
  const int dstb0 = sr0 * 128 + SWZ(sr0, scb0);
  const int dstb1 = sr1 * 128 + SWZ(sr1, scb0);
  const size_t kbase0 = (tb + sr0) * 512 + 256 + h * 64 + c7 * 8;
  const size_t kbase1 = (tb + sr1) * 512 + 256 + h * 64 + c7 * 8;
  // V staging (d rows, PERMUTED token cols): tokens 8c..8c+3 -> pos vb0.., 8c+4..8c+7 -> vb0+8..
  const int vb0 = 32 * (c7 >> 2) + 8 * ((2 * c7) & 3) + 4 * ((c7 >> 1) & 1);
  const int vx0 = (vb0 * 2) ^ ((sr0 & 7) << 4);        // (sr1&7)==(sr0&7)
  const int vx1 = (vb0 * 2 + 16) ^ ((sr0 & 7) << 4);
  const size_t vbase0 = ((size_t)b * 256 + h * 64 + sr0) * 1024 + c7 * 8;
  const size_t vbase1 = ((size_t)b * 256 + h * 64 + sr1) * 1024 + c7 * 8;

  uint4 rk0 = *reinterpret_cast<const uint4*>(QKh + kbase0);
  uint4 rk1 = *reinterpret_cast<const uint4*>(QKh + kbase1);
  uint4 rv0 = *reinterpret_cast<const uint4*>(Vt + vbase0);
  uint4 rv1 = *reinterpret_cast<const uint4*>(Vt + vbase1);
  *reinterpret_cast<uint4*>((char*)Kh[0] + dstb0) = rk0;
  *reinterpret_cast<uint4*>((char*)Kh[0] + dstb1) = rk1;
  {
    uint2 lo0 = {rv0.x, rv0.y}, hi0 = {rv0.z, rv0.w};
    uint2 lo1 = {rv1.x, rv1.y}, hi1 = {rv1.z, rv1.w};
    *reinterpret_cast<uint2*>((char*)Vs[0] + sr0 * 128 + vx0) = lo0;
    *reinterpret_cast<uint2*>((char*)Vs[0] + sr0 * 128 + vx1) = hi0;
    *reinterpret_cast<uint2*>((char*)Vs[0] + sr1 * 128 + vx0) = lo1;
    *reinterpret_cast<uint2*>((char*)Vs[0] + sr1 * 128 + vx1) = hi1;
  }
  __syncthreads();

  int cur = 0;
  for (int kt = 0; kt < 16; ++kt) {
    if (kt < 15) {
      rk0 = *reinterpret_cast<const uint4*>(QKh + kbase0 + (size_t)(kt + 1) * 32768);
      rk1 = *reinterpret_cast<const uint4*>(QKh + kbase1 + (size_t)(kt + 1) * 32768);
      rv0 = *reinterpret_cast<const uint4*>(Vt + vbase0 + (size_t)(kt + 1) * 64);
      rv1 = *reinterpret_cast<const uint4*>(Vt + vbase1 + (size_t)(kt + 1) * 64);
    }

    // QK^T swapped, 2-term: lane holds q=lane&15, k-tokens {16n+4G+r}
    f32x4 sc[4] = {};
    __builtin_amdgcn_s_setprio(1);
#pragma unroll
    for (int kk = 0; kk < 2; ++kk)
#pragma unroll
      for (int n = 0; n < 4; ++n) {
        int krow = n * 16 + q;
        int kb_ = krow * 128 + SWZ(krow, kk * 64 + G * 16);
        bf16x8 akh = *reinterpret_cast<const bf16x8*>((const char*)Kh[cur] + kb_);
        sc[n] = __builtin_amdgcn_mfma_f32_16x16x32_bf16(akh, qh[kk], sc[n], 0, 0, 0);
        sc[n] = __builtin_amdgcn_mfma_f32_16x16x32_bf16(akh, ql[kk], sc[n], 0, 0, 0);
      }
    __builtin_amdgcn_s_setprio(0);

    float vm;
    {
      float a0 = fmaxf(fmaxf(sc[0][0], sc[0][1]), fmaxf(sc[0][2], sc[0][3]));
      float a1 = fmaxf(fmaxf(sc[1][0], sc[1][1]), fmaxf(sc[1][2], sc[1][3]));
      float a2 = fmaxf(fmaxf(sc[2][0], sc[2][1]), fmaxf(sc[2][2], sc[2][3]));
      float a3 = fmaxf(fmaxf(sc[3][0], sc[3][1]), fmaxf(sc[3][2], sc[3][3]));
      vm = fmaxf(fmaxf(a0, a1), fmaxf(a2, a3));
      vm = fmaxf(vm, __shfl_xor(vm, 16, 64));
      vm = fmaxf(vm, __shfl_xor(vm, 32, 64));
    }
    bool ok = (vm <= mprev + 8.f);
    if (!__all(ok)) {
      float mn = fmaxf(mprev, vm);
      float scl = __expf(mprev - mn);
      mprev = mn;
      lsum *= scl;
      float sclr[4];
#pragma unroll
      for (int r = 0; r < 4; ++r) sclr[r] = __shfl(scl, G * 4 + r, 64);
#pragma unroll
      for (int dn = 0; dn < 4; ++dn)
#pragma unroll
        for (int r = 0; r < 4; ++r) oacc[dn][r] *= sclr[r];
    }
    float lt = 0.f;
#pragma unroll
    for (int n = 0; n < 4; ++n)
#pragma unroll
      for (int r = 0; r < 4; ++r) {
        float p = __expf(sc[n][r] - mprev);
        sc[n][r] = p;
        lt += p;
      }
    lsum += lt;
    // P pack: pa[kk] = own words only (k-permutation makes A-fragment lane-local)
    bf16x8 pa[2];
    {
      uint4 pw0, pw1;
      pw0.x = cvt_pk_bf16(sc[0][0], sc[0][1]);
      pw0.y = cvt_pk_bf16(sc[0][2], sc[0][3]);
      pw0.z = cvt_pk_bf16(sc[1][0], sc[1][1]);
      pw0.w = cvt_pk_bf16(sc[1][2], sc[1][3]);
      pw1.x = cvt_pk_bf16(sc[2][0], sc[2][1]);
      pw1.y = cvt_pk_bf16(sc[2][2], sc[2][3]);
      pw1.z = cvt_pk_bf16(sc[3][0], sc[3][1]);
      pw1.w = cvt_pk_bf16(sc[3][2], sc[3][3]);
      pa[0] = *reinterpret_cast<bf16x8*>(&pw0);
      pa[1] = *reinterpret_cast<bf16x8*>(&pw1);
    }
    // PV over permuted-k V tiles
    __builtin_amdgcn_s_setprio(1);
#pragma unroll
    for (int kk = 0; kk < 2; ++kk)
#pragma unroll
      for (int dn = 0; dn < 4; ++dn) {
        int vrow = dn * 16 + q;
        int vb_ = vrow * 128 + SWZ(vrow, kk * 64 + G * 16);
        bf16x8 vv = *reinterpret_cast<const bf16x8*>((const char*)Vs[cur] + vb_);
        oacc[dn] = __builtin_amdgcn_mfma_f32_16x16x32_bf16(pa[kk], vv, oacc[dn], 0, 0, 0);
      }
    __builtin_amdgcn_s_setprio(0);
    if (kt < 15) {
      *reinterpret_cast<uint4*>((char*)Kh[cur ^ 1] + dstb0) = rk0;
      *reinterpret_cast<uint4*>((char*)Kh[cur ^ 1] + dstb1) = rk1;
      uint2 lo0 = {rv0.x, rv0.y}, hi0 = {rv0.z, rv0.w};
      uint2 lo1 = {rv1.x, rv1.y}, hi1 = {rv1.z, rv1.w};
      *reinterpret_cast<uint2*>((char*)Vs[cur ^ 1] + sr0 * 128 + vx0) = lo0;
      *reinterpret_cast<uint2*>((char*)Vs[cur ^ 1] + sr0 * 128 + vx1) = hi0;
      *reinterpret_cast<uint2*>((char*)Vs[cur ^ 1] + sr1 * 128 + vx0) = lo1;
      *reinterpret_cast<uint2*>((char*)Vs[cur ^ 1] + sr1 * 128 + vx1) = hi1;
    }
    __syncthreads();
    cur ^= 1;
  }
  float lf = lsum;
  lf += __shfl_xor(lf, 16, 64);
  lf += __shfl_xor(lf, 32, 64);
  float rinv[4];
#pragma unroll
  for (int r = 0; r < 4; ++r) rinv[r] = 1.f / __shfl(lf, G * 4 + r, 64);

  // epilogue: O/l + residual x (direct from [B,C,N], float4 per dn), fused BN1 stats
  const int row0 = qrow0 + G * 4;
  const float* xp = x + ((size_t)b * 256 + h * 64) * 1024;
  float s1a[4] = {0.f, 0.f, 0.f, 0.f}, s2a[4] = {0.f, 0.f, 0.f, 0.f};
#pragma unroll
  for (int dn = 0; dn < 4; ++dn) {
    int col = dn * 16 + q;
    float4 xv = *reinterpret_cast<const float4*>(xp + (size_t)col * 1024 + row0);
    const float* xvp = reinterpret_cast<const float*>(&xv);
#pragma unroll
    for (int r = 0; r < 4; ++r) {
      size_t gi = (tb + row0 + r) * 256 + h * 64 + col;
      float v = oacc[dn][r] * rinv[r] + xvp[r];
      Sout[gi] = v;
      s1a[dn] += v;
      s2a[dn] += v * v;
    }
  }
#pragma unroll
  for (int dn = 0; dn < 4; ++dn) {
    float a1 = s1a[dn];
    a1 += __shfl_xor(a1, 16, 64);
    a1 += __shfl_xor(a1, 32, 64);
    float a2 = s2a[dn];
    a2 += __shfl_xor(a2, 16, 64);
    a2 += __shfl_xor(a2, 32, 64);
    if (lane < 16) {
      atomicAdd(&sred[0][dn * 16 + lane], a1);
      atomicAdd(&sred[1][dn * 16 + lane], a2);
    }
  }
  __syncthreads();
  if (tid < 64) {
    atomicAdd(&stats[h * 64 + tid], sred[0][tid]);
    atomicAdd(&stats[256 + h * 64 + tid], sred[1][tid]);
  }
}

// ---------------- BN finalize ----------------
__global__ void bn_finalize(const float* __restrict__ stats, const float* __restrict__ gamma,
                            const float* __restrict__ beta, float* __restrict__ ss) {
  int c = threadIdx.x;
  float mean = stats[c] * (1.f / 16384.f);
  float var = stats[256 + c] * (1.f / 16384.f) - mean * mean;
  float rstd = rsqrtf(var + 1e-5f);
  float scg = gamma[c] * rstd;
  ss[c] = scg;
  ss[256 + c] = beta[c] - mean * scg;
}

// final BN + transpose [T,C] -> [B,C,N]
__global__ __launch_bounds__(256) void bn_final_out(const float* __restrict__ T2,
                                                    const float* __restrict__ ss,
                                                    float* __restrict__ out) {
  __shared__ float tile[32][33];
  int n0 = (blockIdx.x & 31) * 32;
  int b = blockIdx.x >> 5;
  int c0 = blockIdx.y * 32;
  int tx = threadIdx.x, ty = threadIdx.y;
#pragma unroll
  for (int j = 0; j < 4; ++j) {
    int r = ty + j * 8;
    int c = c0 + tx;
    float v = T2[((size_t)b * 1024 + n0 + r) * 256 + c];
    tile[r][tx] = v * ss[c] + ss[256 + c];
  }
  __syncthreads();
#pragma unroll
  for (int j = 0; j < 4; ++j) {
    int c = c0 + ty + j * 8;
    out[((size_t)b * 256 + c) * 1024 + n0 + tx] = tile[tx][ty + j * 8];
  }
}

// ---------------- launch ----------------
extern "C" void kernel_launch(void* const* d_in, const int* in_sizes, int n_in,
                              void* d_out, int out_size, void* d_ws, size_t ws_size,
                              hipStream_t stream) {
  const float* x = (const float*)d_in[0];
  const float* Wq = (const float*)d_in[1];
  const float* bq = (const float*)d_in[2];
  const float* Wk = (const float*)d_in[3];
  const float* bk = (const float*)d_in[4];
  const float* Wv = (const float*)d_in[5];
  const float* bv = (const float*)d_in[6];
  const float* gamma = (const float*)d_in[7];
  const float* beta = (const float*)d_in[8];
  const float* W1 = (const float*)d_in[9];
  const float* b1 = (const float*)d_in[10];
  const float* a = (const float*)d_in[11];
  const float* W2 = (const float*)d_in[12];
  const float* b2 = (const float*)d_in[13];
  float* out = (float*)d_out;

  char* wsb = (char*)d_ws;
  const size_t MB = 1ull << 20;
  u16* XtbH = (u16*)(wsb + 0 * MB);       // 8MB
  u16* XtbL = (u16*)(wsb + 8 * MB);       // 8MB
  float* T2 = (float*)(wsb + 16 * MB);    // 16MB (ffn2 out)
  u16* QKh = (u16*)(wsb + 32 * MB);       // 16MB; aliased by H1B (32MB) after attn
  u16* QKl = (u16*)(wsb + 48 * MB);       // 16MB
  u16* Vt = (u16*)(wsb + 64 * MB);        // 8MB
  char* wp = wsb + 72 * MB;
  u16* WallH = (u16*)(wp);                // 256KB
  u16* WallL = (u16*)(wp + 262144);       // 256KB
  u16* WvH = (u16*)(wp + 524288);         // 128KB
  u16* WvL = (u16*)(wp + 655360);         // 128KB
  u16* W1b = (u16*)(wp + 786432);         // 512KB
  u16* W2b = (u16*)(wp + 1310720);        // 512KB
  float* bqk = (float*)(wp + 1835008);    // 2KB
  float* stats = (float*)(wp + 1837056);  // 8KB: stats1|ss1|stats2|ss2
  if (ws_size < 75 * MB) return;

  u16* H1B = QKh;    // [T,1024] bf16, after attn
  float* S = out;    // d_out doubles as o+x raw residual buffer [T,256]

  hipMemsetAsync(stats, 0, 8192, stream);
  transpose_x<<<dim3(32, 8, 16), dim3(32, 8), 0, stream>>>(x, XtbH, XtbL);
  prep_weights<<<1024, 256, 0, stream>>>(Wq, Wk, Wv, bq, bk, W1, W2,
                                         WallH, WallL, WvH, WvL, W1b, W2b, bqk);
  // QK projection: [16384,256] x [512,256]^T -> QKh/QKl [16384,512]
  gemm_qk<<<512, 256, 0, stream>>>(XtbH, XtbL, WallH, WallL, bqk, QKh, QKl);
  // V projection transposed: per batch [256,256] x [1024,256]^T -> Vt[b,256,1024]
  gemm_vt<<<dim3(8, 2, 16), 256, 0, stream>>>(WvH, WvL, XtbH, bv, Vt);
  // attention + residual + BN1 stats
  attn_kernel<<<dim3(64, 16), 256, 0, stream>>>(QKh, QKl, Vt, x, S, stats);
  bn_finalize<<<1, 256, 0, stream>>>(stats, gamma, beta, stats + 512);
  // FFN1: A = BN1(S) on the fly -> H1B bf16, bias+PReLU
  gemm_ffn1<<<1024, 256, 0, stream>>>(S, W1b, b1, a, stats + 512, H1B);
  // FFN2: [16384,1024] x [256,1024]^T -> T2 f32, bias + BN1(S) resid + BN2 stats
  gemm_ffn2<<<512, 256, 0, stream>>>(H1B, W2b, b2, S, stats + 512, T2, stats + 1024);
  bn_finalize<<<1, 256, 0, stream>>>(stats + 1024, gamma, beta, stats + 1536);
  // BN2 apply + transpose out
  bn_final_out<<<dim3(512, 8), dim3(32, 8), 0, stream>>>(T2, stats + 1536, out);
}

// Round 10
// 154.265 us; speedup vs baseline: 1.9792x; 1.0259x over previous
//
#include <hip/hip_runtime.h>
#include <hip/hip_bf16.h>

typedef unsigned short u16;
typedef unsigned int u32;
typedef __attribute__((ext_vector_type(8))) __bf16 bf16x8;
typedef __attribute__((ext_vector_type(4))) float f32x4;

__device__ inline u16 f2bf(float f) {
  unsigned int x = __float_as_uint(f);
  unsigned int r = (x + 0x7FFFu + ((x >> 16) & 1u)) >> 16;
  return (u16)r;
}
__device__ inline float bf2f(u16 u) { return __uint_as_float(((unsigned int)u) << 16); }
__device__ inline void split2(float v, u16& h, u16& l) {
  h = f2bf(v);
  l = f2bf(v - bf2f(h));
}
__device__ inline u32 cvt_pk_bf16(float lo, float hi) {
  u32 r;
  asm("v_cvt_pk_bf16_f32 %0, %1, %2" : "=v"(r) : "v"(lo), "v"(hi));
  return r;
}
// async global->LDS, 16B/lane; dest = wave-uniform base + lane*16
__device__ inline void gll16(const u16* g, u16* l) {
  __builtin_amdgcn_global_load_lds((const __attribute__((address_space(1))) void*)g,
                                   (__attribute__((address_space(3))) void*)l, 16, 0, 0);
}
// [R][32]-bf16 linear tile: logical (row, 16B-slot s) -> physical byte offset (XOR swizzle)
#define TOFF(r, s) (((r) << 6) + ((((s) ^ (((r) >> 1) & 3))) << 4))

// ---------------- x transpose: [B,C,N] f32 -> [B,N,C] bf16 hi/lo ----------------
__global__ __launch_bounds__(256) void transpose_x(const float* __restrict__ x,
                                                   u16* __restrict__ XtbH,
                                                   u16* __restrict__ XtbL) {
  __shared__ float tile[32][33];
  int n0 = blockIdx.x * 32;
  int c0 = blockIdx.y * 32;
  int b  = blockIdx.z;
  int tx = threadIdx.x, ty = threadIdx.y;
#pragma unroll
  for (int j = 0; j < 4; ++j) {
    int c = c0 + ty + j * 8;
    tile[ty + j * 8][tx] = x[((size_t)b * 256 + c) * 1024 + n0 + tx];
  }
  __syncthreads();
#pragma unroll
  for (int j = 0; j < 4; ++j) {
    int n = n0 + ty + j * 8;
    float v = tile[tx][ty + j * 8];
    size_t o = ((size_t)b * 1024 + n) * 256 + c0 + tx;
    u16 h, l;
    split2(v, h, l);
    XtbH[o] = h; XtbL[o] = l;
  }
}

// ---------------- weight prep ----------------
__global__ __launch_bounds__(256) void prep_weights(
    const float* __restrict__ Wq, const float* __restrict__ Wk, const float* __restrict__ Wv,
    const float* __restrict__ bq, const float* __restrict__ bk,
    const float* __restrict__ W1, const float* __restrict__ W2,
    u16* __restrict__ WallH, u16* __restrict__ WallL,
    u16* __restrict__ WvH, u16* __restrict__ WvL,
    u16* __restrict__ W1b, u16* __restrict__ W2b,
    float* __restrict__ bqk) {
  int i = blockIdx.x * 256 + threadIdx.x;
  if (i < 131072) {
    float w = (i < 65536) ? Wq[i] : Wk[i - 65536];
    u16 h, l;
    split2(w, h, l);
    WallH[i] = h; WallL[i] = l;
  }
  if (i < 65536) {
    u16 h, l;
    split2(Wv[i], h, l);
    WvH[i] = h; WvL[i] = l;
  }
  if (i < 262144) { W1b[i] = f2bf(W1[i]); W2b[i] = f2bf(W2[i]); }
  if (i < 256) bqk[i] = bq[i];
  else if (i < 512) bqk[i] = bk[i - 256];
}

// ---------------- QK projection GEMM, global_load_lds, XCD-chunked n-minor grid ----------
// grid 512: xcd=orig&7, eff=xcd*64+orig/8; n=eff&3, m=eff>>2 (XCD keeps 16 A-panels in L2)
__global__ __launch_bounds__(256) void gemm_qk(
    const u16* __restrict__ Ah_, const u16* __restrict__ Al_,
    const u16* __restrict__ Bh_, const u16* __restrict__ Bl_,
    const float* __restrict__ bias,
    u16* __restrict__ Ch, u16* __restrict__ Cl) {
  __shared__ u16 Ah[4096], Al[4096], Bh[4096], Bl[4096];
  const int tid = threadIdx.x;
  const int lane = tid & 63, w = tid >> 6;
  const int wr = w >> 1, wc = w & 1;
  const int q = lane & 15, G = lane >> 4;
  const int eff = (blockIdx.x & 7) * 64 + (blockIdx.x >> 3);
  const int m0 = (eff >> 2) * 128, n0 = (eff & 3) * 128;
  const bool isQ = (n0 < 256);  // K cols: bf16-hi output, skip W-lo term + Cl write

  const int rr0 = w * 32 + (lane >> 2), rr1 = rr0 + 16;
  const int sl0 = (lane & 3) ^ ((rr0 >> 1) & 3);
  const int sl1 = (lane & 3) ^ ((rr1 >> 1) & 3);
  const size_t a0 = (size_t)(m0 + rr0) * 256 + sl0 * 8;
  const size_t a1 = (size_t)(m0 + rr1) * 256 + sl1 * 8;
  const size_t b0 = (size_t)(n0 + rr0) * 256 + sl0 * 8;
  const size_t b1 = (size_t)(n0 + rr1) * 256 + sl1 * 8;

  f32x4 acc[4][4] = {};
  for (int kt = 0; kt < 256; kt += 32) {
    __syncthreads();
    gll16(Ah_ + a0 + kt, &Ah[w * 1024]);
    gll16(Ah_ + a1 + kt, &Ah[w * 1024 + 512]);
    gll16(Al_ + a0 + kt, &Al[w * 1024]);
    gll16(Al_ + a1 + kt, &Al[w * 1024 + 512]);
    gll16(Bh_ + b0 + kt, &Bh[w * 1024]);
    gll16(Bh_ + b1 + kt, &Bh[w * 1024 + 512]);
    gll16(Bl_ + b0 + kt, &Bl[w * 1024]);
    gll16(Bl_ + b1 + kt, &Bl[w * 1024 + 512]);
    __syncthreads();
    bf16x8 afh[4], afl[4], bfh[4], bfl[4];
#pragma unroll
    for (int m = 0; m < 4; ++m) {
      int off = TOFF(wr * 64 + m * 16 + q, G);
      afh[m] = *reinterpret_cast<const bf16x8*>((const char*)Ah + off);
      afl[m] = *reinterpret_cast<const bf16x8*>((const char*)Al + off);
    }
#pragma unroll
    for (int n = 0; n < 4; ++n) {
      int off = TOFF(wc * 64 + n * 16 + q, G);
      bfh[n] = *reinterpret_cast<const bf16x8*>((const char*)Bh + off);
      bfl[n] = *reinterpret_cast<const bf16x8*>((const char*)Bl + off);
    }
#pragma unroll
    for (int m = 0; m < 4; ++m)
#pragma unroll
      for (int n = 0; n < 4; ++n) {
        acc[m][n] = __builtin_amdgcn_mfma_f32_16x16x32_bf16(afh[m], bfh[n], acc[m][n], 0, 0, 0);
        acc[m][n] = __builtin_amdgcn_mfma_f32_16x16x32_bf16(afl[m], bfh[n], acc[m][n], 0, 0, 0);
      }
    if (isQ) {
#pragma unroll
      for (int m = 0; m < 4; ++m)
#pragma unroll
        for (int n = 0; n < 4; ++n)
          acc[m][n] = __builtin_amdgcn_mfma_f32_16x16x32_bf16(afh[m], bfl[n], acc[m][n], 0, 0, 0);
    }
  }
#pragma unroll
  for (int m = 0; m < 4; ++m) {
    int row_b = m0 + wr * 64 + m * 16 + G * 4;
#pragma unroll
    for (int n = 0; n < 4; ++n) {
      int col = n0 + wc * 64 + n * 16 + q;
      float bb = bias[col];
#pragma unroll
      for (int r = 0; r < 4; ++r) {
        size_t o = (size_t)(row_b + r) * 512 + col;
        u16 h, l;
        split2(acc[m][n][r] + bb, h, l);
        Ch[o] = h;
        if (isQ) Cl[o] = l;
      }
    }
  }
}

// ---------------- V projection, transposed output: Vt[b,d,n], XCD-chunked grid ----------
// grid 256: eff=(orig&7)*32+orig/8; m=eff&1, n=(eff>>1)&7, b=eff>>4
__global__ __launch_bounds__(256) void gemm_vt(
    const u16* __restrict__ WvH_, const u16* __restrict__ WvL_,
    const u16* __restrict__ XtbH, const float* __restrict__ bv,
    u16* __restrict__ Vt) {
  __shared__ u16 Ah[4096], Al[4096], Bh[4096];
  const int tid = threadIdx.x;
  const int lane = tid & 63, w = tid >> 6;
  const int wr = w >> 1, wc = w & 1;
  const int q = lane & 15, G = lane >> 4;
  const int eff = (blockIdx.x & 7) * 32 + (blockIdx.x >> 3);
  const int m0 = (eff & 1) * 128, n0 = ((eff >> 1) & 7) * 128, b = eff >> 4;
  const u16* Bp = XtbH + (size_t)b * 1024 * 256;

  const int rr0 = w * 32 + (lane >> 2), rr1 = rr0 + 16;
  const int sl0 = (lane & 3) ^ ((rr0 >> 1) & 3);
  const int sl1 = (lane & 3) ^ ((rr1 >> 1) & 3);
  const size_t a0 = (size_t)(m0 + rr0) * 256 + sl0 * 8;
  const size_t a1 = (size_t)(m0 + rr1) * 256 + sl1 * 8;
  const size_t b0 = (size_t)(n0 + rr0) * 256 + sl0 * 8;
  const size_t b1 = (size_t)(n0 + rr1) * 256 + sl1 * 8;

  f32x4 acc[4][4] = {};
  for (int kt = 0; kt < 256; kt += 32) {
    __syncthreads();
    gll16(WvH_ + a0 + kt, &Ah[w * 1024]);
    gll16(WvH_ + a1 + kt, &Ah[w * 1024 + 512]);
    gll16(WvL_ + a0 + kt, &Al[w * 1024]);
    gll16(WvL_ + a1 + kt, &Al[w * 1024 + 512]);
    gll16(Bp + b0 + kt, &Bh[w * 1024]);
    gll16(Bp + b1 + kt, &Bh[w * 1024 + 512]);
    __syncthreads();
    bf16x8 afh[4], afl[4], bfr[4];
#pragma unroll
    for (int m = 0; m < 4; ++m) {
      int off = TOFF(wr * 64 + m * 16 + q, G);
      afh[m] = *reinterpret_cast<const bf16x8*>((const char*)Ah + off);
      afl[m] = *reinterpret_cast<const bf16x8*>((const char*)Al + off);
    }
#pragma unroll
    for (int n = 0; n < 4; ++n)
      bfr[n] = *reinterpret_cast<const bf16x8*>((const char*)Bh + TOFF(wc * 64 + n * 16 + q, G));
#pragma unroll
    for (int m = 0; m < 4; ++m)
#pragma unroll
      for (int n = 0; n < 4; ++n) {
        acc[m][n] = __builtin_amdgcn_mfma_f32_16x16x32_bf16(afh[m], bfr[n], acc[m][n], 0, 0, 0);
        acc[m][n] = __builtin_amdgcn_mfma_f32_16x16x32_bf16(afl[m], bfr[n], acc[m][n], 0, 0, 0);
      }
  }
#pragma unroll
  for (int m = 0; m < 4; ++m) {
    int row_b = m0 + wr * 64 + m * 16 + G * 4;  // d index
#pragma unroll
    for (int n = 0; n < 4; ++n) {
      int col = n0 + wc * 64 + n * 16 + q;      // token n
#pragma unroll
      for (int r = 0; r < 4; ++r) {
        int row = row_b + r;
        Vt[((size_t)b * 256 + row) * 1024 + col] = f2bf(acc[m][n][r] + bv[row]);
      }
    }
  }
}

// ---------------- FFN1: A = BN(Sraw) reg-staged (swizzled), XCD-chunked grid ----------
// grid 1024: eff=(orig&7)*128+orig/8; n=eff&7, m=eff>>3 (A-panel L2-resident per XCD)
__global__ __launch_bounds__(256) void gemm_ffn1(
    const float* __restrict__ Sraw,
    const u16* __restrict__ B_,
    const float* __restrict__ bias,
    const float* __restrict__ aslope,
    const float* __restrict__ ss,
    u16* __restrict__ H1B) {
  __shared__ u16 As[4096], Bs[4096];
  __shared__ float ssl[512];
  const int tid = threadIdx.x;
  const int lane = tid & 63, w = tid >> 6;
  const int wr = w >> 1, wc = w & 1;
  const int q = lane & 15, G = lane >> 4;
  const int eff = (blockIdx.x & 7) * 128 + (blockIdx.x >> 3);
  const int m0 = (eff >> 3) * 128, n0 = (eff & 7) * 128;
  ssl[tid] = ss[tid];
  ssl[256 + tid] = ss[256 + tid];

  const int rr0 = w * 32 + (lane >> 2), rr1 = rr0 + 16;
  const int sl0 = (lane & 3) ^ ((rr0 >> 1) & 3);
  const int sl1 = (lane & 3) ^ ((rr1 >> 1) & 3);
  const size_t b0 = (size_t)(n0 + rr0) * 256 + sl0 * 8;
  const size_t b1 = (size_t)(n0 + rr1) * 256 + sl1 * 8;

  f32x4 acc[4][4] = {};
  for (int kt = 0; kt < 256; kt += 32) {
    __syncthreads();
    gll16(B_ + b0 + kt, &Bs[w * 1024]);
    gll16(B_ + b1 + kt, &Bs[w * 1024 + 512]);
#pragma unroll
    for (int i = 0; i < 4; ++i) {
      int idx = tid + i * 256;
      int r = idx >> 3, cc = idx & 7;
      int c4 = cc * 4;
      float4 v = *reinterpret_cast<const float4*>(Sraw + (size_t)(m0 + r) * 256 + kt + c4);
      ushort4 o;
      o.x = f2bf(v.x * ssl[kt + c4 + 0] + ssl[256 + kt + c4 + 0]);
      o.y = f2bf(v.y * ssl[kt + c4 + 1] + ssl[256 + kt + c4 + 1]);
      o.z = f2bf(v.z * ssl[kt + c4 + 2] + ssl[256 + kt + c4 + 2]);
      o.w = f2bf(v.w * ssl[kt + c4 + 3] + ssl[256 + kt + c4 + 3]);
      int off = (r << 6) + ((((cc >> 1) ^ ((r >> 1) & 3))) << 4) + (cc & 1) * 8;
      *reinterpret_cast<ushort4*>((char*)As + off) = o;
    }
    __syncthreads();
    bf16x8 af[4], bfr[4];
#pragma unroll
    for (int m = 0; m < 4; ++m)
      af[m] = *reinterpret_cast<const bf16x8*>((const char*)As + TOFF(wr * 64 + m * 16 + q, G));
#pragma unroll
    for (int n = 0; n < 4; ++n)
      bfr[n] = *reinterpret_cast<const bf16x8*>((const char*)Bs + TOFF(wc * 64 + n * 16 + q, G));
#pragma unroll
    for (int m = 0; m < 4; ++m)
#pragma unroll
      for (int n = 0; n < 4; ++n)
        acc[m][n] = __builtin_amdgcn_mfma_f32_16x16x32_bf16(af[m], bfr[n], acc[m][n], 0, 0, 0);
  }
  float a = aslope[0];
#pragma unroll
  for (int m = 0; m < 4; ++m) {
    int row_b = m0 + wr * 64 + m * 16 + G * 4;
#pragma unroll
    for (int n = 0; n < 4; ++n) {
      int col = n0 + wc * 64 + n * 16 + q;
      float bb = bias[col];
#pragma unroll
      for (int r = 0; r < 4; ++r) {
        float v = acc[m][n][r] + bb;
        v = (v >= 0.f) ? v : a * v;
        H1B[(size_t)(row_b + r) * 1024 + col] = f2bf(v);
      }
    }
  }
}

// ---------------- FFN2: BM=128 x BN=64, XCD-chunked grid, fused resid + BN2 stats ------
// grid 512: eff=(orig&7)*64+orig/8; n=eff&3, m=eff>>2 (A-panel L2-resident per XCD)
__global__ __launch_bounds__(256) void gemm_ffn2(
    const u16* __restrict__ A_,
    const u16* __restrict__ B_,
    const float* __restrict__ bias,
    const float* __restrict__ Sraw,
    const float* __restrict__ ss,
    float* __restrict__ T2,
    float* __restrict__ stats2) {
  __shared__ u16 As[4096], Bs[2048];
  __shared__ float sred[2][64];
  const int tid = threadIdx.x;
  const int lane = tid & 63, w = tid >> 6;
  const int wr = w >> 1, wc = w & 1;
  const int q = lane & 15, G = lane >> 4;
  const int eff = (blockIdx.x & 7) * 64 + (blockIdx.x >> 3);
  const int m0 = (eff >> 2) * 128, n0 = (eff & 3) * 64;
  if (tid < 64) { sred[0][tid] = 0.f; sred[1][tid] = 0.f; }

  const int rrA0 = w * 32 + (lane >> 2), rrA1 = rrA0 + 16;
  const int slA0 = (lane & 3) ^ ((rrA0 >> 1) & 3);
  const int slA1 = (lane & 3) ^ ((rrA1 >> 1) & 3);
  const size_t a0 = (size_t)(m0 + rrA0) * 1024 + slA0 * 8;
  const size_t a1 = (size_t)(m0 + rrA1) * 1024 + slA1 * 8;
  const int rrB = w * 16 + (lane >> 2);
  const int slB = (lane & 3) ^ ((rrB >> 1) & 3);
  const size_t b0 = (size_t)(n0 + rrB) * 1024 + slB * 8;

  f32x4 acc[4][2] = {};
  for (int kt = 0; kt < 1024; kt += 32) {
    __syncthreads();
    gll16(A_ + a0 + kt, &As[w * 1024]);
    gll16(A_ + a1 + kt, &As[w * 1024 + 512]);
    gll16(B_ + b0 + kt, &Bs[w * 512]);
    __syncthreads();
    bf16x8 af[4], bf2[2];
#pragma unroll
    for (int m = 0; m < 4; ++m)
      af[m] = *reinterpret_cast<const bf16x8*>((const char*)As + TOFF(wr * 64 + m * 16 + q, G));
#pragma unroll
    for (int n = 0; n < 2; ++n)
      bf2[n] = *reinterpret_cast<const bf16x8*>((const char*)Bs + TOFF(wc * 32 + n * 16 + q, G));
#pragma unroll
    for (int m = 0; m < 4; ++m)
#pragma unroll
      for (int n = 0; n < 2; ++n)
        acc[m][n] = __builtin_amdgcn_mfma_f32_16x16x32_bf16(af[m], bf2[n], acc[m][n], 0, 0, 0);
  }
  float s1a[2] = {0.f, 0.f}, s2a[2] = {0.f, 0.f};
#pragma unroll
  for (int m = 0; m < 4; ++m) {
    int row_b = m0 + wr * 64 + m * 16 + G * 4;
#pragma unroll
    for (int n = 0; n < 2; ++n) {
      int col = n0 + wc * 32 + n * 16 + q;
      float bb = bias[col];
      float sc_ = ss[col], of_ = ss[256 + col];
#pragma unroll
      for (int r = 0; r < 4; ++r) {
        int row = row_b + r;
        float resid = Sraw[(size_t)row * 256 + col] * sc_ + of_;
        float v = acc[m][n][r] + bb + resid;
        T2[(size_t)row * 256 + col] = v;
        s1a[n] += v;
        s2a[n] += v * v;
      }
    }
  }
#pragma unroll
  for (int n = 0; n < 2; ++n) {
    float a1 = s1a[n];
    a1 += __shfl_xor(a1, 16, 64);
    a1 += __shfl_xor(a1, 32, 64);
    float a2 = s2a[n];
    a2 += __shfl_xor(a2, 16, 64);
    a2 += __shfl_xor(a2, 32, 64);
    if (lane < 16) {
      atomicAdd(&sred[0][wc * 32 + n * 16 + lane], a1);
      atomicAdd(&sred[1][wc * 32 + n * 16 + lane], a2);
    }
  }
  __syncthreads();
  if (tid < 64) {
    atomicAdd(&stats2[n0 + tid], sred[0][tid]);
    atomicAdd(&stats2[256 + n0 + tid], sred[1][tid]);
  }
}

// ---------------- fused flash attention: swapped QK^T, permuted-k PV (zero shuffles) --------
#define SWZ(row, bcol) ((bcol) ^ (((row) & 7) << 4))
__global__ __launch_bounds__(256, 4) void attn_kernel(const u16* __restrict__ QKh,
                                                      const u16* __restrict__ QKl,
                                                      const u16* __restrict__ Vt,
                                                      const float* __restrict__ x,
                                                      float* __restrict__ Sout,
                                                      float* __restrict__ stats) {
  __shared__ u16 Kh[2][4096], Vs[2][4096];
  __shared__ float sred[2][64];
  const int tid = threadIdx.x, lane = tid & 63, w = tid >> 6;
  const int hb = blockIdx.x, h = hb & 3, b = hb >> 2;
  const size_t tb = (size_t)b * 1024;
  const int qrow0 = blockIdx.y * 64 + w * 16;
  const int q = lane & 15, G = lane >> 4;

  if (tid < 64) { sred[0][tid] = 0.f; sred[1][tid] = 0.f; }

  bf16x8 qh[2], ql[2];
#pragma unroll
  for (int kk = 0; kk < 2; ++kk) {
    size_t ro = (tb + qrow0 + q) * 512 + h * 64 + kk * 32 + G * 8;
    qh[kk] = *reinterpret_cast<const bf16x8*>(QKh + ro);
    ql[kk] = *reinterpret_cast<const bf16x8*>(QKl + ro);
  }

  f32x4 oacc[4] = {};
  float mprev = -3e38f, lsum = 0.f;

  const int sr0 = tid >> 3, sr1 = sr0 + 32;
  const int c7 = tid & 7;
  const int scb0 = c7 << 4;
  const int dstb0 = sr0 * 128 + SWZ(sr0, scb0);
  const int dstb1 = sr1 * 128 + SWZ(sr1, scb0);
  const size_t kbase0 = (tb + sr0) * 512 + 256 + h * 64 + c7 * 8;
  const size_t kbase1 = (tb + sr1) * 512 + 256 + h * 64 + c7 * 8;
  const int vb0 = 32 * (c7 >> 2) + 8 * ((2 * c7) & 3) + 4 * ((c7 >> 1) & 1);
  const int vx0 = (vb0 * 2) ^ ((sr0 & 7) << 4);
  const int vx1 = (vb0 * 2 + 16) ^ ((sr0 & 7) << 4);
  const size_t vbase0 = ((size_t)b * 256 + h * 64 + sr0) * 1024 + c7 * 8;
  const size_t vbase1 = ((size_t)b * 256 + h * 64 + sr1) * 1024 + c7 * 8;

  uint4 rk0 = *reinterpret_cast<const uint4*>(QKh + kbase0);
  uint4 rk1 = *reinterpret_cast<const uint4*>(QKh + kbase1);
  uint4 rv0 = *reinterpret_cast<const uint4*>(Vt + vbase0);
  uint4 rv1 = *reinterpret_cast<const uint4*>(Vt + vbase1);
  *reinterpret_cast<uint4*>((char*)Kh[0] + dstb0) = rk0;
  *reinterpret_cast<uint4*>((char*)Kh[0] + dstb1) = rk1;
  {
    uint2 lo0 = {rv0.x, rv0.y}, hi0 = {rv0.z, rv0.w};
    uint2 lo1 = {rv1.x, rv1.y}, hi1 = {rv1.z, rv1.w};
    *reinterpret_cast<uint2*>((char*)Vs[0] + sr0 * 128 + vx0) = lo0;
    *reinterpret_cast<uint2*>((char*)Vs[0] + sr0 * 128 + vx1) = hi0;
    *reinterpret_cast<uint2*>((char*)Vs[0] + sr1 * 128 + vx0) = lo1;
    *reinterpret_cast<uint2*>((char*)Vs[0] + sr1 * 128 + vx1) = hi1;
  }
  __syncthreads();

  int cur = 0;
  for (int kt = 0; kt < 16; ++kt) {
    if (kt < 15) {
      rk0 = *reinterpret_cast<const uint4*>(QKh + kbase0 + (size_t)(kt + 1) * 32768);
      rk1 = *reinterpret_cast<const uint4*>(QKh + kbase1 + (size_t)(kt + 1) * 32768);
      rv0 = *reinterpret_cast<const uint4*>(Vt + vbase0 + (size_t)(kt + 1) * 64);
      rv1 = *reinterpret_cast<const uint4*>(Vt + vbase1 + (size_t)(kt + 1) * 64);
    }

    f32x4 sc[4] = {};
    __builtin_amdgcn_s_setprio(1);
#pragma unroll
    for (int kk = 0; kk < 2; ++kk)
#pragma unroll
      for (int n = 0; n < 4; ++n) {
        int krow = n * 16 + q;
        int kb_ = krow * 128 + SWZ(krow, kk * 64 + G * 16);
        bf16x8 akh = *reinterpret_cast<const bf16x8*>((const char*)Kh[cur] + kb_);
        sc[n] = __builtin_amdgcn_mfma_f32_16x16x32_bf16(akh, qh[kk], sc[n], 0, 0, 0);
        sc[n] = __builtin_amdgcn_mfma_f32_16x16x32_bf16(akh, ql[kk], sc[n], 0, 0, 0);
      }
    __builtin_amdgcn_s_setprio(0);

    float vm;
    {
      float a0 = fmaxf(fmaxf(sc[0][0], sc[0][1]), fmaxf(sc[0][2], sc[0][3]));
      float a1 = fmaxf(fmaxf(sc[1][0], sc[1][1]), fmaxf(sc[1][2], sc[1][3]));
      float a2 = fmaxf(fmaxf(sc[2][0], sc[2][1]), fmaxf(sc[2][2], sc[2][3]));
      float a3 = fmaxf(fmaxf(sc[3][0], sc[3][1]), fmaxf(sc[3][2], sc[3][3]));
      vm = fmaxf(fmaxf(a0, a1), fmaxf(a2, a3));
      vm = fmaxf(vm, __shfl_xor(vm, 16, 64));
      vm = fmaxf(vm, __shfl_xor(vm, 32, 64));
    }
    bool ok = (vm <= mprev + 8.f);
    if (!__all(ok)) {
      float mn = fmaxf(mprev, vm);
      float scl = __expf(mprev - mn);
      mprev = mn;
      lsum *= scl;
      float sclr[4];
#pragma unroll
      for (int r = 0; r < 4; ++r) sclr[r] = __shfl(scl, G * 4 + r, 64);
#pragma unroll
      for (int dn = 0; dn < 4; ++dn)
#pragma unroll
        for (int r = 0; r < 4; ++r) oacc[dn][r] *= sclr[r];
    }
    float lt = 0.f;
#pragma unroll
    for (int n = 0; n < 4; ++n)
#pragma unroll
      for (int r = 0; r < 4; ++r) {
        float p = __expf(sc[n][r] - mprev);
        sc[n][r] = p;
        lt += p;
      }
    lsum += lt;
    bf16x8 pa[2];
    {
      uint4 pw0, pw1;
      pw0.x = cvt_pk_bf16(sc[0][0], sc[0][1]);
      pw0.y = cvt_pk_bf16(sc[0][2], sc[0][3]);
      pw0.z = cvt_pk_bf16(sc[1][0], sc[1][1]);
      pw0.w = cvt_pk_bf16(sc[1][2], sc[1][3]);
      pw1.x = cvt_pk_bf16(sc[2][0], sc[2][1]);
      pw1.y = cvt_pk_bf16(sc[2][2], sc[2][3]);
      pw1.z = cvt_pk_bf16(sc[3][0], sc[3][1]);
      pw1.w = cvt_pk_bf16(sc[3][2], sc[3][3]);
      pa[0] = *reinterpret_cast<bf16x8*>(&pw0);
      pa[1] = *reinterpret_cast<bf16x8*>(&pw1);
    }
    __builtin_amdgcn_s_setprio(1);
#pragma unroll
    for (int kk = 0; kk < 2; ++kk)
#pragma unroll
      for (int dn = 0; dn < 4; ++dn) {
        int vrow = dn * 16 + q;
        int vb_ = vrow * 128 + SWZ(vrow, kk * 64 + G * 16);
        bf16x8 vv = *reinterpret_cast<const bf16x8*>((const char*)Vs[cur] + vb_);
        oacc[dn] = __builtin_amdgcn_mfma_f32_16x16x32_bf16(pa[kk], vv, oacc[dn], 0, 0, 0);
      }
    __builtin_amdgcn_s_setprio(0);
    if (kt < 15) {
      *reinterpret_cast<uint4*>((char*)Kh[cur ^ 1] + dstb0) = rk0;
      *reinterpret_cast<uint4*>((char*)Kh[cur ^ 1] + dstb1) = rk1;
      uint2 lo0 = {rv0.x, rv0.y}, hi0 = {rv0.z, rv0.w};
      uint2 lo1 = {rv1.x, rv1.y}, hi1 = {rv1.z, rv1.w};
      *reinterpret_cast<uint2*>((char*)Vs[cur ^ 1] + sr0 * 128 + vx0) = lo0;
      *reinterpret_cast<uint2*>((char*)Vs[cur ^ 1] + sr0 * 128 + vx1) = hi0;
      *reinterpret_cast<uint2*>((char*)Vs[cur ^ 1] + sr1 * 128 + vx0) = lo1;
      *reinterpret_cast<uint2*>((char*)Vs[cur ^ 1] + sr1 * 128 + vx1) = hi1;
    }
    __syncthreads();
    cur ^= 1;
  }
  float lf = lsum;
  lf += __shfl_xor(lf, 16, 64);
  lf += __shfl_xor(lf, 32, 64);
  float rinv[4];
#pragma unroll
  for (int r = 0; r < 4; ++r) rinv[r] = 1.f / __shfl(lf, G * 4 + r, 64);

  const int row0 = qrow0 + G * 4;
  const float* xp = x + ((size_t)b * 256 + h * 64) * 1024;
  float s1a[4] = {0.f, 0.f, 0.f, 0.f}, s2a[4] = {0.f, 0.f, 0.f, 0.f};
#pragma unroll
  for (int dn = 0; dn < 4; ++dn) {
    int col = dn * 16 + q;
    float4 xv = *reinterpret_cast<const float4*>(xp + (size_t)col * 1024 + row0);
    const float* xvp = reinterpret_cast<const float*>(&xv);
#pragma unroll
    for (int r = 0; r < 4; ++r) {
      size_t gi = (tb + row0 + r) * 256 + h * 64 + col;
      float v = oacc[dn][r] * rinv[r] + xvp[r];
      Sout[gi] = v;
      s1a[dn] += v;
      s2a[dn] += v * v;
    }
  }
#pragma unroll
  for (int dn = 0; dn < 4; ++dn) {
    float a1 = s1a[dn];
    a1 += __shfl_xor(a1, 16, 64);
    a1 += __shfl_xor(a1, 32, 64);
    float a2 = s2a[dn];
    a2 += __shfl_xor(a2, 16, 64);
    a2 += __shfl_xor(a2, 32, 64);
    if (lane < 16) {
      atomicAdd(&sred[0][dn * 16 + lane], a1);
      atomicAdd(&sred[1][dn * 16 + lane], a2);
    }
  }
  __syncthreads();
  if (tid < 64) {
    atomicAdd(&stats[h * 64 + tid], sred[0][tid]);
    atomicAdd(&stats[256 + h * 64 + tid], sred[1][tid]);
  }
}

// ---------------- BN finalize ----------------
__global__ void bn_finalize(const float* __restrict__ stats, const float* __restrict__ gamma,
                            const float* __restrict__ beta, float* __restrict__ ss) {
  int c = threadIdx.x;
  float mean = stats[c] * (1.f / 16384.f);
  float var = stats[256 + c] * (1.f / 16384.f) - mean * mean;
  float rstd = rsqrtf(var + 1e-5f);
  float scg = gamma[c] * rstd;
  ss[c] = scg;
  ss[256 + c] = beta[c] - mean * scg;
}

// final BN + transpose [T,C] -> [B,C,N]
__global__ __launch_bounds__(256) void bn_final_out(const float* __restrict__ T2,
                                                    const float* __restrict__ ss,
                                                    float* __restrict__ out) {
  __shared__ float tile[32][33];
  int n0 = (blockIdx.x & 31) * 32;
  int b = blockIdx.x >> 5;
  int c0 = blockIdx.y * 32;
  int tx = threadIdx.x, ty = threadIdx.y;
#pragma unroll
  for (int j = 0; j < 4; ++j) {
    int r = ty + j * 8;
    int c = c0 + tx;
    float v = T2[((size_t)b * 1024 + n0 + r) * 256 + c];
    tile[r][tx] = v * ss[c] + ss[256 + c];
  }
  __syncthreads();
#pragma unroll
  for (int j = 0; j < 4; ++j) {
    int c = c0 + ty + j * 8;
    out[((size_t)b * 256 + c) * 1024 + n0 + tx] = tile[tx][ty + j * 8];
  }
}

// ---------------- launch ----------------
extern "C" void kernel_launch(void* const* d_in, const int* in_sizes, int n_in,
                              void* d_out, int out_size, void* d_ws, size_t ws_size,
                              hipStream_t stream) {
  const float* x = (const float*)d_in[0];
  const float* Wq = (const float*)d_in[1];
  const float* bq = (const float*)d_in[2];
  const float* Wk = (const float*)d_in[3];
  const float* bk = (const float*)d_in[4];
  const float* Wv = (const float*)d_in[5];
  const float* bv = (const float*)d_in[6];
  const float* gamma = (const float*)d_in[7];
  const float* beta = (const float*)d_in[8];
  const float* W1 = (const float*)d_in[9];
  const float* b1 = (const float*)d_in[10];
  const float* a = (const float*)d_in[11];
  const float* W2 = (const float*)d_in[12];
  const float* b2 = (const float*)d_in[13];
  float* out = (float*)d_out;

  char* wsb = (char*)d_ws;
  const size_t MB = 1ull << 20;
  u16* XtbH = (u16*)(wsb + 0 * MB);       // 8MB
  u16* XtbL = (u16*)(wsb + 8 * MB);       // 8MB
  float* T2 = (float*)(wsb + 16 * MB);    // 16MB (ffn2 out)
  u16* QKh = (u16*)(wsb + 32 * MB);       // 16MB; aliased by H1B (32MB) after attn
  u16* QKl = (u16*)(wsb + 48 * MB);       // 16MB
  u16* Vt = (u16*)(wsb + 64 * MB);        // 8MB
  char* wp = wsb + 72 * MB;
  u16* WallH = (u16*)(wp);                // 256KB
  u16* WallL = (u16*)(wp + 262144);       // 256KB
  u16* WvH = (u16*)(wp + 524288);         // 128KB
  u16* WvL = (u16*)(wp + 655360);         // 128KB
  u16* W1b = (u16*)(wp + 786432);         // 512KB
  u16* W2b = (u16*)(wp + 1310720);        // 512KB
  float* bqk = (float*)(wp + 1835008);    // 2KB
  float* stats = (float*)(wp + 1837056);  // 8KB: stats1|ss1|stats2|ss2
  if (ws_size < 75 * MB) return;

  u16* H1B = QKh;    // [T,1024] bf16, after attn
  float* S = out;    // d_out doubles as o+x raw residual buffer [T,256]

  hipMemsetAsync(stats, 0, 8192, stream);
  transpose_x<<<dim3(32, 8, 16), dim3(32, 8), 0, stream>>>(x, XtbH, XtbL);
  prep_weights<<<1024, 256, 0, stream>>>(Wq, Wk, Wv, bq, bk, W1, W2,
                                         WallH, WallL, WvH, WvL, W1b, W2b, bqk);
  // QK projection: [16384,256] x [512,256]^T -> QKh/QKl [16384,512]
  gemm_qk<<<512, 256, 0, stream>>>(XtbH, XtbL, WallH, WallL, bqk, QKh, QKl);
  // V projection transposed: per batch [256,256] x [1024,256]^T -> Vt[b,256,1024]
  gemm_vt<<<256, 256, 0, stream>>>(WvH, WvL, XtbH, bv, Vt);
  // attention + residual + BN1 stats
  attn_kernel<<<dim3(64, 16), 256, 0, stream>>>(QKh, QKl, Vt, x, S, stats);
  bn_finalize<<<1, 256, 0, stream>>>(stats, gamma, beta, stats + 512);
  // FFN1: A = BN1(S) on the fly -> H1B bf16, bias+PReLU
  gemm_ffn1<<<1024, 256, 0, stream>>>(S, W1b, b1, a, stats + 512, H1B);
  // FFN2: [16384,1024] x [256,1024]^T -> T2 f32, bias + BN1(S) resid + BN2 stats
  gemm_ffn2<<<512, 256, 0, stream>>>(H1B, W2b, b2, S, stats + 512, T2, stats + 1024);
  bn_finalize<<<1, 256, 0, stream>>>(stats + 1024, gamma, beta, stats + 1536);
  // BN2 apply + transpose out
  bn_final_out<<<dim3(512, 8), dim3(32, 8), 0, stream>>>(T2, stats + 1536, out);
}

// Round 11
// 143.179 us; speedup vs baseline: 2.1324x; 1.0774x over previous
//
#include <hip/hip_runtime.h>
#include <hip/hip_bf16.h>

typedef unsigned short u16;
typedef unsigned int u32;
typedef __attribute__((ext_vector_type(8))) __bf16 bf16x8;
typedef __attribute__((ext_vector_type(4))) float f32x4;

__device__ inline u16 f2bf(float f) {
  unsigned int x = __float_as_uint(f);
  unsigned int r = (x + 0x7FFFu + ((x >> 16) & 1u)) >> 16;
  return (u16)r;
}
__device__ inline float bf2f(u16 u) { return __uint_as_float(((unsigned int)u) << 16); }
__device__ inline void split2(float v, u16& h, u16& l) {
  h = f2bf(v);
  l = f2bf(v - bf2f(h));
}
__device__ inline u32 cvt_pk_bf16(float lo, float hi) {
  u32 r;
  asm("v_cvt_pk_bf16_f32 %0, %1, %2" : "=v"(r) : "v"(lo), "v"(hi));
  return r;
}
// async global->LDS, 16B/lane; dest = wave-uniform base + lane*16
__device__ inline void gll16(const u16* g, u16* l) {
  __builtin_amdgcn_global_load_lds((const __attribute__((address_space(1))) void*)g,
                                   (__attribute__((address_space(3))) void*)l, 16, 0, 0);
}
// [R][32]-bf16 tile (64B rows): logical (row, slot s in 0..3) -> physical byte offset
#define TOFF(r, s) (((r) << 6) + ((((s) ^ (((r) >> 1) & 3))) << 4))
// [R][64]-bf16 tile (128B rows): logical (row, slot s in 0..7) -> physical byte offset
#define TOFF2(r, s) (((r) << 7) + ((((s) ^ ((r) & 7))) << 4))

// ---------------- fused: x transpose + weight prep ----------------
__global__ __launch_bounds__(256) void prep_all(
    const float* __restrict__ x,
    const float* __restrict__ Wq, const float* __restrict__ Wk, const float* __restrict__ Wv,
    const float* __restrict__ bq, const float* __restrict__ bk,
    const float* __restrict__ W1, const float* __restrict__ W2,
    u16* __restrict__ XtbH, u16* __restrict__ XtbL,
    u16* __restrict__ WallH, u16* __restrict__ WallL,
    u16* __restrict__ WvH, u16* __restrict__ WvL,
    u16* __restrict__ W1b, u16* __restrict__ W2b,
    float* __restrict__ bqk) {
  __shared__ float tile[32][33];
  const int id = blockIdx.x;
  if (id < 4096) {
    // transpose role: [B,C,N] f32 -> [B,N,C] bf16 hi/lo
    int n0 = (id & 31) * 32, c0 = ((id >> 5) & 7) * 32, b = id >> 8;
    int tx = threadIdx.x & 31, ty = threadIdx.x >> 5;
#pragma unroll
    for (int j = 0; j < 4; ++j) {
      int c = c0 + ty + j * 8;
      tile[ty + j * 8][tx] = x[((size_t)b * 256 + c) * 1024 + n0 + tx];
    }
    __syncthreads();
#pragma unroll
    for (int j = 0; j < 4; ++j) {
      int n = n0 + ty + j * 8;
      float v = tile[tx][ty + j * 8];
      size_t o = ((size_t)b * 1024 + n) * 256 + c0 + tx;
      u16 h, l;
      split2(v, h, l);
      XtbH[o] = h; XtbL[o] = l;
    }
  } else {
    int i = (id - 4096) * 256 + threadIdx.x;
    if (i < 131072) {
      float w = (i < 65536) ? Wq[i] : Wk[i - 65536];
      u16 h, l;
      split2(w, h, l);
      WallH[i] = h; WallL[i] = l;
    }
    if (i < 65536) {
      u16 h, l;
      split2(Wv[i], h, l);
      WvH[i] = h; WvL[i] = l;
    }
    if (i < 262144) { W1b[i] = f2bf(W1[i]); W2b[i] = f2bf(W2[i]); }
    if (i < 256) bqk[i] = bq[i];
    else if (i < 512) bqk[i] = bk[i - 256];
  }
}

// ---------------- fused QK-projection + V-projection (one dispatch, role by id) ----------
// id < 512: QK role (eff=(id&7)*64+id/8; n=eff&3, m=eff>>2)
// id >= 512: Vt role (o=id-512; eff=(o&7)*32+o/8; m=eff&1, n=(eff>>1)&7, b=eff>>4)
__global__ __launch_bounds__(256) void gemm_qkvt(
    const u16* __restrict__ Ah_, const u16* __restrict__ Al_,
    const u16* __restrict__ Bh_, const u16* __restrict__ Bl_,
    const float* __restrict__ bias,
    u16* __restrict__ Ch, u16* __restrict__ Cl,
    const u16* __restrict__ WvH_, const u16* __restrict__ WvL_,
    const float* __restrict__ bv, u16* __restrict__ Vt) {
  __shared__ u16 Ah[4096], Al[4096], Bh[4096], Bl[4096];
  const int tid = threadIdx.x;
  const int lane = tid & 63, w = tid >> 6;
  const int wr = w >> 1, wc = w & 1;
  const int q = lane & 15, G = lane >> 4;
  const int rr0 = w * 32 + (lane >> 2), rr1 = rr0 + 16;
  const int sl0 = (lane & 3) ^ ((rr0 >> 1) & 3);
  const int sl1 = (lane & 3) ^ ((rr1 >> 1) & 3);

  if (blockIdx.x < 512) {
    // ---- QK role ----
    const int eff = (blockIdx.x & 7) * 64 + (blockIdx.x >> 3);
    const int m0 = (eff >> 2) * 128, n0 = (eff & 3) * 128;
    const bool isQ = (n0 < 256);
    const size_t a0 = (size_t)(m0 + rr0) * 256 + sl0 * 8;
    const size_t a1 = (size_t)(m0 + rr1) * 256 + sl1 * 8;
    const size_t b0 = (size_t)(n0 + rr0) * 256 + sl0 * 8;
    const size_t b1 = (size_t)(n0 + rr1) * 256 + sl1 * 8;

    f32x4 acc[4][4] = {};
    for (int kt = 0; kt < 256; kt += 32) {
      __syncthreads();
      gll16(Ah_ + a0 + kt, &Ah[w * 1024]);
      gll16(Ah_ + a1 + kt, &Ah[w * 1024 + 512]);
      gll16(Al_ + a0 + kt, &Al[w * 1024]);
      gll16(Al_ + a1 + kt, &Al[w * 1024 + 512]);
      gll16(Bh_ + b0 + kt, &Bh[w * 1024]);
      gll16(Bh_ + b1 + kt, &Bh[w * 1024 + 512]);
      gll16(Bl_ + b0 + kt, &Bl[w * 1024]);
      gll16(Bl_ + b1 + kt, &Bl[w * 1024 + 512]);
      __syncthreads();
      bf16x8 afh[4], afl[4], bfh[4], bfl[4];
#pragma unroll
      for (int m = 0; m < 4; ++m) {
        int off = TOFF(wr * 64 + m * 16 + q, G);
        afh[m] = *reinterpret_cast<const bf16x8*>((const char*)Ah + off);
        afl[m] = *reinterpret_cast<const bf16x8*>((const char*)Al + off);
      }
#pragma unroll
      for (int n = 0; n < 4; ++n) {
        int off = TOFF(wc * 64 + n * 16 + q, G);
        bfh[n] = *reinterpret_cast<const bf16x8*>((const char*)Bh + off);
        bfl[n] = *reinterpret_cast<const bf16x8*>((const char*)Bl + off);
      }
#pragma unroll
      for (int m = 0; m < 4; ++m)
#pragma unroll
        for (int n = 0; n < 4; ++n) {
          acc[m][n] = __builtin_amdgcn_mfma_f32_16x16x32_bf16(afh[m], bfh[n], acc[m][n], 0, 0, 0);
          acc[m][n] = __builtin_amdgcn_mfma_f32_16x16x32_bf16(afl[m], bfh[n], acc[m][n], 0, 0, 0);
        }
      if (isQ) {
#pragma unroll
        for (int m = 0; m < 4; ++m)
#pragma unroll
          for (int n = 0; n < 4; ++n)
            acc[m][n] = __builtin_amdgcn_mfma_f32_16x16x32_bf16(afh[m], bfl[n], acc[m][n], 0, 0, 0);
      }
    }
#pragma unroll
    for (int m = 0; m < 4; ++m) {
      int row_b = m0 + wr * 64 + m * 16 + G * 4;
#pragma unroll
      for (int n = 0; n < 4; ++n) {
        int col = n0 + wc * 64 + n * 16 + q;
        float bb = bias[col];
#pragma unroll
        for (int r = 0; r < 4; ++r) {
          size_t o = (size_t)(row_b + r) * 512 + col;
          u16 h, l;
          split2(acc[m][n][r] + bb, h, l);
          Ch[o] = h;
          if (isQ) Cl[o] = l;
        }
      }
    }
  } else {
    // ---- Vt role ----
    const int o_ = blockIdx.x - 512;
    const int eff = (o_ & 7) * 32 + (o_ >> 3);
    const int m0 = (eff & 1) * 128, n0 = ((eff >> 1) & 7) * 128, b = eff >> 4;
    const u16* Bp = Ah_ + (size_t)b * 1024 * 256;  // XtbH
    const size_t a0 = (size_t)(m0 + rr0) * 256 + sl0 * 8;
    const size_t a1 = (size_t)(m0 + rr1) * 256 + sl1 * 8;
    const size_t b0 = (size_t)(n0 + rr0) * 256 + sl0 * 8;
    const size_t b1 = (size_t)(n0 + rr1) * 256 + sl1 * 8;

    f32x4 acc[4][4] = {};
    for (int kt = 0; kt < 256; kt += 32) {
      __syncthreads();
      gll16(WvH_ + a0 + kt, &Ah[w * 1024]);
      gll16(WvH_ + a1 + kt, &Ah[w * 1024 + 512]);
      gll16(WvL_ + a0 + kt, &Al[w * 1024]);
      gll16(WvL_ + a1 + kt, &Al[w * 1024 + 512]);
      gll16(Bp + b0 + kt, &Bh[w * 1024]);
      gll16(Bp + b1 + kt, &Bh[w * 1024 + 512]);
      __syncthreads();
      bf16x8 afh[4], afl[4], bfr[4];
#pragma unroll
      for (int m = 0; m < 4; ++m) {
        int off = TOFF(wr * 64 + m * 16 + q, G);
        afh[m] = *reinterpret_cast<const bf16x8*>((const char*)Ah + off);
        afl[m] = *reinterpret_cast<const bf16x8*>((const char*)Al + off);
      }
#pragma unroll
      for (int n = 0; n < 4; ++n)
        bfr[n] = *reinterpret_cast<const bf16x8*>((const char*)Bh + TOFF(wc * 64 + n * 16 + q, G));
#pragma unroll
      for (int m = 0; m < 4; ++m)
#pragma unroll
        for (int n = 0; n < 4; ++n) {
          acc[m][n] = __builtin_amdgcn_mfma_f32_16x16x32_bf16(afh[m], bfr[n], acc[m][n], 0, 0, 0);
          acc[m][n] = __builtin_amdgcn_mfma_f32_16x16x32_bf16(afl[m], bfr[n], acc[m][n], 0, 0, 0);
        }
    }
#pragma unroll
    for (int m = 0; m < 4; ++m) {
      int row_b = m0 + wr * 64 + m * 16 + G * 4;  // d index
#pragma unroll
      for (int n = 0; n < 4; ++n) {
        int col = n0 + wc * 64 + n * 16 + q;      // token n
#pragma unroll
        for (int r = 0; r < 4; ++r) {
          int row = row_b + r;
          Vt[((size_t)b * 256 + row) * 1024 + col] = f2bf(acc[m][n][r] + bv[row]);
        }
      }
    }
  }
}

// ---------------- FFN1: A = BN(Sraw) reg-staged (swizzled), inline BN finalize ----------
// grid 1024: eff=(orig&7)*128+orig/8; n=eff&7, m=eff>>3
__global__ __launch_bounds__(256) void gemm_ffn1(
    const float* __restrict__ Sraw,
    const u16* __restrict__ B_,
    const float* __restrict__ bias,
    const float* __restrict__ aslope,
    const float* __restrict__ stats1,
    const float* __restrict__ gamma,
    const float* __restrict__ beta,
    u16* __restrict__ H1B) {
  __shared__ u16 As[4096], Bs[4096];
  __shared__ float ssl[512];
  const int tid = threadIdx.x;
  const int lane = tid & 63, w = tid >> 6;
  const int wr = w >> 1, wc = w & 1;
  const int q = lane & 15, G = lane >> 4;
  const int eff = (blockIdx.x & 7) * 128 + (blockIdx.x >> 3);
  const int m0 = (eff >> 3) * 128, n0 = (eff & 7) * 128;
  {
    float mean = stats1[tid] * (1.f / 16384.f);
    float var = stats1[256 + tid] * (1.f / 16384.f) - mean * mean;
    float scg = gamma[tid] * rsqrtf(var + 1e-5f);
    ssl[tid] = scg;
    ssl[256 + tid] = beta[tid] - mean * scg;
  }

  const int rr0 = w * 32 + (lane >> 2), rr1 = rr0 + 16;
  const int sl0 = (lane & 3) ^ ((rr0 >> 1) & 3);
  const int sl1 = (lane & 3) ^ ((rr1 >> 1) & 3);
  const size_t b0 = (size_t)(n0 + rr0) * 256 + sl0 * 8;
  const size_t b1 = (size_t)(n0 + rr1) * 256 + sl1 * 8;

  f32x4 acc[4][4] = {};
  for (int kt = 0; kt < 256; kt += 32) {
    __syncthreads();
    gll16(B_ + b0 + kt, &Bs[w * 1024]);
    gll16(B_ + b1 + kt, &Bs[w * 1024 + 512]);
#pragma unroll
    for (int i = 0; i < 4; ++i) {
      int idx = tid + i * 256;
      int r = idx >> 3, cc = idx & 7;
      int c4 = cc * 4;
      float4 v = *reinterpret_cast<const float4*>(Sraw + (size_t)(m0 + r) * 256 + kt + c4);
      ushort4 o;
      o.x = f2bf(v.x * ssl[kt + c4 + 0] + ssl[256 + kt + c4 + 0]);
      o.y = f2bf(v.y * ssl[kt + c4 + 1] + ssl[256 + kt + c4 + 1]);
      o.z = f2bf(v.z * ssl[kt + c4 + 2] + ssl[256 + kt + c4 + 2]);
      o.w = f2bf(v.w * ssl[kt + c4 + 3] + ssl[256 + kt + c4 + 3]);
      int off = (r << 6) + ((((cc >> 1) ^ ((r >> 1) & 3))) << 4) + (cc & 1) * 8;
      *reinterpret_cast<ushort4*>((char*)As + off) = o;
    }
    __syncthreads();
    bf16x8 af[4], bfr[4];
#pragma unroll
    for (int m = 0; m < 4; ++m)
      af[m] = *reinterpret_cast<const bf16x8*>((const char*)As + TOFF(wr * 64 + m * 16 + q, G));
#pragma unroll
    for (int n = 0; n < 4; ++n)
      bfr[n] = *reinterpret_cast<const bf16x8*>((const char*)Bs + TOFF(wc * 64 + n * 16 + q, G));
#pragma unroll
    for (int m = 0; m < 4; ++m)
#pragma unroll
      for (int n = 0; n < 4; ++n)
        acc[m][n] = __builtin_amdgcn_mfma_f32_16x16x32_bf16(af[m], bfr[n], acc[m][n], 0, 0, 0);
  }
  float a = aslope[0];
#pragma unroll
  for (int m = 0; m < 4; ++m) {
    int row_b = m0 + wr * 64 + m * 16 + G * 4;
#pragma unroll
    for (int n = 0; n < 4; ++n) {
      int col = n0 + wc * 64 + n * 16 + q;
      float bb = bias[col];
#pragma unroll
      for (int r = 0; r < 4; ++r) {
        float v = acc[m][n][r] + bb;
        v = (v >= 0.f) ? v : a * v;
        H1B[(size_t)(row_b + r) * 1024 + col] = f2bf(v);
      }
    }
  }
}

// ---------------- FFN2: BM=64 x BN=64 x BK=64, grid 1024, inline BN, fused stats ------
// eff=(orig&7)*128+orig/8; n=eff&3 (64-col blocks), m=eff>>2 (64-row blocks)
__global__ __launch_bounds__(256) void gemm_ffn2(
    const u16* __restrict__ A_,
    const u16* __restrict__ B_,
    const float* __restrict__ bias,
    const float* __restrict__ Sraw,
    const float* __restrict__ stats1,
    const float* __restrict__ gamma,
    const float* __restrict__ beta,
    float* __restrict__ T2,
    float* __restrict__ stats2) {
  __shared__ u16 As[4096], Bs[4096];   // 64x64 bf16 each
  __shared__ float ssl[512];
  __shared__ float sred[2][64];
  const int tid = threadIdx.x;
  const int lane = tid & 63, w = tid >> 6;
  const int wr = w >> 1, wc = w & 1;
  const int q = lane & 15, G = lane >> 4;
  const int eff = (blockIdx.x & 7) * 128 + (blockIdx.x >> 3);
  const int m0 = (eff >> 2) * 64, n0 = (eff & 3) * 64;
  {
    float mean = stats1[tid] * (1.f / 16384.f);
    float var = stats1[256 + tid] * (1.f / 16384.f) - mean * mean;
    float scg = gamma[tid] * rsqrtf(var + 1e-5f);
    ssl[tid] = scg;
    ssl[256 + tid] = beta[tid] - mean * scg;
  }
  if (tid < 64) { sred[0][tid] = 0.f; sred[1][tid] = 0.f; }

  const int rl = lane >> 3, sl8 = lane & 7;
  const int ssrc = (sl8 ^ rl) * 8;  // inverse-swizzled source col (TOFF2 pairing)

  f32x4 acc[2][2] = {};
  for (int kt = 0; kt < 1024; kt += 64) {
    __syncthreads();
#pragma unroll
    for (int i = 0; i < 2; ++i) {
      int rb = (i * 4 + w) * 8;
      gll16(A_ + (size_t)(m0 + rb + rl) * 1024 + kt + ssrc, &As[rb * 64]);
      gll16(B_ + (size_t)(n0 + rb + rl) * 1024 + kt + ssrc, &Bs[rb * 64]);
    }
    __syncthreads();
#pragma unroll
    for (int kk = 0; kk < 2; ++kk) {
      bf16x8 af[2], bf2[2];
#pragma unroll
      for (int m = 0; m < 2; ++m)
        af[m] = *reinterpret_cast<const bf16x8*>((const char*)As + TOFF2(wr * 32 + m * 16 + q, kk * 4 + G));
#pragma unroll
      for (int n = 0; n < 2; ++n)
        bf2[n] = *reinterpret_cast<const bf16x8*>((const char*)Bs + TOFF2(wc * 32 + n * 16 + q, kk * 4 + G));
#pragma unroll
      for (int m = 0; m < 2; ++m)
#pragma unroll
        for (int n = 0; n < 2; ++n)
          acc[m][n] = __builtin_amdgcn_mfma_f32_16x16x32_bf16(af[m], bf2[n], acc[m][n], 0, 0, 0);
    }
  }
  float s1a[2] = {0.f, 0.f}, s2a[2] = {0.f, 0.f};
#pragma unroll
  for (int m = 0; m < 2; ++m) {
    int row_b = m0 + wr * 32 + m * 16 + G * 4;
#pragma unroll
    for (int n = 0; n < 2; ++n) {
      int col = n0 + wc * 32 + n * 16 + q;
      float bb = bias[col];
      float sc_ = ssl[col], of_ = ssl[256 + col];
#pragma unroll
      for (int r = 0; r < 4; ++r) {
        int row = row_b + r;
        float resid = Sraw[(size_t)row * 256 + col] * sc_ + of_;
        float v = acc[m][n][r] + bb + resid;
        T2[(size_t)row * 256 + col] = v;
        s1a[n] += v;
        s2a[n] += v * v;
      }
    }
  }
#pragma unroll
  for (int n = 0; n < 2; ++n) {
    float a1 = s1a[n];
    a1 += __shfl_xor(a1, 16, 64);
    a1 += __shfl_xor(a1, 32, 64);
    float a2 = s2a[n];
    a2 += __shfl_xor(a2, 16, 64);
    a2 += __shfl_xor(a2, 32, 64);
    if (lane < 16) {
      atomicAdd(&sred[0][wc * 32 + n * 16 + lane], a1);
      atomicAdd(&sred[1][wc * 32 + n * 16 + lane], a2);
    }
  }
  __syncthreads();
  if (tid < 64) {
    atomicAdd(&stats2[n0 + tid], sred[0][tid]);
    atomicAdd(&stats2[256 + n0 + tid], sred[1][tid]);
  }
}

// ---------------- fused flash attention: swapped QK^T, permuted-k PV (zero shuffles) --------
#define SWZ(row, bcol) ((bcol) ^ (((row) & 7) << 4))
__global__ __launch_bounds__(256, 4) void attn_kernel(const u16* __restrict__ QKh,
                                                      const u16* __restrict__ QKl,
                                                      const u16* __restrict__ Vt,
                                                      const float* __restrict__ x,
                                                      float* __restrict__ Sout,
                                                      float* __restrict__ stats) {
  __shared__ u16 Kh[2][4096], Vs[2][4096];
  __shared__ float sred[2][64];
  const int tid = threadIdx.x, lane = tid & 63, w = tid >> 6;
  const int hb = blockIdx.x, h = hb & 3, b = hb >> 2;
  const size_t tb = (size_t)b * 1024;
  const int qrow0 = blockIdx.y * 64 + w * 16;
  const int q = lane & 15, G = lane >> 4;

  if (tid < 64) { sred[0][tid] = 0.f; sred[1][tid] = 0.f; }

  bf16x8 qh[2], ql[2];
#pragma unroll
  for (int kk = 0; kk < 2; ++kk) {
    size_t ro = (tb + qrow0 + q) * 512 + h * 64 + kk * 32 + G * 8;
    qh[kk] = *reinterpret_cast<const bf16x8*>(QKh + ro);
    ql[kk] = *reinterpret_cast<const bf16x8*>(QKl + ro);
  }

  f32x4 oacc[4] = {};
  float mprev = -3e38f, lsum = 0.f;

  const int sr0 = tid >> 3, sr1 = sr0 + 32;
  const int c7 = tid & 7;
  const int scb0 = c7 << 4;
  const int dstb0 = sr0 * 128 + SWZ(sr0, scb0);
  const int dstb1 = sr1 * 128 + SWZ(sr1, scb0);
  const size_t kbase0 = (tb + sr0) * 512 + 256 + h * 64 + c7 * 8;
  const size_t kbase1 = (tb + sr1) * 512 + 256 + h * 64 + c7 * 8;
  const int vb0 = 32 * (c7 >> 2) + 8 * ((2 * c7) & 3) + 4 * ((c7 >> 1) & 1);
  const int vx0 = (vb0 * 2) ^ ((sr0 & 7) << 4);
  const int vx1 = (vb0 * 2 + 16) ^ ((sr0 & 7) << 4);
  const size_t vbase0 = ((size_t)b * 256 + h * 64 + sr0) * 1024 + c7 * 8;
  const size_t vbase1 = ((size_t)b * 256 + h * 64 + sr1) * 1024 + c7 * 8;

  uint4 rk0 = *reinterpret_cast<const uint4*>(QKh + kbase0);
  uint4 rk1 = *reinterpret_cast<const uint4*>(QKh + kbase1);
  uint4 rv0 = *reinterpret_cast<const uint4*>(Vt + vbase0);
  uint4 rv1 = *reinterpret_cast<const uint4*>(Vt + vbase1);
  *reinterpret_cast<uint4*>((char*)Kh[0] + dstb0) = rk0;
  *reinterpret_cast<uint4*>((char*)Kh[0] + dstb1) = rk1;
  {
    uint2 lo0 = {rv0.x, rv0.y}, hi0 = {rv0.z, rv0.w};
    uint2 lo1 = {rv1.x, rv1.y}, hi1 = {rv1.z, rv1.w};
    *reinterpret_cast<uint2*>((char*)Vs[0] + sr0 * 128 + vx0) = lo0;
    *reinterpret_cast<uint2*>((char*)Vs[0] + sr0 * 128 + vx1) = hi0;
    *reinterpret_cast<uint2*>((char*)Vs[0] + sr1 * 128 + vx0) = lo1;
    *reinterpret_cast<uint2*>((char*)Vs[0] + sr1 * 128 + vx1) = hi1;
  }
  __syncthreads();

  int cur = 0;
  for (int kt = 0; kt < 16; ++kt) {
    if (kt < 15) {
      rk0 = *reinterpret_cast<const uint4*>(QKh + kbase0 + (size_t)(kt + 1) * 32768);
      rk1 = *reinterpret_cast<const uint4*>(QKh + kbase1 + (size_t)(kt + 1) * 32768);
      rv0 = *reinterpret_cast<const uint4*>(Vt + vbase0 + (size_t)(kt + 1) * 64);
      rv1 = *reinterpret_cast<const uint4*>(Vt + vbase1 + (size_t)(kt + 1) * 64);
    }

    f32x4 sc[4] = {};
    __builtin_amdgcn_s_setprio(1);
#pragma unroll
    for (int kk = 0; kk < 2; ++kk)
#pragma unroll
      for (int n = 0; n < 4; ++n) {
        int krow = n * 16 + q;
        int kb_ = krow * 128 + SWZ(krow, kk * 64 + G * 16);
        bf16x8 akh = *reinterpret_cast<const bf16x8*>((const char*)Kh[cur] + kb_);
        sc[n] = __builtin_amdgcn_mfma_f32_16x16x32_bf16(akh, qh[kk], sc[n], 0, 0, 0);
        sc[n] = __builtin_amdgcn_mfma_f32_16x16x32_bf16(akh, ql[kk], sc[n], 0, 0, 0);
      }
    __builtin_amdgcn_s_setprio(0);

    // row max via v_max3 chains (16 values -> 8 ops)
    float vm;
    {
      float t0 = fmaxf(fmaxf(sc[0][0], sc[0][1]), sc[0][2]);
      float t1 = fmaxf(fmaxf(sc[0][3], sc[1][0]), sc[1][1]);
      float t2 = fmaxf(fmaxf(sc[1][2], sc[1][3]), sc[2][0]);
      float t3 = fmaxf(fmaxf(sc[2][1], sc[2][2]), sc[2][3]);
      float t4 = fmaxf(fmaxf(sc[3][0], sc[3][1]), sc[3][2]);
      vm = fmaxf(fmaxf(fmaxf(t0, t1), t2), fmaxf(fmaxf(t3, t4), sc[3][3]));
      vm = fmaxf(vm, __shfl_xor(vm, 16, 64));
      vm = fmaxf(vm, __shfl_xor(vm, 32, 64));
    }
    bool ok = (vm <= mprev + 8.f);
    if (!__all(ok)) {
      float mn = fmaxf(mprev, vm);
      float scl = __expf(mprev - mn);
      mprev = mn;
      lsum *= scl;
      float sclr[4];
#pragma unroll
      for (int r = 0; r < 4; ++r) sclr[r] = __shfl(scl, G * 4 + r, 64);
#pragma unroll
      for (int dn = 0; dn < 4; ++dn)
#pragma unroll
        for (int r = 0; r < 4; ++r) oacc[dn][r] *= sclr[r];
    }
    float lt = 0.f;
#pragma unroll
    for (int n = 0; n < 4; ++n)
#pragma unroll
      for (int r = 0; r < 4; ++r) {
        float p = __expf(sc[n][r] - mprev);
        sc[n][r] = p;
        lt += p;
      }
    lsum += lt;
    bf16x8 pa[2];
    {
      uint4 pw0, pw1;
      pw0.x = cvt_pk_bf16(sc[0][0], sc[0][1]);
      pw0.y = cvt_pk_bf16(sc[0][2], sc[0][3]);
      pw0.z = cvt_pk_bf16(sc[1][0], sc[1][1]);
      pw0.w = cvt_pk_bf16(sc[1][2], sc[1][3]);
      pw1.x = cvt_pk_bf16(sc[2][0], sc[2][1]);
      pw1.y = cvt_pk_bf16(sc[2][2], sc[2][3]);
      pw1.z = cvt_pk_bf16(sc[3][0], sc[3][1]);
      pw1.w = cvt_pk_bf16(sc[3][2], sc[3][3]);
      pa[0] = *reinterpret_cast<bf16x8*>(&pw0);
      pa[1] = *reinterpret_cast<bf16x8*>(&pw1);
    }
    __builtin_amdgcn_s_setprio(1);
#pragma unroll
    for (int kk = 0; kk < 2; ++kk)
#pragma unroll
      for (int dn = 0; dn < 4; ++dn) {
        int vrow = dn * 16 + q;
        int vb_ = vrow * 128 + SWZ(vrow, kk * 64 + G * 16);
        bf16x8 vv = *reinterpret_cast<const bf16x8*>((const char*)Vs[cur] + vb_);
        oacc[dn] = __builtin_amdgcn_mfma_f32_16x16x32_bf16(pa[kk], vv, oacc[dn], 0, 0, 0);
      }
    __builtin_amdgcn_s_setprio(0);
    if (kt < 15) {
      *reinterpret_cast<uint4*>((char*)Kh[cur ^ 1] + dstb0) = rk0;
      *reinterpret_cast<uint4*>((char*)Kh[cur ^ 1] + dstb1) = rk1;
      uint2 lo0 = {rv0.x, rv0.y}, hi0 = {rv0.z, rv0.w};
      uint2 lo1 = {rv1.x, rv1.y}, hi1 = {rv1.z, rv1.w};
      *reinterpret_cast<uint2*>((char*)Vs[cur ^ 1] + sr0 * 128 + vx0) = lo0;
      *reinterpret_cast<uint2*>((char*)Vs[cur ^ 1] + sr0 * 128 + vx1) = hi0;
      *reinterpret_cast<uint2*>((char*)Vs[cur ^ 1] + sr1 * 128 + vx0) = lo1;
      *reinterpret_cast<uint2*>((char*)Vs[cur ^ 1] + sr1 * 128 + vx1) = hi1;
    }
    __syncthreads();
    cur ^= 1;
  }
  float lf = lsum;
  lf += __shfl_xor(lf, 16, 64);
  lf += __shfl_xor(lf, 32, 64);
  float rinv[4];
#pragma unroll
  for (int r = 0; r < 4; ++r) rinv[r] = 1.f / __shfl(lf, G * 4 + r, 64);

  const int row0 = qrow0 + G * 4;
  const float* xp = x + ((size_t)b * 256 + h * 64) * 1024;
  float s1a[4] = {0.f, 0.f, 0.f, 0.f}, s2a[4] = {0.f, 0.f, 0.f, 0.f};
#pragma unroll
  for (int dn = 0; dn < 4; ++dn) {
    int col = dn * 16 + q;
    float4 xv = *reinterpret_cast<const float4*>(xp + (size_t)col * 1024 + row0);
    const float* xvp = reinterpret_cast<const float*>(&xv);
#pragma unroll
    for (int r = 0; r < 4; ++r) {
      size_t gi = (tb + row0 + r) * 256 + h * 64 + col;
      float v = oacc[dn][r] * rinv[r] + xvp[r];
      Sout[gi] = v;
      s1a[dn] += v;
      s2a[dn] += v * v;
    }
  }
#pragma unroll
  for (int dn = 0; dn < 4; ++dn) {
    float a1 = s1a[dn];
    a1 += __shfl_xor(a1, 16, 64);
    a1 += __shfl_xor(a1, 32, 64);
    float a2 = s2a[dn];
    a2 += __shfl_xor(a2, 16, 64);
    a2 += __shfl_xor(a2, 32, 64);
    if (lane < 16) {
      atomicAdd(&sred[0][dn * 16 + lane], a1);
      atomicAdd(&sred[1][dn * 16 + lane], a2);
    }
  }
  __syncthreads();
  if (tid < 64) {
    atomicAdd(&stats[h * 64 + tid], sred[0][tid]);
    atomicAdd(&stats[256 + h * 64 + tid], sred[1][tid]);
  }
}

// ---------------- final BN (inline from stats2) + transpose [T,C] -> [B,C,N] ----------
__global__ __launch_bounds__(256) void bn_final_out(const float* __restrict__ T2,
                                                    const float* __restrict__ stats2,
                                                    const float* __restrict__ gamma,
                                                    const float* __restrict__ beta,
                                                    float* __restrict__ out) {
  __shared__ float tile[32][33];
  int n0 = (blockIdx.x & 31) * 32;
  int b = blockIdx.x >> 5;
  int c0 = blockIdx.y * 32;
  int tx = threadIdx.x, ty = threadIdx.y;
  int c = c0 + tx;
  float mean = stats2[c] * (1.f / 16384.f);
  float var = stats2[256 + c] * (1.f / 16384.f) - mean * mean;
  float scg = gamma[c] * rsqrtf(var + 1e-5f);
  float off = beta[c] - mean * scg;
#pragma unroll
  for (int j = 0; j < 4; ++j) {
    int r = ty + j * 8;
    float v = T2[((size_t)b * 1024 + n0 + r) * 256 + c];
    tile[r][tx] = v * scg + off;
  }
  __syncthreads();
#pragma unroll
  for (int j = 0; j < 4; ++j) {
    int cc = c0 + ty + j * 8;
    out[((size_t)b * 256 + cc) * 1024 + n0 + tx] = tile[tx][ty + j * 8];
  }
}

// ---------------- launch ----------------
extern "C" void kernel_launch(void* const* d_in, const int* in_sizes, int n_in,
                              void* d_out, int out_size, void* d_ws, size_t ws_size,
                              hipStream_t stream) {
  const float* x = (const float*)d_in[0];
  const float* Wq = (const float*)d_in[1];
  const float* bq = (const float*)d_in[2];
  const float* Wk = (const float*)d_in[3];
  const float* bk = (const float*)d_in[4];
  const float* Wv = (const float*)d_in[5];
  const float* bv = (const float*)d_in[6];
  const float* gamma = (const float*)d_in[7];
  const float* beta = (const float*)d_in[8];
  const float* W1 = (const float*)d_in[9];
  const float* b1 = (const float*)d_in[10];
  const float* a = (const float*)d_in[11];
  const float* W2 = (const float*)d_in[12];
  const float* b2 = (const float*)d_in[13];
  float* out = (float*)d_out;

  char* wsb = (char*)d_ws;
  const size_t MB = 1ull << 20;
  u16* XtbH = (u16*)(wsb + 0 * MB);       // 8MB
  u16* XtbL = (u16*)(wsb + 8 * MB);       // 8MB
  float* T2 = (float*)(wsb + 16 * MB);    // 16MB (ffn2 out)
  u16* QKh = (u16*)(wsb + 32 * MB);       // 16MB; aliased by H1B (32MB) after attn
  u16* QKl = (u16*)(wsb + 48 * MB);       // 16MB
  u16* Vt = (u16*)(wsb + 64 * MB);        // 8MB
  char* wp = wsb + 72 * MB;
  u16* WallH = (u16*)(wp);                // 256KB
  u16* WallL = (u16*)(wp + 262144);       // 256KB
  u16* WvH = (u16*)(wp + 524288);         // 128KB
  u16* WvL = (u16*)(wp + 655360);         // 128KB
  u16* W1b = (u16*)(wp + 786432);         // 512KB
  u16* W2b = (u16*)(wp + 1310720);        // 512KB
  float* bqk = (float*)(wp + 1835008);    // 2KB
  float* stats = (float*)(wp + 1837056);  // 8KB: stats1 | (unused) | stats2 | (unused)
  if (ws_size < 75 * MB) return;

  u16* H1B = QKh;    // [T,1024] bf16, after attn
  float* S = out;    // d_out doubles as o+x raw residual buffer [T,256]

  hipMemsetAsync(stats, 0, 8192, stream);
  // fused x-transpose + weight prep
  prep_all<<<5120, 256, 0, stream>>>(x, Wq, Wk, Wv, bq, bk, W1, W2,
                                     XtbH, XtbL, WallH, WallL, WvH, WvL, W1b, W2b, bqk);
  // fused QK projection (512 blocks) + V projection transposed (256 blocks)
  gemm_qkvt<<<768, 256, 0, stream>>>(XtbH, XtbL, WallH, WallL, bqk, QKh, QKl,
                                     WvH, WvL, bv, Vt);
  // attention + residual + BN1 stats
  attn_kernel<<<dim3(64, 16), 256, 0, stream>>>(QKh, QKl, Vt, x, S, stats);
  // FFN1: A = BN1(S) on the fly (inline finalize) -> H1B bf16, bias+PReLU
  gemm_ffn1<<<1024, 256, 0, stream>>>(S, W1b, b1, a, stats, gamma, beta, H1B);
  // FFN2: 64x64x64 tiles -> T2 f32, bias + BN1(S) resid (inline finalize) + BN2 stats
  gemm_ffn2<<<1024, 256, 0, stream>>>(H1B, W2b, b2, S, stats, gamma, beta, T2, stats + 1024);
  // BN2 apply (inline finalize) + transpose out
  bn_final_out<<<dim3(512, 8), dim3(32, 8), 0, stream>>>(T2, stats + 1024, gamma, beta, out);
}

// Round 13
// 142.607 us; speedup vs baseline: 2.1410x; 1.0040x over previous
//
#include <hip/hip_runtime.h>
#include <hip/hip_bf16.h>
#include <hip/hip_cooperative_groups.h>

namespace cg = cooperative_groups;

typedef unsigned short u16;
typedef unsigned int u32;
typedef __attribute__((ext_vector_type(8))) __bf16 bf16x8;
typedef __attribute__((ext_vector_type(4))) float f32x4;

#define LOG2E 1.44269504088896340736f

__device__ inline u16 f2bf(float f) {
  unsigned int x = __float_as_uint(f);
  unsigned int r = (x + 0x7FFFu + ((x >> 16) & 1u)) >> 16;
  return (u16)r;
}
__device__ inline float bf2f(u16 u) { return __uint_as_float(((unsigned int)u) << 16); }
__device__ inline void split2(float v, u16& h, u16& l) {
  h = f2bf(v);
  l = f2bf(v - bf2f(h));
}
__device__ inline u32 cvt_pk_bf16(float lo, float hi) {
  u32 r;
  asm("v_cvt_pk_bf16_f32 %0, %1, %2" : "=v"(r) : "v"(lo), "v"(hi));
  return r;
}
__device__ inline float exp2_fast(float x) {
  float r;
  asm("v_exp_f32 %0, %1" : "=v"(r) : "v"(x));
  return r;
}
// async global->LDS, 16B/lane; dest = wave-uniform base + lane*16
__device__ inline void gll16(const u16* g, u16* l) {
  __builtin_amdgcn_global_load_lds((const __attribute__((address_space(1))) void*)g,
                                   (__attribute__((address_space(3))) void*)l, 16, 0, 0);
}
// [R][32]-bf16 tile (64B rows): logical (row, slot s in 0..3) -> physical byte offset
#define TOFF(r, s) (((r) << 6) + ((((s) ^ (((r) >> 1) & 3))) << 4))
// [R][64]-bf16 tile (128B rows): logical (row, slot s in 0..7) -> physical byte offset
#define TOFF2(r, s) (((r) << 7) + ((((s) ^ ((r) & 7))) << 4))

// ---------------- fused: x transpose + weight prep ----------------
__global__ __launch_bounds__(256) void prep_all(
    const float* __restrict__ x,
    const float* __restrict__ Wq, const float* __restrict__ Wk, const float* __restrict__ Wv,
    const float* __restrict__ bq, const float* __restrict__ bk,
    const float* __restrict__ W1, const float* __restrict__ W2,
    u16* __restrict__ XtbH, u16* __restrict__ XtbL,
    u16* __restrict__ WallH, u16* __restrict__ WallL,
    u16* __restrict__ WvH, u16* __restrict__ WvL,
    u16* __restrict__ W1b, u16* __restrict__ W2b,
    float* __restrict__ bqk) {
  __shared__ float tile[32][33];
  const int id = blockIdx.x;
  if (id < 4096) {
    int n0 = (id & 31) * 32, c0 = ((id >> 5) & 7) * 32, b = id >> 8;
    int tx = threadIdx.x & 31, ty = threadIdx.x >> 5;
#pragma unroll
    for (int j = 0; j < 4; ++j) {
      int c = c0 + ty + j * 8;
      tile[ty + j * 8][tx] = x[((size_t)b * 256 + c) * 1024 + n0 + tx];
    }
    __syncthreads();
#pragma unroll
    for (int j = 0; j < 4; ++j) {
      int n = n0 + ty + j * 8;
      float v = tile[tx][ty + j * 8];
      size_t o = ((size_t)b * 1024 + n) * 256 + c0 + tx;
      u16 h, l;
      split2(v, h, l);
      XtbH[o] = h; XtbL[o] = l;
    }
  } else {
    int i = (id - 4096) * 256 + threadIdx.x;
    if (i < 131072) {
      float w = (i < 65536) ? Wq[i] : Wk[i - 65536];
      u16 h, l;
      split2(w, h, l);
      WallH[i] = h; WallL[i] = l;
    }
    if (i < 65536) {
      u16 h, l;
      split2(Wv[i], h, l);
      WvH[i] = h; WvL[i] = l;
    }
    if (i < 262144) { W1b[i] = f2bf(W1[i]); W2b[i] = f2bf(W2[i]); }
    if (i < 256) bqk[i] = bq[i];
    else if (i < 512) bqk[i] = bk[i - 256];
  }
}

// ---------------- fused QK-projection + V-projection (one dispatch, role by id) ----------
// Q-half outputs are pre-scaled by log2(e) so attention softmax can use raw v_exp_f32.
__global__ __launch_bounds__(256) void gemm_qkvt(
    const u16* __restrict__ Ah_, const u16* __restrict__ Al_,
    const u16* __restrict__ Bh_, const u16* __restrict__ Bl_,
    const float* __restrict__ bias,
    u16* __restrict__ Ch, u16* __restrict__ Cl,
    const u16* __restrict__ WvH_, const u16* __restrict__ WvL_,
    const float* __restrict__ bv, u16* __restrict__ Vt) {
  __shared__ u16 Ah[4096], Al[4096], Bh[4096], Bl[4096];
  const int tid = threadIdx.x;
  const int lane = tid & 63, w = tid >> 6;
  const int wr = w >> 1, wc = w & 1;
  const int q = lane & 15, G = lane >> 4;
  const int rr0 = w * 32 + (lane >> 2), rr1 = rr0 + 16;
  const int sl0 = (lane & 3) ^ ((rr0 >> 1) & 3);
  const int sl1 = (lane & 3) ^ ((rr1 >> 1) & 3);

  if (blockIdx.x < 512) {
    // ---- QK role ----
    const int eff = (blockIdx.x & 7) * 64 + (blockIdx.x >> 3);
    const int m0 = (eff >> 2) * 128, n0 = (eff & 3) * 128;
    const bool isQ = (n0 < 256);
    const size_t a0 = (size_t)(m0 + rr0) * 256 + sl0 * 8;
    const size_t a1 = (size_t)(m0 + rr1) * 256 + sl1 * 8;
    const size_t b0 = (size_t)(n0 + rr0) * 256 + sl0 * 8;
    const size_t b1 = (size_t)(n0 + rr1) * 256 + sl1 * 8;

    f32x4 acc[4][4] = {};
    for (int kt = 0; kt < 256; kt += 32) {
      __syncthreads();
      gll16(Ah_ + a0 + kt, &Ah[w * 1024]);
      gll16(Ah_ + a1 + kt, &Ah[w * 1024 + 512]);
      gll16(Al_ + a0 + kt, &Al[w * 1024]);
      gll16(Al_ + a1 + kt, &Al[w * 1024 + 512]);
      gll16(Bh_ + b0 + kt, &Bh[w * 1024]);
      gll16(Bh_ + b1 + kt, &Bh[w * 1024 + 512]);
      gll16(Bl_ + b0 + kt, &Bl[w * 1024]);
      gll16(Bl_ + b1 + kt, &Bl[w * 1024 + 512]);
      __syncthreads();
      bf16x8 afh[4], afl[4], bfh[4], bfl[4];
#pragma unroll
      for (int m = 0; m < 4; ++m) {
        int off = TOFF(wr * 64 + m * 16 + q, G);
        afh[m] = *reinterpret_cast<const bf16x8*>((const char*)Ah + off);
        afl[m] = *reinterpret_cast<const bf16x8*>((const char*)Al + off);
      }
#pragma unroll
      for (int n = 0; n < 4; ++n) {
        int off = TOFF(wc * 64 + n * 16 + q, G);
        bfh[n] = *reinterpret_cast<const bf16x8*>((const char*)Bh + off);
        bfl[n] = *reinterpret_cast<const bf16x8*>((const char*)Bl + off);
      }
#pragma unroll
      for (int m = 0; m < 4; ++m)
#pragma unroll
        for (int n = 0; n < 4; ++n) {
          acc[m][n] = __builtin_amdgcn_mfma_f32_16x16x32_bf16(afh[m], bfh[n], acc[m][n], 0, 0, 0);
          acc[m][n] = __builtin_amdgcn_mfma_f32_16x16x32_bf16(afl[m], bfh[n], acc[m][n], 0, 0, 0);
        }
      if (isQ) {
#pragma unroll
        for (int m = 0; m < 4; ++m)
#pragma unroll
          for (int n = 0; n < 4; ++n)
            acc[m][n] = __builtin_amdgcn_mfma_f32_16x16x32_bf16(afh[m], bfl[n], acc[m][n], 0, 0, 0);
      }
    }
    const float qscale = isQ ? LOG2E : 1.f;
#pragma unroll
    for (int m = 0; m < 4; ++m) {
      int row_b = m0 + wr * 64 + m * 16 + G * 4;
#pragma unroll
      for (int n = 0; n < 4; ++n) {
        int col = n0 + wc * 64 + n * 16 + q;
        float bb = bias[col];
#pragma unroll
        for (int r = 0; r < 4; ++r) {
          size_t o = (size_t)(row_b + r) * 512 + col;
          u16 h, l;
          split2((acc[m][n][r] + bb) * qscale, h, l);
          Ch[o] = h;
          if (isQ) Cl[o] = l;
        }
      }
    }
  } else {
    // ---- Vt role ----
    const int o_ = blockIdx.x - 512;
    const int eff = (o_ & 7) * 32 + (o_ >> 3);
    const int m0 = (eff & 1) * 128, n0 = ((eff >> 1) & 7) * 128, b = eff >> 4;
    const u16* Bp = Ah_ + (size_t)b * 1024 * 256;  // XtbH
    const size_t a0 = (size_t)(m0 + rr0) * 256 + sl0 * 8;
    const size_t a1 = (size_t)(m0 + rr1) * 256 + sl1 * 8;
    const size_t b0 = (size_t)(n0 + rr0) * 256 + sl0 * 8;
    const size_t b1 = (size_t)(n0 + rr1) * 256 + sl1 * 8;

    f32x4 acc[4][4] = {};
    for (int kt = 0; kt < 256; kt += 32) {
      __syncthreads();
      gll16(WvH_ + a0 + kt, &Ah[w * 1024]);
      gll16(WvH_ + a1 + kt, &Ah[w * 1024 + 512]);
      gll16(WvL_ + a0 + kt, &Al[w * 1024]);
      gll16(WvL_ + a1 + kt, &Al[w * 1024 + 512]);
      gll16(Bp + b0 + kt, &Bh[w * 1024]);
      gll16(Bp + b1 + kt, &Bh[w * 1024 + 512]);
      __syncthreads();
      bf16x8 afh[4], afl[4], bfr[4];
#pragma unroll
      for (int m = 0; m < 4; ++m) {
        int off = TOFF(wr * 64 + m * 16 + q, G);
        afh[m] = *reinterpret_cast<const bf16x8*>((const char*)Ah + off);
        afl[m] = *reinterpret_cast<const bf16x8*>((const char*)Al + off);
      }
#pragma unroll
      for (int n = 0; n < 4; ++n)
        bfr[n] = *reinterpret_cast<const bf16x8*>((const char*)Bh + TOFF(wc * 64 + n * 16 + q, G));
#pragma unroll
      for (int m = 0; m < 4; ++m)
#pragma unroll
        for (int n = 0; n < 4; ++n) {
          acc[m][n] = __builtin_amdgcn_mfma_f32_16x16x32_bf16(afh[m], bfr[n], acc[m][n], 0, 0, 0);
          acc[m][n] = __builtin_amdgcn_mfma_f32_16x16x32_bf16(afl[m], bfr[n], acc[m][n], 0, 0, 0);
        }
    }
#pragma unroll
    for (int m = 0; m < 4; ++m) {
      int row_b = m0 + wr * 64 + m * 16 + G * 4;  // d index
#pragma unroll
      for (int n = 0; n < 4; ++n) {
        int col = n0 + wc * 64 + n * 16 + q;      // token n
#pragma unroll
        for (int r = 0; r < 4; ++r) {
          int row = row_b + r;
          Vt[((size_t)b * 256 + row) * 1024 + col] = f2bf(acc[m][n][r] + bv[row]);
        }
      }
    }
  }
}

// ---------------- FFN1: A = BN(Sraw) reg-staged (swizzled), inline BN finalize ----------
__global__ __launch_bounds__(256) void gemm_ffn1(
    const float* __restrict__ Sraw,
    const u16* __restrict__ B_,
    const float* __restrict__ bias,
    const float* __restrict__ aslope,
    const float* __restrict__ stats1,
    const float* __restrict__ gamma,
    const float* __restrict__ beta,
    u16* __restrict__ H1B) {
  __shared__ u16 As[4096], Bs[4096];
  __shared__ float ssl[512];
  const int tid = threadIdx.x;
  const int lane = tid & 63, w = tid >> 6;
  const int wr = w >> 1, wc = w & 1;
  const int q = lane & 15, G = lane >> 4;
  const int eff = (blockIdx.x & 7) * 128 + (blockIdx.x >> 3);
  const int m0 = (eff >> 3) * 128, n0 = (eff & 7) * 128;
  {
    float mean = stats1[tid] * (1.f / 16384.f);
    float var = stats1[256 + tid] * (1.f / 16384.f) - mean * mean;
    float scg = gamma[tid] * rsqrtf(var + 1e-5f);
    ssl[tid] = scg;
    ssl[256 + tid] = beta[tid] - mean * scg;
  }

  const int rr0 = w * 32 + (lane >> 2), rr1 = rr0 + 16;
  const int sl0 = (lane & 3) ^ ((rr0 >> 1) & 3);
  const int sl1 = (lane & 3) ^ ((rr1 >> 1) & 3);
  const size_t b0 = (size_t)(n0 + rr0) * 256 + sl0 * 8;
  const size_t b1 = (size_t)(n0 + rr1) * 256 + sl1 * 8;

  f32x4 acc[4][4] = {};
  for (int kt = 0; kt < 256; kt += 32) {
    __syncthreads();
    gll16(B_ + b0 + kt, &Bs[w * 1024]);
    gll16(B_ + b1 + kt, &Bs[w * 1024 + 512]);
#pragma unroll
    for (int i = 0; i < 4; ++i) {
      int idx = tid + i * 256;
      int r = idx >> 3, cc = idx & 7;
      int c4 = cc * 4;
      float4 v = *reinterpret_cast<const float4*>(Sraw + (size_t)(m0 + r) * 256 + kt + c4);
      ushort4 o;
      o.x = f2bf(v.x * ssl[kt + c4 + 0] + ssl[256 + kt + c4 + 0]);
      o.y = f2bf(v.y * ssl[kt + c4 + 1] + ssl[256 + kt + c4 + 1]);
      o.z = f2bf(v.z * ssl[kt + c4 + 2] + ssl[256 + kt + c4 + 2]);
      o.w = f2bf(v.w * ssl[kt + c4 + 3] + ssl[256 + kt + c4 + 3]);
      int off = (r << 6) + ((((cc >> 1) ^ ((r >> 1) & 3))) << 4) + (cc & 1) * 8;
      *reinterpret_cast<ushort4*>((char*)As + off) = o;
    }
    __syncthreads();
    bf16x8 af[4], bfr[4];
#pragma unroll
    for (int m = 0; m < 4; ++m)
      af[m] = *reinterpret_cast<const bf16x8*>((const char*)As + TOFF(wr * 64 + m * 16 + q, G));
#pragma unroll
    for (int n = 0; n < 4; ++n)
      bfr[n] = *reinterpret_cast<const bf16x8*>((const char*)Bs + TOFF(wc * 64 + n * 16 + q, G));
#pragma unroll
    for (int m = 0; m < 4; ++m)
#pragma unroll
      for (int n = 0; n < 4; ++n)
        acc[m][n] = __builtin_amdgcn_mfma_f32_16x16x32_bf16(af[m], bfr[n], acc[m][n], 0, 0, 0);
  }
  float a = aslope[0];
#pragma unroll
  for (int m = 0; m < 4; ++m) {
    int row_b = m0 + wr * 64 + m * 16 + G * 4;
#pragma unroll
    for (int n = 0; n < 4; ++n) {
      int col = n0 + wc * 64 + n * 16 + q;
      float bb = bias[col];
#pragma unroll
      for (int r = 0; r < 4; ++r) {
        float v = acc[m][n][r] + bb;
        v = (v >= 0.f) ? v : a * v;
        H1B[(size_t)(row_b + r) * 1024 + col] = f2bf(v);
      }
    }
  }
}

// ---------------- FFN2 cooperative: GEMM + BN2 stats, grid.sync, BN2 apply + transposed out
// __launch_bounds__(256,4): cap VGPR<=128 -> >=4 blocks/CU so grid 1024 is co-residable.
__global__ __launch_bounds__(256, 4) void gemm_ffn2co(
    const u16* __restrict__ A_,
    const u16* __restrict__ B_,
    const float* __restrict__ bias,
    const float* __restrict__ Sraw,
    const float* __restrict__ stats1,
    const float* __restrict__ gamma,
    const float* __restrict__ beta,
    float* __restrict__ stats2,
    float* __restrict__ out) {
  __shared__ u16 As[4096], Bs[4096];
  __shared__ float ssl[512];
  __shared__ float sred[2][64];
  const int tid = threadIdx.x;
  const int lane = tid & 63, w = tid >> 6;
  const int wr = w >> 1, wc = w & 1;
  const int q = lane & 15, G = lane >> 4;
  const int eff = (blockIdx.x & 7) * 128 + (blockIdx.x >> 3);
  const int m0 = (eff >> 2) * 64, n0 = (eff & 3) * 64;
  {
    float mean = stats1[tid] * (1.f / 16384.f);
    float var = stats1[256 + tid] * (1.f / 16384.f) - mean * mean;
    float scg = gamma[tid] * rsqrtf(var + 1e-5f);
    ssl[tid] = scg;
    ssl[256 + tid] = beta[tid] - mean * scg;
  }
  if (tid < 64) { sred[0][tid] = 0.f; sred[1][tid] = 0.f; }

  const int rl = lane >> 3, sl8 = lane & 7;
  const int ssrc = (sl8 ^ rl) * 8;

  f32x4 acc[2][2] = {};
  for (int kt = 0; kt < 1024; kt += 64) {
    __syncthreads();
#pragma unroll
    for (int i = 0; i < 2; ++i) {
      int rb = (i * 4 + w) * 8;
      gll16(A_ + (size_t)(m0 + rb + rl) * 1024 + kt + ssrc, &As[rb * 64]);
      gll16(B_ + (size_t)(n0 + rb + rl) * 1024 + kt + ssrc, &Bs[rb * 64]);
    }
    __syncthreads();
#pragma unroll
    for (int kk = 0; kk < 2; ++kk) {
      bf16x8 af[2], bf2[2];
#pragma unroll
      for (int m = 0; m < 2; ++m)
        af[m] = *reinterpret_cast<const bf16x8*>((const char*)As + TOFF2(wr * 32 + m * 16 + q, kk * 4 + G));
#pragma unroll
      for (int n = 0; n < 2; ++n)
        bf2[n] = *reinterpret_cast<const bf16x8*>((const char*)Bs + TOFF2(wc * 32 + n * 16 + q, kk * 4 + G));
#pragma unroll
      for (int m = 0; m < 2; ++m)
#pragma unroll
        for (int n = 0; n < 2; ++n)
          acc[m][n] = __builtin_amdgcn_mfma_f32_16x16x32_bf16(af[m], bf2[n], acc[m][n], 0, 0, 0);
    }
  }
  // phase 1 epilogue: v = acc + bias + BN1(resid); accumulate BN2 stats; keep v in regs
  float s1a[2] = {0.f, 0.f}, s2a[2] = {0.f, 0.f};
#pragma unroll
  for (int m = 0; m < 2; ++m) {
    int row_b = m0 + wr * 32 + m * 16 + G * 4;
#pragma unroll
    for (int n = 0; n < 2; ++n) {
      int col = n0 + wc * 32 + n * 16 + q;
      float bb = bias[col];
      float sc_ = ssl[col], of_ = ssl[256 + col];
#pragma unroll
      for (int r = 0; r < 4; ++r) {
        int row = row_b + r;
        float resid = Sraw[(size_t)row * 256 + col] * sc_ + of_;
        float v = acc[m][n][r] + bb + resid;
        acc[m][n][r] = v;
        s1a[n] += v;
        s2a[n] += v * v;
      }
    }
  }
#pragma unroll
  for (int n = 0; n < 2; ++n) {
    float a1 = s1a[n];
    a1 += __shfl_xor(a1, 16, 64);
    a1 += __shfl_xor(a1, 32, 64);
    float a2 = s2a[n];
    a2 += __shfl_xor(a2, 16, 64);
    a2 += __shfl_xor(a2, 32, 64);
    if (lane < 16) {
      atomicAdd(&sred[0][wc * 32 + n * 16 + lane], a1);
      atomicAdd(&sred[1][wc * 32 + n * 16 + lane], a2);
    }
  }
  __syncthreads();
  if (tid < 64) {
    atomicAdd(&stats2[n0 + tid], sred[0][tid]);
    atomicAdd(&stats2[256 + n0 + tid], sred[1][tid]);
  }
  __threadfence();
  cg::this_grid().sync();
  // phase 2: BN2 apply from completed stats2, transposed write out[b][c][n]
#pragma unroll
  for (int n = 0; n < 2; ++n) {
    int col = n0 + wc * 32 + n * 16 + q;
    float s1 = __hip_atomic_load(&stats2[col], __ATOMIC_RELAXED, __HIP_MEMORY_SCOPE_AGENT);
    float s2 = __hip_atomic_load(&stats2[256 + col], __ATOMIC_RELAXED, __HIP_MEMORY_SCOPE_AGENT);
    float mean = s1 * (1.f / 16384.f);
    float var = s2 * (1.f / 16384.f) - mean * mean;
    float scg = gamma[col] * rsqrtf(var + 1e-5f);
    float off = beta[col] - mean * scg;
#pragma unroll
    for (int m = 0; m < 2; ++m) {
      int row0 = m0 + wr * 32 + m * 16 + G * 4;
      int b = row0 >> 10, nr = row0 & 1023;
      float4 o4;
      o4.x = acc[m][n][0] * scg + off;
      o4.y = acc[m][n][1] * scg + off;
      o4.z = acc[m][n][2] * scg + off;
      o4.w = acc[m][n][3] * scg + off;
      *reinterpret_cast<float4*>(out + ((size_t)b * 256 + col) * 1024 + nr) = o4;
    }
  }
}

// ---------------- FFN2 fallback (classic, writes T2 + stats2) ----------------
__global__ __launch_bounds__(256) void gemm_ffn2(
    const u16* __restrict__ A_,
    const u16* __restrict__ B_,
    const float* __restrict__ bias,
    const float* __restrict__ Sraw,
    const float* __restrict__ stats1,
    const float* __restrict__ gamma,
    const float* __restrict__ beta,
    float* __restrict__ T2,
    float* __restrict__ stats2) {
  __shared__ u16 As[4096], Bs[4096];
  __shared__ float ssl[512];
  __shared__ float sred[2][64];
  const int tid = threadIdx.x;
  const int lane = tid & 63, w = tid >> 6;
  const int wr = w >> 1, wc = w & 1;
  const int q = lane & 15, G = lane >> 4;
  const int eff = (blockIdx.x & 7) * 128 + (blockIdx.x >> 3);
  const int m0 = (eff >> 2) * 64, n0 = (eff & 3) * 64;
  {
    float mean = stats1[tid] * (1.f / 16384.f);
    float var = stats1[256 + tid] * (1.f / 16384.f) - mean * mean;
    float scg = gamma[tid] * rsqrtf(var + 1e-5f);
    ssl[tid] = scg;
    ssl[256 + tid] = beta[tid] - mean * scg;
  }
  if (tid < 64) { sred[0][tid] = 0.f; sred[1][tid] = 0.f; }

  const int rl = lane >> 3, sl8 = lane & 7;
  const int ssrc = (sl8 ^ rl) * 8;

  f32x4 acc[2][2] = {};
  for (int kt = 0; kt < 1024; kt += 64) {
    __syncthreads();
#pragma unroll
    for (int i = 0; i < 2; ++i) {
      int rb = (i * 4 + w) * 8;
      gll16(A_ + (size_t)(m0 + rb + rl) * 1024 + kt + ssrc, &As[rb * 64]);
      gll16(B_ + (size_t)(n0 + rb + rl) * 1024 + kt + ssrc, &Bs[rb * 64]);
    }
    __syncthreads();
#pragma unroll
    for (int kk = 0; kk < 2; ++kk) {
      bf16x8 af[2], bf2[2];
#pragma unroll
      for (int m = 0; m < 2; ++m)
        af[m] = *reinterpret_cast<const bf16x8*>((const char*)As + TOFF2(wr * 32 + m * 16 + q, kk * 4 + G));
#pragma unroll
      for (int n = 0; n < 2; ++n)
        bf2[n] = *reinterpret_cast<const bf16x8*>((const char*)Bs + TOFF2(wc * 32 + n * 16 + q, kk * 4 + G));
#pragma unroll
      for (int m = 0; m < 2; ++m)
#pragma unroll
        for (int n = 0; n < 2; ++n)
          acc[m][n] = __builtin_amdgcn_mfma_f32_16x16x32_bf16(af[m], bf2[n], acc[m][n], 0, 0, 0);
    }
  }
  float s1a[2] = {0.f, 0.f}, s2a[2] = {0.f, 0.f};
#pragma unroll
  for (int m = 0; m < 2; ++m) {
    int row_b = m0 + wr * 32 + m * 16 + G * 4;
#pragma unroll
    for (int n = 0; n < 2; ++n) {
      int col = n0 + wc * 32 + n * 16 + q;
      float bb = bias[col];
      float sc_ = ssl[col], of_ = ssl[256 + col];
#pragma unroll
      for (int r = 0; r < 4; ++r) {
        int row = row_b + r;
        float resid = Sraw[(size_t)row * 256 + col] * sc_ + of_;
        float v = acc[m][n][r] + bb + resid;
        T2[(size_t)row * 256 + col] = v;
        s1a[n] += v;
        s2a[n] += v * v;
      }
    }
  }
#pragma unroll
  for (int n = 0; n < 2; ++n) {
    float a1 = s1a[n];
    a1 += __shfl_xor(a1, 16, 64);
    a1 += __shfl_xor(a1, 32, 64);
    float a2 = s2a[n];
    a2 += __shfl_xor(a2, 16, 64);
    a2 += __shfl_xor(a2, 32, 64);
    if (lane < 16) {
      atomicAdd(&sred[0][wc * 32 + n * 16 + lane], a1);
      atomicAdd(&sred[1][wc * 32 + n * 16 + lane], a2);
    }
  }
  __syncthreads();
  if (tid < 64) {
    atomicAdd(&stats2[n0 + tid], sred[0][tid]);
    atomicAdd(&stats2[256 + n0 + tid], sred[1][tid]);
  }
}

// ---------------- fallback: final BN (inline from stats2) + transpose ----------
__global__ __launch_bounds__(256) void bn_final_out(const float* __restrict__ T2,
                                                    const float* __restrict__ stats2,
                                                    const float* __restrict__ gamma,
                                                    const float* __restrict__ beta,
                                                    float* __restrict__ out) {
  __shared__ float tile[32][33];
  int n0 = (blockIdx.x & 31) * 32;
  int b = blockIdx.x >> 5;
  int c0 = blockIdx.y * 32;
  int tx = threadIdx.x, ty = threadIdx.y;
  int c = c0 + tx;
  float mean = stats2[c] * (1.f / 16384.f);
  float var = stats2[256 + c] * (1.f / 16384.f) - mean * mean;
  float scg = gamma[c] * rsqrtf(var + 1e-5f);
  float off = beta[c] - mean * scg;
#pragma unroll
  for (int j = 0; j < 4; ++j) {
    int r = ty + j * 8;
    float v = T2[((size_t)b * 1024 + n0 + r) * 256 + c];
    tile[r][tx] = v * scg + off;
  }
  __syncthreads();
#pragma unroll
  for (int j = 0; j < 4; ++j) {
    int cc = c0 + ty + j * 8;
    out[((size_t)b * 256 + cc) * 1024 + n0 + tx] = tile[tx][ty + j * 8];
  }
}

// ---------------- fused flash attention: swapped QK^T, permuted-k PV, exp2-direct --------
#define SWZ(row, bcol) ((bcol) ^ (((row) & 7) << 4))
__global__ __launch_bounds__(256, 4) void attn_kernel(const u16* __restrict__ QKh,
                                                      const u16* __restrict__ QKl,
                                                      const u16* __restrict__ Vt,
                                                      const float* __restrict__ x,
                                                      float* __restrict__ Sout,
                                                      float* __restrict__ stats) {
  __shared__ u16 Kh[2][4096], Vs[2][4096];
  __shared__ float sred[2][64];
  const int tid = threadIdx.x, lane = tid & 63, w = tid >> 6;
  const int hb = blockIdx.x, h = hb & 3, b = hb >> 2;
  const size_t tb = (size_t)b * 1024;
  const int qrow0 = blockIdx.y * 64 + w * 16;
  const int q = lane & 15, G = lane >> 4;

  if (tid < 64) { sred[0][tid] = 0.f; sred[1][tid] = 0.f; }

  bf16x8 qh[2], ql[2];
#pragma unroll
  for (int kk = 0; kk < 2; ++kk) {
    size_t ro = (tb + qrow0 + q) * 512 + h * 64 + kk * 32 + G * 8;
    qh[kk] = *reinterpret_cast<const bf16x8*>(QKh + ro);
    ql[kk] = *reinterpret_cast<const bf16x8*>(QKl + ro);
  }

  f32x4 oacc[4] = {};
  float mprev = -3e38f, lsum = 0.f;

  const int sr0 = tid >> 3, sr1 = sr0 + 32;
  const int c7 = tid & 7;
  const int scb0 = c7 << 4;
  const int dstb0 = sr0 * 128 + SWZ(sr0, scb0);
  const int dstb1 = sr1 * 128 + SWZ(sr1, scb0);
  const size_t kbase0 = (tb + sr0) * 512 + 256 + h * 64 + c7 * 8;
  const size_t kbase1 = (tb + sr1) * 512 + 256 + h * 64 + c7 * 8;
  const int vb0 = 32 * (c7 >> 2) + 8 * ((2 * c7) & 3) + 4 * ((c7 >> 1) & 1);
  const int vx0 = (vb0 * 2) ^ ((sr0 & 7) << 4);
  const int vx1 = (vb0 * 2 + 16) ^ ((sr0 & 7) << 4);
  const size_t vbase0 = ((size_t)b * 256 + h * 64 + sr0) * 1024 + c7 * 8;
  const size_t vbase1 = ((size_t)b * 256 + h * 64 + sr1) * 1024 + c7 * 8;

  uint4 rk0 = *reinterpret_cast<const uint4*>(QKh + kbase0);
  uint4 rk1 = *reinterpret_cast<const uint4*>(QKh + kbase1);
  uint4 rv0 = *reinterpret_cast<const uint4*>(Vt + vbase0);
  uint4 rv1 = *reinterpret_cast<const uint4*>(Vt + vbase1);
  *reinterpret_cast<uint4*>((char*)Kh[0] + dstb0) = rk0;
  *reinterpret_cast<uint4*>((char*)Kh[0] + dstb1) = rk1;
  {
    uint2 lo0 = {rv0.x, rv0.y}, hi0 = {rv0.z, rv0.w};
    uint2 lo1 = {rv1.x, rv1.y}, hi1 = {rv1.z, rv1.w};
    *reinterpret_cast<uint2*>((char*)Vs[0] + sr0 * 128 + vx0) = lo0;
    *reinterpret_cast<uint2*>((char*)Vs[0] + sr0 * 128 + vx1) = hi0;
    *reinterpret_cast<uint2*>((char*)Vs[0] + sr1 * 128 + vx0) = lo1;
    *reinterpret_cast<uint2*>((char*)Vs[0] + sr1 * 128 + vx1) = hi1;
  }
  __syncthreads();

  int cur = 0;
  for (int kt = 0; kt < 16; ++kt) {
    if (kt < 15) {
      rk0 = *reinterpret_cast<const uint4*>(QKh + kbase0 + (size_t)(kt + 1) * 32768);
      rk1 = *reinterpret_cast<const uint4*>(QKh + kbase1 + (size_t)(kt + 1) * 32768);
      rv0 = *reinterpret_cast<const uint4*>(Vt + vbase0 + (size_t)(kt + 1) * 64);
      rv1 = *reinterpret_cast<const uint4*>(Vt + vbase1 + (size_t)(kt + 1) * 64);
    }

    f32x4 sc[4] = {};
    __builtin_amdgcn_s_setprio(1);
#pragma unroll
    for (int kk = 0; kk < 2; ++kk)
#pragma unroll
      for (int n = 0; n < 4; ++n) {
        int krow = n * 16 + q;
        int kb_ = krow * 128 + SWZ(krow, kk * 64 + G * 16);
        bf16x8 akh = *reinterpret_cast<const bf16x8*>((const char*)Kh[cur] + kb_);
        sc[n] = __builtin_amdgcn_mfma_f32_16x16x32_bf16(akh, qh[kk], sc[n], 0, 0, 0);
        sc[n] = __builtin_amdgcn_mfma_f32_16x16x32_bf16(akh, ql[kk], sc[n], 0, 0, 0);
      }
    __builtin_amdgcn_s_setprio(0);

    float vm;
    {
      float t0 = fmaxf(fmaxf(sc[0][0], sc[0][1]), sc[0][2]);
      float t1 = fmaxf(fmaxf(sc[0][3], sc[1][0]), sc[1][1]);
      float t2 = fmaxf(fmaxf(sc[1][2], sc[1][3]), sc[2][0]);
      float t3 = fmaxf(fmaxf(sc[2][1], sc[2][2]), sc[2][3]);
      float t4 = fmaxf(fmaxf(sc[3][0], sc[3][1]), sc[3][2]);
      vm = fmaxf(fmaxf(fmaxf(t0, t1), t2), fmaxf(fmaxf(t3, t4), sc[3][3]));
      vm = fmaxf(vm, __shfl_xor(vm, 16, 64));
      vm = fmaxf(vm, __shfl_xor(vm, 32, 64));
    }
    bool ok = (vm <= mprev + 11.54f);
    if (!__all(ok)) {
      float mn = fmaxf(mprev, vm);
      float scl = exp2_fast(mprev - mn);
      mprev = mn;
      lsum *= scl;
      float sclr[4];
#pragma unroll
      for (int r = 0; r < 4; ++r) sclr[r] = __shfl(scl, G * 4 + r, 64);
#pragma unroll
      for (int dn = 0; dn < 4; ++dn)
#pragma unroll
        for (int r = 0; r < 4; ++r) oacc[dn][r] *= sclr[r];
    }
    float lt = 0.f;
#pragma unroll
    for (int n = 0; n < 4; ++n)
#pragma unroll
      for (int r = 0; r < 4; ++r) {
        float p = exp2_fast(sc[n][r] - mprev);
        sc[n][r] = p;
        lt += p;
      }
    lsum += lt;
    bf16x8 pa[2];
    {
      uint4 pw0, pw1;
      pw0.x = cvt_pk_bf16(sc[0][0], sc[0][1]);
      pw0.y = cvt_pk_bf16(sc[0][2], sc[0][3]);
      pw0.z = cvt_pk_bf16(sc[1][0], sc[1][1]);
      pw0.w = cvt_pk_bf16(sc[1][2], sc[1][3]);
      pw1.x = cvt_pk_bf16(sc[2][0], sc[2][1]);
      pw1.y = cvt_pk_bf16(sc[2][2], sc[2][3]);
      pw1.z = cvt_pk_bf16(sc[3][0], sc[3][1]);
      pw1.w = cvt_pk_bf16(sc[3][2], sc[3][3]);
      pa[0] = *reinterpret_cast<bf16x8*>(&pw0);
      pa[1] = *reinterpret_cast<bf16x8*>(&pw1);
    }
    __builtin_amdgcn_s_setprio(1);
#pragma unroll
    for (int kk = 0; kk < 2; ++kk)
#pragma unroll
      for (int dn = 0; dn < 4; ++dn) {
        int vrow = dn * 16 + q;
        int vb_ = vrow * 128 + SWZ(vrow, kk * 64 + G * 16);
        bf16x8 vv = *reinterpret_cast<const bf16x8*>((const char*)Vs[cur] + vb_);
        oacc[dn] = __builtin_amdgcn_mfma_f32_16x16x32_bf16(pa[kk], vv, oacc[dn], 0, 0, 0);
      }
    __builtin_amdgcn_s_setprio(0);
    if (kt < 15) {
      *reinterpret_cast<uint4*>((char*)Kh[cur ^ 1] + dstb0) = rk0;
      *reinterpret_cast<uint4*>((char*)Kh[cur ^ 1] + dstb1) = rk1;
      uint2 lo0 = {rv0.x, rv0.y}, hi0 = {rv0.z, rv0.w};
      uint2 lo1 = {rv1.x, rv1.y}, hi1 = {rv1.z, rv1.w};
      *reinterpret_cast<uint2*>((char*)Vs[cur ^ 1] + sr0 * 128 + vx0) = lo0;
      *reinterpret_cast<uint2*>((char*)Vs[cur ^ 1] + sr0 * 128 + vx1) = hi0;
      *reinterpret_cast<uint2*>((char*)Vs[cur ^ 1] + sr1 * 128 + vx0) = lo1;
      *reinterpret_cast<uint2*>((char*)Vs[cur ^ 1] + sr1 * 128 + vx1) = hi1;
    }
    __syncthreads();
    cur ^= 1;
  }
  float lf = lsum;
  lf += __shfl_xor(lf, 16, 64);
  lf += __shfl_xor(lf, 32, 64);
  float rinv[4];
#pragma unroll
  for (int r = 0; r < 4; ++r) rinv[r] = 1.f / __shfl(lf, G * 4 + r, 64);

  const int row0 = qrow0 + G * 4;
  const float* xp = x + ((size_t)b * 256 + h * 64) * 1024;
  float s1a[4] = {0.f, 0.f, 0.f, 0.f}, s2a[4] = {0.f, 0.f, 0.f, 0.f};
#pragma unroll
  for (int dn = 0; dn < 4; ++dn) {
    int col = dn * 16 + q;
    float4 xv = *reinterpret_cast<const float4*>(xp + (size_t)col * 1024 + row0);
    const float* xvp = reinterpret_cast<const float*>(&xv);
#pragma unroll
    for (int r = 0; r < 4; ++r) {
      size_t gi = (tb + row0 + r) * 256 + h * 64 + col;
      float v = oacc[dn][r] * rinv[r] + xvp[r];
      Sout[gi] = v;
      s1a[dn] += v;
      s2a[dn] += v * v;
    }
  }
#pragma unroll
  for (int dn = 0; dn < 4; ++dn) {
    float a1 = s1a[dn];
    a1 += __shfl_xor(a1, 16, 64);
    a1 += __shfl_xor(a1, 32, 64);
    float a2 = s2a[dn];
    a2 += __shfl_xor(a2, 16, 64);
    a2 += __shfl_xor(a2, 32, 64);
    if (lane < 16) {
      atomicAdd(&sred[0][dn * 16 + lane], a1);
      atomicAdd(&sred[1][dn * 16 + lane], a2);
    }
  }
  __syncthreads();
  if (tid < 64) {
    atomicAdd(&stats[h * 64 + tid], sred[0][tid]);
    atomicAdd(&stats[256 + h * 64 + tid], sred[1][tid]);
  }
}

// ---------------- launch ----------------
extern "C" void kernel_launch(void* const* d_in, const int* in_sizes, int n_in,
                              void* d_out, int out_size, void* d_ws, size_t ws_size,
                              hipStream_t stream) {
  const float* x = (const float*)d_in[0];
  const float* Wq = (const float*)d_in[1];
  const float* bq = (const float*)d_in[2];
  const float* Wk = (const float*)d_in[3];
  const float* bk = (const float*)d_in[4];
  const float* Wv = (const float*)d_in[5];
  const float* bv = (const float*)d_in[6];
  const float* gamma = (const float*)d_in[7];
  const float* beta = (const float*)d_in[8];
  const float* W1 = (const float*)d_in[9];
  const float* b1 = (const float*)d_in[10];
  const float* a = (const float*)d_in[11];
  const float* W2 = (const float*)d_in[12];
  const float* b2 = (const float*)d_in[13];
  float* out = (float*)d_out;

  char* wsb = (char*)d_ws;
  const size_t MB = 1ull << 20;
  u16* XtbH = (u16*)(wsb + 0 * MB);       // 8MB
  u16* XtbL = (u16*)(wsb + 8 * MB);       // 8MB
  float* T2 = (float*)(wsb + 16 * MB);    // 16MB (fallback path only)
  u16* QKh = (u16*)(wsb + 32 * MB);       // 16MB; aliased by H1B (32MB) after attn
  u16* QKl = (u16*)(wsb + 48 * MB);       // 16MB
  u16* Vt = (u16*)(wsb + 64 * MB);        // 8MB
  char* wp = wsb + 72 * MB;
  u16* WallH = (u16*)(wp);                // 256KB
  u16* WallL = (u16*)(wp + 262144);       // 256KB
  u16* WvH = (u16*)(wp + 524288);         // 128KB
  u16* WvL = (u16*)(wp + 655360);         // 128KB
  u16* W1b = (u16*)(wp + 786432);         // 512KB
  u16* W2b = (u16*)(wp + 1310720);        // 512KB
  float* bqk = (float*)(wp + 1835008);    // 2KB
  float* stats = (float*)(wp + 1837056);  // 8KB: stats1 | pad | stats2 | pad
  if (ws_size < 75 * MB) return;

  u16* H1B = QKh;    // [T,1024] bf16, after attn
  float* S = out;    // d_out doubles as o+x raw residual buffer [T,256]
  float* stats2 = stats + 1024;

  hipMemsetAsync(stats, 0, 8192, stream);
  // fused x-transpose + weight prep
  prep_all<<<5120, 256, 0, stream>>>(x, Wq, Wk, Wv, bq, bk, W1, W2,
                                     XtbH, XtbL, WallH, WallL, WvH, WvL, W1b, W2b, bqk);
  // fused QK projection (Q pre-scaled by log2e) + V projection transposed
  gemm_qkvt<<<768, 256, 0, stream>>>(XtbH, XtbL, WallH, WallL, bqk, QKh, QKl,
                                     WvH, WvL, bv, Vt);
  // attention + residual + BN1 stats
  attn_kernel<<<dim3(64, 16), 256, 0, stream>>>(QKh, QKl, Vt, x, S, stats);
  // FFN1: A = BN1(S) on the fly (inline finalize) -> H1B bf16, bias+PReLU
  gemm_ffn1<<<1024, 256, 0, stream>>>(S, W1b, b1, a, stats, gamma, beta, H1B);

  // FFN2: cooperative single-pass if the grid is co-residable, else classic two-pass.
  int maxB = 0;
  hipOccupancyMaxActiveBlocksPerMultiprocessor(&maxB, gemm_ffn2co, 256, 0);
  int numCU = 0, dev = 0;
  hipGetDevice(&dev);
  hipDeviceGetAttribute(&numCU, hipDeviceAttributeMultiprocessorCount, dev);
  bool coop = ((long)maxB * numCU >= 1024);
  hipError_t cerr = hipErrorUnknown;
  if (coop) {
    void* args[] = {(void*)&H1B, (void*)&W2b, (void*)&b2, (void*)&S, (void*)&stats,
                    (void*)&gamma, (void*)&beta, (void*)&stats2, (void*)&out};
    cerr = hipLaunchCooperativeKernel(reinterpret_cast<void*>(gemm_ffn2co),
                                      dim3(1024), dim3(256), args, 0, stream);
  }
  if (!coop || cerr != hipSuccess) {
    gemm_ffn2<<<1024, 256, 0, stream>>>(H1B, W2b, b2, S, stats, gamma, beta, T2, stats2);
    bn_final_out<<<dim3(512, 8), dim3(32, 8), 0, stream>>>(T2, stats2, gamma, beta, out);
  }
}

// Round 14
// 126.450 us; speedup vs baseline: 2.4145x; 1.1278x over previous
//
#include <hip/hip_runtime.h>
#include <hip/hip_bf16.h>

typedef unsigned short u16;
typedef unsigned int u32;
typedef __attribute__((ext_vector_type(8))) __bf16 bf16x8;
typedef __attribute__((ext_vector_type(4))) float f32x4;

#define LOG2E 1.44269504088896340736f

__device__ inline u16 f2bf(float f) {
  unsigned int x = __float_as_uint(f);
  unsigned int r = (x + 0x7FFFu + ((x >> 16) & 1u)) >> 16;
  return (u16)r;
}
__device__ inline float bf2f(u16 u) { return __uint_as_float(((unsigned int)u) << 16); }
__device__ inline void split2(float v, u16& h, u16& l) {
  h = f2bf(v);
  l = f2bf(v - bf2f(h));
}
__device__ inline u32 cvt_pk_bf16(float lo, float hi) {
  u32 r;
  asm("v_cvt_pk_bf16_f32 %0, %1, %2" : "=v"(r) : "v"(lo), "v"(hi));
  return r;
}
__device__ inline float exp2_fast(float x) {
  float r;
  asm("v_exp_f32 %0, %1" : "=v"(r) : "v"(x));
  return r;
}
// async global->LDS, 16B/lane; dest = wave-uniform base + lane*16
__device__ inline void gll16(const u16* g, u16* l) {
  __builtin_amdgcn_global_load_lds((const __attribute__((address_space(1))) void*)g,
                                   (__attribute__((address_space(3))) void*)l, 16, 0, 0);
}
// [R][32]-bf16 tile (64B rows): logical (row, slot s in 0..3) -> physical byte offset
#define TOFF(r, s) (((r) << 6) + ((((s) ^ (((r) >> 1) & 3))) << 4))
// [R][64]-bf16 tile (128B rows): logical (row, slot s in 0..7) -> physical byte offset
#define TOFF2(r, s) (((r) << 7) + ((((s) ^ ((r) & 7))) << 4))

// ---------------- fused: x transpose + weight prep ----------------
__global__ __launch_bounds__(256) void prep_all(
    const float* __restrict__ x,
    const float* __restrict__ Wq, const float* __restrict__ Wk, const float* __restrict__ Wv,
    const float* __restrict__ bq, const float* __restrict__ bk,
    const float* __restrict__ W2,
    u16* __restrict__ XtbH, u16* __restrict__ XtbL,
    u16* __restrict__ WallH, u16* __restrict__ WallL,
    u16* __restrict__ WvH, u16* __restrict__ WvL,
    u16* __restrict__ W2b,
    float* __restrict__ bqk) {
  __shared__ float tile[32][33];
  const int id = blockIdx.x;
  if (id < 4096) {
    int n0 = (id & 31) * 32, c0 = ((id >> 5) & 7) * 32, b = id >> 8;
    int tx = threadIdx.x & 31, ty = threadIdx.x >> 5;
#pragma unroll
    for (int j = 0; j < 4; ++j) {
      int c = c0 + ty + j * 8;
      tile[ty + j * 8][tx] = x[((size_t)b * 256 + c) * 1024 + n0 + tx];
    }
    __syncthreads();
#pragma unroll
    for (int j = 0; j < 4; ++j) {
      int n = n0 + ty + j * 8;
      float v = tile[tx][ty + j * 8];
      size_t o = ((size_t)b * 1024 + n) * 256 + c0 + tx;
      u16 h, l;
      split2(v, h, l);
      XtbH[o] = h; XtbL[o] = l;
    }
  } else {
    int i = (id - 4096) * 256 + threadIdx.x;
    if (i < 131072) {
      float w = (i < 65536) ? Wq[i] : Wk[i - 65536];
      u16 h, l;
      split2(w, h, l);
      WallH[i] = h; WallL[i] = l;
    }
    if (i < 65536) {
      u16 h, l;
      split2(Wv[i], h, l);
      WvH[i] = h; WvL[i] = l;
    }
    if (i < 262144) W2b[i] = f2bf(W2[i]);
    if (i < 256) bqk[i] = bq[i];
    else if (i < 512) bqk[i] = bk[i - 256];
  }
}

// ---------------- fused QK-projection + V-projection (one dispatch, role by id) ----------
// Q-half outputs are pre-scaled by log2(e) so attention softmax can use raw v_exp_f32.
__global__ __launch_bounds__(256) void gemm_qkvt(
    const u16* __restrict__ Ah_, const u16* __restrict__ Al_,
    const u16* __restrict__ Bh_, const u16* __restrict__ Bl_,
    const float* __restrict__ bias,
    u16* __restrict__ Ch, u16* __restrict__ Cl,
    const u16* __restrict__ WvH_, const u16* __restrict__ WvL_,
    const float* __restrict__ bv, u16* __restrict__ Vt) {
  __shared__ u16 Ah[4096], Al[4096], Bh[4096], Bl[4096];
  const int tid = threadIdx.x;
  const int lane = tid & 63, w = tid >> 6;
  const int wr = w >> 1, wc = w & 1;
  const int q = lane & 15, G = lane >> 4;
  const int rr0 = w * 32 + (lane >> 2), rr1 = rr0 + 16;
  const int sl0 = (lane & 3) ^ ((rr0 >> 1) & 3);
  const int sl1 = (lane & 3) ^ ((rr1 >> 1) & 3);

  if (blockIdx.x < 512) {
    // ---- QK role ----
    const int eff = (blockIdx.x & 7) * 64 + (blockIdx.x >> 3);
    const int m0 = (eff >> 2) * 128, n0 = (eff & 3) * 128;
    const bool isQ = (n0 < 256);
    const size_t a0 = (size_t)(m0 + rr0) * 256 + sl0 * 8;
    const size_t a1 = (size_t)(m0 + rr1) * 256 + sl1 * 8;
    const size_t b0 = (size_t)(n0 + rr0) * 256 + sl0 * 8;
    const size_t b1 = (size_t)(n0 + rr1) * 256 + sl1 * 8;

    f32x4 acc[4][4] = {};
    for (int kt = 0; kt < 256; kt += 32) {
      __syncthreads();
      gll16(Ah_ + a0 + kt, &Ah[w * 1024]);
      gll16(Ah_ + a1 + kt, &Ah[w * 1024 + 512]);
      gll16(Al_ + a0 + kt, &Al[w * 1024]);
      gll16(Al_ + a1 + kt, &Al[w * 1024 + 512]);
      gll16(Bh_ + b0 + kt, &Bh[w * 1024]);
      gll16(Bh_ + b1 + kt, &Bh[w * 1024 + 512]);
      gll16(Bl_ + b0 + kt, &Bl[w * 1024]);
      gll16(Bl_ + b1 + kt, &Bl[w * 1024 + 512]);
      __syncthreads();
      bf16x8 afh[4], afl[4], bfh[4], bfl[4];
#pragma unroll
      for (int m = 0; m < 4; ++m) {
        int off = TOFF(wr * 64 + m * 16 + q, G);
        afh[m] = *reinterpret_cast<const bf16x8*>((const char*)Ah + off);
        afl[m] = *reinterpret_cast<const bf16x8*>((const char*)Al + off);
      }
#pragma unroll
      for (int n = 0; n < 4; ++n) {
        int off = TOFF(wc * 64 + n * 16 + q, G);
        bfh[n] = *reinterpret_cast<const bf16x8*>((const char*)Bh + off);
        bfl[n] = *reinterpret_cast<const bf16x8*>((const char*)Bl + off);
      }
#pragma unroll
      for (int m = 0; m < 4; ++m)
#pragma unroll
        for (int n = 0; n < 4; ++n) {
          acc[m][n] = __builtin_amdgcn_mfma_f32_16x16x32_bf16(afh[m], bfh[n], acc[m][n], 0, 0, 0);
          acc[m][n] = __builtin_amdgcn_mfma_f32_16x16x32_bf16(afl[m], bfh[n], acc[m][n], 0, 0, 0);
        }
      if (isQ) {
#pragma unroll
        for (int m = 0; m < 4; ++m)
#pragma unroll
          for (int n = 0; n < 4; ++n)
            acc[m][n] = __builtin_amdgcn_mfma_f32_16x16x32_bf16(afh[m], bfl[n], acc[m][n], 0, 0, 0);
      }
    }
    const float qscale = isQ ? LOG2E : 1.f;
#pragma unroll
    for (int m = 0; m < 4; ++m) {
      int row_b = m0 + wr * 64 + m * 16 + G * 4;
#pragma unroll
      for (int n = 0; n < 4; ++n) {
        int col = n0 + wc * 64 + n * 16 + q;
        float bb = bias[col];
#pragma unroll
        for (int r = 0; r < 4; ++r) {
          size_t o = (size_t)(row_b + r) * 512 + col;
          u16 h, l;
          split2((acc[m][n][r] + bb) * qscale, h, l);
          Ch[o] = h;
          if (isQ) Cl[o] = l;
        }
      }
    }
  } else {
    // ---- Vt role ----
    const int o_ = blockIdx.x - 512;
    const int eff = (o_ & 7) * 32 + (o_ >> 3);
    const int m0 = (eff & 1) * 128, n0 = ((eff >> 1) & 7) * 128, b = eff >> 4;
    const u16* Bp = Ah_ + (size_t)b * 1024 * 256;  // XtbH
    const size_t a0 = (size_t)(m0 + rr0) * 256 + sl0 * 8;
    const size_t a1 = (size_t)(m0 + rr1) * 256 + sl1 * 8;
    const size_t b0 = (size_t)(n0 + rr0) * 256 + sl0 * 8;
    const size_t b1 = (size_t)(n0 + rr1) * 256 + sl1 * 8;

    f32x4 acc[4][4] = {};
    for (int kt = 0; kt < 256; kt += 32) {
      __syncthreads();
      gll16(WvH_ + a0 + kt, &Ah[w * 1024]);
      gll16(WvH_ + a1 + kt, &Ah[w * 1024 + 512]);
      gll16(WvL_ + a0 + kt, &Al[w * 1024]);
      gll16(WvL_ + a1 + kt, &Al[w * 1024 + 512]);
      gll16(Bp + b0 + kt, &Bh[w * 1024]);
      gll16(Bp + b1 + kt, &Bh[w * 1024 + 512]);
      __syncthreads();
      bf16x8 afh[4], afl[4], bfr[4];
#pragma unroll
      for (int m = 0; m < 4; ++m) {
        int off = TOFF(wr * 64 + m * 16 + q, G);
        afh[m] = *reinterpret_cast<const bf16x8*>((const char*)Ah + off);
        afl[m] = *reinterpret_cast<const bf16x8*>((const char*)Al + off);
      }
#pragma unroll
      for (int n = 0; n < 4; ++n)
        bfr[n] = *reinterpret_cast<const bf16x8*>((const char*)Bh + TOFF(wc * 64 + n * 16 + q, G));
#pragma unroll
      for (int m = 0; m < 4; ++m)
#pragma unroll
        for (int n = 0; n < 4; ++n) {
          acc[m][n] = __builtin_amdgcn_mfma_f32_16x16x32_bf16(afh[m], bfr[n], acc[m][n], 0, 0, 0);
          acc[m][n] = __builtin_amdgcn_mfma_f32_16x16x32_bf16(afl[m], bfr[n], acc[m][n], 0, 0, 0);
        }
    }
#pragma unroll
    for (int m = 0; m < 4; ++m) {
      int row_b = m0 + wr * 64 + m * 16 + G * 4;  // d index
#pragma unroll
      for (int n = 0; n < 4; ++n) {
        int col = n0 + wc * 64 + n * 16 + q;      // token n
#pragma unroll
        for (int r = 0; r < 4; ++r) {
          int row = row_b + r;
          Vt[((size_t)b * 256 + row) * 1024 + col] = f2bf(acc[m][n][r] + bv[row]);
        }
      }
    }
  }
}

// ---------------- w1prep: ss1 from stats1; W1s = bf16(W1*sc); h0 = b1 + W1*of ----------
__global__ __launch_bounds__(256) void w1prep(
    const float* __restrict__ W1, const float* __restrict__ b1,
    const float* __restrict__ stats1, const float* __restrict__ gamma,
    const float* __restrict__ beta,
    u16* __restrict__ W1s, float* __restrict__ h0) {
  __shared__ float ssl[512];
  const int tid = threadIdx.x;
  {
    float mean = stats1[tid] * (1.f / 16384.f);
    float var = stats1[256 + tid] * (1.f / 16384.f) - mean * mean;
    float scg = gamma[tid] * rsqrtf(var + 1e-5f);
    ssl[tid] = scg;
    ssl[256 + tid] = beta[tid] - mean * scg;
  }
  __syncthreads();
  const int lane = tid & 63, w = tid >> 6;
#pragma unroll
  for (int rr = 0; rr < 2; ++rr) {
    int f = blockIdx.x * 8 + w * 2 + rr;
    int c = lane * 4;
    float4 wv = *reinterpret_cast<const float4*>(W1 + (size_t)f * 256 + c);
    ushort4 o;
    o.x = f2bf(wv.x * ssl[c + 0]);
    o.y = f2bf(wv.y * ssl[c + 1]);
    o.z = f2bf(wv.z * ssl[c + 2]);
    o.w = f2bf(wv.w * ssl[c + 3]);
    *reinterpret_cast<ushort4*>(W1s + (size_t)f * 256 + c) = o;
    float h = wv.x * ssl[256 + c] + wv.y * ssl[257 + c] +
              wv.z * ssl[258 + c] + wv.w * ssl[259 + c];
    h += __shfl_xor(h, 1, 64);
    h += __shfl_xor(h, 2, 64);
    h += __shfl_xor(h, 4, 64);
    h += __shfl_xor(h, 8, 64);
    h += __shfl_xor(h, 16, 64);
    h += __shfl_xor(h, 32, 64);
    if (lane == 0) h0[f] = b1[f] + h;
  }
}

// ---------------- FFN1: pure gll16 GEMM, A = SoutB bf16, B = W1s (BN pre-folded) --------
// grid 1024: eff=(orig&7)*128+orig/8; n=eff&7, m=eff>>3
__global__ __launch_bounds__(256) void gemm_ffn1(
    const u16* __restrict__ A_,
    const u16* __restrict__ B_,
    const float* __restrict__ h0,
    const float* __restrict__ aslope,
    u16* __restrict__ H1B) {
  __shared__ u16 As[4096], Bs[4096];
  const int tid = threadIdx.x;
  const int lane = tid & 63, w = tid >> 6;
  const int wr = w >> 1, wc = w & 1;
  const int q = lane & 15, G = lane >> 4;
  const int eff = (blockIdx.x & 7) * 128 + (blockIdx.x >> 3);
  const int m0 = (eff >> 3) * 128, n0 = (eff & 7) * 128;

  const int rr0 = w * 32 + (lane >> 2), rr1 = rr0 + 16;
  const int sl0 = (lane & 3) ^ ((rr0 >> 1) & 3);
  const int sl1 = (lane & 3) ^ ((rr1 >> 1) & 3);
  const size_t a0 = (size_t)(m0 + rr0) * 256 + sl0 * 8;
  const size_t a1 = (size_t)(m0 + rr1) * 256 + sl1 * 8;
  const size_t b0 = (size_t)(n0 + rr0) * 256 + sl0 * 8;
  const size_t b1 = (size_t)(n0 + rr1) * 256 + sl1 * 8;

  f32x4 acc[4][4] = {};
  for (int kt = 0; kt < 256; kt += 32) {
    __syncthreads();
    gll16(A_ + a0 + kt, &As[w * 1024]);
    gll16(A_ + a1 + kt, &As[w * 1024 + 512]);
    gll16(B_ + b0 + kt, &Bs[w * 1024]);
    gll16(B_ + b1 + kt, &Bs[w * 1024 + 512]);
    __syncthreads();
    bf16x8 af[4], bfr[4];
#pragma unroll
    for (int m = 0; m < 4; ++m)
      af[m] = *reinterpret_cast<const bf16x8*>((const char*)As + TOFF(wr * 64 + m * 16 + q, G));
#pragma unroll
    for (int n = 0; n < 4; ++n)
      bfr[n] = *reinterpret_cast<const bf16x8*>((const char*)Bs + TOFF(wc * 64 + n * 16 + q, G));
#pragma unroll
    for (int m = 0; m < 4; ++m)
#pragma unroll
      for (int n = 0; n < 4; ++n)
        acc[m][n] = __builtin_amdgcn_mfma_f32_16x16x32_bf16(af[m], bfr[n], acc[m][n], 0, 0, 0);
  }
  float a = aslope[0];
#pragma unroll
  for (int m = 0; m < 4; ++m) {
    int row_b = m0 + wr * 64 + m * 16 + G * 4;
#pragma unroll
    for (int n = 0; n < 4; ++n) {
      int col = n0 + wc * 64 + n * 16 + q;
      float bb = h0[col];
#pragma unroll
      for (int r = 0; r < 4; ++r) {
        float v = acc[m][n][r] + bb;
        v = (v >= 0.f) ? v : a * v;
        H1B[(size_t)(row_b + r) * 1024 + col] = f2bf(v);
      }
    }
  }
}

// ---------------- FFN2: BM=64 x BN=64 x BK=64, resid from SoutB, fused BN2 stats ------
__global__ __launch_bounds__(256) void gemm_ffn2(
    const u16* __restrict__ A_,
    const u16* __restrict__ B_,
    const float* __restrict__ bias,
    const u16* __restrict__ SoutB,
    const float* __restrict__ stats1,
    const float* __restrict__ gamma,
    const float* __restrict__ beta,
    float* __restrict__ T2,
    float* __restrict__ stats2) {
  __shared__ u16 As[4096], Bs[4096];
  __shared__ float ssl[512];
  __shared__ float sred[2][64];
  const int tid = threadIdx.x;
  const int lane = tid & 63, w = tid >> 6;
  const int wr = w >> 1, wc = w & 1;
  const int q = lane & 15, G = lane >> 4;
  const int eff = (blockIdx.x & 7) * 128 + (blockIdx.x >> 3);
  const int m0 = (eff >> 2) * 64, n0 = (eff & 3) * 64;
  {
    float mean = stats1[tid] * (1.f / 16384.f);
    float var = stats1[256 + tid] * (1.f / 16384.f) - mean * mean;
    float scg = gamma[tid] * rsqrtf(var + 1e-5f);
    ssl[tid] = scg;
    ssl[256 + tid] = beta[tid] - mean * scg;
  }
  if (tid < 64) { sred[0][tid] = 0.f; sred[1][tid] = 0.f; }

  const int rl = lane >> 3, sl8 = lane & 7;
  const int ssrc = (sl8 ^ rl) * 8;

  f32x4 acc[2][2] = {};
  for (int kt = 0; kt < 1024; kt += 64) {
    __syncthreads();
#pragma unroll
    for (int i = 0; i < 2; ++i) {
      int rb = (i * 4 + w) * 8;
      gll16(A_ + (size_t)(m0 + rb + rl) * 1024 + kt + ssrc, &As[rb * 64]);
      gll16(B_ + (size_t)(n0 + rb + rl) * 1024 + kt + ssrc, &Bs[rb * 64]);
    }
    __syncthreads();
#pragma unroll
    for (int kk = 0; kk < 2; ++kk) {
      bf16x8 af[2], bf2[2];
#pragma unroll
      for (int m = 0; m < 2; ++m)
        af[m] = *reinterpret_cast<const bf16x8*>((const char*)As + TOFF2(wr * 32 + m * 16 + q, kk * 4 + G));
#pragma unroll
      for (int n = 0; n < 2; ++n)
        bf2[n] = *reinterpret_cast<const bf16x8*>((const char*)Bs + TOFF2(wc * 32 + n * 16 + q, kk * 4 + G));
#pragma unroll
      for (int m = 0; m < 2; ++m)
#pragma unroll
        for (int n = 0; n < 2; ++n)
          acc[m][n] = __builtin_amdgcn_mfma_f32_16x16x32_bf16(af[m], bf2[n], acc[m][n], 0, 0, 0);
    }
  }
  float s1a[2] = {0.f, 0.f}, s2a[2] = {0.f, 0.f};
#pragma unroll
  for (int m = 0; m < 2; ++m) {
    int row_b = m0 + wr * 32 + m * 16 + G * 4;
#pragma unroll
    for (int n = 0; n < 2; ++n) {
      int col = n0 + wc * 32 + n * 16 + q;
      float bb = bias[col];
      float sc_ = ssl[col], of_ = ssl[256 + col];
#pragma unroll
      for (int r = 0; r < 4; ++r) {
        int row = row_b + r;
        float resid = bf2f(SoutB[(size_t)row * 256 + col]) * sc_ + of_;
        float v = acc[m][n][r] + bb + resid;
        T2[(size_t)row * 256 + col] = v;
        s1a[n] += v;
        s2a[n] += v * v;
      }
    }
  }
#pragma unroll
  for (int n = 0; n < 2; ++n) {
    float a1 = s1a[n];
    a1 += __shfl_xor(a1, 16, 64);
    a1 += __shfl_xor(a1, 32, 64);
    float a2 = s2a[n];
    a2 += __shfl_xor(a2, 16, 64);
    a2 += __shfl_xor(a2, 32, 64);
    if (lane < 16) {
      atomicAdd(&sred[0][wc * 32 + n * 16 + lane], a1);
      atomicAdd(&sred[1][wc * 32 + n * 16 + lane], a2);
    }
  }
  __syncthreads();
  if (tid < 64) {
    atomicAdd(&stats2[n0 + tid], sred[0][tid]);
    atomicAdd(&stats2[256 + n0 + tid], sred[1][tid]);
  }
}

// ---------------- final BN (inline from stats2) + transpose [T,C] -> [B,C,N] ----------
__global__ __launch_bounds__(256) void bn_final_out(const float* __restrict__ T2,
                                                    const float* __restrict__ stats2,
                                                    const float* __restrict__ gamma,
                                                    const float* __restrict__ beta,
                                                    float* __restrict__ out) {
  __shared__ float tile[32][33];
  int n0 = (blockIdx.x & 31) * 32;
  int b = blockIdx.x >> 5;
  int c0 = blockIdx.y * 32;
  int tx = threadIdx.x, ty = threadIdx.y;
  int c = c0 + tx;
  float mean = stats2[c] * (1.f / 16384.f);
  float var = stats2[256 + c] * (1.f / 16384.f) - mean * mean;
  float scg = gamma[c] * rsqrtf(var + 1e-5f);
  float off = beta[c] - mean * scg;
#pragma unroll
  for (int j = 0; j < 4; ++j) {
    int r = ty + j * 8;
    float v = T2[((size_t)b * 1024 + n0 + r) * 256 + c];
    tile[r][tx] = v * scg + off;
  }
  __syncthreads();
#pragma unroll
  for (int j = 0; j < 4; ++j) {
    int cc = c0 + ty + j * 8;
    out[((size_t)b * 256 + cc) * 1024 + n0 + tx] = tile[tx][ty + j * 8];
  }
}

// ---------------- fused flash attention: swapped QK^T, permuted-k PV, exp2-direct --------
#define SWZ(row, bcol) ((bcol) ^ (((row) & 7) << 4))
__global__ __launch_bounds__(256, 4) void attn_kernel(const u16* __restrict__ QKh,
                                                      const u16* __restrict__ QKl,
                                                      const u16* __restrict__ Vt,
                                                      const float* __restrict__ x,
                                                      float* __restrict__ Sout,
                                                      u16* __restrict__ SoutB,
                                                      float* __restrict__ stats) {
  __shared__ u16 Kh[2][4096], Vs[2][4096];
  __shared__ float sred[2][64];
  const int tid = threadIdx.x, lane = tid & 63, w = tid >> 6;
  const int hb = blockIdx.x, h = hb & 3, b = hb >> 2;
  const size_t tb = (size_t)b * 1024;
  const int qrow0 = blockIdx.y * 64 + w * 16;
  const int q = lane & 15, G = lane >> 4;

  if (tid < 64) { sred[0][tid] = 0.f; sred[1][tid] = 0.f; }

  bf16x8 qh[2], ql[2];
#pragma unroll
  for (int kk = 0; kk < 2; ++kk) {
    size_t ro = (tb + qrow0 + q) * 512 + h * 64 + kk * 32 + G * 8;
    qh[kk] = *reinterpret_cast<const bf16x8*>(QKh + ro);
    ql[kk] = *reinterpret_cast<const bf16x8*>(QKl + ro);
  }

  f32x4 oacc[4] = {};
  float mprev = -3e38f, lsum = 0.f;

  const int sr0 = tid >> 3, sr1 = sr0 + 32;
  const int c7 = tid & 7;
  const int scb0 = c7 << 4;
  const int dstb0 = sr0 * 128 + SWZ(sr0, scb0);
  const int dstb1 = sr1 * 128 + SWZ(sr1, scb0);
  const size_t kbase0 = (tb + sr0) * 512 + 256 + h * 64 + c7 * 8;
  const size_t kbase1 = (tb + sr1) * 512 + 256 + h * 64 + c7 * 8;
  const int vb0 = 32 * (c7 >> 2) + 8 * ((2 * c7) & 3) + 4 * ((c7 >> 1) & 1);
  const int vx0 = (vb0 * 2) ^ ((sr0 & 7) << 4);
  const int vx1 = (vb0 * 2 + 16) ^ ((sr0 & 7) << 4);
  const size_t vbase0 = ((size_t)b * 256 + h * 64 + sr0) * 1024 + c7 * 8;
  const size_t vbase1 = ((size_t)b * 256 + h * 64 + sr1) * 1024 + c7 * 8;

  uint4 rk0 = *reinterpret_cast<const uint4*>(QKh + kbase0);
  uint4 rk1 = *reinterpret_cast<const uint4*>(QKh + kbase1);
  uint4 rv0 = *reinterpret_cast<const uint4*>(Vt + vbase0);
  uint4 rv1 = *reinterpret_cast<const uint4*>(Vt + vbase1);
  *reinterpret_cast<uint4*>((char*)Kh[0] + dstb0) = rk0;
  *reinterpret_cast<uint4*>((char*)Kh[0] + dstb1) = rk1;
  {
    uint2 lo0 = {rv0.x, rv0.y}, hi0 = {rv0.z, rv0.w};
    uint2 lo1 = {rv1.x, rv1.y}, hi1 = {rv1.z, rv1.w};
    *reinterpret_cast<uint2*>((char*)Vs[0] + sr0 * 128 + vx0) = lo0;
    *reinterpret_cast<uint2*>((char*)Vs[0] + sr0 * 128 + vx1) = hi0;
    *reinterpret_cast<uint2*>((char*)Vs[0] + sr1 * 128 + vx0) = lo1;
    *reinterpret_cast<uint2*>((char*)Vs[0] + sr1 * 128 + vx1) = hi1;
  }
  __syncthreads();

  int cur = 0;
  for (int kt = 0; kt < 16; ++kt) {
    if (kt < 15) {
      rk0 = *reinterpret_cast<const uint4*>(QKh + kbase0 + (size_t)(kt + 1) * 32768);
      rk1 = *reinterpret_cast<const uint4*>(QKh + kbase1 + (size_t)(kt + 1) * 32768);
      rv0 = *reinterpret_cast<const uint4*>(Vt + vbase0 + (size_t)(kt + 1) * 64);
      rv1 = *reinterpret_cast<const uint4*>(Vt + vbase1 + (size_t)(kt + 1) * 64);
    }

    f32x4 sc[4] = {};
    __builtin_amdgcn_s_setprio(1);
#pragma unroll
    for (int kk = 0; kk < 2; ++kk)
#pragma unroll
      for (int n = 0; n < 4; ++n) {
        int krow = n * 16 + q;
        int kb_ = krow * 128 + SWZ(krow, kk * 64 + G * 16);
        bf16x8 akh = *reinterpret_cast<const bf16x8*>((const char*)Kh[cur] + kb_);
        sc[n] = __builtin_amdgcn_mfma_f32_16x16x32_bf16(akh, qh[kk], sc[n], 0, 0, 0);
        sc[n] = __builtin_amdgcn_mfma_f32_16x16x32_bf16(akh, ql[kk], sc[n], 0, 0, 0);
      }
    __builtin_amdgcn_s_setprio(0);

    float vm;
    {
      float t0 = fmaxf(fmaxf(sc[0][0], sc[0][1]), sc[0][2]);
      float t1 = fmaxf(fmaxf(sc[0][3], sc[1][0]), sc[1][1]);
      float t2 = fmaxf(fmaxf(sc[1][2], sc[1][3]), sc[2][0]);
      float t3 = fmaxf(fmaxf(sc[2][1], sc[2][2]), sc[2][3]);
      float t4 = fmaxf(fmaxf(sc[3][0], sc[3][1]), sc[3][2]);
      vm = fmaxf(fmaxf(fmaxf(t0, t1), t2), fmaxf(fmaxf(t3, t4), sc[3][3]));
      vm = fmaxf(vm, __shfl_xor(vm, 16, 64));
      vm = fmaxf(vm, __shfl_xor(vm, 32, 64));
    }
    bool ok = (vm <= mprev + 11.54f);
    if (!__all(ok)) {
      float mn = fmaxf(mprev, vm);
      float scl = exp2_fast(mprev - mn);
      mprev = mn;
      lsum *= scl;
      float sclr[4];
#pragma unroll
      for (int r = 0; r < 4; ++r) sclr[r] = __shfl(scl, G * 4 + r, 64);
#pragma unroll
      for (int dn = 0; dn < 4; ++dn)
#pragma unroll
        for (int r = 0; r < 4; ++r) oacc[dn][r] *= sclr[r];
    }
    float lt = 0.f;
#pragma unroll
    for (int n = 0; n < 4; ++n)
#pragma unroll
      for (int r = 0; r < 4; ++r) {
        float p = exp2_fast(sc[n][r] - mprev);
        sc[n][r] = p;
        lt += p;
      }
    lsum += lt;
    bf16x8 pa[2];
    {
      uint4 pw0, pw1;
      pw0.x = cvt_pk_bf16(sc[0][0], sc[0][1]);
      pw0.y = cvt_pk_bf16(sc[0][2], sc[0][3]);
      pw0.z = cvt_pk_bf16(sc[1][0], sc[1][1]);
      pw0.w = cvt_pk_bf16(sc[1][2], sc[1][3]);
      pw1.x = cvt_pk_bf16(sc[2][0], sc[2][1]);
      pw1.y = cvt_pk_bf16(sc[2][2], sc[2][3]);
      pw1.z = cvt_pk_bf16(sc[3][0], sc[3][1]);
      pw1.w = cvt_pk_bf16(sc[3][2], sc[3][3]);
      pa[0] = *reinterpret_cast<bf16x8*>(&pw0);
      pa[1] = *reinterpret_cast<bf16x8*>(&pw1);
    }
    __builtin_amdgcn_s_setprio(1);
#pragma unroll
    for (int kk = 0; kk < 2; ++kk)
#pragma unroll
      for (int dn = 0; dn < 4; ++dn) {
        int vrow = dn * 16 + q;
        int vb_ = vrow * 128 + SWZ(vrow, kk * 64 + G * 16);
        bf16x8 vv = *reinterpret_cast<const bf16x8*>((const char*)Vs[cur] + vb_);
        oacc[dn] = __builtin_amdgcn_mfma_f32_16x16x32_bf16(pa[kk], vv, oacc[dn], 0, 0, 0);
      }
    __builtin_amdgcn_s_setprio(0);
    if (kt < 15) {
      *reinterpret_cast<uint4*>((char*)Kh[cur ^ 1] + dstb0) = rk0;
      *reinterpret_cast<uint4*>((char*)Kh[cur ^ 1] + dstb1) = rk1;
      uint2 lo0 = {rv0.x, rv0.y}, hi0 = {rv0.z, rv0.w};
      uint2 lo1 = {rv1.x, rv1.y}, hi1 = {rv1.z, rv1.w};
      *reinterpret_cast<uint2*>((char*)Vs[cur ^ 1] + sr0 * 128 + vx0) = lo0;
      *reinterpret_cast<uint2*>((char*)Vs[cur ^ 1] + sr0 * 128 + vx1) = hi0;
      *reinterpret_cast<uint2*>((char*)Vs[cur ^ 1] + sr1 * 128 + vx0) = lo1;
      *reinterpret_cast<uint2*>((char*)Vs[cur ^ 1] + sr1 * 128 + vx1) = hi1;
    }
    __syncthreads();
    cur ^= 1;
  }
  float lf = lsum;
  lf += __shfl_xor(lf, 16, 64);
  lf += __shfl_xor(lf, 32, 64);
  float rinv[4];
#pragma unroll
  for (int r = 0; r < 4; ++r) rinv[r] = 1.f / __shfl(lf, G * 4 + r, 64);

  const int row0 = qrow0 + G * 4;
  const float* xp = x + ((size_t)b * 256 + h * 64) * 1024;
  float s1a[4] = {0.f, 0.f, 0.f, 0.f}, s2a[4] = {0.f, 0.f, 0.f, 0.f};
#pragma unroll
  for (int dn = 0; dn < 4; ++dn) {
    int col = dn * 16 + q;
    float4 xv = *reinterpret_cast<const float4*>(xp + (size_t)col * 1024 + row0);
    const float* xvp = reinterpret_cast<const float*>(&xv);
#pragma unroll
    for (int r = 0; r < 4; ++r) {
      size_t gi = (tb + row0 + r) * 256 + h * 64 + col;
      float v = oacc[dn][r] * rinv[r] + xvp[r];
      Sout[gi] = v;
      SoutB[gi] = f2bf(v);
      s1a[dn] += v;
      s2a[dn] += v * v;
    }
  }
#pragma unroll
  for (int dn = 0; dn < 4; ++dn) {
    float a1 = s1a[dn];
    a1 += __shfl_xor(a1, 16, 64);
    a1 += __shfl_xor(a1, 32, 64);
    float a2 = s2a[dn];
    a2 += __shfl_xor(a2, 16, 64);
    a2 += __shfl_xor(a2, 32, 64);
    if (lane < 16) {
      atomicAdd(&sred[0][dn * 16 + lane], a1);
      atomicAdd(&sred[1][dn * 16 + lane], a2);
    }
  }
  __syncthreads();
  if (tid < 64) {
    atomicAdd(&stats[h * 64 + tid], sred[0][tid]);
    atomicAdd(&stats[256 + h * 64 + tid], sred[1][tid]);
  }
}

// ---------------- launch ----------------
extern "C" void kernel_launch(void* const* d_in, const int* in_sizes, int n_in,
                              void* d_out, int out_size, void* d_ws, size_t ws_size,
                              hipStream_t stream) {
  const float* x = (const float*)d_in[0];
  const float* Wq = (const float*)d_in[1];
  const float* bq = (const float*)d_in[2];
  const float* Wk = (const float*)d_in[3];
  const float* bk = (const float*)d_in[4];
  const float* Wv = (const float*)d_in[5];
  const float* bv = (const float*)d_in[6];
  const float* gamma = (const float*)d_in[7];
  const float* beta = (const float*)d_in[8];
  const float* W1 = (const float*)d_in[9];
  const float* b1 = (const float*)d_in[10];
  const float* a = (const float*)d_in[11];
  const float* W2 = (const float*)d_in[12];
  const float* b2 = (const float*)d_in[13];
  float* out = (float*)d_out;

  char* wsb = (char*)d_ws;
  const size_t MB = 1ull << 20;
  u16* XtbH = (u16*)(wsb + 0 * MB);        // 8MB; region [0,16) reused as T2 after qkvt
  u16* XtbL = (u16*)(wsb + 8 * MB);        // 8MB
  float* T2 = (float*)(wsb + 0 * MB);      // 16MB (alias XtbH/L, live from ffn2 on)
  u16* SoutB = (u16*)(wsb + 16 * MB);      // 8MB (raw o+x in bf16)
  u16* QKh = (u16*)(wsb + 32 * MB);        // 16MB; [32,64) reused as H1B after attn
  u16* QKl = (u16*)(wsb + 48 * MB);        // 16MB
  u16* Vt = (u16*)(wsb + 64 * MB);         // 8MB
  char* wp = wsb + 72 * MB;
  u16* WallH = (u16*)(wp);                 // 256KB
  u16* WallL = (u16*)(wp + 262144);        // 256KB
  u16* WvH = (u16*)(wp + 524288);          // 128KB
  u16* WvL = (u16*)(wp + 655360);          // 128KB
  u16* W1s = (u16*)(wp + 786432);          // 512KB (BN-scaled W1, by w1prep)
  u16* W2b = (u16*)(wp + 1310720);         // 512KB
  float* bqk = (float*)(wp + 1835008);     // 2KB
  float* stats = (float*)(wp + 1837056);   // 8KB: stats1 | pad | stats2 | pad
  float* h0 = (float*)(wp + 1845248);      // 4KB
  if (ws_size < 73 * MB) return;

  u16* H1B = QKh;    // [T,1024] bf16, after attn
  float* S = out;    // d_out doubles as o+x raw residual buffer [T,256]
  float* stats2 = stats + 1024;

  hipMemsetAsync(stats, 0, 8192, stream);
  // fused x-transpose + weight prep
  prep_all<<<5120, 256, 0, stream>>>(x, Wq, Wk, Wv, bq, bk, W2,
                                     XtbH, XtbL, WallH, WallL, WvH, WvL, W2b, bqk);
  // fused QK projection (Q pre-scaled by log2e) + V projection transposed
  gemm_qkvt<<<768, 256, 0, stream>>>(XtbH, XtbL, WallH, WallL, bqk, QKh, QKl,
                                     WvH, WvL, bv, Vt);
  // attention + residual (f32 + bf16 outputs) + BN1 stats
  attn_kernel<<<dim3(64, 16), 256, 0, stream>>>(QKh, QKl, Vt, x, S, SoutB, stats);
  // fold BN1 into W1: W1s = bf16(W1*sc), h0 = b1 + W1*of
  w1prep<<<128, 256, 0, stream>>>(W1, b1, stats, gamma, beta, W1s, h0);
  // FFN1: pure gll16 GEMM (A=SoutB, B=W1s), bias h0, PReLU
  gemm_ffn1<<<1024, 256, 0, stream>>>(SoutB, W1s, h0, a, H1B);
  // FFN2: bias + BN1(resid from SoutB) + BN2 stats -> T2
  gemm_ffn2<<<1024, 256, 0, stream>>>(H1B, W2b, b2, SoutB, stats, gamma, beta, T2, stats2);
  // BN2 apply (inline finalize) + transpose out
  bn_final_out<<<dim3(512, 8), dim3(32, 8), 0, stream>>>(T2, stats2, gamma, beta, out);
}

// Round 15
// 123.470 us; speedup vs baseline: 2.4728x; 1.0241x over previous
//
#include <hip/hip_runtime.h>
#include <hip/hip_bf16.h>

typedef unsigned short u16;
typedef unsigned int u32;
typedef __attribute__((ext_vector_type(8))) __bf16 bf16x8;
typedef __attribute__((ext_vector_type(4))) float f32x4;

#define LOG2E 1.44269504088896340736f

__device__ inline u16 f2bf(float f) {
  unsigned int x = __float_as_uint(f);
  unsigned int r = (x + 0x7FFFu + ((x >> 16) & 1u)) >> 16;
  return (u16)r;
}
__device__ inline float bf2f(u16 u) { return __uint_as_float(((unsigned int)u) << 16); }
__device__ inline void split2(float v, u16& h, u16& l) {
  h = f2bf(v);
  l = f2bf(v - bf2f(h));
}
__device__ inline u32 cvt_pk_bf16(float lo, float hi) {
  u32 r;
  asm("v_cvt_pk_bf16_f32 %0, %1, %2" : "=v"(r) : "v"(lo), "v"(hi));
  return r;
}
__device__ inline float exp2_fast(float x) {
  float r;
  asm("v_exp_f32 %0, %1" : "=v"(r) : "v"(x));
  return r;
}
// async global->LDS, 16B/lane; dest = wave-uniform base + lane*16
__device__ inline void gll16(const u16* g, u16* l) {
  __builtin_amdgcn_global_load_lds((const __attribute__((address_space(1))) void*)g,
                                   (__attribute__((address_space(3))) void*)l, 16, 0, 0);
}
// [R][32]-bf16 tile (64B rows): logical (row, slot s in 0..3) -> physical byte offset
#define TOFF(r, s) (((r) << 6) + ((((s) ^ (((r) >> 1) & 3))) << 4))
// [R][64]-bf16 tile (128B rows): logical (row, slot s in 0..7) -> physical byte offset
#define TOFF2(r, s) (((r) << 7) + ((((s) ^ ((r) & 7))) << 4))

// ---------------- fused: x transpose + weight prep ----------------
__global__ __launch_bounds__(256) void prep_all(
    const float* __restrict__ x,
    const float* __restrict__ Wq, const float* __restrict__ Wk, const float* __restrict__ Wv,
    const float* __restrict__ bq, const float* __restrict__ bk,
    const float* __restrict__ W2,
    u16* __restrict__ XtbH, u16* __restrict__ XtbL,
    u16* __restrict__ WallH, u16* __restrict__ WallL,
    u16* __restrict__ WvH, u16* __restrict__ WvL,
    u16* __restrict__ W2b,
    float* __restrict__ bqk) {
  __shared__ float tile[32][33];
  const int id = blockIdx.x;
  if (id < 4096) {
    int n0 = (id & 31) * 32, c0 = ((id >> 5) & 7) * 32, b = id >> 8;
    int tx = threadIdx.x & 31, ty = threadIdx.x >> 5;
#pragma unroll
    for (int j = 0; j < 4; ++j) {
      int c = c0 + ty + j * 8;
      tile[ty + j * 8][tx] = x[((size_t)b * 256 + c) * 1024 + n0 + tx];
    }
    __syncthreads();
#pragma unroll
    for (int j = 0; j < 4; ++j) {
      int n = n0 + ty + j * 8;
      float v = tile[tx][ty + j * 8];
      size_t o = ((size_t)b * 1024 + n) * 256 + c0 + tx;
      u16 h, l;
      split2(v, h, l);
      XtbH[o] = h; XtbL[o] = l;
    }
  } else {
    int i = (id - 4096) * 256 + threadIdx.x;
    if (i < 131072) {
      float w = (i < 65536) ? Wq[i] : Wk[i - 65536];
      u16 h, l;
      split2(w, h, l);
      WallH[i] = h; WallL[i] = l;
    }
    if (i < 65536) {
      u16 h, l;
      split2(Wv[i], h, l);
      WvH[i] = h; WvL[i] = l;
    }
    if (i < 262144) W2b[i] = f2bf(W2[i]);
    if (i < 256) bqk[i] = bq[i];
    else if (i < 512) bqk[i] = bk[i - 256];
  }
}

// ---------------- fused QK-projection + V-projection (one dispatch, role by id) ----------
// Q-half outputs are pre-scaled by log2(e) so attention softmax can use raw v_exp_f32.
__global__ __launch_bounds__(256) void gemm_qkvt(
    const u16* __restrict__ Ah_, const u16* __restrict__ Al_,
    const u16* __restrict__ Bh_, const u16* __restrict__ Bl_,
    const float* __restrict__ bias,
    u16* __restrict__ Ch, u16* __restrict__ Cl,
    const u16* __restrict__ WvH_, const u16* __restrict__ WvL_,
    const float* __restrict__ bv, u16* __restrict__ Vt) {
  __shared__ u16 Ah[4096], Al[4096], Bh[4096], Bl[4096];
  const int tid = threadIdx.x;
  const int lane = tid & 63, w = tid >> 6;
  const int wr = w >> 1, wc = w & 1;
  const int q = lane & 15, G = lane >> 4;
  const int rr0 = w * 32 + (lane >> 2), rr1 = rr0 + 16;
  const int sl0 = (lane & 3) ^ ((rr0 >> 1) & 3);
  const int sl1 = (lane & 3) ^ ((rr1 >> 1) & 3);

  if (blockIdx.x < 512) {
    // ---- QK role ----
    const int eff = (blockIdx.x & 7) * 64 + (blockIdx.x >> 3);
    const int m0 = (eff >> 2) * 128, n0 = (eff & 3) * 128;
    const bool isQ = (n0 < 256);
    const size_t a0 = (size_t)(m0 + rr0) * 256 + sl0 * 8;
    const size_t a1 = (size_t)(m0 + rr1) * 256 + sl1 * 8;
    const size_t b0 = (size_t)(n0 + rr0) * 256 + sl0 * 8;
    const size_t b1 = (size_t)(n0 + rr1) * 256 + sl1 * 8;

    f32x4 acc[4][4] = {};
    for (int kt = 0; kt < 256; kt += 32) {
      __syncthreads();
      gll16(Ah_ + a0 + kt, &Ah[w * 1024]);
      gll16(Ah_ + a1 + kt, &Ah[w * 1024 + 512]);
      gll16(Al_ + a0 + kt, &Al[w * 1024]);
      gll16(Al_ + a1 + kt, &Al[w * 1024 + 512]);
      gll16(Bh_ + b0 + kt, &Bh[w * 1024]);
      gll16(Bh_ + b1 + kt, &Bh[w * 1024 + 512]);
      gll16(Bl_ + b0 + kt, &Bl[w * 1024]);
      gll16(Bl_ + b1 + kt, &Bl[w * 1024 + 512]);
      __syncthreads();
      bf16x8 afh[4], afl[4], bfh[4], bfl[4];
#pragma unroll
      for (int m = 0; m < 4; ++m) {
        int off = TOFF(wr * 64 + m * 16 + q, G);
        afh[m] = *reinterpret_cast<const bf16x8*>((const char*)Ah + off);
        afl[m] = *reinterpret_cast<const bf16x8*>((const char*)Al + off);
      }
#pragma unroll
      for (int n = 0; n < 4; ++n) {
        int off = TOFF(wc * 64 + n * 16 + q, G);
        bfh[n] = *reinterpret_cast<const bf16x8*>((const char*)Bh + off);
        bfl[n] = *reinterpret_cast<const bf16x8*>((const char*)Bl + off);
      }
#pragma unroll
      for (int m = 0; m < 4; ++m)
#pragma unroll
        for (int n = 0; n < 4; ++n) {
          acc[m][n] = __builtin_amdgcn_mfma_f32_16x16x32_bf16(afh[m], bfh[n], acc[m][n], 0, 0, 0);
          acc[m][n] = __builtin_amdgcn_mfma_f32_16x16x32_bf16(afl[m], bfh[n], acc[m][n], 0, 0, 0);
        }
      if (isQ) {
#pragma unroll
        for (int m = 0; m < 4; ++m)
#pragma unroll
          for (int n = 0; n < 4; ++n)
            acc[m][n] = __builtin_amdgcn_mfma_f32_16x16x32_bf16(afh[m], bfl[n], acc[m][n], 0, 0, 0);
      }
    }
    const float qscale = isQ ? LOG2E : 1.f;
#pragma unroll
    for (int m = 0; m < 4; ++m) {
      int row_b = m0 + wr * 64 + m * 16 + G * 4;
#pragma unroll
      for (int n = 0; n < 4; ++n) {
        int col = n0 + wc * 64 + n * 16 + q;
        float bb = bias[col];
#pragma unroll
        for (int r = 0; r < 4; ++r) {
          size_t o = (size_t)(row_b + r) * 512 + col;
          u16 h, l;
          split2((acc[m][n][r] + bb) * qscale, h, l);
          Ch[o] = h;
          if (isQ) Cl[o] = l;
        }
      }
    }
  } else {
    // ---- Vt role ----
    const int o_ = blockIdx.x - 512;
    const int eff = (o_ & 7) * 32 + (o_ >> 3);
    const int m0 = (eff & 1) * 128, n0 = ((eff >> 1) & 7) * 128, b = eff >> 4;
    const u16* Bp = Ah_ + (size_t)b * 1024 * 256;  // XtbH
    const size_t a0 = (size_t)(m0 + rr0) * 256 + sl0 * 8;
    const size_t a1 = (size_t)(m0 + rr1) * 256 + sl1 * 8;
    const size_t b0 = (size_t)(n0 + rr0) * 256 + sl0 * 8;
    const size_t b1 = (size_t)(n0 + rr1) * 256 + sl1 * 8;

    f32x4 acc[4][4] = {};
    for (int kt = 0; kt < 256; kt += 32) {
      __syncthreads();
      gll16(WvH_ + a0 + kt, &Ah[w * 1024]);
      gll16(WvH_ + a1 + kt, &Ah[w * 1024 + 512]);
      gll16(WvL_ + a0 + kt, &Al[w * 1024]);
      gll16(WvL_ + a1 + kt, &Al[w * 1024 + 512]);
      gll16(Bp + b0 + kt, &Bh[w * 1024]);
      gll16(Bp + b1 + kt, &Bh[w * 1024 + 512]);
      __syncthreads();
      bf16x8 afh[4], afl[4], bfr[4];
#pragma unroll
      for (int m = 0; m < 4; ++m) {
        int off = TOFF(wr * 64 + m * 16 + q, G);
        afh[m] = *reinterpret_cast<const bf16x8*>((const char*)Ah + off);
        afl[m] = *reinterpret_cast<const bf16x8*>((const char*)Al + off);
      }
#pragma unroll
      for (int n = 0; n < 4; ++n)
        bfr[n] = *reinterpret_cast<const bf16x8*>((const char*)Bh + TOFF(wc * 64 + n * 16 + q, G));
#pragma unroll
      for (int m = 0; m < 4; ++m)
#pragma unroll
        for (int n = 0; n < 4; ++n) {
          acc[m][n] = __builtin_amdgcn_mfma_f32_16x16x32_bf16(afh[m], bfr[n], acc[m][n], 0, 0, 0);
          acc[m][n] = __builtin_amdgcn_mfma_f32_16x16x32_bf16(afl[m], bfr[n], acc[m][n], 0, 0, 0);
        }
    }
#pragma unroll
    for (int m = 0; m < 4; ++m) {
      int row_b = m0 + wr * 64 + m * 16 + G * 4;  // d index
#pragma unroll
      for (int n = 0; n < 4; ++n) {
        int col = n0 + wc * 64 + n * 16 + q;      // token n
#pragma unroll
        for (int r = 0; r < 4; ++r) {
          int row = row_b + r;
          Vt[((size_t)b * 256 + row) * 1024 + col] = f2bf(acc[m][n][r] + bv[row]);
        }
      }
    }
  }
}

// ---------------- w1prep: ss1 from stats1; W1s = bf16(W1*sc); h0 = b1 + W1*of ----------
__global__ __launch_bounds__(256) void w1prep(
    const float* __restrict__ W1, const float* __restrict__ b1,
    const float* __restrict__ stats1, const float* __restrict__ gamma,
    const float* __restrict__ beta,
    u16* __restrict__ W1s, float* __restrict__ h0) {
  __shared__ float ssl[512];
  const int tid = threadIdx.x;
  {
    float mean = stats1[tid] * (1.f / 16384.f);
    float var = stats1[256 + tid] * (1.f / 16384.f) - mean * mean;
    float scg = gamma[tid] * rsqrtf(var + 1e-5f);
    ssl[tid] = scg;
    ssl[256 + tid] = beta[tid] - mean * scg;
  }
  __syncthreads();
  const int lane = tid & 63, w = tid >> 6;
#pragma unroll
  for (int rr = 0; rr < 2; ++rr) {
    int f = blockIdx.x * 8 + w * 2 + rr;
    int c = lane * 4;
    float4 wv = *reinterpret_cast<const float4*>(W1 + (size_t)f * 256 + c);
    ushort4 o;
    o.x = f2bf(wv.x * ssl[c + 0]);
    o.y = f2bf(wv.y * ssl[c + 1]);
    o.z = f2bf(wv.z * ssl[c + 2]);
    o.w = f2bf(wv.w * ssl[c + 3]);
    *reinterpret_cast<ushort4*>(W1s + (size_t)f * 256 + c) = o;
    float h = wv.x * ssl[256 + c] + wv.y * ssl[257 + c] +
              wv.z * ssl[258 + c] + wv.w * ssl[259 + c];
    h += __shfl_xor(h, 1, 64);
    h += __shfl_xor(h, 2, 64);
    h += __shfl_xor(h, 4, 64);
    h += __shfl_xor(h, 8, 64);
    h += __shfl_xor(h, 16, 64);
    h += __shfl_xor(h, 32, 64);
    if (lane == 0) h0[f] = b1[f] + h;
  }
}

// ---------------- FFN1: pure gll16 GEMM, BK=64, A = SoutB bf16, B = W1s ----------------
// grid 1024: eff=(orig&7)*128+orig/8; n=eff&7, m=eff>>3
__global__ __launch_bounds__(256) void gemm_ffn1(
    const u16* __restrict__ A_,
    const u16* __restrict__ B_,
    const float* __restrict__ h0,
    const float* __restrict__ aslope,
    u16* __restrict__ H1B) {
  __shared__ u16 As[8192], Bs[8192];   // [128][64] bf16 each, TOFF2 layout
  const int tid = threadIdx.x;
  const int lane = tid & 63, w = tid >> 6;
  const int wr = w >> 1, wc = w & 1;
  const int q = lane & 15, G = lane >> 4;
  const int eff = (blockIdx.x & 7) * 128 + (blockIdx.x >> 3);
  const int m0 = (eff >> 3) * 128, n0 = (eff & 7) * 128;

  const int rl = lane >> 3, sl8 = lane & 7;
  const int ssrc = (sl8 ^ rl) * 8;  // inverse-swizzled source col (TOFF2 pairing)

  f32x4 acc[4][4] = {};
  for (int kt = 0; kt < 256; kt += 64) {
    __syncthreads();
#pragma unroll
    for (int i = 0; i < 4; ++i) {
      int rb = (i * 4 + w) * 8;
      gll16(A_ + (size_t)(m0 + rb + rl) * 256 + kt + ssrc, &As[rb * 64]);
      gll16(B_ + (size_t)(n0 + rb + rl) * 256 + kt + ssrc, &Bs[rb * 64]);
    }
    __syncthreads();
#pragma unroll
    for (int kk = 0; kk < 2; ++kk) {
      bf16x8 af[4], bfr[4];
#pragma unroll
      for (int m = 0; m < 4; ++m)
        af[m] = *reinterpret_cast<const bf16x8*>((const char*)As + TOFF2(wr * 64 + m * 16 + q, kk * 4 + G));
#pragma unroll
      for (int n = 0; n < 4; ++n)
        bfr[n] = *reinterpret_cast<const bf16x8*>((const char*)Bs + TOFF2(wc * 64 + n * 16 + q, kk * 4 + G));
#pragma unroll
      for (int m = 0; m < 4; ++m)
#pragma unroll
        for (int n = 0; n < 4; ++n)
          acc[m][n] = __builtin_amdgcn_mfma_f32_16x16x32_bf16(af[m], bfr[n], acc[m][n], 0, 0, 0);
    }
  }
  float a = aslope[0];
#pragma unroll
  for (int m = 0; m < 4; ++m) {
    int row_b = m0 + wr * 64 + m * 16 + G * 4;
#pragma unroll
    for (int n = 0; n < 4; ++n) {
      int col = n0 + wc * 64 + n * 16 + q;
      float bb = h0[col];
#pragma unroll
      for (int r = 0; r < 4; ++r) {
        float v = acc[m][n][r] + bb;
        v = (v >= 0.f) ? v : a * v;
        H1B[(size_t)(row_b + r) * 1024 + col] = f2bf(v);
      }
    }
  }
}

// ---------------- FFN2: BM=64 x BN=64 x BK=64, resid from SoutB, fused BN2 stats ------
__global__ __launch_bounds__(256) void gemm_ffn2(
    const u16* __restrict__ A_,
    const u16* __restrict__ B_,
    const float* __restrict__ bias,
    const u16* __restrict__ SoutB,
    const float* __restrict__ stats1,
    const float* __restrict__ gamma,
    const float* __restrict__ beta,
    float* __restrict__ T2,
    float* __restrict__ stats2) {
  __shared__ u16 As[4096], Bs[4096];
  __shared__ float ssl[512];
  __shared__ float sred[2][64];
  const int tid = threadIdx.x;
  const int lane = tid & 63, w = tid >> 6;
  const int wr = w >> 1, wc = w & 1;
  const int q = lane & 15, G = lane >> 4;
  const int eff = (blockIdx.x & 7) * 128 + (blockIdx.x >> 3);
  const int m0 = (eff >> 2) * 64, n0 = (eff & 3) * 64;
  {
    float mean = stats1[tid] * (1.f / 16384.f);
    float var = stats1[256 + tid] * (1.f / 16384.f) - mean * mean;
    float scg = gamma[tid] * rsqrtf(var + 1e-5f);
    ssl[tid] = scg;
    ssl[256 + tid] = beta[tid] - mean * scg;
  }
  if (tid < 64) { sred[0][tid] = 0.f; sred[1][tid] = 0.f; }

  const int rl = lane >> 3, sl8 = lane & 7;
  const int ssrc = (sl8 ^ rl) * 8;

  f32x4 acc[2][2] = {};
  for (int kt = 0; kt < 1024; kt += 64) {
    __syncthreads();
#pragma unroll
    for (int i = 0; i < 2; ++i) {
      int rb = (i * 4 + w) * 8;
      gll16(A_ + (size_t)(m0 + rb + rl) * 1024 + kt + ssrc, &As[rb * 64]);
      gll16(B_ + (size_t)(n0 + rb + rl) * 1024 + kt + ssrc, &Bs[rb * 64]);
    }
    __syncthreads();
#pragma unroll
    for (int kk = 0; kk < 2; ++kk) {
      bf16x8 af[2], bf2[2];
#pragma unroll
      for (int m = 0; m < 2; ++m)
        af[m] = *reinterpret_cast<const bf16x8*>((const char*)As + TOFF2(wr * 32 + m * 16 + q, kk * 4 + G));
#pragma unroll
      for (int n = 0; n < 2; ++n)
        bf2[n] = *reinterpret_cast<const bf16x8*>((const char*)Bs + TOFF2(wc * 32 + n * 16 + q, kk * 4 + G));
#pragma unroll
      for (int m = 0; m < 2; ++m)
#pragma unroll
        for (int n = 0; n < 2; ++n)
          acc[m][n] = __builtin_amdgcn_mfma_f32_16x16x32_bf16(af[m], bf2[n], acc[m][n], 0, 0, 0);
    }
  }
  float s1a[2] = {0.f, 0.f}, s2a[2] = {0.f, 0.f};
#pragma unroll
  for (int m = 0; m < 2; ++m) {
    int row_b = m0 + wr * 32 + m * 16 + G * 4;
#pragma unroll
    for (int n = 0; n < 2; ++n) {
      int col = n0 + wc * 32 + n * 16 + q;
      float bb = bias[col];
      float sc_ = ssl[col], of_ = ssl[256 + col];
#pragma unroll
      for (int r = 0; r < 4; ++r) {
        int row = row_b + r;
        float resid = bf2f(SoutB[(size_t)row * 256 + col]) * sc_ + of_;
        float v = acc[m][n][r] + bb + resid;
        T2[(size_t)row * 256 + col] = v;
        s1a[n] += v;
        s2a[n] += v * v;
      }
    }
  }
#pragma unroll
  for (int n = 0; n < 2; ++n) {
    float a1 = s1a[n];
    a1 += __shfl_xor(a1, 16, 64);
    a1 += __shfl_xor(a1, 32, 64);
    float a2 = s2a[n];
    a2 += __shfl_xor(a2, 16, 64);
    a2 += __shfl_xor(a2, 32, 64);
    if (lane < 16) {
      atomicAdd(&sred[0][wc * 32 + n * 16 + lane], a1);
      atomicAdd(&sred[1][wc * 32 + n * 16 + lane], a2);
    }
  }
  __syncthreads();
  if (tid < 64) {
    atomicAdd(&stats2[n0 + tid], sred[0][tid]);
    atomicAdd(&stats2[256 + n0 + tid], sred[1][tid]);
  }
}

// ---------------- final BN (inline from stats2) + transpose [T,C] -> [B,C,N] ----------
__global__ __launch_bounds__(256) void bn_final_out(const float* __restrict__ T2,
                                                    const float* __restrict__ stats2,
                                                    const float* __restrict__ gamma,
                                                    const float* __restrict__ beta,
                                                    float* __restrict__ out) {
  __shared__ float tile[32][33];
  int n0 = (blockIdx.x & 31) * 32;
  int b = blockIdx.x >> 5;
  int c0 = blockIdx.y * 32;
  int tx = threadIdx.x, ty = threadIdx.y;
  int c = c0 + tx;
  float mean = stats2[c] * (1.f / 16384.f);
  float var = stats2[256 + c] * (1.f / 16384.f) - mean * mean;
  float scg = gamma[c] * rsqrtf(var + 1e-5f);
  float off = beta[c] - mean * scg;
#pragma unroll
  for (int j = 0; j < 4; ++j) {
    int r = ty + j * 8;
    float v = T2[((size_t)b * 1024 + n0 + r) * 256 + c];
    tile[r][tx] = v * scg + off;
  }
  __syncthreads();
#pragma unroll
  for (int j = 0; j < 4; ++j) {
    int cc = c0 + ty + j * 8;
    out[((size_t)b * 256 + cc) * 1024 + n0 + tx] = tile[tx][ty + j * 8];
  }
}

// ---------------- fused flash attention: no-shift softmax (exp2-direct, m == 0) --------
#define SWZ(row, bcol) ((bcol) ^ (((row) & 7) << 4))
__global__ __launch_bounds__(256, 4) void attn_kernel(const u16* __restrict__ QKh,
                                                      const u16* __restrict__ QKl,
                                                      const u16* __restrict__ Vt,
                                                      const float* __restrict__ x,
                                                      u16* __restrict__ SoutB,
                                                      float* __restrict__ stats) {
  __shared__ u16 Kh[2][4096], Vs[2][4096];
  __shared__ float sred[2][64];
  const int tid = threadIdx.x, lane = tid & 63, w = tid >> 6;
  const int hb = blockIdx.x, h = hb & 3, b = hb >> 2;
  const size_t tb = (size_t)b * 1024;
  const int qrow0 = blockIdx.y * 64 + w * 16;
  const int q = lane & 15, G = lane >> 4;

  if (tid < 64) { sred[0][tid] = 0.f; sred[1][tid] = 0.f; }

  bf16x8 qh[2], ql[2];
#pragma unroll
  for (int kk = 0; kk < 2; ++kk) {
    size_t ro = (tb + qrow0 + q) * 512 + h * 64 + kk * 32 + G * 8;
    qh[kk] = *reinterpret_cast<const bf16x8*>(QKh + ro);
    ql[kk] = *reinterpret_cast<const bf16x8*>(QKl + ro);
  }

  f32x4 oacc[4] = {};
  float lsum = 0.f;

  const int sr0 = tid >> 3, sr1 = sr0 + 32;
  const int c7 = tid & 7;
  const int scb0 = c7 << 4;
  const int dstb0 = sr0 * 128 + SWZ(sr0, scb0);
  const int dstb1 = sr1 * 128 + SWZ(sr1, scb0);
  const size_t kbase0 = (tb + sr0) * 512 + 256 + h * 64 + c7 * 8;
  const size_t kbase1 = (tb + sr1) * 512 + 256 + h * 64 + c7 * 8;
  const int vb0 = 32 * (c7 >> 2) + 8 * ((2 * c7) & 3) + 4 * ((c7 >> 1) & 1);
  const int vx0 = (vb0 * 2) ^ ((sr0 & 7) << 4);
  const int vx1 = (vb0 * 2 + 16) ^ ((sr0 & 7) << 4);
  const size_t vbase0 = ((size_t)b * 256 + h * 64 + sr0) * 1024 + c7 * 8;
  const size_t vbase1 = ((size_t)b * 256 + h * 64 + sr1) * 1024 + c7 * 8;

  uint4 rk0 = *reinterpret_cast<const uint4*>(QKh + kbase0);
  uint4 rk1 = *reinterpret_cast<const uint4*>(QKh + kbase1);
  uint4 rv0 = *reinterpret_cast<const uint4*>(Vt + vbase0);
  uint4 rv1 = *reinterpret_cast<const uint4*>(Vt + vbase1);
  *reinterpret_cast<uint4*>((char*)Kh[0] + dstb0) = rk0;
  *reinterpret_cast<uint4*>((char*)Kh[0] + dstb1) = rk1;
  {
    uint2 lo0 = {rv0.x, rv0.y}, hi0 = {rv0.z, rv0.w};
    uint2 lo1 = {rv1.x, rv1.y}, hi1 = {rv1.z, rv1.w};
    *reinterpret_cast<uint2*>((char*)Vs[0] + sr0 * 128 + vx0) = lo0;
    *reinterpret_cast<uint2*>((char*)Vs[0] + sr0 * 128 + vx1) = hi0;
    *reinterpret_cast<uint2*>((char*)Vs[0] + sr1 * 128 + vx0) = lo1;
    *reinterpret_cast<uint2*>((char*)Vs[0] + sr1 * 128 + vx1) = hi1;
  }
  __syncthreads();

  int cur = 0;
  for (int kt = 0; kt < 16; ++kt) {
    if (kt < 15) {
      rk0 = *reinterpret_cast<const uint4*>(QKh + kbase0 + (size_t)(kt + 1) * 32768);
      rk1 = *reinterpret_cast<const uint4*>(QKh + kbase1 + (size_t)(kt + 1) * 32768);
      rv0 = *reinterpret_cast<const uint4*>(Vt + vbase0 + (size_t)(kt + 1) * 64);
      rv1 = *reinterpret_cast<const uint4*>(Vt + vbase1 + (size_t)(kt + 1) * 64);
    }

    f32x4 sc[4] = {};
    __builtin_amdgcn_s_setprio(1);
#pragma unroll
    for (int kk = 0; kk < 2; ++kk)
#pragma unroll
      for (int n = 0; n < 4; ++n) {
        int krow = n * 16 + q;
        int kb_ = krow * 128 + SWZ(krow, kk * 64 + G * 16);
        bf16x8 akh = *reinterpret_cast<const bf16x8*>((const char*)Kh[cur] + kb_);
        sc[n] = __builtin_amdgcn_mfma_f32_16x16x32_bf16(akh, qh[kk], sc[n], 0, 0, 0);
        sc[n] = __builtin_amdgcn_mfma_f32_16x16x32_bf16(akh, ql[kk], sc[n], 0, 0, 0);
      }
    __builtin_amdgcn_s_setprio(0);

    // no-shift softmax: P = 2^S directly (range-safe; see analysis), lsum accumulates
    float lt = 0.f;
#pragma unroll
    for (int n = 0; n < 4; ++n)
#pragma unroll
      for (int r = 0; r < 4; ++r) {
        float p = exp2_fast(sc[n][r]);
        sc[n][r] = p;
        lt += p;
      }
    lsum += lt;
    bf16x8 pa[2];
    {
      uint4 pw0, pw1;
      pw0.x = cvt_pk_bf16(sc[0][0], sc[0][1]);
      pw0.y = cvt_pk_bf16(sc[0][2], sc[0][3]);
      pw0.z = cvt_pk_bf16(sc[1][0], sc[1][1]);
      pw0.w = cvt_pk_bf16(sc[1][2], sc[1][3]);
      pw1.x = cvt_pk_bf16(sc[2][0], sc[2][1]);
      pw1.y = cvt_pk_bf16(sc[2][2], sc[2][3]);
      pw1.z = cvt_pk_bf16(sc[3][0], sc[3][1]);
      pw1.w = cvt_pk_bf16(sc[3][2], sc[3][3]);
      pa[0] = *reinterpret_cast<bf16x8*>(&pw0);
      pa[1] = *reinterpret_cast<bf16x8*>(&pw1);
    }
    __builtin_amdgcn_s_setprio(1);
#pragma unroll
    for (int kk = 0; kk < 2; ++kk)
#pragma unroll
      for (int dn = 0; dn < 4; ++dn) {
        int vrow = dn * 16 + q;
        int vb_ = vrow * 128 + SWZ(vrow, kk * 64 + G * 16);
        bf16x8 vv = *reinterpret_cast<const bf16x8*>((const char*)Vs[cur] + vb_);
        oacc[dn] = __builtin_amdgcn_mfma_f32_16x16x32_bf16(pa[kk], vv, oacc[dn], 0, 0, 0);
      }
    __builtin_amdgcn_s_setprio(0);
    if (kt < 15) {
      *reinterpret_cast<uint4*>((char*)Kh[cur ^ 1] + dstb0) = rk0;
      *reinterpret_cast<uint4*>((char*)Kh[cur ^ 1] + dstb1) = rk1;
      uint2 lo0 = {rv0.x, rv0.y}, hi0 = {rv0.z, rv0.w};
      uint2 lo1 = {rv1.x, rv1.y}, hi1 = {rv1.z, rv1.w};
      *reinterpret_cast<uint2*>((char*)Vs[cur ^ 1] + sr0 * 128 + vx0) = lo0;
      *reinterpret_cast<uint2*>((char*)Vs[cur ^ 1] + sr0 * 128 + vx1) = hi0;
      *reinterpret_cast<uint2*>((char*)Vs[cur ^ 1] + sr1 * 128 + vx0) = lo1;
      *reinterpret_cast<uint2*>((char*)Vs[cur ^ 1] + sr1 * 128 + vx1) = hi1;
    }
    __syncthreads();
    cur ^= 1;
  }
  float lf = lsum;
  lf += __shfl_xor(lf, 16, 64);
  lf += __shfl_xor(lf, 32, 64);
  float rinv[4];
#pragma unroll
  for (int r = 0; r < 4; ++r) rinv[r] = 1.f / __shfl(lf, G * 4 + r, 64);

  const int row0 = qrow0 + G * 4;
  const float* xp = x + ((size_t)b * 256 + h * 64) * 1024;
  float s1a[4] = {0.f, 0.f, 0.f, 0.f}, s2a[4] = {0.f, 0.f, 0.f, 0.f};
#pragma unroll
  for (int dn = 0; dn < 4; ++dn) {
    int col = dn * 16 + q;
    float4 xv = *reinterpret_cast<const float4*>(xp + (size_t)col * 1024 + row0);
    const float* xvp = reinterpret_cast<const float*>(&xv);
#pragma unroll
    for (int r = 0; r < 4; ++r) {
      size_t gi = (tb + row0 + r) * 256 + h * 64 + col;
      float v = oacc[dn][r] * rinv[r] + xvp[r];
      SoutB[gi] = f2bf(v);
      s1a[dn] += v;
      s2a[dn] += v * v;
    }
  }
#pragma unroll
  for (int dn = 0; dn < 4; ++dn) {
    float a1 = s1a[dn];
    a1 += __shfl_xor(a1, 16, 64);
    a1 += __shfl_xor(a1, 32, 64);
    float a2 = s2a[dn];
    a2 += __shfl_xor(a2, 16, 64);
    a2 += __shfl_xor(a2, 32, 64);
    if (lane < 16) {
      atomicAdd(&sred[0][dn * 16 + lane], a1);
      atomicAdd(&sred[1][dn * 16 + lane], a2);
    }
  }
  __syncthreads();
  if (tid < 64) {
    atomicAdd(&stats[h * 64 + tid], sred[0][tid]);
    atomicAdd(&stats[256 + h * 64 + tid], sred[1][tid]);
  }
}

// ---------------- launch ----------------
extern "C" void kernel_launch(void* const* d_in, const int* in_sizes, int n_in,
                              void* d_out, int out_size, void* d_ws, size_t ws_size,
                              hipStream_t stream) {
  const float* x = (const float*)d_in[0];
  const float* Wq = (const float*)d_in[1];
  const float* bq = (const float*)d_in[2];
  const float* Wk = (const float*)d_in[3];
  const float* bk = (const float*)d_in[4];
  const float* Wv = (const float*)d_in[5];
  const float* bv = (const float*)d_in[6];
  const float* gamma = (const float*)d_in[7];
  const float* beta = (const float*)d_in[8];
  const float* W1 = (const float*)d_in[9];
  const float* b1 = (const float*)d_in[10];
  const float* a = (const float*)d_in[11];
  const float* W2 = (const float*)d_in[12];
  const float* b2 = (const float*)d_in[13];
  float* out = (float*)d_out;

  char* wsb = (char*)d_ws;
  const size_t MB = 1ull << 20;
  u16* XtbH = (u16*)(wsb + 0 * MB);        // 8MB; region [0,16) reused as T2 after qkvt
  u16* XtbL = (u16*)(wsb + 8 * MB);        // 8MB
  float* T2 = (float*)(wsb + 0 * MB);      // 16MB (alias XtbH/L, live from ffn2 on)
  u16* SoutB = (u16*)(wsb + 16 * MB);      // 8MB (raw o+x in bf16)
  u16* QKh = (u16*)(wsb + 32 * MB);        // 16MB; [32,64) reused as H1B after attn
  u16* QKl = (u16*)(wsb + 48 * MB);        // 16MB
  u16* Vt = (u16*)(wsb + 64 * MB);         // 8MB
  char* wp = wsb + 72 * MB;
  u16* WallH = (u16*)(wp);                 // 256KB
  u16* WallL = (u16*)(wp + 262144);        // 256KB
  u16* WvH = (u16*)(wp + 524288);          // 128KB
  u16* WvL = (u16*)(wp + 655360);          // 128KB
  u16* W1s = (u16*)(wp + 786432);          // 512KB (BN-scaled W1, by w1prep)
  u16* W2b = (u16*)(wp + 1310720);         // 512KB
  float* bqk = (float*)(wp + 1835008);     // 2KB
  float* stats = (float*)(wp + 1837056);   // 8KB: stats1 | pad | stats2 | pad
  float* h0 = (float*)(wp + 1845248);      // 4KB
  if (ws_size < 73 * MB) return;

  u16* H1B = QKh;    // [T,1024] bf16, after attn
  float* stats2 = stats + 1024;

  hipMemsetAsync(stats, 0, 8192, stream);
  // fused x-transpose + weight prep
  prep_all<<<5120, 256, 0, stream>>>(x, Wq, Wk, Wv, bq, bk, W2,
                                     XtbH, XtbL, WallH, WallL, WvH, WvL, W2b, bqk);
  // fused QK projection (Q pre-scaled by log2e) + V projection transposed
  gemm_qkvt<<<768, 256, 0, stream>>>(XtbH, XtbL, WallH, WallL, bqk, QKh, QKl,
                                     WvH, WvL, bv, Vt);
  // attention + residual (bf16 output only) + BN1 stats
  attn_kernel<<<dim3(64, 16), 256, 0, stream>>>(QKh, QKl, Vt, x, SoutB, stats);
  // fold BN1 into W1: W1s = bf16(W1*sc), h0 = b1 + W1*of
  w1prep<<<128, 256, 0, stream>>>(W1, b1, stats, gamma, beta, W1s, h0);
  // FFN1: pure gll16 GEMM BK=64 (A=SoutB, B=W1s), bias h0, PReLU
  gemm_ffn1<<<1024, 256, 0, stream>>>(SoutB, W1s, h0, a, H1B);
  // FFN2: bias + BN1(resid from SoutB) + BN2 stats -> T2
  gemm_ffn2<<<1024, 256, 0, stream>>>(H1B, W2b, b2, SoutB, stats, gamma, beta, T2, stats2);
  // BN2 apply (inline finalize) + transpose out
  bn_final_out<<<dim3(512, 8), dim3(32, 8), 0, stream>>>(T2, stats2, gamma, beta, out);
}

// Round 16
// 121.213 us; speedup vs baseline: 2.5189x; 1.0186x over previous
//
#include <hip/hip_runtime.h>
#include <hip/hip_bf16.h>

typedef unsigned short u16;
typedef unsigned int u32;
typedef __attribute__((ext_vector_type(8))) __bf16 bf16x8;
typedef __attribute__((ext_vector_type(4))) float f32x4;

#define LOG2E 1.44269504088896340736f

__device__ inline u16 f2bf(float f) {
  unsigned int x = __float_as_uint(f);
  unsigned int r = (x + 0x7FFFu + ((x >> 16) & 1u)) >> 16;
  return (u16)r;
}
__device__ inline float bf2f(u16 u) { return __uint_as_float(((unsigned int)u) << 16); }
__device__ inline void split2(float v, u16& h, u16& l) {
  h = f2bf(v);
  l = f2bf(v - bf2f(h));
}
__device__ inline u32 cvt_pk_bf16(float lo, float hi) {
  u32 r;
  asm("v_cvt_pk_bf16_f32 %0, %1, %2" : "=v"(r) : "v"(lo), "v"(hi));
  return r;
}
__device__ inline float exp2_fast(float x) {
  float r;
  asm("v_exp_f32 %0, %1" : "=v"(r) : "v"(x));
  return r;
}
// async global->LDS, 16B/lane; dest = wave-uniform base + lane*16
__device__ inline void gll16(const u16* g, u16* l) {
  __builtin_amdgcn_global_load_lds((const __attribute__((address_space(1))) void*)g,
                                   (__attribute__((address_space(3))) void*)l, 16, 0, 0);
}
// [R][32]-bf16 tile (64B rows): logical (row, slot s in 0..3) -> physical byte offset
#define TOFF(r, s) (((r) << 6) + ((((s) ^ (((r) >> 1) & 3))) << 4))
// [R][64]-bf16 tile (128B rows): logical (row, slot s in 0..7) -> physical byte offset
#define TOFF2(r, s) (((r) << 7) + ((((s) ^ ((r) & 7))) << 4))

// ---------------- fused: x transpose + weight prep ----------------
__global__ __launch_bounds__(256) void prep_all(
    const float* __restrict__ x,
    const float* __restrict__ Wq, const float* __restrict__ Wk, const float* __restrict__ Wv,
    const float* __restrict__ bq, const float* __restrict__ bk,
    const float* __restrict__ W2,
    u16* __restrict__ XtbH, u16* __restrict__ XtbL,
    u16* __restrict__ WallH, u16* __restrict__ WallL,
    u16* __restrict__ WvH, u16* __restrict__ WvL,
    u16* __restrict__ W2b,
    float* __restrict__ bqk) {
  __shared__ float tile[32][33];
  const int id = blockIdx.x;
  if (id < 4096) {
    int n0 = (id & 31) * 32, c0 = ((id >> 5) & 7) * 32, b = id >> 8;
    int tx = threadIdx.x & 31, ty = threadIdx.x >> 5;
#pragma unroll
    for (int j = 0; j < 4; ++j) {
      int c = c0 + ty + j * 8;
      tile[ty + j * 8][tx] = x[((size_t)b * 256 + c) * 1024 + n0 + tx];
    }
    __syncthreads();
#pragma unroll
    for (int j = 0; j < 4; ++j) {
      int n = n0 + ty + j * 8;
      float v = tile[tx][ty + j * 8];
      size_t o = ((size_t)b * 1024 + n) * 256 + c0 + tx;
      u16 h, l;
      split2(v, h, l);
      XtbH[o] = h; XtbL[o] = l;
    }
  } else {
    int i = (id - 4096) * 256 + threadIdx.x;
    if (i < 131072) {
      float w = (i < 65536) ? Wq[i] : Wk[i - 65536];
      u16 h, l;
      split2(w, h, l);
      WallH[i] = h; WallL[i] = l;
    }
    if (i < 65536) {
      u16 h, l;
      split2(Wv[i], h, l);
      WvH[i] = h; WvL[i] = l;
    }
    if (i < 262144) W2b[i] = f2bf(W2[i]);
    if (i < 256) bqk[i] = bq[i];
    else if (i < 512) bqk[i] = bk[i - 256];
  }
}

// ---------------- fused QK-projection + V-projection (one dispatch, role by id) ----------
// Q-half outputs are pre-scaled by log2(e) so attention softmax can use raw v_exp_f32.
__global__ __launch_bounds__(256) void gemm_qkvt(
    const u16* __restrict__ Ah_, const u16* __restrict__ Al_,
    const u16* __restrict__ Bh_, const u16* __restrict__ Bl_,
    const float* __restrict__ bias,
    u16* __restrict__ Ch, u16* __restrict__ Cl,
    const u16* __restrict__ WvH_, const u16* __restrict__ WvL_,
    const float* __restrict__ bv, u16* __restrict__ Vt) {
  __shared__ u16 Ah[4096], Al[4096], Bh[4096], Bl[4096];
  const int tid = threadIdx.x;
  const int lane = tid & 63, w = tid >> 6;
  const int wr = w >> 1, wc = w & 1;
  const int q = lane & 15, G = lane >> 4;
  const int rr0 = w * 32 + (lane >> 2), rr1 = rr0 + 16;
  const int sl0 = (lane & 3) ^ ((rr0 >> 1) & 3);
  const int sl1 = (lane & 3) ^ ((rr1 >> 1) & 3);

  if (blockIdx.x < 512) {
    // ---- QK role ----
    const int eff = (blockIdx.x & 7) * 64 + (blockIdx.x >> 3);
    const int m0 = (eff >> 2) * 128, n0 = (eff & 3) * 128;
    const bool isQ = (n0 < 256);
    const size_t a0 = (size_t)(m0 + rr0) * 256 + sl0 * 8;
    const size_t a1 = (size_t)(m0 + rr1) * 256 + sl1 * 8;
    const size_t b0 = (size_t)(n0 + rr0) * 256 + sl0 * 8;
    const size_t b1 = (size_t)(n0 + rr1) * 256 + sl1 * 8;

    f32x4 acc[4][4] = {};
    for (int kt = 0; kt < 256; kt += 32) {
      __syncthreads();
      gll16(Ah_ + a0 + kt, &Ah[w * 1024]);
      gll16(Ah_ + a1 + kt, &Ah[w * 1024 + 512]);
      gll16(Al_ + a0 + kt, &Al[w * 1024]);
      gll16(Al_ + a1 + kt, &Al[w * 1024 + 512]);
      gll16(Bh_ + b0 + kt, &Bh[w * 1024]);
      gll16(Bh_ + b1 + kt, &Bh[w * 1024 + 512]);
      gll16(Bl_ + b0 + kt, &Bl[w * 1024]);
      gll16(Bl_ + b1 + kt, &Bl[w * 1024 + 512]);
      __syncthreads();
      bf16x8 afh[4], afl[4], bfh[4], bfl[4];
#pragma unroll
      for (int m = 0; m < 4; ++m) {
        int off = TOFF(wr * 64 + m * 16 + q, G);
        afh[m] = *reinterpret_cast<const bf16x8*>((const char*)Ah + off);
        afl[m] = *reinterpret_cast<const bf16x8*>((const char*)Al + off);
      }
#pragma unroll
      for (int n = 0; n < 4; ++n) {
        int off = TOFF(wc * 64 + n * 16 + q, G);
        bfh[n] = *reinterpret_cast<const bf16x8*>((const char*)Bh + off);
        bfl[n] = *reinterpret_cast<const bf16x8*>((const char*)Bl + off);
      }
#pragma unroll
      for (int m = 0; m < 4; ++m)
#pragma unroll
        for (int n = 0; n < 4; ++n) {
          acc[m][n] = __builtin_amdgcn_mfma_f32_16x16x32_bf16(afh[m], bfh[n], acc[m][n], 0, 0, 0);
          acc[m][n] = __builtin_amdgcn_mfma_f32_16x16x32_bf16(afl[m], bfh[n], acc[m][n], 0, 0, 0);
        }
      if (isQ) {
#pragma unroll
        for (int m = 0; m < 4; ++m)
#pragma unroll
          for (int n = 0; n < 4; ++n)
            acc[m][n] = __builtin_amdgcn_mfma_f32_16x16x32_bf16(afh[m], bfl[n], acc[m][n], 0, 0, 0);
      }
    }
    const float qscale = isQ ? LOG2E : 1.f;
#pragma unroll
    for (int m = 0; m < 4; ++m) {
      int row_b = m0 + wr * 64 + m * 16 + G * 4;
#pragma unroll
      for (int n = 0; n < 4; ++n) {
        int col = n0 + wc * 64 + n * 16 + q;
        float bb = bias[col];
#pragma unroll
        for (int r = 0; r < 4; ++r) {
          size_t o = (size_t)(row_b + r) * 512 + col;
          u16 h, l;
          split2((acc[m][n][r] + bb) * qscale, h, l);
          Ch[o] = h;
          if (isQ) Cl[o] = l;
        }
      }
    }
  } else {
    // ---- Vt role ----
    const int o_ = blockIdx.x - 512;
    const int eff = (o_ & 7) * 32 + (o_ >> 3);
    const int m0 = (eff & 1) * 128, n0 = ((eff >> 1) & 7) * 128, b = eff >> 4;
    const u16* Bp = Ah_ + (size_t)b * 1024 * 256;  // XtbH
    const size_t a0 = (size_t)(m0 + rr0) * 256 + sl0 * 8;
    const size_t a1 = (size_t)(m0 + rr1) * 256 + sl1 * 8;
    const size_t b0 = (size_t)(n0 + rr0) * 256 + sl0 * 8;
    const size_t b1 = (size_t)(n0 + rr1) * 256 + sl1 * 8;

    f32x4 acc[4][4] = {};
    for (int kt = 0; kt < 256; kt += 32) {
      __syncthreads();
      gll16(WvH_ + a0 + kt, &Ah[w * 1024]);
      gll16(WvH_ + a1 + kt, &Ah[w * 1024 + 512]);
      gll16(WvL_ + a0 + kt, &Al[w * 1024]);
      gll16(WvL_ + a1 + kt, &Al[w * 1024 + 512]);
      gll16(Bp + b0 + kt, &Bh[w * 1024]);
      gll16(Bp + b1 + kt, &Bh[w * 1024 + 512]);
      __syncthreads();
      bf16x8 afh[4], afl[4], bfr[4];
#pragma unroll
      for (int m = 0; m < 4; ++m) {
        int off = TOFF(wr * 64 + m * 16 + q, G);
        afh[m] = *reinterpret_cast<const bf16x8*>((const char*)Ah + off);
        afl[m] = *reinterpret_cast<const bf16x8*>((const char*)Al + off);
      }
#pragma unroll
      for (int n = 0; n < 4; ++n)
        bfr[n] = *reinterpret_cast<const bf16x8*>((const char*)Bh + TOFF(wc * 64 + n * 16 + q, G));
#pragma unroll
      for (int m = 0; m < 4; ++m)
#pragma unroll
        for (int n = 0; n < 4; ++n) {
          acc[m][n] = __builtin_amdgcn_mfma_f32_16x16x32_bf16(afh[m], bfr[n], acc[m][n], 0, 0, 0);
          acc[m][n] = __builtin_amdgcn_mfma_f32_16x16x32_bf16(afl[m], bfr[n], acc[m][n], 0, 0, 0);
        }
    }
#pragma unroll
    for (int m = 0; m < 4; ++m) {
      int row_b = m0 + wr * 64 + m * 16 + G * 4;  // d index
#pragma unroll
      for (int n = 0; n < 4; ++n) {
        int col = n0 + wc * 64 + n * 16 + q;      // token n
#pragma unroll
        for (int r = 0; r < 4; ++r) {
          int row = row_b + r;
          Vt[((size_t)b * 256 + row) * 1024 + col] = f2bf(acc[m][n][r] + bv[row]);
        }
      }
    }
  }
}

// ---------------- w1prep: ss1 from stats1; W1s = bf16(W1*sc); h0 = b1 + W1*of ----------
__global__ __launch_bounds__(256) void w1prep(
    const float* __restrict__ W1, const float* __restrict__ b1,
    const float* __restrict__ stats1, const float* __restrict__ gamma,
    const float* __restrict__ beta,
    u16* __restrict__ W1s, float* __restrict__ h0) {
  __shared__ float ssl[512];
  const int tid = threadIdx.x;
  {
    float mean = stats1[tid] * (1.f / 16384.f);
    float var = stats1[256 + tid] * (1.f / 16384.f) - mean * mean;
    float scg = gamma[tid] * rsqrtf(var + 1e-5f);
    ssl[tid] = scg;
    ssl[256 + tid] = beta[tid] - mean * scg;
  }
  __syncthreads();
  const int lane = tid & 63, w = tid >> 6;
#pragma unroll
  for (int rr = 0; rr < 2; ++rr) {
    int f = blockIdx.x * 8 + w * 2 + rr;
    int c = lane * 4;
    float4 wv = *reinterpret_cast<const float4*>(W1 + (size_t)f * 256 + c);
    ushort4 o;
    o.x = f2bf(wv.x * ssl[c + 0]);
    o.y = f2bf(wv.y * ssl[c + 1]);
    o.z = f2bf(wv.z * ssl[c + 2]);
    o.w = f2bf(wv.w * ssl[c + 3]);
    *reinterpret_cast<ushort4*>(W1s + (size_t)f * 256 + c) = o;
    float h = wv.x * ssl[256 + c] + wv.y * ssl[257 + c] +
              wv.z * ssl[258 + c] + wv.w * ssl[259 + c];
    h += __shfl_xor(h, 1, 64);
    h += __shfl_xor(h, 2, 64);
    h += __shfl_xor(h, 4, 64);
    h += __shfl_xor(h, 8, 64);
    h += __shfl_xor(h, 16, 64);
    h += __shfl_xor(h, 32, 64);
    if (lane == 0) h0[f] = b1[f] + h;
  }
}

// ---------------- FFN1: pure gll16 GEMM, BK=64, A = SoutB bf16, B = W1s ----------------
// grid 1024: eff=(orig&7)*128+orig/8; n=eff&7, m=eff>>3
__global__ __launch_bounds__(256) void gemm_ffn1(
    const u16* __restrict__ A_,
    const u16* __restrict__ B_,
    const float* __restrict__ h0,
    const float* __restrict__ aslope,
    u16* __restrict__ H1B) {
  __shared__ u16 As[8192], Bs[8192];   // [128][64] bf16 each, TOFF2 layout
  const int tid = threadIdx.x;
  const int lane = tid & 63, w = tid >> 6;
  const int wr = w >> 1, wc = w & 1;
  const int q = lane & 15, G = lane >> 4;
  const int eff = (blockIdx.x & 7) * 128 + (blockIdx.x >> 3);
  const int m0 = (eff >> 3) * 128, n0 = (eff & 7) * 128;

  const int rl = lane >> 3, sl8 = lane & 7;
  const int ssrc = (sl8 ^ rl) * 8;  // inverse-swizzled source col (TOFF2 pairing)

  f32x4 acc[4][4] = {};
  for (int kt = 0; kt < 256; kt += 64) {
    __syncthreads();
#pragma unroll
    for (int i = 0; i < 4; ++i) {
      int rb = (i * 4 + w) * 8;
      gll16(A_ + (size_t)(m0 + rb + rl) * 256 + kt + ssrc, &As[rb * 64]);
      gll16(B_ + (size_t)(n0 + rb + rl) * 256 + kt + ssrc, &Bs[rb * 64]);
    }
    __syncthreads();
#pragma unroll
    for (int kk = 0; kk < 2; ++kk) {
      bf16x8 af[4], bfr[4];
#pragma unroll
      for (int m = 0; m < 4; ++m)
        af[m] = *reinterpret_cast<const bf16x8*>((const char*)As + TOFF2(wr * 64 + m * 16 + q, kk * 4 + G));
#pragma unroll
      for (int n = 0; n < 4; ++n)
        bfr[n] = *reinterpret_cast<const bf16x8*>((const char*)Bs + TOFF2(wc * 64 + n * 16 + q, kk * 4 + G));
#pragma unroll
      for (int m = 0; m < 4; ++m)
#pragma unroll
        for (int n = 0; n < 4; ++n)
          acc[m][n] = __builtin_amdgcn_mfma_f32_16x16x32_bf16(af[m], bfr[n], acc[m][n], 0, 0, 0);
    }
  }
  float a = aslope[0];
#pragma unroll
  for (int m = 0; m < 4; ++m) {
    int row_b = m0 + wr * 64 + m * 16 + G * 4;
#pragma unroll
    for (int n = 0; n < 4; ++n) {
      int col = n0 + wc * 64 + n * 16 + q;
      float bb = h0[col];
#pragma unroll
      for (int r = 0; r < 4; ++r) {
        float v = acc[m][n][r] + bb;
        v = (v >= 0.f) ? v : a * v;
        H1B[(size_t)(row_b + r) * 1024 + col] = f2bf(v);
      }
    }
  }
}

// ---------------- FFN2: BM=64 x BN=64 x BK=64, resid from SoutB, fused BN2 stats ------
__global__ __launch_bounds__(256) void gemm_ffn2(
    const u16* __restrict__ A_,
    const u16* __restrict__ B_,
    const float* __restrict__ bias,
    const u16* __restrict__ SoutB,
    const float* __restrict__ stats1,
    const float* __restrict__ gamma,
    const float* __restrict__ beta,
    float* __restrict__ T2,
    float* __restrict__ stats2) {
  __shared__ u16 As[4096], Bs[4096];
  __shared__ float ssl[512];
  __shared__ float sred[2][64];
  const int tid = threadIdx.x;
  const int lane = tid & 63, w = tid >> 6;
  const int wr = w >> 1, wc = w & 1;
  const int q = lane & 15, G = lane >> 4;
  const int eff = (blockIdx.x & 7) * 128 + (blockIdx.x >> 3);
  const int m0 = (eff >> 2) * 64, n0 = (eff & 3) * 64;
  {
    float mean = stats1[tid] * (1.f / 16384.f);
    float var = stats1[256 + tid] * (1.f / 16384.f) - mean * mean;
    float scg = gamma[tid] * rsqrtf(var + 1e-5f);
    ssl[tid] = scg;
    ssl[256 + tid] = beta[tid] - mean * scg;
  }
  if (tid < 64) { sred[0][tid] = 0.f; sred[1][tid] = 0.f; }

  const int rl = lane >> 3, sl8 = lane & 7;
  const int ssrc = (sl8 ^ rl) * 8;

  f32x4 acc[2][2] = {};
  for (int kt = 0; kt < 1024; kt += 64) {
    __syncthreads();
#pragma unroll
    for (int i = 0; i < 2; ++i) {
      int rb = (i * 4 + w) * 8;
      gll16(A_ + (size_t)(m0 + rb + rl) * 1024 + kt + ssrc, &As[rb * 64]);
      gll16(B_ + (size_t)(n0 + rb + rl) * 1024 + kt + ssrc, &Bs[rb * 64]);
    }
    __syncthreads();
#pragma unroll
    for (int kk = 0; kk < 2; ++kk) {
      bf16x8 af[2], bf2[2];
#pragma unroll
      for (int m = 0; m < 2; ++m)
        af[m] = *reinterpret_cast<const bf16x8*>((const char*)As + TOFF2(wr * 32 + m * 16 + q, kk * 4 + G));
#pragma unroll
      for (int n = 0; n < 2; ++n)
        bf2[n] = *reinterpret_cast<const bf16x8*>((const char*)Bs + TOFF2(wc * 32 + n * 16 + q, kk * 4 + G));
#pragma unroll
      for (int m = 0; m < 2; ++m)
#pragma unroll
        for (int n = 0; n < 2; ++n)
          acc[m][n] = __builtin_amdgcn_mfma_f32_16x16x32_bf16(af[m], bf2[n], acc[m][n], 0, 0, 0);
    }
  }
  float s1a[2] = {0.f, 0.f}, s2a[2] = {0.f, 0.f};
#pragma unroll
  for (int m = 0; m < 2; ++m) {
    int row_b = m0 + wr * 32 + m * 16 + G * 4;
#pragma unroll
    for (int n = 0; n < 2; ++n) {
      int col = n0 + wc * 32 + n * 16 + q;
      float bb = bias[col];
      float sc_ = ssl[col], of_ = ssl[256 + col];
#pragma unroll
      for (int r = 0; r < 4; ++r) {
        int row = row_b + r;
        float resid = bf2f(SoutB[(size_t)row * 256 + col]) * sc_ + of_;
        float v = acc[m][n][r] + bb + resid;
        T2[(size_t)row * 256 + col] = v;
        s1a[n] += v;
        s2a[n] += v * v;
      }
    }
  }
#pragma unroll
  for (int n = 0; n < 2; ++n) {
    float a1 = s1a[n];
    a1 += __shfl_xor(a1, 16, 64);
    a1 += __shfl_xor(a1, 32, 64);
    float a2 = s2a[n];
    a2 += __shfl_xor(a2, 16, 64);
    a2 += __shfl_xor(a2, 32, 64);
    if (lane < 16) {
      atomicAdd(&sred[0][wc * 32 + n * 16 + lane], a1);
      atomicAdd(&sred[1][wc * 32 + n * 16 + lane], a2);
    }
  }
  __syncthreads();
  if (tid < 64) {
    atomicAdd(&stats2[n0 + tid], sred[0][tid]);
    atomicAdd(&stats2[256 + n0 + tid], sred[1][tid]);
  }
}

// ---------------- final BN (inline from stats2) + transpose [T,C] -> [B,C,N] ----------
__global__ __launch_bounds__(256) void bn_final_out(const float* __restrict__ T2,
                                                    const float* __restrict__ stats2,
                                                    const float* __restrict__ gamma,
                                                    const float* __restrict__ beta,
                                                    float* __restrict__ out) {
  __shared__ float tile[32][33];
  int n0 = (blockIdx.x & 31) * 32;
  int b = blockIdx.x >> 5;
  int c0 = blockIdx.y * 32;
  int tx = threadIdx.x, ty = threadIdx.y;
  int c = c0 + tx;
  float mean = stats2[c] * (1.f / 16384.f);
  float var = stats2[256 + c] * (1.f / 16384.f) - mean * mean;
  float scg = gamma[c] * rsqrtf(var + 1e-5f);
  float off = beta[c] - mean * scg;
#pragma unroll
  for (int j = 0; j < 4; ++j) {
    int r = ty + j * 8;
    float v = T2[((size_t)b * 1024 + n0 + r) * 256 + c];
    tile[r][tx] = v * scg + off;
  }
  __syncthreads();
#pragma unroll
  for (int j = 0; j < 4; ++j) {
    int cc = c0 + ty + j * 8;
    out[((size_t)b * 256 + cc) * 1024 + n0 + tx] = tile[tx][ty + j * 8];
  }
}

// ---------------- fused flash attention: 8 waves / 128 q-rows, no-shift softmax --------
// grid (64, 8): 512 blocks, 2 blocks/CU x 8 waves = 16 waves/CU; staging halves vs 4-wave.
#define SWZ(row, bcol) ((bcol) ^ (((row) & 7) << 4))
__global__ __launch_bounds__(512, 4) void attn_kernel(const u16* __restrict__ QKh,
                                                      const u16* __restrict__ QKl,
                                                      const u16* __restrict__ Vt,
                                                      const float* __restrict__ x,
                                                      u16* __restrict__ SoutB,
                                                      float* __restrict__ stats) {
  __shared__ u16 Kh[2][4096], Vs[2][4096];
  __shared__ float sred[2][64];
  const int tid = threadIdx.x, lane = tid & 63, w = tid >> 6;
  const int hb = blockIdx.x, h = hb & 3, b = hb >> 2;
  const size_t tb = (size_t)b * 1024;
  const int qrow0 = blockIdx.y * 128 + w * 16;
  const int q = lane & 15, G = lane >> 4;

  if (tid < 64) { sred[0][tid] = 0.f; sred[1][tid] = 0.f; }

  bf16x8 qh[2], ql[2];
#pragma unroll
  for (int kk = 0; kk < 2; ++kk) {
    size_t ro = (tb + qrow0 + q) * 512 + h * 64 + kk * 32 + G * 8;
    qh[kk] = *reinterpret_cast<const bf16x8*>(QKh + ro);
    ql[kk] = *reinterpret_cast<const bf16x8*>(QKl + ro);
  }

  f32x4 oacc[4] = {};
  float lsum = 0.f;

  // staging: 512 threads, 1 K uint4 + 2 V uint2 each (rows 0..63, 8 slots)
  const int sr = tid >> 3;
  const int c7 = tid & 7;
  const int dstb = sr * 128 + SWZ(sr, c7 << 4);
  const size_t kbase = (tb + sr) * 512 + 256 + h * 64 + c7 * 8;
  const int vb0 = 32 * (c7 >> 2) + 8 * ((2 * c7) & 3) + 4 * ((c7 >> 1) & 1);
  const int vx0 = (vb0 * 2) ^ ((sr & 7) << 4);
  const int vx1 = (vb0 * 2 + 16) ^ ((sr & 7) << 4);
  const size_t vbase = ((size_t)b * 256 + h * 64 + sr) * 1024 + c7 * 8;

  uint4 rk = *reinterpret_cast<const uint4*>(QKh + kbase);
  uint4 rv = *reinterpret_cast<const uint4*>(Vt + vbase);
  *reinterpret_cast<uint4*>((char*)Kh[0] + dstb) = rk;
  {
    uint2 lo = {rv.x, rv.y}, hi = {rv.z, rv.w};
    *reinterpret_cast<uint2*>((char*)Vs[0] + sr * 128 + vx0) = lo;
    *reinterpret_cast<uint2*>((char*)Vs[0] + sr * 128 + vx1) = hi;
  }
  __syncthreads();

  int cur = 0;
  for (int kt = 0; kt < 16; ++kt) {
    if (kt < 15) {
      rk = *reinterpret_cast<const uint4*>(QKh + kbase + (size_t)(kt + 1) * 32768);
      rv = *reinterpret_cast<const uint4*>(Vt + vbase + (size_t)(kt + 1) * 64);
    }

    f32x4 sc[4] = {};
    __builtin_amdgcn_s_setprio(1);
#pragma unroll
    for (int kk = 0; kk < 2; ++kk)
#pragma unroll
      for (int n = 0; n < 4; ++n) {
        int krow = n * 16 + q;
        int kb_ = krow * 128 + SWZ(krow, kk * 64 + G * 16);
        bf16x8 akh = *reinterpret_cast<const bf16x8*>((const char*)Kh[cur] + kb_);
        sc[n] = __builtin_amdgcn_mfma_f32_16x16x32_bf16(akh, qh[kk], sc[n], 0, 0, 0);
        sc[n] = __builtin_amdgcn_mfma_f32_16x16x32_bf16(akh, ql[kk], sc[n], 0, 0, 0);
      }
    __builtin_amdgcn_s_setprio(0);

    // no-shift softmax: P = 2^S directly (range-safe), per-lane partial lsum
    float lt = 0.f;
#pragma unroll
    for (int n = 0; n < 4; ++n)
#pragma unroll
      for (int r = 0; r < 4; ++r) {
        float p = exp2_fast(sc[n][r]);
        sc[n][r] = p;
        lt += p;
      }
    lsum += lt;
    bf16x8 pa[2];
    {
      uint4 pw0, pw1;
      pw0.x = cvt_pk_bf16(sc[0][0], sc[0][1]);
      pw0.y = cvt_pk_bf16(sc[0][2], sc[0][3]);
      pw0.z = cvt_pk_bf16(sc[1][0], sc[1][1]);
      pw0.w = cvt_pk_bf16(sc[1][2], sc[1][3]);
      pw1.x = cvt_pk_bf16(sc[2][0], sc[2][1]);
      pw1.y = cvt_pk_bf16(sc[2][2], sc[2][3]);
      pw1.z = cvt_pk_bf16(sc[3][0], sc[3][1]);
      pw1.w = cvt_pk_bf16(sc[3][2], sc[3][3]);
      pa[0] = *reinterpret_cast<bf16x8*>(&pw0);
      pa[1] = *reinterpret_cast<bf16x8*>(&pw1);
    }
    __builtin_amdgcn_s_setprio(1);
#pragma unroll
    for (int kk = 0; kk < 2; ++kk)
#pragma unroll
      for (int dn = 0; dn < 4; ++dn) {
        int vrow = dn * 16 + q;
        int vb_ = vrow * 128 + SWZ(vrow, kk * 64 + G * 16);
        bf16x8 vv = *reinterpret_cast<const bf16x8*>((const char*)Vs[cur] + vb_);
        oacc[dn] = __builtin_amdgcn_mfma_f32_16x16x32_bf16(pa[kk], vv, oacc[dn], 0, 0, 0);
      }
    __builtin_amdgcn_s_setprio(0);
    if (kt < 15) {
      *reinterpret_cast<uint4*>((char*)Kh[cur ^ 1] + dstb) = rk;
      uint2 lo = {rv.x, rv.y}, hi = {rv.z, rv.w};
      *reinterpret_cast<uint2*>((char*)Vs[cur ^ 1] + sr * 128 + vx0) = lo;
      *reinterpret_cast<uint2*>((char*)Vs[cur ^ 1] + sr * 128 + vx1) = hi;
    }
    __syncthreads();
    cur ^= 1;
  }
  float lf = lsum;
  lf += __shfl_xor(lf, 16, 64);
  lf += __shfl_xor(lf, 32, 64);
  float rinv[4];
#pragma unroll
  for (int r = 0; r < 4; ++r) rinv[r] = 1.f / __shfl(lf, G * 4 + r, 64);

  const int row0 = qrow0 + G * 4;
  const float* xp = x + ((size_t)b * 256 + h * 64) * 1024;
  float s1a[4] = {0.f, 0.f, 0.f, 0.f}, s2a[4] = {0.f, 0.f, 0.f, 0.f};
#pragma unroll
  for (int dn = 0; dn < 4; ++dn) {
    int col = dn * 16 + q;
    float4 xv = *reinterpret_cast<const float4*>(xp + (size_t)col * 1024 + row0);
    const float* xvp = reinterpret_cast<const float*>(&xv);
#pragma unroll
    for (int r = 0; r < 4; ++r) {
      size_t gi = (tb + row0 + r) * 256 + h * 64 + col;
      float v = oacc[dn][r] * rinv[r] + xvp[r];
      SoutB[gi] = f2bf(v);
      s1a[dn] += v;
      s2a[dn] += v * v;
    }
  }
#pragma unroll
  for (int dn = 0; dn < 4; ++dn) {
    float a1 = s1a[dn];
    a1 += __shfl_xor(a1, 16, 64);
    a1 += __shfl_xor(a1, 32, 64);
    float a2 = s2a[dn];
    a2 += __shfl_xor(a2, 16, 64);
    a2 += __shfl_xor(a2, 32, 64);
    if (lane < 16) {
      atomicAdd(&sred[0][dn * 16 + lane], a1);
      atomicAdd(&sred[1][dn * 16 + lane], a2);
    }
  }
  __syncthreads();
  if (tid < 64) {
    atomicAdd(&stats[h * 64 + tid], sred[0][tid]);
    atomicAdd(&stats[256 + h * 64 + tid], sred[1][tid]);
  }
}

// ---------------- launch ----------------
extern "C" void kernel_launch(void* const* d_in, const int* in_sizes, int n_in,
                              void* d_out, int out_size, void* d_ws, size_t ws_size,
                              hipStream_t stream) {
  const float* x = (const float*)d_in[0];
  const float* Wq = (const float*)d_in[1];
  const float* bq = (const float*)d_in[2];
  const float* Wk = (const float*)d_in[3];
  const float* bk = (const float*)d_in[4];
  const float* Wv = (const float*)d_in[5];
  const float* bv = (const float*)d_in[6];
  const float* gamma = (const float*)d_in[7];
  const float* beta = (const float*)d_in[8];
  const float* W1 = (const float*)d_in[9];
  const float* b1 = (const float*)d_in[10];
  const float* a = (const float*)d_in[11];
  const float* W2 = (const float*)d_in[12];
  const float* b2 = (const float*)d_in[13];
  float* out = (float*)d_out;

  char* wsb = (char*)d_ws;
  const size_t MB = 1ull << 20;
  u16* XtbH = (u16*)(wsb + 0 * MB);        // 8MB; region [0,16) reused as T2 after qkvt
  u16* XtbL = (u16*)(wsb + 8 * MB);        // 8MB
  float* T2 = (float*)(wsb + 0 * MB);      // 16MB (alias XtbH/L, live from ffn2 on)
  u16* SoutB = (u16*)(wsb + 16 * MB);      // 8MB (raw o+x in bf16)
  u16* QKh = (u16*)(wsb + 32 * MB);        // 16MB; [32,64) reused as H1B after attn
  u16* QKl = (u16*)(wsb + 48 * MB);        // 16MB
  u16* Vt = (u16*)(wsb + 64 * MB);         // 8MB
  char* wp = wsb + 72 * MB;
  u16* WallH = (u16*)(wp);                 // 256KB
  u16* WallL = (u16*)(wp + 262144);        // 256KB
  u16* WvH = (u16*)(wp + 524288);          // 128KB
  u16* WvL = (u16*)(wp + 655360);          // 128KB
  u16* W1s = (u16*)(wp + 786432);          // 512KB (BN-scaled W1, by w1prep)
  u16* W2b = (u16*)(wp + 1310720);         // 512KB
  float* bqk = (float*)(wp + 1835008);     // 2KB
  float* stats = (float*)(wp + 1837056);   // 8KB: stats1 | pad | stats2 | pad
  float* h0 = (float*)(wp + 1845248);      // 4KB
  if (ws_size < 73 * MB) return;

  u16* H1B = QKh;    // [T,1024] bf16, after attn
  float* stats2 = stats + 1024;

  hipMemsetAsync(stats, 0, 8192, stream);
  // fused x-transpose + weight prep
  prep_all<<<5120, 256, 0, stream>>>(x, Wq, Wk, Wv, bq, bk, W2,
                                     XtbH, XtbL, WallH, WallL, WvH, WvL, W2b, bqk);
  // fused QK projection (Q pre-scaled by log2e) + V projection transposed
  gemm_qkvt<<<768, 256, 0, stream>>>(XtbH, XtbL, WallH, WallL, bqk, QKh, QKl,
                                     WvH, WvL, bv, Vt);
  // attention + residual (bf16 output) + BN1 stats: 8-wave blocks, halved staging
  attn_kernel<<<dim3(64, 8), 512, 0, stream>>>(QKh, QKl, Vt, x, SoutB, stats);
  // fold BN1 into W1: W1s = bf16(W1*sc), h0 = b1 + W1*of
  w1prep<<<128, 256, 0, stream>>>(W1, b1, stats, gamma, beta, W1s, h0);
  // FFN1: pure gll16 GEMM BK=64 (A=SoutB, B=W1s), bias h0, PReLU
  gemm_ffn1<<<1024, 256, 0, stream>>>(SoutB, W1s, h0, a, H1B);
  // FFN2: bias + BN1(resid from SoutB) + BN2 stats -> T2
  gemm_ffn2<<<1024, 256, 0, stream>>>(H1B, W2b, b2, SoutB, stats, gamma, beta, T2, stats2);
  // BN2 apply (inline finalize) + transpose out
  bn_final_out<<<dim3(512, 8), dim3(32, 8), 0, stream>>>(T2, stats2, gamma, beta, out);
}

// Round 17
// 114.266 us; speedup vs baseline: 2.6720x; 1.0608x over previous
//
#include <hip/hip_runtime.h>
#include <hip/hip_bf16.h>

typedef unsigned short u16;
typedef unsigned int u32;
typedef _Float16 f16;
typedef __attribute__((ext_vector_type(8))) __bf16 bf16x8;
typedef __attribute__((ext_vector_type(4))) float f32x4;

#define LOG2E 1.44269504088896340736f

__device__ inline u16 f2bf(float f) {
  unsigned int x = __float_as_uint(f);
  unsigned int r = (x + 0x7FFFu + ((x >> 16) & 1u)) >> 16;
  return (u16)r;
}
__device__ inline float bf2f(u16 u) { return __uint_as_float(((unsigned int)u) << 16); }
__device__ inline void split2(float v, u16& h, u16& l) {
  h = f2bf(v);
  l = f2bf(v - bf2f(h));
}
__device__ inline u32 cvt_pk_bf16(float lo, float hi) {
  u32 r;
  asm("v_cvt_pk_bf16_f32 %0, %1, %2" : "=v"(r) : "v"(lo), "v"(hi));
  return r;
}
__device__ inline float exp2_fast(float x) {
  float r;
  asm("v_exp_f32 %0, %1" : "=v"(r) : "v"(x));
  return r;
}
// async global->LDS, 16B/lane; dest = wave-uniform base + lane*16
__device__ inline void gll16(const u16* g, u16* l) {
  __builtin_amdgcn_global_load_lds((const __attribute__((address_space(1))) void*)g,
                                   (__attribute__((address_space(3))) void*)l, 16, 0, 0);
}
// [R][32]-bf16 tile (64B rows): logical (row, slot s in 0..3) -> physical byte offset
#define TOFF(r, s) (((r) << 6) + ((((s) ^ (((r) >> 1) & 3))) << 4))
// [R][64]-bf16 tile (128B rows): logical (row, slot s in 0..7) -> physical byte offset
#define TOFF2(r, s) (((r) << 7) + ((((s) ^ ((r) & 7))) << 4))

// ---------------- fused: x transpose + weight prep + stats zeroing ----------------
__global__ __launch_bounds__(256) void prep_all(
    const float* __restrict__ x,
    const float* __restrict__ Wq, const float* __restrict__ Wk, const float* __restrict__ Wv,
    const float* __restrict__ bq, const float* __restrict__ bk,
    const float* __restrict__ W2,
    u16* __restrict__ XtbH, u16* __restrict__ XtbL,
    u16* __restrict__ WallH, u16* __restrict__ WallL,
    u16* __restrict__ WvH, u16* __restrict__ WvL,
    u16* __restrict__ W2b,
    float* __restrict__ bqk, float* __restrict__ statsZ) {
  __shared__ float tile[32][33];
  const int id = blockIdx.x;
  if (id < 4096) {
    int n0 = (id & 31) * 32, c0 = ((id >> 5) & 7) * 32, b = id >> 8;
    int tx = threadIdx.x & 31, ty = threadIdx.x >> 5;
#pragma unroll
    for (int j = 0; j < 4; ++j) {
      int c = c0 + ty + j * 8;
      tile[ty + j * 8][tx] = x[((size_t)b * 256 + c) * 1024 + n0 + tx];
    }
    __syncthreads();
#pragma unroll
    for (int j = 0; j < 4; ++j) {
      int n = n0 + ty + j * 8;
      float v = tile[tx][ty + j * 8];
      size_t o = ((size_t)b * 1024 + n) * 256 + c0 + tx;
      u16 h, l;
      split2(v, h, l);
      XtbH[o] = h; XtbL[o] = l;
    }
  } else {
    int i = (id - 4096) * 256 + threadIdx.x;
    if (i < 2048) statsZ[i] = 0.f;   // stats1|pad|stats2|pad (runs before attn/ffn2 atomics)
    if (i < 131072) {
      float w = (i < 65536) ? Wq[i] : Wk[i - 65536];
      u16 h, l;
      split2(w, h, l);
      WallH[i] = h; WallL[i] = l;
    }
    if (i < 65536) {
      u16 h, l;
      split2(Wv[i], h, l);
      WvH[i] = h; WvL[i] = l;
    }
    if (i < 262144) W2b[i] = f2bf(W2[i]);
    if (i < 256) bqk[i] = bq[i];
    else if (i < 512) bqk[i] = bk[i - 256];
  }
}

// ---------------- fused QK-projection + V-projection (one dispatch, role by id) ----------
// Q-half outputs are pre-scaled by log2(e) so attention softmax can use raw v_exp_f32.
__global__ __launch_bounds__(256) void gemm_qkvt(
    const u16* __restrict__ Ah_, const u16* __restrict__ Al_,
    const u16* __restrict__ Bh_, const u16* __restrict__ Bl_,
    const float* __restrict__ bias,
    u16* __restrict__ Ch, u16* __restrict__ Cl,
    const u16* __restrict__ WvH_, const u16* __restrict__ WvL_,
    const float* __restrict__ bv, u16* __restrict__ Vt) {
  __shared__ u16 Ah[4096], Al[4096], Bh[4096], Bl[4096];
  const int tid = threadIdx.x;
  const int lane = tid & 63, w = tid >> 6;
  const int wr = w >> 1, wc = w & 1;
  const int q = lane & 15, G = lane >> 4;
  const int rr0 = w * 32 + (lane >> 2), rr1 = rr0 + 16;
  const int sl0 = (lane & 3) ^ ((rr0 >> 1) & 3);
  const int sl1 = (lane & 3) ^ ((rr1 >> 1) & 3);

  if (blockIdx.x < 512) {
    // ---- QK role ----
    const int eff = (blockIdx.x & 7) * 64 + (blockIdx.x >> 3);
    const int m0 = (eff >> 2) * 128, n0 = (eff & 3) * 128;
    const bool isQ = (n0 < 256);
    const size_t a0 = (size_t)(m0 + rr0) * 256 + sl0 * 8;
    const size_t a1 = (size_t)(m0 + rr1) * 256 + sl1 * 8;
    const size_t b0 = (size_t)(n0 + rr0) * 256 + sl0 * 8;
    const size_t b1 = (size_t)(n0 + rr1) * 256 + sl1 * 8;

    f32x4 acc[4][4] = {};
    for (int kt = 0; kt < 256; kt += 32) {
      __syncthreads();
      gll16(Ah_ + a0 + kt, &Ah[w * 1024]);
      gll16(Ah_ + a1 + kt, &Ah[w * 1024 + 512]);
      gll16(Al_ + a0 + kt, &Al[w * 1024]);
      gll16(Al_ + a1 + kt, &Al[w * 1024 + 512]);
      gll16(Bh_ + b0 + kt, &Bh[w * 1024]);
      gll16(Bh_ + b1 + kt, &Bh[w * 1024 + 512]);
      gll16(Bl_ + b0 + kt, &Bl[w * 1024]);
      gll16(Bl_ + b1 + kt, &Bl[w * 1024 + 512]);
      __syncthreads();
      bf16x8 afh[4], afl[4], bfh[4], bfl[4];
#pragma unroll
      for (int m = 0; m < 4; ++m) {
        int off = TOFF(wr * 64 + m * 16 + q, G);
        afh[m] = *reinterpret_cast<const bf16x8*>((const char*)Ah + off);
        afl[m] = *reinterpret_cast<const bf16x8*>((const char*)Al + off);
      }
#pragma unroll
      for (int n = 0; n < 4; ++n) {
        int off = TOFF(wc * 64 + n * 16 + q, G);
        bfh[n] = *reinterpret_cast<const bf16x8*>((const char*)Bh + off);
        bfl[n] = *reinterpret_cast<const bf16x8*>((const char*)Bl + off);
      }
#pragma unroll
      for (int m = 0; m < 4; ++m)
#pragma unroll
        for (int n = 0; n < 4; ++n) {
          acc[m][n] = __builtin_amdgcn_mfma_f32_16x16x32_bf16(afh[m], bfh[n], acc[m][n], 0, 0, 0);
          acc[m][n] = __builtin_amdgcn_mfma_f32_16x16x32_bf16(afl[m], bfh[n], acc[m][n], 0, 0, 0);
        }
      if (isQ) {
#pragma unroll
        for (int m = 0; m < 4; ++m)
#pragma unroll
          for (int n = 0; n < 4; ++n)
            acc[m][n] = __builtin_amdgcn_mfma_f32_16x16x32_bf16(afh[m], bfl[n], acc[m][n], 0, 0, 0);
      }
    }
    const float qscale = isQ ? LOG2E : 1.f;
#pragma unroll
    for (int m = 0; m < 4; ++m) {
      int row_b = m0 + wr * 64 + m * 16 + G * 4;
#pragma unroll
      for (int n = 0; n < 4; ++n) {
        int col = n0 + wc * 64 + n * 16 + q;
        float bb = bias[col];
#pragma unroll
        for (int r = 0; r < 4; ++r) {
          size_t o = (size_t)(row_b + r) * 512 + col;
          u16 h, l;
          split2((acc[m][n][r] + bb) * qscale, h, l);
          Ch[o] = h;
          if (isQ) Cl[o] = l;
        }
      }
    }
  } else {
    // ---- Vt role ----
    const int o_ = blockIdx.x - 512;
    const int eff = (o_ & 7) * 32 + (o_ >> 3);
    const int m0 = (eff & 1) * 128, n0 = ((eff >> 1) & 7) * 128, b = eff >> 4;
    const u16* Bp = Ah_ + (size_t)b * 1024 * 256;  // XtbH
    const size_t a0 = (size_t)(m0 + rr0) * 256 + sl0 * 8;
    const size_t a1 = (size_t)(m0 + rr1) * 256 + sl1 * 8;
    const size_t b0 = (size_t)(n0 + rr0) * 256 + sl0 * 8;
    const size_t b1 = (size_t)(n0 + rr1) * 256 + sl1 * 8;

    f32x4 acc[4][4] = {};
    for (int kt = 0; kt < 256; kt += 32) {
      __syncthreads();
      gll16(WvH_ + a0 + kt, &Ah[w * 1024]);
      gll16(WvH_ + a1 + kt, &Ah[w * 1024 + 512]);
      gll16(WvL_ + a0 + kt, &Al[w * 1024]);
      gll16(WvL_ + a1 + kt, &Al[w * 1024 + 512]);
      gll16(Bp + b0 + kt, &Bh[w * 1024]);
      gll16(Bp + b1 + kt, &Bh[w * 1024 + 512]);
      __syncthreads();
      bf16x8 afh[4], afl[4], bfr[4];
#pragma unroll
      for (int m = 0; m < 4; ++m) {
        int off = TOFF(wr * 64 + m * 16 + q, G);
        afh[m] = *reinterpret_cast<const bf16x8*>((const char*)Ah + off);
        afl[m] = *reinterpret_cast<const bf16x8*>((const char*)Al + off);
      }
#pragma unroll
      for (int n = 0; n < 4; ++n)
        bfr[n] = *reinterpret_cast<const bf16x8*>((const char*)Bh + TOFF(wc * 64 + n * 16 + q, G));
#pragma unroll
      for (int m = 0; m < 4; ++m)
#pragma unroll
        for (int n = 0; n < 4; ++n) {
          acc[m][n] = __builtin_amdgcn_mfma_f32_16x16x32_bf16(afh[m], bfr[n], acc[m][n], 0, 0, 0);
          acc[m][n] = __builtin_amdgcn_mfma_f32_16x16x32_bf16(afl[m], bfr[n], acc[m][n], 0, 0, 0);
        }
    }
#pragma unroll
    for (int m = 0; m < 4; ++m) {
      int row_b = m0 + wr * 64 + m * 16 + G * 4;  // d index
#pragma unroll
      for (int n = 0; n < 4; ++n) {
        int col = n0 + wc * 64 + n * 16 + q;      // token n
#pragma unroll
        for (int r = 0; r < 4; ++r) {
          int row = row_b + r;
          Vt[((size_t)b * 256 + row) * 1024 + col] = f2bf(acc[m][n][r] + bv[row]);
        }
      }
    }
  }
}

// ---------------- w1prep: ss1 from stats1; W1s = bf16(W1*sc); h0 = b1 + W1*of ----------
__global__ __launch_bounds__(256) void w1prep(
    const float* __restrict__ W1, const float* __restrict__ b1,
    const float* __restrict__ stats1, const float* __restrict__ gamma,
    const float* __restrict__ beta,
    u16* __restrict__ W1s, float* __restrict__ h0) {
  __shared__ float ssl[512];
  const int tid = threadIdx.x;
  {
    float mean = stats1[tid] * (1.f / 16384.f);
    float var = stats1[256 + tid] * (1.f / 16384.f) - mean * mean;
    float scg = gamma[tid] * rsqrtf(var + 1e-5f);
    ssl[tid] = scg;
    ssl[256 + tid] = beta[tid] - mean * scg;
  }
  __syncthreads();
  const int lane = tid & 63, w = tid >> 6;
#pragma unroll
  for (int rr = 0; rr < 2; ++rr) {
    int f = blockIdx.x * 8 + w * 2 + rr;
    int c = lane * 4;
    float4 wv = *reinterpret_cast<const float4*>(W1 + (size_t)f * 256 + c);
    ushort4 o;
    o.x = f2bf(wv.x * ssl[c + 0]);
    o.y = f2bf(wv.y * ssl[c + 1]);
    o.z = f2bf(wv.z * ssl[c + 2]);
    o.w = f2bf(wv.w * ssl[c + 3]);
    *reinterpret_cast<ushort4*>(W1s + (size_t)f * 256 + c) = o;
    float h = wv.x * ssl[256 + c] + wv.y * ssl[257 + c] +
              wv.z * ssl[258 + c] + wv.w * ssl[259 + c];
    h += __shfl_xor(h, 1, 64);
    h += __shfl_xor(h, 2, 64);
    h += __shfl_xor(h, 4, 64);
    h += __shfl_xor(h, 8, 64);
    h += __shfl_xor(h, 16, 64);
    h += __shfl_xor(h, 32, 64);
    if (lane == 0) h0[f] = b1[f] + h;
  }
}

// ---------------- FFN1: pure gll16 GEMM, BK=64, A = SoutB bf16, B = W1s ----------------
// grid 1024: eff=(orig&7)*128+orig/8; n=eff&7, m=eff>>3
__global__ __launch_bounds__(256) void gemm_ffn1(
    const u16* __restrict__ A_,
    const u16* __restrict__ B_,
    const float* __restrict__ h0,
    const float* __restrict__ aslope,
    u16* __restrict__ H1B) {
  __shared__ u16 As[8192], Bs[8192];   // [128][64] bf16 each, TOFF2 layout
  const int tid = threadIdx.x;
  const int lane = tid & 63, w = tid >> 6;
  const int wr = w >> 1, wc = w & 1;
  const int q = lane & 15, G = lane >> 4;
  const int eff = (blockIdx.x & 7) * 128 + (blockIdx.x >> 3);
  const int m0 = (eff >> 3) * 128, n0 = (eff & 7) * 128;

  const int rl = lane >> 3, sl8 = lane & 7;
  const int ssrc = (sl8 ^ rl) * 8;  // inverse-swizzled source col (TOFF2 pairing)

  f32x4 acc[4][4] = {};
  for (int kt = 0; kt < 256; kt += 64) {
    __syncthreads();
#pragma unroll
    for (int i = 0; i < 4; ++i) {
      int rb = (i * 4 + w) * 8;
      gll16(A_ + (size_t)(m0 + rb + rl) * 256 + kt + ssrc, &As[rb * 64]);
      gll16(B_ + (size_t)(n0 + rb + rl) * 256 + kt + ssrc, &Bs[rb * 64]);
    }
    __syncthreads();
#pragma unroll
    for (int kk = 0; kk < 2; ++kk) {
      bf16x8 af[4], bfr[4];
#pragma unroll
      for (int m = 0; m < 4; ++m)
        af[m] = *reinterpret_cast<const bf16x8*>((const char*)As + TOFF2(wr * 64 + m * 16 + q, kk * 4 + G));
#pragma unroll
      for (int n = 0; n < 4; ++n)
        bfr[n] = *reinterpret_cast<const bf16x8*>((const char*)Bs + TOFF2(wc * 64 + n * 16 + q, kk * 4 + G));
#pragma unroll
      for (int m = 0; m < 4; ++m)
#pragma unroll
        for (int n = 0; n < 4; ++n)
          acc[m][n] = __builtin_amdgcn_mfma_f32_16x16x32_bf16(af[m], bfr[n], acc[m][n], 0, 0, 0);
    }
  }
  float a = aslope[0];
#pragma unroll
  for (int m = 0; m < 4; ++m) {
    int row_b = m0 + wr * 64 + m * 16 + G * 4;
#pragma unroll
    for (int n = 0; n < 4; ++n) {
      int col = n0 + wc * 64 + n * 16 + q;
      float bb = h0[col];
#pragma unroll
      for (int r = 0; r < 4; ++r) {
        float v = acc[m][n][r] + bb;
        v = (v >= 0.f) ? v : a * v;
        H1B[(size_t)(row_b + r) * 1024 + col] = f2bf(v);
      }
    }
  }
}

// ---------------- FFN2: BM=64 x BN=64 x BK=64, resid from SoutB, fused BN2 stats ------
// T2 output stored as f16 (range-safe, ~2^-11 rel) to halve epilogue traffic.
__global__ __launch_bounds__(256) void gemm_ffn2(
    const u16* __restrict__ A_,
    const u16* __restrict__ B_,
    const float* __restrict__ bias,
    const u16* __restrict__ SoutB,
    const float* __restrict__ stats1,
    const float* __restrict__ gamma,
    const float* __restrict__ beta,
    f16* __restrict__ T2,
    float* __restrict__ stats2) {
  __shared__ u16 As[4096], Bs[4096];
  __shared__ float ssl[512];
  __shared__ float sred[2][64];
  const int tid = threadIdx.x;
  const int lane = tid & 63, w = tid >> 6;
  const int wr = w >> 1, wc = w & 1;
  const int q = lane & 15, G = lane >> 4;
  const int eff = (blockIdx.x & 7) * 128 + (blockIdx.x >> 3);
  const int m0 = (eff >> 2) * 64, n0 = (eff & 3) * 64;
  {
    float mean = stats1[tid] * (1.f / 16384.f);
    float var = stats1[256 + tid] * (1.f / 16384.f) - mean * mean;
    float scg = gamma[tid] * rsqrtf(var + 1e-5f);
    ssl[tid] = scg;
    ssl[256 + tid] = beta[tid] - mean * scg;
  }
  if (tid < 64) { sred[0][tid] = 0.f; sred[1][tid] = 0.f; }

  const int rl = lane >> 3, sl8 = lane & 7;
  const int ssrc = (sl8 ^ rl) * 8;

  f32x4 acc[2][2] = {};
  for (int kt = 0; kt < 1024; kt += 64) {
    __syncthreads();
#pragma unroll
    for (int i = 0; i < 2; ++i) {
      int rb = (i * 4 + w) * 8;
      gll16(A_ + (size_t)(m0 + rb + rl) * 1024 + kt + ssrc, &As[rb * 64]);
      gll16(B_ + (size_t)(n0 + rb + rl) * 1024 + kt + ssrc, &Bs[rb * 64]);
    }
    __syncthreads();
#pragma unroll
    for (int kk = 0; kk < 2; ++kk) {
      bf16x8 af[2], bf2[2];
#pragma unroll
      for (int m = 0; m < 2; ++m)
        af[m] = *reinterpret_cast<const bf16x8*>((const char*)As + TOFF2(wr * 32 + m * 16 + q, kk * 4 + G));
#pragma unroll
      for (int n = 0; n < 2; ++n)
        bf2[n] = *reinterpret_cast<const bf16x8*>((const char*)Bs + TOFF2(wc * 32 + n * 16 + q, kk * 4 + G));
#pragma unroll
      for (int m = 0; m < 2; ++m)
#pragma unroll
        for (int n = 0; n < 2; ++n)
          acc[m][n] = __builtin_amdgcn_mfma_f32_16x16x32_bf16(af[m], bf2[n], acc[m][n], 0, 0, 0);
    }
  }
  float s1a[2] = {0.f, 0.f}, s2a[2] = {0.f, 0.f};
#pragma unroll
  for (int m = 0; m < 2; ++m) {
    int row_b = m0 + wr * 32 + m * 16 + G * 4;
#pragma unroll
    for (int n = 0; n < 2; ++n) {
      int col = n0 + wc * 32 + n * 16 + q;
      float bb = bias[col];
      float sc_ = ssl[col], of_ = ssl[256 + col];
#pragma unroll
      for (int r = 0; r < 4; ++r) {
        int row = row_b + r;
        float resid = bf2f(SoutB[(size_t)row * 256 + col]) * sc_ + of_;
        float v = acc[m][n][r] + bb + resid;
        T2[(size_t)row * 256 + col] = (f16)v;
        s1a[n] += v;
        s2a[n] += v * v;
      }
    }
  }
#pragma unroll
  for (int n = 0; n < 2; ++n) {
    float a1 = s1a[n];
    a1 += __shfl_xor(a1, 16, 64);
    a1 += __shfl_xor(a1, 32, 64);
    float a2 = s2a[n];
    a2 += __shfl_xor(a2, 16, 64);
    a2 += __shfl_xor(a2, 32, 64);
    if (lane < 16) {
      atomicAdd(&sred[0][wc * 32 + n * 16 + lane], a1);
      atomicAdd(&sred[1][wc * 32 + n * 16 + lane], a2);
    }
  }
  __syncthreads();
  if (tid < 64) {
    atomicAdd(&stats2[n0 + tid], sred[0][tid]);
    atomicAdd(&stats2[256 + n0 + tid], sred[1][tid]);
  }
}

// ---------------- final BN (inline from stats2) + transpose [T,C](f16) -> [B,C,N] ------
__global__ __launch_bounds__(256) void bn_final_out(const f16* __restrict__ T2,
                                                    const float* __restrict__ stats2,
                                                    const float* __restrict__ gamma,
                                                    const float* __restrict__ beta,
                                                    float* __restrict__ out) {
  __shared__ float tile[32][33];
  int n0 = (blockIdx.x & 31) * 32;
  int b = blockIdx.x >> 5;
  int c0 = blockIdx.y * 32;
  int tx = threadIdx.x, ty = threadIdx.y;
  int c = c0 + tx;
  float mean = stats2[c] * (1.f / 16384.f);
  float var = stats2[256 + c] * (1.f / 16384.f) - mean * mean;
  float scg = gamma[c] * rsqrtf(var + 1e-5f);
  float off = beta[c] - mean * scg;
#pragma unroll
  for (int j = 0; j < 4; ++j) {
    int r = ty + j * 8;
    float v = (float)T2[((size_t)b * 1024 + n0 + r) * 256 + c];
    tile[r][tx] = v * scg + off;
  }
  __syncthreads();
#pragma unroll
  for (int j = 0; j < 4; ++j) {
    int cc = c0 + ty + j * 8;
    out[((size_t)b * 256 + cc) * 1024 + n0 + tx] = tile[tx][ty + j * 8];
  }
}

// ---------------- fused flash attention: 8 waves / 128 q-rows, no-shift softmax --------
#define SWZ(row, bcol) ((bcol) ^ (((row) & 7) << 4))
__global__ __launch_bounds__(512, 4) void attn_kernel(const u16* __restrict__ QKh,
                                                      const u16* __restrict__ QKl,
                                                      const u16* __restrict__ Vt,
                                                      const float* __restrict__ x,
                                                      u16* __restrict__ SoutB,
                                                      float* __restrict__ stats) {
  __shared__ u16 Kh[2][4096], Vs[2][4096];
  __shared__ float sred[2][64];
  const int tid = threadIdx.x, lane = tid & 63, w = tid >> 6;
  const int hb = blockIdx.x, h = hb & 3, b = hb >> 2;
  const size_t tb = (size_t)b * 1024;
  const int qrow0 = blockIdx.y * 128 + w * 16;
  const int q = lane & 15, G = lane >> 4;

  if (tid < 64) { sred[0][tid] = 0.f; sred[1][tid] = 0.f; }

  bf16x8 qh[2], ql[2];
#pragma unroll
  for (int kk = 0; kk < 2; ++kk) {
    size_t ro = (tb + qrow0 + q) * 512 + h * 64 + kk * 32 + G * 8;
    qh[kk] = *reinterpret_cast<const bf16x8*>(QKh + ro);
    ql[kk] = *reinterpret_cast<const bf16x8*>(QKl + ro);
  }

  f32x4 oacc[4] = {};
  float lsum = 0.f;

  const int sr = tid >> 3;
  const int c7 = tid & 7;
  const int dstb = sr * 128 + SWZ(sr, c7 << 4);
  const size_t kbase = (tb + sr) * 512 + 256 + h * 64 + c7 * 8;
  const int vb0 = 32 * (c7 >> 2) + 8 * ((2 * c7) & 3) + 4 * ((c7 >> 1) & 1);
  const int vx0 = (vb0 * 2) ^ ((sr & 7) << 4);
  const int vx1 = (vb0 * 2 + 16) ^ ((sr & 7) << 4);
  const size_t vbase = ((size_t)b * 256 + h * 64 + sr) * 1024 + c7 * 8;

  uint4 rk = *reinterpret_cast<const uint4*>(QKh + kbase);
  uint4 rv = *reinterpret_cast<const uint4*>(Vt + vbase);
  *reinterpret_cast<uint4*>((char*)Kh[0] + dstb) = rk;
  {
    uint2 lo = {rv.x, rv.y}, hi = {rv.z, rv.w};
    *reinterpret_cast<uint2*>((char*)Vs[0] + sr * 128 + vx0) = lo;
    *reinterpret_cast<uint2*>((char*)Vs[0] + sr * 128 + vx1) = hi;
  }
  __syncthreads();

  int cur = 0;
  for (int kt = 0; kt < 16; ++kt) {
    if (kt < 15) {
      rk = *reinterpret_cast<const uint4*>(QKh + kbase + (size_t)(kt + 1) * 32768);
      rv = *reinterpret_cast<const uint4*>(Vt + vbase + (size_t)(kt + 1) * 64);
    }

    f32x4 sc[4] = {};
    __builtin_amdgcn_s_setprio(1);
#pragma unroll
    for (int kk = 0; kk < 2; ++kk)
#pragma unroll
      for (int n = 0; n < 4; ++n) {
        int krow = n * 16 + q;
        int kb_ = krow * 128 + SWZ(krow, kk * 64 + G * 16);
        bf16x8 akh = *reinterpret_cast<const bf16x8*>((const char*)Kh[cur] + kb_);
        sc[n] = __builtin_amdgcn_mfma_f32_16x16x32_bf16(akh, qh[kk], sc[n], 0, 0, 0);
        sc[n] = __builtin_amdgcn_mfma_f32_16x16x32_bf16(akh, ql[kk], sc[n], 0, 0, 0);
      }
    __builtin_amdgcn_s_setprio(0);

    float lt = 0.f;
#pragma unroll
    for (int n = 0; n < 4; ++n)
#pragma unroll
      for (int r = 0; r < 4; ++r) {
        float p = exp2_fast(sc[n][r]);
        sc[n][r] = p;
        lt += p;
      }
    lsum += lt;
    bf16x8 pa[2];
    {
      uint4 pw0, pw1;
      pw0.x = cvt_pk_bf16(sc[0][0], sc[0][1]);
      pw0.y = cvt_pk_bf16(sc[0][2], sc[0][3]);
      pw0.z = cvt_pk_bf16(sc[1][0], sc[1][1]);
      pw0.w = cvt_pk_bf16(sc[1][2], sc[1][3]);
      pw1.x = cvt_pk_bf16(sc[2][0], sc[2][1]);
      pw1.y = cvt_pk_bf16(sc[2][2], sc[2][3]);
      pw1.z = cvt_pk_bf16(sc[3][0], sc[3][1]);
      pw1.w = cvt_pk_bf16(sc[3][2], sc[3][3]);
      pa[0] = *reinterpret_cast<bf16x8*>(&pw0);
      pa[1] = *reinterpret_cast<bf16x8*>(&pw1);
    }
    __builtin_amdgcn_s_setprio(1);
#pragma unroll
    for (int kk = 0; kk < 2; ++kk)
#pragma unroll
      for (int dn = 0; dn < 4; ++dn) {
        int vrow = dn * 16 + q;
        int vb_ = vrow * 128 + SWZ(vrow, kk * 64 + G * 16);
        bf16x8 vv = *reinterpret_cast<const bf16x8*>((const char*)Vs[cur] + vb_);
        oacc[dn] = __builtin_amdgcn_mfma_f32_16x16x32_bf16(pa[kk], vv, oacc[dn], 0, 0, 0);
      }
    __builtin_amdgcn_s_setprio(0);
    if (kt < 15) {
      *reinterpret_cast<uint4*>((char*)Kh[cur ^ 1] + dstb) = rk;
      uint2 lo = {rv.x, rv.y}, hi = {rv.z, rv.w};
      *reinterpret_cast<uint2*>((char*)Vs[cur ^ 1] + sr * 128 + vx0) = lo;
      *reinterpret_cast<uint2*>((char*)Vs[cur ^ 1] + sr * 128 + vx1) = hi;
    }
    __syncthreads();
    cur ^= 1;
  }
  float lf = lsum;
  lf += __shfl_xor(lf, 16, 64);
  lf += __shfl_xor(lf, 32, 64);
  float rinv[4];
#pragma unroll
  for (int r = 0; r < 4; ++r) rinv[r] = 1.f / __shfl(lf, G * 4 + r, 64);

  const int row0 = qrow0 + G * 4;
  const float* xp = x + ((size_t)b * 256 + h * 64) * 1024;
  float s1a[4] = {0.f, 0.f, 0.f, 0.f}, s2a[4] = {0.f, 0.f, 0.f, 0.f};
#pragma unroll
  for (int dn = 0; dn < 4; ++dn) {
    int col = dn * 16 + q;
    float4 xv = *reinterpret_cast<const float4*>(xp + (size_t)col * 1024 + row0);
    const float* xvp = reinterpret_cast<const float*>(&xv);
#pragma unroll
    for (int r = 0; r < 4; ++r) {
      size_t gi = (tb + row0 + r) * 256 + h * 64 + col;
      float v = oacc[dn][r] * rinv[r] + xvp[r];
      SoutB[gi] = f2bf(v);
      s1a[dn] += v;
      s2a[dn] += v * v;
    }
  }
#pragma unroll
  for (int dn = 0; dn < 4; ++dn) {
    float a1 = s1a[dn];
    a1 += __shfl_xor(a1, 16, 64);
    a1 += __shfl_xor(a1, 32, 64);
    float a2 = s2a[dn];
    a2 += __shfl_xor(a2, 16, 64);
    a2 += __shfl_xor(a2, 32, 64);
    if (lane < 16) {
      atomicAdd(&sred[0][dn * 16 + lane], a1);
      atomicAdd(&sred[1][dn * 16 + lane], a2);
    }
  }
  __syncthreads();
  if (tid < 64) {
    atomicAdd(&stats[h * 64 + tid], sred[0][tid]);
    atomicAdd(&stats[256 + h * 64 + tid], sred[1][tid]);
  }
}

// ---------------- launch ----------------
extern "C" void kernel_launch(void* const* d_in, const int* in_sizes, int n_in,
                              void* d_out, int out_size, void* d_ws, size_t ws_size,
                              hipStream_t stream) {
  const float* x = (const float*)d_in[0];
  const float* Wq = (const float*)d_in[1];
  const float* bq = (const float*)d_in[2];
  const float* Wk = (const float*)d_in[3];
  const float* bk = (const float*)d_in[4];
  const float* Wv = (const float*)d_in[5];
  const float* bv = (const float*)d_in[6];
  const float* gamma = (const float*)d_in[7];
  const float* beta = (const float*)d_in[8];
  const float* W1 = (const float*)d_in[9];
  const float* b1 = (const float*)d_in[10];
  const float* a = (const float*)d_in[11];
  const float* W2 = (const float*)d_in[12];
  const float* b2 = (const float*)d_in[13];
  float* out = (float*)d_out;

  char* wsb = (char*)d_ws;
  const size_t MB = 1ull << 20;
  u16* XtbH = (u16*)(wsb + 0 * MB);        // 8MB; region [0,8) reused as T2(f16) after qkvt
  u16* XtbL = (u16*)(wsb + 8 * MB);        // 8MB
  f16* T2 = (f16*)(wsb + 0 * MB);          // 8MB f16 (alias XtbH, live from ffn2 on)
  u16* SoutB = (u16*)(wsb + 16 * MB);      // 8MB (raw o+x in bf16)
  u16* QKh = (u16*)(wsb + 32 * MB);        // 16MB; [32,64) reused as H1B after attn
  u16* QKl = (u16*)(wsb + 48 * MB);        // 16MB
  u16* Vt = (u16*)(wsb + 64 * MB);         // 8MB
  char* wp = wsb + 72 * MB;
  u16* WallH = (u16*)(wp);                 // 256KB
  u16* WallL = (u16*)(wp + 262144);        // 256KB
  u16* WvH = (u16*)(wp + 524288);          // 128KB
  u16* WvL = (u16*)(wp + 655360);          // 128KB
  u16* W1s = (u16*)(wp + 786432);          // 512KB (BN-scaled W1, by w1prep)
  u16* W2b = (u16*)(wp + 1310720);         // 512KB
  float* bqk = (float*)(wp + 1835008);     // 2KB
  float* stats = (float*)(wp + 1837056);   // 8KB: stats1 | pad | stats2 | pad
  float* h0 = (float*)(wp + 1845248);      // 4KB
  if (ws_size < 73 * MB) return;

  u16* H1B = QKh;    // [T,1024] bf16, after attn
  float* stats2 = stats + 1024;

  // fused x-transpose + weight prep + stats zeroing (no separate memset dispatch)
  prep_all<<<5120, 256, 0, stream>>>(x, Wq, Wk, Wv, bq, bk, W2,
                                     XtbH, XtbL, WallH, WallL, WvH, WvL, W2b, bqk, stats);
  // fused QK projection (Q pre-scaled by log2e) + V projection transposed
  gemm_qkvt<<<768, 256, 0, stream>>>(XtbH, XtbL, WallH, WallL, bqk, QKh, QKl,
                                     WvH, WvL, bv, Vt);
  // attention + residual (bf16 output) + BN1 stats: 8-wave blocks
  attn_kernel<<<dim3(64, 8), 512, 0, stream>>>(QKh, QKl, Vt, x, SoutB, stats);
  // fold BN1 into W1: W1s = bf16(W1*sc), h0 = b1 + W1*of
  w1prep<<<128, 256, 0, stream>>>(W1, b1, stats, gamma, beta, W1s, h0);
  // FFN1: pure gll16 GEMM BK=64 (A=SoutB, B=W1s), bias h0, PReLU
  gemm_ffn1<<<1024, 256, 0, stream>>>(SoutB, W1s, h0, a, H1B);
  // FFN2: bias + BN1(resid from SoutB) + BN2 stats -> T2 (f16)
  gemm_ffn2<<<1024, 256, 0, stream>>>(H1B, W2b, b2, SoutB, stats, gamma, beta, T2, stats2);
  // BN2 apply (inline finalize) + transpose out
  bn_final_out<<<dim3(512, 8), dim3(32, 8), 0, stream>>>(T2, stats2, gamma, beta, out);
}